// Round 1
// baseline (3738.453 us; speedup 1.0000x reference)
//
#include <hip/hip_runtime.h>
#include <math.h>

#define HH 384
#define WW 384
#define NPIX (HH*WW)          // 147456
#define NB 2
#define BN (NB*NPIX)          // 294912
#define NT 128
#define NBINS 32
#define MEDRANK ((NPIX-1)/2)  // 73727
#define RB 72                 // reduction blocks per batch

// ---- double arena indices (at ws+0, 256 doubles) ----
#define A_BETA 0    // 10: b*5 + {EE,ES,SS,EL,SL}
#define A_XZ   16   // 18: b*9 + {z0,z1,z2,z00,z01,z02,z11,z12,z22}
#define A_GMM  40   // 12: b*6 + {N0,N1,Sx0,Sx1,Sxx0,Sxx1}
#define A_DK   64   // 40: (b*2+k)*10 + {W,s0,s1,s2,m00,m01,m02,m11,m12,m22}
#define A_ES   112  // 10: b*5 + {z0,z1,z00,z01,z11}
#define A_GHIST 128 // 64: b*32+bin

// ---- float arena indices (at ws+8192, 4096 floats) ----
#define F_BETA 0    // 4
#define F_X3   8    // 12: (b*3+ch)*2 {med,mad}
#define F_MEAN 24   // 6
#define F_WWH  32   // 18: b*9 row-major
#define F_AN   56   // 768: (b*128+t)*3
#define F_ASTAR 828 // 6
#define F_GMM  840  // 24: b*12 {mu0,mu1,v0,v1,p0,p1,c0,c1,iv0,iv1}
#define F_ZBQ  868  // 8: b*4
#define F_DKINV 880 // 36: (b*2+k)*9 {i00,i01,i02,i11,i12,i22,mu0,mu1,mu2}
#define F_LLA  918  // 4: b*2 {med,mad}
#define F_GLD  924  // 4
#define F_MM   928  // uint slots: min 928+b, max 930+b
#define F_ES   932  // 8: (b*2+ch)*2
#define F_ESINV 940 // 10: b*5 {mean0,mean1,i00,i01,i11}
#define F_LAQ  952  // 8: b*4
#define F_Q19  960  // 4: b*2 {q1,q9}
#define F_GCDF 968  // 64: b*32+bin

// ---------------- device helpers ----------------
__device__ __forceinline__ double waveSum(double v){
#pragma unroll
  for(int o=32;o;o>>=1) v += __shfl_down(v,o,64);
  return v;
}
__device__ __forceinline__ unsigned f2u(float f){
  unsigned u = __float_as_uint(f);
  return (u & 0x80000000u) ? ~u : (u | 0x80000000u);
}
__device__ __forceinline__ float u2f(unsigned u){
  return __uint_as_float((u & 0x80000000u) ? (u ^ 0x80000000u) : ~u);
}
__device__ __forceinline__ float sp(float x){ // softplus, matches ref
  float t = log1pf(expf(-fabsf(x)));
  return x >= 0.f ? x + t : t;
}

// exact k-th smallest (0-based) over n floats; mode 1 -> |x-center|
__device__ float block_select(const float* src, int n, int rank, int mode, float center){
  __shared__ unsigned hist[256];
  __shared__ unsigned s_sel;
  __shared__ int s_r;
  if(threadIdx.x==0) s_r = rank;
  unsigned prefix = 0u;
  for(int pass=3; pass>=0; --pass){
    int shift = pass*8;
    for(int i=threadIdx.x;i<256;i+=blockDim.x) hist[i]=0u;
    __syncthreads();
    unsigned himask = (pass==3)? 0u : (0xFFFFFFFFu << (shift+8));
    for(int i=threadIdx.x;i<n;i+=blockDim.x){
      float v = src[i];
      if(mode) v = fabsf(v - center);
      unsigned u = f2u(v);
      if((u & himask) == prefix) atomicAdd(&hist[(u>>shift)&255u], 1u);
    }
    __syncthreads();
    if(threadIdx.x==0){
      int r = s_r; unsigned cum=0, sel=0;
      for(unsigned b=0;b<256;b++){
        unsigned h = hist[b];
        if((unsigned)r < cum+h){ sel=b; break; }
        cum+=h;
      }
      s_sel=sel; s_r = r - (int)cum;
    }
    __syncthreads();
    prefix |= (s_sel << shift);
  }
  return u2f(prefix);
}

__device__ inline void estep(const float* F, int b, float x, double& r0, double& r1){
  const float* P = F + F_GMM + b*12;
  double d0 = (double)x - (double)P[0];
  double d1 = (double)x - (double)P[1];
  double l0 = -d0*d0*(double)P[8] + (double)P[6];
  double l1 = -d1*d1*(double)P[9] + (double)P[7];
  double m = fmax(l0,l1);
  double e0 = exp(l0-m), e1 = exp(l1-m);
  double s = e0+e1;
  r0 = e0/s; r1 = e1/s;
}
__device__ inline void set_params(float* F, int b, double mu0,double mu1,double v0,double v1,double p0,double p1){
  float* P = F + F_GMM + b*12;
  P[0]=(float)mu0; P[1]=(float)mu1; P[2]=(float)v0; P[3]=(float)v1; P[4]=(float)p0; P[5]=(float)p1;
  P[6]=(float)(-0.5*log(v0+1e-6) + log(p0+1e-8));
  P[7]=(float)(-0.5*log(v1+1e-6) + log(p1+1e-8));
  P[8]=(float)(0.5/(v0+1e-6));
  P[9]=(float)(0.5/(v1+1e-6));
}

// ---------------- kernels ----------------
__global__ void k_zero(double* A, float* F){
  int i = blockIdx.x*blockDim.x + threadIdx.x;
  if(i < 256) A[i] = 0.0;
  if(i < 4096){
    unsigned* U = (unsigned*)F;
    unsigned v = 0u;
    if(i==F_MM || i==F_MM+1) v = 0xFFFFFFFFu;   // min slots
    U[i] = v;
  }
}

__global__ void k_prep(const float* lab, float* S, float* G2){
  int i = blockIdx.x*256 + threadIdx.x; if(i>=BN) return;
  int b=i/NPIX, n=i%NPIX, y=n/WW, x=n%WW;
  const float* Lb = lab + b*3*NPIX;
  float av = Lb[NPIX+n], bv = Lb[2*NPIX+n];
  S[i] = sqrtf(av*av + bv*bv + 1e-8f);
  auto l = [&](int yy,int xx)->float{
    return (yy<0||yy>=HH||xx<0||xx>=WW)?0.f:Lb[yy*WW+xx]; };
  float gx = -l(y-1,x-1)+l(y-1,x+1) -2.f*l(y,x-1)+2.f*l(y,x+1) -l(y+1,x-1)+l(y+1,x+1);
  float gy = -l(y-1,x-1)-2.f*l(y-1,x)-l(y-1,x+1) +l(y+1,x-1)+2.f*l(y+1,x)+l(y+1,x+1);
  G2[i] = gx*gx + gy*gy;
}

__global__ void k_box3h(const float* in, float* out){
  int i = blockIdx.x*256 + threadIdx.x; if(i>=BN) return;
  int x = (i%NPIX)%WW;
  float s = in[i];
  if(x>0) s += in[i-1];
  if(x<WW-1) s += in[i+1];
  out[i]=s;
}
__global__ void k_box3v(const float* in, float* out){
  int i = blockIdx.x*256 + threadIdx.x; if(i>=BN) return;
  int y = (i%NPIX)/WW;
  float s = in[i];
  if(y>0) s += in[i-WW];
  if(y<HH-1) s += in[i+WW];
  out[i]=s*(1.f/9.f);
}

__global__ void k_beta_red(const float* E,const float* S,const float* lab,double* A){
  int b = blockIdx.x / RB, blk = blockIdx.x % RB;
  double s[5]={0,0,0,0,0};
  for(int n = blk*256 + threadIdx.x; n < NPIX; n += RB*256){
    float e=E[b*NPIX+n], ss=S[b*NPIX+n], l=lab[b*3*NPIX+n];
    s[0]+=(double)e*e; s[1]+=(double)e*ss; s[2]+=(double)ss*ss;
    s[3]+=(double)e*l; s[4]+=(double)ss*l;
  }
#pragma unroll
  for(int q=0;q<5;q++){
    double v = waveSum(s[q]);
    if((threadIdx.x&63)==0) atomicAdd(&A[A_BETA+b*5+q], v);
  }
}
__global__ void k_beta_solve(const double* A, float* F){
  if(threadIdx.x||blockIdx.x) return;
  for(int b=0;b<NB;b++){
    double EE=A[A_BETA+b*5],ES=A[A_BETA+b*5+1],SS=A[A_BETA+b*5+2],EL=A[A_BETA+b*5+3],SL=A[A_BETA+b*5+4];
    double a00=EE+1e-6, a01=ES, a11=SS+1e-6;
    double det=a00*a11-a01*a01;
    F[F_BETA+b*2]  =(float)(( a11*EL - a01*SL)/det);
    F[F_BETA+b*2+1]=(float)((-a01*EL + a00*SL)/det);
  }
}
__global__ void k_lperp(const float* lab,const float* E,const float* S,const float* F,float* out0){
  int i = blockIdx.x*256 + threadIdx.x; if(i>=BN) return;
  int b=i/NPIX, n=i%NPIX;
  out0[i] = lab[b*3*NPIX+n] - F[F_BETA+b*2]*E[i] - F[F_BETA+b*2+1]*S[i];
}

__global__ __launch_bounds__(1024) void k_sel_x3(const float* Lp,const float* E,const float* S,float* F){
  int b = blockIdx.x/3, ch = blockIdx.x%3;
  const float* src = ch==0 ? Lp+b*NPIX : (ch==1 ? E+b*NPIX : S+b*NPIX);
  float med = block_select(src, NPIX, MEDRANK, 0, 0.f);
  float mad = block_select(src, NPIX, MEDRANK, 1, med);
  if(threadIdx.x==0){
    F[F_X3+(b*3+ch)*2]   = med;
    F[F_X3+(b*3+ch)*2+1] = mad*1.4826f + 1e-8f;
  }
}

__global__ void k_xz_red(const float* Lp,const float* E,const float* S,const float* F,double* A){
  int b = blockIdx.x / RB, blk = blockIdx.x % RB;
  const float* M = F + F_X3 + b*6;
  double s[9]={0,0,0,0,0,0,0,0,0};
  for(int n = blk*256 + threadIdx.x; n < NPIX; n += RB*256){
    float z0=(Lp[b*NPIX+n]-M[0])/M[1];
    float z1=(E [b*NPIX+n]-M[2])/M[3];
    float z2=(S [b*NPIX+n]-M[4])/M[5];
    s[0]+=z0; s[1]+=z1; s[2]+=z2;
    s[3]+=(double)z0*z0; s[4]+=(double)z0*z1; s[5]+=(double)z0*z2;
    s[6]+=(double)z1*z1; s[7]+=(double)z1*z2; s[8]+=(double)z2*z2;
  }
#pragma unroll
  for(int q=0;q<9;q++){
    double v = waveSum(s[q]);
    if((threadIdx.x&63)==0) atomicAdd(&A[A_XZ+b*9+q], v);
  }
}
__global__ void k_eigh(const double* A, float* F){
  int b = threadIdx.x;
  if(b>=NB || blockIdx.x) return;
  const double* s = A + A_XZ + b*9;
  double inv = 1.0/(double)NPIX;
  double m0=s[0]*inv, m1=s[1]*inv, m2=s[2]*inv;
  double a[3][3];
  a[0][0]=fmax(s[3]*inv-m0*m0,1e-8);
  a[0][1]=a[1][0]=fmax(s[4]*inv-m0*m1,1e-8);
  a[0][2]=a[2][0]=fmax(s[5]*inv-m0*m2,1e-8);
  a[1][1]=fmax(s[6]*inv-m1*m1,1e-8);
  a[1][2]=a[2][1]=fmax(s[7]*inv-m1*m2,1e-8);
  a[2][2]=fmax(s[8]*inv-m2*m2,1e-8);
  double V[3][3]={{1,0,0},{0,1,0},{0,0,1}};
  for(int sweep=0;sweep<40;sweep++){
    for(int pp=0;pp<3;pp++){
      int p = (pp==2)?1:0;
      int q = (pp==0)?1:2;
      double apq=a[p][q];
      if(fabs(apq)<1e-30) continue;
      double theta=(a[q][q]-a[p][p])/(2.0*apq);
      double t=((theta>=0)?1.0:-1.0)/(fabs(theta)+sqrt(1.0+theta*theta));
      double c=1.0/sqrt(1.0+t*t), sn=t*c;
      for(int k2=0;k2<3;k2++){ double akp=a[k2][p],akq=a[k2][q];
        a[k2][p]=c*akp-sn*akq; a[k2][q]=sn*akp+c*akq; }
      for(int k2=0;k2<3;k2++){ double apk=a[p][k2],aqk=a[q][k2];
        a[p][k2]=c*apk-sn*aqk; a[q][k2]=sn*apk+c*aqk; }
      for(int k2=0;k2<3;k2++){ double vkp=V[k2][p],vkq=V[k2][q];
        V[k2][p]=c*vkp-sn*vkq; V[k2][q]=sn*vkp+c*vkq; }
    }
  }
  double is0=1.0/sqrt(a[0][0]), is1=1.0/sqrt(a[1][1]), is2=1.0/sqrt(a[2][2]);
  for(int i=0;i<3;i++) for(int j=0;j<3;j++){
    double w = V[i][0]*is0*V[j][0] + V[i][1]*is1*V[j][1] + V[i][2]*is2*V[j][2];
    F[F_WWH + b*9 + i*3 + j] = (float)w;
  }
  F[F_MEAN+b*3]=(float)m0; F[F_MEAN+b*3+1]=(float)m1; F[F_MEAN+b*3+2]=(float)m2;
}
__global__ void k_xw(const float* Lp,const float* E,const float* S,const float* F,
                     float* Xw0,float* Xw1,float* Xw2){
  int i = blockIdx.x*256 + threadIdx.x; if(i>=BN) return;
  int b=i/NPIX;
  const float* M = F + F_X3 + b*6;
  float z0=(Lp[i]-M[0])/M[1];
  float z1=(E [i]-M[2])/M[3];
  float z2=(S [i]-M[4])/M[5];
  float d0=z0-F[F_MEAN+b*3], d1=z1-F[F_MEAN+b*3+1], d2=z2-F[F_MEAN+b*3+2];
  const float* Wm = F + F_WWH + b*9;
  Xw0[i]=d0*Wm[0]+d1*Wm[3]+d2*Wm[6];
  Xw1[i]=d0*Wm[1]+d1*Wm[4]+d2*Wm[7];
  Xw2[i]=d0*Wm[2]+d1*Wm[5]+d2*Wm[8];
}
__global__ void k_an(const float* arand, float* F){
  int id = threadIdx.x; if(id >= NB*NT) return;
  const float* a = arand + id*3;
  double nrm = sqrt((double)a[0]*a[0]+(double)a[1]*a[1]+(double)a[2]*a[2]) + 1e-12;
  F[F_AN+id*3]  =(float)(a[0]/nrm);
  F[F_AN+id*3+1]=(float)(a[1]/nrm);
  F[F_AN+id*3+2]=(float)(a[2]/nrm);
}

#define KT_TILE 2304
__global__ __launch_bounds__(256) void k_kurt(const float* Xw0,const float* Xw1,const float* Xw2,
                                              const float* F, double* part){
  __shared__ float xs[3][KT_TILE];
  __shared__ double red[4][4];
  int blk = blockIdx.x;
  int b = blk/64;
  int base = blk*KT_TILE;
  for(int i=threadIdx.x;i<KT_TILE;i+=256){
    xs[0][i]=Xw0[base+i]; xs[1][i]=Xw1[base+i]; xs[2][i]=Xw2[base+i];
  }
  __syncthreads();
  int wave=threadIdx.x>>6, lane=threadIdx.x&63;
  for(int t=0;t<NT;t++){
    float a0=F[F_AN+(b*NT+t)*3], a1=F[F_AN+(b*NT+t)*3+1], a2=F[F_AN+(b*NT+t)*3+2];
    double s1=0,s2=0,s3=0,s4=0;
#pragma unroll
    for(int j=0;j<9;j++){
      int p=threadIdx.x+j*256;
      float z = xs[0][p]*a0 + xs[1][p]*a1 + xs[2][p]*a2;
      double zd=z, z2=zd*zd;
      s1+=zd; s2+=z2; s3+=z2*zd; s4+=z2*z2;
    }
    s1=waveSum(s1); s2=waveSum(s2); s3=waveSum(s3); s4=waveSum(s4);
    if(lane==0){ red[wave][0]=s1; red[wave][1]=s2; red[wave][2]=s3; red[wave][3]=s4; }
    __syncthreads();
    if(threadIdx.x<4){
      double v=red[0][threadIdx.x]+red[1][threadIdx.x]+red[2][threadIdx.x]+red[3][threadIdx.x];
      part[blk*512 + t*4 + threadIdx.x]=v;
    }
    __syncthreads();
  }
}
__global__ void k_kurt_pick(const double* part, float* F){
  int b = blockIdx.x;
  int t = threadIdx.x; // 128 threads
  __shared__ double ak[NT];
  double S1=0,S2=0,S3=0,S4=0;
  for(int blk=b*64; blk<(b+1)*64; ++blk){
    const double* p = part + blk*512 + t*4;
    S1+=p[0]; S2+=p[1]; S3+=p[2]; S4+=p[3];
  }
  double inv=1.0/(double)NPIX;
  double mean=S1*inv, M2=S2*inv, M3=S3*inv, M4=S4*inv;
  double m2 = M2 - mean*mean + 1e-12;
  double m4 = M4 - 4.0*mean*M3 + 6.0*mean*mean*M2 - 3.0*mean*mean*mean*mean;
  double kurt = m4/(m2*m2) - 3.0;
  ak[t] = fabs(kurt);
  __syncthreads();
  if(t==0){
    int best=0; double bv=ak[0];
    for(int j=1;j<NT;j++) if(ak[j]>bv){bv=ak[j];best=j;}
    F[F_ASTAR+b*3]  =F[F_AN+(b*NT+best)*3];
    F[F_ASTAR+b*3+1]=F[F_AN+(b*NT+best)*3+1];
    F[F_ASTAR+b*3+2]=F[F_AN+(b*NT+best)*3+2];
  }
}
__global__ void k_zbest(const float* Xw0,const float* Xw1,const float* Xw2,const float* F,float* zb){
  int i = blockIdx.x*256 + threadIdx.x; if(i>=BN) return;
  int b=i/NPIX;
  zb[i] = Xw0[i]*F[F_ASTAR+b*3] + Xw1[i]*F[F_ASTAR+b*3+1] + Xw2[i]*F[F_ASTAR+b*3+2];
}

__global__ __launch_bounds__(1024) void k_sel4(const float* src, float* F, int r0,int r1,int r2,int r3,int fbase){
  int b = blockIdx.x/4, ri = blockIdx.x%4;
  int rr = (ri==0)?r0:(ri==1)?r1:(ri==2)?r2:r3;
  float v = block_select(src + b*NPIX, NPIX, rr, 0, 0.f);
  if(threadIdx.x==0) F[fbase + b*4 + ri] = v;
}
__global__ __launch_bounds__(1024) void k_sel_medmad(const float* src, float* F, int fbase){
  int b = blockIdx.x;
  float med = block_select(src + b*NPIX, NPIX, MEDRANK, 0, 0.f);
  float mad = block_select(src + b*NPIX, NPIX, MEDRANK, 1, med);
  if(threadIdx.x==0){ F[fbase+b*2]=med; F[fbase+b*2+1]=mad*1.4826f+1e-8f; }
}
__global__ __launch_bounds__(1024) void k_sel_es(const float* E,const float* S,float* F){
  int b = blockIdx.x/2, ch = blockIdx.x%2;
  const float* src = (ch==0 ? E : S) + b*NPIX;
  float med = block_select(src, NPIX, MEDRANK, 0, 0.f);
  float mad = block_select(src, NPIX, MEDRANK, 1, med);
  if(threadIdx.x==0){
    F[F_ES+(b*2+ch)*2]=med; F[F_ES+(b*2+ch)*2+1]=mad*1.4826f+1e-8f;
  }
}

__global__ void k_gmm_init(float* F){
  if(threadIdx.x||blockIdx.x) return;
  for(int b=0;b<NB;b++){
    const float* z = F + F_ZBQ + b*4;
    double h25 = 0.25*(double)(NPIX-1); double f25 = h25 - floor(h25);
    double h75 = 0.75*(double)(NPIX-1); double f75 = h75 - floor(h75);
    double q25 = (double)z[0] + f25*((double)z[1]-(double)z[0]);
    double q75 = (double)z[2] + f75*((double)z[3]-(double)z[2]);
    set_params(F,b,q25,q75,1.0,1.0,0.5,0.5);
  }
}
__global__ void k_gmm_red(const float* zb, const float* F, double* A){
  int b = blockIdx.x / RB, blk = blockIdx.x % RB;
  double s[6]={0,0,0,0,0,0};
  for(int n = blk*256 + threadIdx.x; n < NPIX; n += RB*256){
    float x = zb[b*NPIX+n];
    double r0,r1; estep(F,b,x,r0,r1);
    double xd=x;
    s[0]+=r0; s[1]+=r1; s[2]+=r0*xd; s[3]+=r1*xd; s[4]+=r0*xd*xd; s[5]+=r1*xd*xd;
  }
#pragma unroll
  for(int q=0;q<6;q++){
    double v = waveSum(s[q]);
    if((threadIdx.x&63)==0) atomicAdd(&A[A_GMM+b*6+q], v);
  }
}
__global__ void k_gmm_update(double* A, float* F){
  if(threadIdx.x||blockIdx.x) return;
  for(int b=0;b<NB;b++){
    double* g = A + A_GMM + b*6;
    double N0=g[0],N1=g[1];
    double mu0=g[2]/(N0+1e-8), mu1=g[3]/(N1+1e-8);
    double v0=(g[4]-2.0*mu0*g[2]+mu0*mu0*N0)/(N0+1e-8)+1e-6;
    double v1=(g[5]-2.0*mu1*g[3]+mu1*mu1*N1)/(N1+1e-8)+1e-6;
    double p0=N0/(double)NPIX, p1=N1/(double)NPIX;
    set_params(F,b,mu0,mu1,v0,v1,p0,p1);
    for(int j=0;j<6;j++) g[j]=0.0;
  }
}
__global__ void k_ralpha(const float* zb, const float* F, float* Ra0, float* Ra1){
  int i = blockIdx.x*256 + threadIdx.x; if(i>=BN) return;
  int b=i/NPIX;
  double r0,r1; estep(F,b,zb[i],r0,r1);
  double ra0=pow(r0,0.9), ra1=pow(r1,0.9);
  double s=ra0+ra1+1e-8;
  Ra0[i]=(float)(ra0/s); Ra1[i]=(float)(ra1/s);
}

__global__ void k_dk_red(const float* Lp,const float* E,const float* S,
                         const float* Ra0,const float* Ra1,double* A){
  int b = blockIdx.x / RB, blk = blockIdx.x % RB;
  double s[20];
#pragma unroll
  for(int q=0;q<20;q++) s[q]=0;
  for(int n = blk*256 + threadIdx.x; n < NPIX; n += RB*256){
    int i=b*NPIX+n;
    double w0=Ra0[i], w1=Ra1[i];
    double x0=Lp[i], x1=E[i], x2=S[i];
    s[0]+=w0; s[1]+=w0*x0; s[2]+=w0*x1; s[3]+=w0*x2;
    s[4]+=w0*x0*x0; s[5]+=w0*x0*x1; s[6]+=w0*x0*x2; s[7]+=w0*x1*x1; s[8]+=w0*x1*x2; s[9]+=w0*x2*x2;
    s[10]+=w1; s[11]+=w1*x0; s[12]+=w1*x1; s[13]+=w1*x2;
    s[14]+=w1*x0*x0; s[15]+=w1*x0*x1; s[16]+=w1*x0*x2; s[17]+=w1*x1*x1; s[18]+=w1*x1*x2; s[19]+=w1*x2*x2;
  }
#pragma unroll
  for(int q=0;q<20;q++){
    double v = waveSum(s[q]);
    if((threadIdx.x&63)==0) atomicAdd(&A[A_DK+b*20+q], v);
  }
}
__global__ void k_dk_inv(const double* A, float* F){
  if(threadIdx.x||blockIdx.x) return;
  for(int b=0;b<NB;b++) for(int k=0;k<2;k++){
    const double* s = A + A_DK + (b*2+k)*10;
    double W0=s[0], Ws=W0+1e-8;
    double mu0=s[1]/Ws, mu1=s[2]/Ws, mu2=s[3]/Ws;
    double C00=(s[4]-2.0*mu0*s[1]+mu0*mu0*W0)/Ws + 1e-6;
    double C01=(s[5]-mu0*s[2]-mu1*s[1]+mu0*mu1*W0)/Ws;
    double C02=(s[6]-mu0*s[3]-mu2*s[1]+mu0*mu2*W0)/Ws;
    double C11=(s[7]-2.0*mu1*s[2]+mu1*mu1*W0)/Ws + 1e-6;
    double C12=(s[8]-mu1*s[3]-mu2*s[2]+mu1*mu2*W0)/Ws;
    double C22=(s[9]-2.0*mu2*s[3]+mu2*mu2*W0)/Ws + 1e-6;
    double det = C00*(C11*C22-C12*C12) - C01*(C01*C22-C12*C02) + C02*(C01*C12-C11*C02);
    double id = 1.0/det;
    float* P = F + F_DKINV + (b*2+k)*9;
    P[0]=(float)((C11*C22-C12*C12)*id);
    P[1]=(float)((C02*C12-C01*C22)*id);
    P[2]=(float)((C01*C12-C02*C11)*id);
    P[3]=(float)((C00*C22-C02*C02)*id);
    P[4]=(float)((C01*C02-C00*C12)*id);
    P[5]=(float)((C00*C11-C01*C01)*id);
    P[6]=(float)mu0; P[7]=(float)mu1; P[8]=(float)mu2;
  }
}
__global__ void k_dm(const float* Lp,const float* E,const float* S,
                     const float* Ra0,const float* Ra1,const float* F,float* DM){
  int i = blockIdx.x*256 + threadIdx.x; if(i>=BN) return;
  int b=i/NPIX;
  float x0=Lp[i], x1=E[i], x2=S[i];
  float D[2];
#pragma unroll
  for(int k=0;k<2;k++){
    const float* P = F + F_DKINV + (b*2+k)*9;
    float d0=x0-P[6], d1=x1-P[7], d2=x2-P[8];
    float q = d0*d0*P[0] + d1*d1*P[3] + d2*d2*P[5]
            + 2.f*(d0*d1*P[1] + d0*d2*P[2] + d1*d2*P[4]);
    D[k]=sqrtf(q+1e-8f);
  }
  float w0=Ra0[i]+1e-8f, w1=Ra1[i]+1e-8f;
  DM[i] = (w0*D[0]+w1*D[1])/(w0+w1);
}

__global__ void k_minmax(const float* Lp, float* F){
  int i = blockIdx.x*256 + threadIdx.x; if(i>=BN) return;
  int b=i/NPIX;
  unsigned u = f2u(Lp[i]);
  unsigned mn=u, mx=u;
#pragma unroll
  for(int o=32;o;o>>=1){
    unsigned a = __shfl_down(mn,o,64); mn = (a<mn)?a:mn;
    unsigned c = __shfl_down(mx,o,64); mx = (c>mx)?c:mx;
  }
  unsigned* U = (unsigned*)F;
  if((threadIdx.x&63)==0){ atomicMin(&U[F_MM+b], mn); atomicMax(&U[F_MM+2+b], mx); }
}
__global__ void k_idx(const float* Lp, const float* F, int* idxP){
  int i = blockIdx.x*256 + threadIdx.x; if(i>=BN) return;
  int b=i/NPIX;
  const unsigned* U = (const unsigned*)F;
  float mn=u2f(U[F_MM+b]), mx=u2f(U[F_MM+2+b]);
  float ln = (Lp[i]-mn)/(mx-mn+1e-8f);
  ln = fminf(fmaxf(ln,0.f),1.f);
  int id = (int)(ln*32.f);
  idxP[i] = id>31?31:(id<0?0:id);
}

__global__ void k_lla_boxh(const float* rk,const float* Lp,float* tA,float* tB,float* tC){
  int i = blockIdx.x*256 + threadIdx.x; if(i>=BN) return;
  int n=i%NPIX, x=n%WW;
  int x0 = x-7<0?0:x-7, x1 = x+7>WW-1?WW-1:x+7;
  float s0=0,s1=0,s2=0;
  for(int xx=x0;xx<=x1;xx++){
    int j = i - x + xx;
    float r=rk[j], l=Lp[j];
    s0+=r; s1+=r*l; s2+=r*l*l;
  }
  tA[i]=s0; tB[i]=s1; tC[i]=s2;
}
__global__ void k_lla_boxv(const float* tA,const float* tB,const float* tC,const float* Lp,
                           float* tmpL,float* BSrk){
  int i = blockIdx.x*256 + threadIdx.x; if(i>=BN) return;
  int n=i%NPIX, y=n/WW, x=n%WW;
  int y0 = y-7<0?0:y-7, y1 = y+7>HH-1?HH-1:y+7;
  float S0=0,S1=0,S2=0;
  for(int yy=y0;yy<=y1;yy++){
    int j = i + (yy-y)*WW;
    S0+=tA[j]; S1+=tB[j]; S2+=tC[j];
  }
  float cy = (float)((y+8<HH?y+8:HH)-(y-7>0?y-7:0));
  float cx = (float)((x+8<WW?x+8:WW)-(x-7>0?x-7:0));
  float cnt = cy*cx;
  float den = S0/cnt + 1e-8f;
  float mu  = (S1/cnt)/den;
  float var = fmaxf((S2/cnt)/den - mu*mu, 1e-8f);
  tmpL[i] = fabsf(Lp[i]-mu)/(sqrtf(var)+1e-8f);
  BSrk[i] = S0;
}

__global__ void k_ghist(const float* rk,const int* idxP,double* A){
  __shared__ float h[NBINS];
  if(threadIdx.x<NBINS) h[threadIdx.x]=0.f;
  __syncthreads();
  int i = blockIdx.x*256 + threadIdx.x;
  int b = i/NPIX;
  atomicAdd(&h[idxP[i]], rk[i]);
  __syncthreads();
  if(threadIdx.x<NBINS && h[threadIdx.x]!=0.f)
    atomicAdd(&A[A_GHIST+b*NBINS+threadIdx.x], (double)h[threadIdx.x]);
}
__global__ void k_gcdf(double* A, float* F){
  int b = threadIdx.x;
  if(b>=NB || blockIdx.x) return;
  double sum=0;
  for(int j=0;j<NBINS;j++) sum += A[A_GHIST+b*NBINS+j];
  double c=0;
  for(int j=0;j<NBINS;j++){
    double g = A[A_GHIST+b*NBINS+j]/(sum+1e-8);
    c += g;
    F[F_GCDF+b*NBINS+j]=(float)c;
    A[A_GHIST+b*NBINS+j]=0.0;
  }
}
__global__ __launch_bounds__(256) void k_histh(const float* rk_b,const int* idx_b,float* bufA){
  __shared__ float acc[256*33];
  int tid=threadIdx.x;
  float* my = acc + tid*33;
#pragma unroll
  for(int j=0;j<NBINS;j++) my[j]=0.f;
  int n = blockIdx.x*256+tid;
  int y=n/WW, x=n%WW;
  int x0 = x-7<0?0:x-7, x1 = x+7>WW-1?WW-1:x+7;
  for(int xx=x0;xx<=x1;xx++){
    int m = y*WW+xx;
    my[idx_b[m]] += rk_b[m];
  }
#pragma unroll
  for(int bin=0;bin<NBINS;bin++) bufA[bin*NPIX + n] = my[bin];
}
__global__ void k_histv(const float* bufA, float* bufB){
  int id = blockIdx.x*256 + threadIdx.x;
  if(id >= NBINS*NPIX) return;
  int bin = id/NPIX, n = id%NPIX, y=n/WW;
  int y0 = y-7<0?0:y-7, y1 = y+7>HH-1?HH-1:y+7;
  float s=0;
  for(int yy=y0;yy<=y1;yy++) s += bufA[bin*NPIX + n + (yy-y)*WW];
  bufB[id]=s;
}
__global__ void k_gld(const float* bufB,const float* BSrk,const float* F,int b,float* tmpG){
  __shared__ float gc[NBINS];
  if(threadIdx.x<NBINS) gc[threadIdx.x]=F[F_GCDF+b*NBINS+threadIdx.x];
  __syncthreads();
  int n = blockIdx.x*256 + threadIdx.x;
  int y=n/WW, x=n%WW;
  float cy = (float)((y+8<HH?y+8:HH)-(y-7>0?y-7:0));
  float cx = (float)((x+8<WW?x+8:WW)-(x-7>0?x-7:0));
  float cnt = cy*cx;
  float den = BSrk[b*NPIX+n]/cnt + 1e-8f;
  float cs=0, acc=0;
  for(int bin=0;bin<NBINS;bin++){
    cs += bufB[bin*NPIX+n];
    float loc = (cs/cnt)/den;
    acc += fabsf(loc - gc[bin]);
  }
  tmpG[b*NPIX+n] = acc*(1.f/32.f);
}
__global__ void k_gamma(const float* tmpL,const float* tmpG,const float* rk,const float* F,
                        float* gamma,int first){
  int i = blockIdx.x*256 + threadIdx.x; if(i>=BN) return;
  int b=i/NPIX;
  float zl=(tmpL[i]-F[F_LLA+b*2])/F[F_LLA+b*2+1];
  float zg=(tmpG[i]-F[F_GLD+b*2])/F[F_GLD+b*2+1];
  float c = rk[i]*(0.5f*sp(zl)+0.5f*sp(zg));
  gamma[i] = first ? 1.0f + c : gamma[i] + c;
}

__global__ void k_es_red(const float* E,const float* S,const float* F,double* A){
  int b = blockIdx.x / RB, blk = blockIdx.x % RB;
  const float* M = F + F_ES + b*4;
  double s[5]={0,0,0,0,0};
  for(int n = blk*256 + threadIdx.x; n < NPIX; n += RB*256){
    float z0=(E[b*NPIX+n]-M[0])/M[1];
    float z1=(S[b*NPIX+n]-M[2])/M[3];
    s[0]+=z0; s[1]+=z1; s[2]+=(double)z0*z0; s[3]+=(double)z0*z1; s[4]+=(double)z1*z1;
  }
#pragma unroll
  for(int q=0;q<5;q++){
    double v = waveSum(s[q]);
    if((threadIdx.x&63)==0) atomicAdd(&A[A_ES+b*5+q], v);
  }
}
__global__ void k_es_inv(const double* A, float* F){
  if(threadIdx.x||blockIdx.x) return;
  for(int b=0;b<NB;b++){
    const double* s = A + A_ES + b*5;
    double inv=1.0/(double)NPIX;
    double m0=s[0]*inv, m1=s[1]*inv;
    double c00=s[2]*inv - m0*m0 + 1e-6;
    double c01=s[3]*inv - m0*m1;
    double c11=s[4]*inv - m1*m1 + 1e-6;
    double det=c00*c11-c01*c01;
    float* P = F + F_ESINV + b*5;
    P[0]=(float)m0; P[1]=(float)m1;
    P[2]=(float)(c11/det); P[3]=(float)(-c01/det); P[4]=(float)(c00/det);
  }
}
__global__ void k_lanom(const float* E,const float* S,const float* DM,const float* gamma,
                        const float* F,float* La){
  int i = blockIdx.x*256 + threadIdx.x; if(i>=BN) return;
  int b=i/NPIX;
  const float* M = F + F_ES + b*4;
  const float* P = F + F_ESINV + b*5;
  float z0=(E[i]-M[0])/M[1];
  float z1=(S[i]-M[2])/M[3];
  float d0=z0-P[0], d1=z1-P[1];
  float d2 = d0*d0*P[2] + 2.f*d0*d1*P[3] + d1*d1*P[4];
  float Rs = expf(-0.5f*d2);
  La[i] = fmaxf(DM[i]*gamma[i]*(1.f-Rs), 0.f);
}
__global__ void k_la_q(float* F){
  if(threadIdx.x||blockIdx.x) return;
  for(int b=0;b<NB;b++){
    const float* v = F + F_LAQ + b*4;
    double h1 = 0.01*(double)(NPIX-1); double f1 = h1 - floor(h1);
    double h9 = 0.99*(double)(NPIX-1); double f9 = h9 - floor(h9);
    F[F_Q19+b*2]  =(float)((double)v[0] + f1*((double)v[1]-(double)v[0]));
    F[F_Q19+b*2+1]=(float)((double)v[2] + f9*((double)v[3]-(double)v[2]));
  }
}
__global__ void k_out2(const float* La, const float* F, float* out){
  int i = blockIdx.x*256 + threadIdx.x; if(i>=BN) return;
  int b=i/NPIX;
  float q1=F[F_Q19+b*2], q9=F[F_Q19+b*2+1];
  float v = (La[i]-q1)/(q9-q1+1e-8f);
  out[BN + i] = fminf(fmaxf(v,0.f),1.f);
}

// ---------------- host ----------------
extern "C" void kernel_launch(void* const* d_in, const int* in_sizes, int n_in,
                              void* d_out, int out_size, void* d_ws, size_t ws_size,
                              hipStream_t stream){
  (void)in_sizes; (void)n_in; (void)out_size; (void)ws_size;
  const float* lab   = (const float*)d_in[0];
  const float* arand = (const float*)d_in[1];
  float* out = (float*)d_out;
  char* wsb = (char*)d_ws;
  double* A = (double*)wsb;
  float*  F = (float*)(wsb + 8192);
  float* planes = (float*)(wsb + 32768);
  float* E    = planes;
  float* S    = planes + (size_t)BN;
  float* tA   = planes + (size_t)2*BN;
  float* tB   = planes + (size_t)3*BN;
  float* tC   = planes + (size_t)4*BN;
  float* tmpL = planes + (size_t)5*BN;
  float* tmpG = planes + (size_t)6*BN;
  float* Xw0  = planes + (size_t)7*BN;
  float* Xw1  = planes + (size_t)8*BN;
  float* Xw2  = planes + (size_t)9*BN;
  float* zb   = planes + (size_t)10*BN;
  float* Ra0  = planes + (size_t)11*BN;
  float* Ra1  = planes + (size_t)12*BN;
  float* DM   = planes + (size_t)13*BN;
  float* gamma= planes + (size_t)14*BN;
  float* BSrk = planes + (size_t)15*BN;
  int*   idxP = (int*)(planes + (size_t)16*BN);
  float* bufA = planes + (size_t)17*BN;
  float* bufB = bufA + (size_t)NBINS*NPIX;
  double* kpart = (double*)bufA;  // kurt partials reuse bufA (disjoint in time)

  const int GBN = BN/256;      // 1152
  const int GN  = NPIX/256;    // 576
  const int GH  = (NBINS*NPIX)/256; // 18432

  k_zero<<<16,256,0,stream>>>(A,F);
  k_prep<<<GBN,256,0,stream>>>(lab,S,tA);
  k_box3h<<<GBN,256,0,stream>>>(tA,tB);
  k_box3v<<<GBN,256,0,stream>>>(tB,E);
  k_beta_red<<<NB*RB,256,0,stream>>>(E,S,lab,A);
  k_beta_solve<<<1,1,0,stream>>>(A,F);
  k_lperp<<<GBN,256,0,stream>>>(lab,E,S,F,out);
  k_sel_x3<<<6,1024,0,stream>>>(out,E,S,F);
  k_xz_red<<<NB*RB,256,0,stream>>>(out,E,S,F,A);
  k_eigh<<<1,64,0,stream>>>(A,F);
  k_xw<<<GBN,256,0,stream>>>(out,E,S,F,Xw0,Xw1,Xw2);
  k_an<<<1,256,0,stream>>>(arand,F);
  k_kurt<<<128,256,0,stream>>>(Xw0,Xw1,Xw2,F,kpart);
  k_kurt_pick<<<NB,128,0,stream>>>(kpart,F);
  k_zbest<<<GBN,256,0,stream>>>(Xw0,Xw1,Xw2,F,zb);
  k_sel4<<<8,1024,0,stream>>>(zb,F,36863,36864,110591,110592,F_ZBQ);
  k_gmm_init<<<1,1,0,stream>>>(F);
  for(int it=0; it<9; ++it){
    k_gmm_red<<<NB*RB,256,0,stream>>>(zb,F,A);
    k_gmm_update<<<1,1,0,stream>>>(A,F);
  }
  k_ralpha<<<GBN,256,0,stream>>>(zb,F,Ra0,Ra1);
  k_dk_red<<<NB*RB,256,0,stream>>>(out,E,S,Ra0,Ra1,A);
  k_dk_inv<<<1,1,0,stream>>>(A,F);
  k_dm<<<GBN,256,0,stream>>>(out,E,S,Ra0,Ra1,F,DM);
  k_minmax<<<GBN,256,0,stream>>>(out,F);
  k_idx<<<GBN,256,0,stream>>>(out,F,idxP);
  for(int k=0;k<2;k++){
    const float* Rk = k ? Ra1 : Ra0;
    k_lla_boxh<<<GBN,256,0,stream>>>(Rk,out,tA,tB,tC);
    k_lla_boxv<<<GBN,256,0,stream>>>(tA,tB,tC,out,tmpL,BSrk);
    k_sel_medmad<<<2,1024,0,stream>>>(tmpL,F,F_LLA);
    k_ghist<<<GBN,256,0,stream>>>(Rk,idxP,A);
    k_gcdf<<<1,64,0,stream>>>(A,F);
    for(int b=0;b<NB;b++){
      k_histh<<<GN,256,0,stream>>>(Rk+(size_t)b*NPIX, idxP+(size_t)b*NPIX, bufA);
      k_histv<<<GH,256,0,stream>>>(bufA,bufB);
      k_gld<<<GN,256,0,stream>>>(bufB,BSrk,F,b,tmpG);
    }
    k_sel_medmad<<<2,1024,0,stream>>>(tmpG,F,F_GLD);
    k_gamma<<<GBN,256,0,stream>>>(tmpL,tmpG,Rk,F,gamma,k==0?1:0);
  }
  k_sel_es<<<4,1024,0,stream>>>(E,S,F);
  k_es_red<<<NB*RB,256,0,stream>>>(E,S,F,A);
  k_es_inv<<<1,1,0,stream>>>(A,F);
  k_lanom<<<GBN,256,0,stream>>>(E,S,DM,gamma,F,tA);
  k_sel4<<<8,1024,0,stream>>>(tA,F,1474,1475,145980,145981,F_LAQ);
  k_la_q<<<1,1,0,stream>>>(F);
  k_out2<<<GBN,256,0,stream>>>(tA,F,out);
}

// Round 2
// 1836.630 us; speedup vs baseline: 2.0355x; 2.0355x over previous
//
#include <hip/hip_runtime.h>
#include <math.h>

#define HH 384
#define WW 384
#define NPIX (HH*WW)          // 147456
#define NB 2
#define BN (NB*NPIX)          // 294912
#define NT 128
#define NBINS 32
#define MEDRANK ((NPIX-1)/2)  // 73727
#define RB 72                 // reduction blocks per batch
#define SEL_BLK 288           // blocks per select task per pass

// ---- double arena (at ws+0, 512 doubles) ----
#define A_BETA 0    // 10
#define A_XZ   16   // 18
#define A_ES   40   // 10
#define A_DK   56   // 40
#define A_GHIST 96  // 64
#define A_GMM  160  // 9 iters * 12 = 108

// ---- float arena (at ws+8192, 4096 floats) ----
#define F_BETA 0
#define F_X3   8    // 12: (b*3+ch)*2 {med,mad}; ch1=E, ch2=S reused for ES stage
#define F_MEAN 24
#define F_WWH  32
#define F_AN   56
#define F_ASTAR 828
#define F_GMM  840
#define F_ZBQ  868
#define F_DKINV 880
#define F_LLA  918
#define F_GLD  924
#define F_MM   928
#define F_LAQ  952
#define F_Q19  960
#define F_GCDF 968

// ---------------- device helpers ----------------
__device__ __forceinline__ double waveSum(double v){
#pragma unroll
  for(int o=32;o;o>>=1) v += __shfl_down(v,o,64);
  return v;
}
__device__ __forceinline__ unsigned f2u(float f){
  unsigned u = __float_as_uint(f);
  return (u & 0x80000000u) ? ~u : (u | 0x80000000u);
}
__device__ __forceinline__ float u2f(unsigned u){
  return __uint_as_float((u & 0x80000000u) ? (u ^ 0x80000000u) : ~u);
}
__device__ __forceinline__ float sp(float x){
  float t = log1pf(expf(-fabsf(x)));
  return x >= 0.f ? x + t : t;
}

// ---- parallel batched radix select machinery ----
// hist layout: H[task*2048 + stage*1024 + pass*256 + bin]
struct SelBatch {
  const float* src[8];
  int rank[8];
  int fslot[8];
  int nt;
  int medmad;
};

// block-parallel: find bin containing rank in 256-bin hist (blockDim.x==256)
__device__ void pick256(const unsigned* hp, int rank, unsigned& sel, int& nrank){
  __shared__ unsigned s_cum[256];
  __shared__ unsigned s_res[2];
  int tid = threadIdx.x;
  unsigned x = hp[tid];
  s_cum[tid] = x;
  __syncthreads();
  for(int o=1;o<256;o<<=1){
    unsigned t = (tid>=o)? s_cum[tid-o] : 0u;
    __syncthreads();
    s_cum[tid] += t;
    __syncthreads();
  }
  unsigned cum = s_cum[tid];
  unsigned ex  = cum - x;
  if(x>0u && (unsigned)rank>=ex && (unsigned)rank<cum){
    s_res[0]=(unsigned)tid; s_res[1]=(unsigned)(rank-(int)ex);
  }
  __syncthreads();
  sel = s_res[0]; nrank = (int)s_res[1];
  __syncthreads();
}
__device__ float reconstruct_val(const unsigned* hbase, int rank){
  unsigned prefix=0; int r=rank;
  for(int p=3;p>=0;--p){
    unsigned sel; int nr;
    pick256(hbase+p*256, r, sel, nr);
    prefix |= sel<<(p*8); r=nr;
  }
  return u2f(prefix);
}
__device__ unsigned reconstruct_prefix(const unsigned* hbase, int rank, int downto, int& rout){
  unsigned prefix=0; int r=rank;
  for(int p=3;p>downto;--p){
    unsigned sel; int nr;
    pick256(hbase+p*256, r, sel, nr);
    prefix |= sel<<(p*8); r=nr;
  }
  rout=r; return prefix;
}

__global__ void k_selz(unsigned* H){
  int i = blockIdx.x*256 + threadIdx.x;
  if(i < 8*2048) H[i]=0u;
}
__global__ __launch_bounds__(256) void k_selp(SelBatch sb, unsigned* H, int stage, int pass){
  int task = blockIdx.x / SEL_BLK;
  int blk  = blockIdx.x % SEL_BLK;
  const unsigned* h0 = H + task*2048;
  float center = 0.f;
  if(stage==1) center = reconstruct_val(h0, sb.rank[task]);
  int r;
  unsigned prefix = reconstruct_prefix(h0 + stage*1024, sb.rank[task], pass, r);
  __shared__ unsigned lh[256];
  lh[threadIdx.x]=0u; __syncthreads();
  unsigned himask = (pass==3)?0u:(0xFFFFFFFFu<<((pass+1)*8));
  const float* src = sb.src[task];
  for(int i=blk*256+threadIdx.x; i<NPIX; i+=SEL_BLK*256){
    float v = src[i];
    if(stage) v = fabsf(v-center);
    unsigned u = f2u(v);
    if((u&himask)==prefix) atomicAdd(&lh[(u>>(pass*8))&255u],1u);
  }
  __syncthreads();
  unsigned c = lh[threadIdx.x];
  if(c) atomicAdd(H + task*2048 + stage*1024 + pass*256 + threadIdx.x, c);
}
__global__ __launch_bounds__(256) void k_self(SelBatch sb, const unsigned* H, float* F){
  int task = blockIdx.x;
  const unsigned* h0 = H + task*2048;
  float med = reconstruct_val(h0, sb.rank[task]);
  if(sb.medmad){
    float mad = reconstruct_val(h0+1024, sb.rank[task]);
    if(threadIdx.x==0){
      F[sb.fslot[task]]   = med;
      F[sb.fslot[task]+1] = mad*1.4826f + 1e-8f;
    }
  } else if(threadIdx.x==0){
    F[sb.fslot[task]] = med;
  }
}

// GMM param derivation: params after `it` updates (it==0 -> init from F)
__device__ void derive_params(const float* F, const double* A, int it, int b,
                              double& mu0,double& mu1,double& iv0h,double& iv1h,
                              double& c0,double& c1){
  if(it==0){
    const float* P = F + F_GMM + b*12;
    mu0=P[0]; mu1=P[1]; c0=P[6]; c1=P[7]; iv0h=P[8]; iv1h=P[9];
  } else {
    const double* g = A + A_GMM + (it-1)*12 + b*6;
    double N0=g[0],N1=g[1];
    mu0=g[2]/(N0+1e-8); mu1=g[3]/(N1+1e-8);
    double v0=(g[4]-2.0*mu0*g[2]+mu0*mu0*N0)/(N0+1e-8)+1e-6;
    double v1=(g[5]-2.0*mu1*g[3]+mu1*mu1*N1)/(N1+1e-8)+1e-6;
    double p0=N0/(double)NPIX, p1=N1/(double)NPIX;
    c0=-0.5*log(v0+1e-6)+log(p0+1e-8);
    c1=-0.5*log(v1+1e-6)+log(p1+1e-8);
    iv0h=0.5/(v0+1e-6); iv1h=0.5/(v1+1e-6);
  }
}
__device__ __forceinline__ void estep2(double x,double mu0,double mu1,double iv0h,double iv1h,
                                       double c0,double c1,double& r0,double& r1){
  double d0=x-mu0, d1=x-mu1;
  double l0=-d0*d0*iv0h+c0, l1=-d1*d1*iv1h+c1;
  double m=fmax(l0,l1);
  double e0=exp(l0-m), e1=exp(l1-m);
  double s=e0+e1;
  r0=e0/s; r1=e1/s;
}

// ---------------- kernels ----------------
__global__ void k_zero(double* A, float* F){
  int i = blockIdx.x*blockDim.x + threadIdx.x;
  if(i < 512) A[i] = 0.0;
  if(i < 4096){
    unsigned* U = (unsigned*)F;
    unsigned v = 0u;
    if(i==F_MM || i==F_MM+1) v = 0xFFFFFFFFu;
    U[i] = v;
  }
}

__global__ void k_prep(const float* lab, float* S, float* G2){
  int i = blockIdx.x*256 + threadIdx.x; if(i>=BN) return;
  int b=i/NPIX, n=i%NPIX, y=n/WW, x=n%WW;
  const float* Lb = lab + b*3*NPIX;
  float av = Lb[NPIX+n], bv = Lb[2*NPIX+n];
  S[i] = sqrtf(av*av + bv*bv + 1e-8f);
  auto l = [&](int yy,int xx)->float{
    return (yy<0||yy>=HH||xx<0||xx>=WW)?0.f:Lb[yy*WW+xx]; };
  float gx = -l(y-1,x-1)+l(y-1,x+1) -2.f*l(y,x-1)+2.f*l(y,x+1) -l(y+1,x-1)+l(y+1,x+1);
  float gy = -l(y-1,x-1)-2.f*l(y-1,x)-l(y-1,x+1) +l(y+1,x-1)+2.f*l(y+1,x)+l(y+1,x+1);
  G2[i] = gx*gx + gy*gy;
}

__global__ void k_box3h(const float* in, float* out){
  int i = blockIdx.x*256 + threadIdx.x; if(i>=BN) return;
  int x = (i%NPIX)%WW;
  float s = in[i];
  if(x>0) s += in[i-1];
  if(x<WW-1) s += in[i+1];
  out[i]=s;
}
__global__ void k_box3v(const float* in, float* out){
  int i = blockIdx.x*256 + threadIdx.x; if(i>=BN) return;
  int y = (i%NPIX)/WW;
  float s = in[i];
  if(y>0) s += in[i-WW];
  if(y<HH-1) s += in[i+WW];
  out[i]=s*(1.f/9.f);
}

__global__ void k_beta_red(const float* E,const float* S,const float* lab,double* A){
  int b = blockIdx.x / RB, blk = blockIdx.x % RB;
  double s[5]={0,0,0,0,0};
  for(int n = blk*256 + threadIdx.x; n < NPIX; n += RB*256){
    float e=E[b*NPIX+n], ss=S[b*NPIX+n], l=lab[b*3*NPIX+n];
    s[0]+=(double)e*e; s[1]+=(double)e*ss; s[2]+=(double)ss*ss;
    s[3]+=(double)e*l; s[4]+=(double)ss*l;
  }
#pragma unroll
  for(int q=0;q<5;q++){
    double v = waveSum(s[q]);
    if((threadIdx.x&63)==0) atomicAdd(&A[A_BETA+b*5+q], v);
  }
}
__global__ void k_beta_solve(const double* A, float* F){
  if(threadIdx.x||blockIdx.x) return;
  for(int b=0;b<NB;b++){
    double EE=A[A_BETA+b*5],ES=A[A_BETA+b*5+1],SS=A[A_BETA+b*5+2],EL=A[A_BETA+b*5+3],SL=A[A_BETA+b*5+4];
    double a00=EE+1e-6, a01=ES, a11=SS+1e-6;
    double det=a00*a11-a01*a01;
    F[F_BETA+b*2]  =(float)(( a11*EL - a01*SL)/det);
    F[F_BETA+b*2+1]=(float)((-a01*EL + a00*SL)/det);
  }
}
__global__ void k_lperp(const float* lab,const float* E,const float* S,const float* F,float* out0){
  int i = blockIdx.x*256 + threadIdx.x; if(i>=BN) return;
  int b=i/NPIX, n=i%NPIX;
  out0[i] = lab[b*3*NPIX+n] - F[F_BETA+b*2]*E[i] - F[F_BETA+b*2+1]*S[i];
}

__global__ void k_xz_red(const float* Lp,const float* E,const float* S,const float* F,double* A){
  int b = blockIdx.x / RB, blk = blockIdx.x % RB;
  const float* M = F + F_X3 + b*6;
  double s[9]={0,0,0,0,0,0,0,0,0};
  for(int n = blk*256 + threadIdx.x; n < NPIX; n += RB*256){
    float z0=(Lp[b*NPIX+n]-M[0])/M[1];
    float z1=(E [b*NPIX+n]-M[2])/M[3];
    float z2=(S [b*NPIX+n]-M[4])/M[5];
    s[0]+=z0; s[1]+=z1; s[2]+=z2;
    s[3]+=(double)z0*z0; s[4]+=(double)z0*z1; s[5]+=(double)z0*z2;
    s[6]+=(double)z1*z1; s[7]+=(double)z1*z2; s[8]+=(double)z2*z2;
  }
#pragma unroll
  for(int q=0;q<9;q++){
    double v = waveSum(s[q]);
    if((threadIdx.x&63)==0) atomicAdd(&A[A_XZ+b*9+q], v);
  }
}
__global__ void k_eigh(const double* A, float* F){
  int b = threadIdx.x;
  if(b>=NB || blockIdx.x) return;
  const double* s = A + A_XZ + b*9;
  double inv = 1.0/(double)NPIX;
  double m0=s[0]*inv, m1=s[1]*inv, m2=s[2]*inv;
  double a[3][3];
  a[0][0]=fmax(s[3]*inv-m0*m0,1e-8);
  a[0][1]=a[1][0]=fmax(s[4]*inv-m0*m1,1e-8);
  a[0][2]=a[2][0]=fmax(s[5]*inv-m0*m2,1e-8);
  a[1][1]=fmax(s[6]*inv-m1*m1,1e-8);
  a[1][2]=a[2][1]=fmax(s[7]*inv-m1*m2,1e-8);
  a[2][2]=fmax(s[8]*inv-m2*m2,1e-8);
  double V[3][3]={{1,0,0},{0,1,0},{0,0,1}};
  for(int sweep=0;sweep<40;sweep++){
    for(int pp=0;pp<3;pp++){
      int p = (pp==2)?1:0;
      int q = (pp==0)?1:2;
      double apq=a[p][q];
      if(fabs(apq)<1e-30) continue;
      double theta=(a[q][q]-a[p][p])/(2.0*apq);
      double t=((theta>=0)?1.0:-1.0)/(fabs(theta)+sqrt(1.0+theta*theta));
      double c=1.0/sqrt(1.0+t*t), sn=t*c;
      for(int k2=0;k2<3;k2++){ double akp=a[k2][p],akq=a[k2][q];
        a[k2][p]=c*akp-sn*akq; a[k2][q]=sn*akp+c*akq; }
      for(int k2=0;k2<3;k2++){ double apk=a[p][k2],aqk=a[q][k2];
        a[p][k2]=c*apk-sn*aqk; a[q][k2]=sn*apk+c*aqk; }
      for(int k2=0;k2<3;k2++){ double vkp=V[k2][p],vkq=V[k2][q];
        V[k2][p]=c*vkp-sn*vkq; V[k2][q]=sn*vkp+c*vkq; }
    }
  }
  double is0=1.0/sqrt(a[0][0]), is1=1.0/sqrt(a[1][1]), is2=1.0/sqrt(a[2][2]);
  for(int i=0;i<3;i++) for(int j=0;j<3;j++){
    double w = V[i][0]*is0*V[j][0] + V[i][1]*is1*V[j][1] + V[i][2]*is2*V[j][2];
    F[F_WWH + b*9 + i*3 + j] = (float)w;
  }
  F[F_MEAN+b*3]=(float)m0; F[F_MEAN+b*3+1]=(float)m1; F[F_MEAN+b*3+2]=(float)m2;
}
__global__ void k_xw(const float* Lp,const float* E,const float* S,const float* F,
                     float* Xw0,float* Xw1,float* Xw2){
  int i = blockIdx.x*256 + threadIdx.x; if(i>=BN) return;
  int b=i/NPIX;
  const float* M = F + F_X3 + b*6;
  float z0=(Lp[i]-M[0])/M[1];
  float z1=(E [i]-M[2])/M[3];
  float z2=(S [i]-M[4])/M[5];
  float d0=z0-F[F_MEAN+b*3], d1=z1-F[F_MEAN+b*3+1], d2=z2-F[F_MEAN+b*3+2];
  const float* Wm = F + F_WWH + b*9;
  Xw0[i]=d0*Wm[0]+d1*Wm[3]+d2*Wm[6];
  Xw1[i]=d0*Wm[1]+d1*Wm[4]+d2*Wm[7];
  Xw2[i]=d0*Wm[2]+d1*Wm[5]+d2*Wm[8];
}
__global__ void k_an(const float* arand, float* F){
  int id = threadIdx.x; if(id >= NB*NT) return;
  const float* a = arand + id*3;
  double nrm = sqrt((double)a[0]*a[0]+(double)a[1]*a[1]+(double)a[2]*a[2]) + 1e-12;
  F[F_AN+id*3]  =(float)(a[0]/nrm);
  F[F_AN+id*3+1]=(float)(a[1]/nrm);
  F[F_AN+id*3+2]=(float)(a[2]/nrm);
}

#define KT_TILE 2304
__global__ __launch_bounds__(256) void k_kurt(const float* Xw0,const float* Xw1,const float* Xw2,
                                              const float* F, double* part){
  __shared__ float xs[3][KT_TILE];
  __shared__ double red[4][4];
  int blk = blockIdx.x;
  int b = blk/64;
  int base = blk*KT_TILE;
  for(int i=threadIdx.x;i<KT_TILE;i+=256){
    xs[0][i]=Xw0[base+i]; xs[1][i]=Xw1[base+i]; xs[2][i]=Xw2[base+i];
  }
  __syncthreads();
  int wave=threadIdx.x>>6, lane=threadIdx.x&63;
  for(int t=0;t<NT;t++){
    float a0=F[F_AN+(b*NT+t)*3], a1=F[F_AN+(b*NT+t)*3+1], a2=F[F_AN+(b*NT+t)*3+2];
    double s1=0,s2=0,s3=0,s4=0;
#pragma unroll
    for(int j=0;j<9;j++){
      int p=threadIdx.x+j*256;
      float z = xs[0][p]*a0 + xs[1][p]*a1 + xs[2][p]*a2;
      double zd=z, z2=zd*zd;
      s1+=zd; s2+=z2; s3+=z2*zd; s4+=z2*z2;
    }
    s1=waveSum(s1); s2=waveSum(s2); s3=waveSum(s3); s4=waveSum(s4);
    if(lane==0){ red[wave][0]=s1; red[wave][1]=s2; red[wave][2]=s3; red[wave][3]=s4; }
    __syncthreads();
    if(threadIdx.x<4){
      double v=red[0][threadIdx.x]+red[1][threadIdx.x]+red[2][threadIdx.x]+red[3][threadIdx.x];
      part[blk*512 + t*4 + threadIdx.x]=v;
    }
    __syncthreads();
  }
}
__global__ void k_kurt_pick(const double* part, float* F){
  int b = blockIdx.x;
  int t = threadIdx.x;
  __shared__ double ak[NT];
  double S1=0,S2=0,S3=0,S4=0;
  for(int blk=b*64; blk<(b+1)*64; ++blk){
    const double* p = part + blk*512 + t*4;
    S1+=p[0]; S2+=p[1]; S3+=p[2]; S4+=p[3];
  }
  double inv=1.0/(double)NPIX;
  double mean=S1*inv, M2=S2*inv, M3=S3*inv, M4=S4*inv;
  double m2 = M2 - mean*mean + 1e-12;
  double m4 = M4 - 4.0*mean*M3 + 6.0*mean*mean*M2 - 3.0*mean*mean*mean*mean;
  double kurt = m4/(m2*m2) - 3.0;
  ak[t] = fabs(kurt);
  __syncthreads();
  if(t==0){
    int best=0; double bv=ak[0];
    for(int j=1;j<NT;j++) if(ak[j]>bv){bv=ak[j];best=j;}
    F[F_ASTAR+b*3]  =F[F_AN+(b*NT+best)*3];
    F[F_ASTAR+b*3+1]=F[F_AN+(b*NT+best)*3+1];
    F[F_ASTAR+b*3+2]=F[F_AN+(b*NT+best)*3+2];
  }
}
__global__ void k_zbest(const float* Xw0,const float* Xw1,const float* Xw2,const float* F,float* zb){
  int i = blockIdx.x*256 + threadIdx.x; if(i>=BN) return;
  int b=i/NPIX;
  zb[i] = Xw0[i]*F[F_ASTAR+b*3] + Xw1[i]*F[F_ASTAR+b*3+1] + Xw2[i]*F[F_ASTAR+b*3+2];
}

__global__ void k_gmm_init(float* F){
  if(threadIdx.x||blockIdx.x) return;
  for(int b=0;b<NB;b++){
    const float* z = F + F_ZBQ + b*4;
    double h25 = 0.25*(double)(NPIX-1); double f25 = h25 - floor(h25);
    double h75 = 0.75*(double)(NPIX-1); double f75 = h75 - floor(h75);
    double q25 = (double)z[0] + f25*((double)z[1]-(double)z[0]);
    double q75 = (double)z[2] + f75*((double)z[3]-(double)z[2]);
    float* P = F + F_GMM + b*12;
    double v0=1.0, v1=1.0, p0=0.5, p1=0.5;
    P[0]=(float)q25; P[1]=(float)q75;
    P[6]=(float)(-0.5*log(v0+1e-6)+log(p0+1e-8));
    P[7]=(float)(-0.5*log(v1+1e-6)+log(p1+1e-8));
    P[8]=(float)(0.5/(v0+1e-6));
    P[9]=(float)(0.5/(v1+1e-6));
  }
}
// E-step with params-after-`it`-updates, accumulate sums into slot `it`
__global__ void k_gmm_red(const float* zb, const float* F, double* A, int it){
  int b = blockIdx.x / RB, blk = blockIdx.x % RB;
  double mu0,mu1,iv0h,iv1h,c0,c1;
  derive_params(F,A,it,b,mu0,mu1,iv0h,iv1h,c0,c1);
  double s[6]={0,0,0,0,0,0};
  for(int n = blk*256 + threadIdx.x; n < NPIX; n += RB*256){
    double x = (double)zb[b*NPIX+n];
    double r0,r1; estep2(x,mu0,mu1,iv0h,iv1h,c0,c1,r0,r1);
    s[0]+=r0; s[1]+=r1; s[2]+=r0*x; s[3]+=r1*x; s[4]+=r0*x*x; s[5]+=r1*x*x;
  }
#pragma unroll
  for(int q=0;q<6;q++){
    double v = waveSum(s[q]);
    if((threadIdx.x&63)==0) atomicAdd(&A[A_GMM+it*12+b*6+q], v);
  }
}
__global__ void k_ralpha(const float* zb, const float* F, const double* A, float* Ra0, float* Ra1){
  int i = blockIdx.x*256 + threadIdx.x; if(i>=BN) return;
  int b=i/NPIX;
  double mu0,mu1,iv0h,iv1h,c0,c1;
  derive_params(F,A,9,b,mu0,mu1,iv0h,iv1h,c0,c1);
  double r0,r1; estep2((double)zb[i],mu0,mu1,iv0h,iv1h,c0,c1,r0,r1);
  double ra0=pow(r0,0.9), ra1=pow(r1,0.9);
  double s=ra0+ra1+1e-8;
  Ra0[i]=(float)(ra0/s); Ra1[i]=(float)(ra1/s);
}

__global__ void k_dk_red(const float* Lp,const float* E,const float* S,
                         const float* Ra0,const float* Ra1,double* A){
  int b = blockIdx.x / RB, blk = blockIdx.x % RB;
  double s[20];
#pragma unroll
  for(int q=0;q<20;q++) s[q]=0;
  for(int n = blk*256 + threadIdx.x; n < NPIX; n += RB*256){
    int i=b*NPIX+n;
    double w0=Ra0[i], w1=Ra1[i];
    double x0=Lp[i], x1=E[i], x2=S[i];
    s[0]+=w0; s[1]+=w0*x0; s[2]+=w0*x1; s[3]+=w0*x2;
    s[4]+=w0*x0*x0; s[5]+=w0*x0*x1; s[6]+=w0*x0*x2; s[7]+=w0*x1*x1; s[8]+=w0*x1*x2; s[9]+=w0*x2*x2;
    s[10]+=w1; s[11]+=w1*x0; s[12]+=w1*x1; s[13]+=w1*x2;
    s[14]+=w1*x0*x0; s[15]+=w1*x0*x1; s[16]+=w1*x0*x2; s[17]+=w1*x1*x1; s[18]+=w1*x1*x2; s[19]+=w1*x2*x2;
  }
#pragma unroll
  for(int q=0;q<20;q++){
    double v = waveSum(s[q]);
    if((threadIdx.x&63)==0) atomicAdd(&A[A_DK+b*20+q], v);
  }
}
__global__ void k_dk_inv(const double* A, float* F){
  if(threadIdx.x||blockIdx.x) return;
  for(int b=0;b<NB;b++) for(int k=0;k<2;k++){
    const double* s = A + A_DK + (b*2+k)*10;
    double W0=s[0], Ws=W0+1e-8;
    double mu0=s[1]/Ws, mu1=s[2]/Ws, mu2=s[3]/Ws;
    double C00=(s[4]-2.0*mu0*s[1]+mu0*mu0*W0)/Ws + 1e-6;
    double C01=(s[5]-mu0*s[2]-mu1*s[1]+mu0*mu1*W0)/Ws;
    double C02=(s[6]-mu0*s[3]-mu2*s[1]+mu0*mu2*W0)/Ws;
    double C11=(s[7]-2.0*mu1*s[2]+mu1*mu1*W0)/Ws + 1e-6;
    double C12=(s[8]-mu1*s[3]-mu2*s[2]+mu1*mu2*W0)/Ws;
    double C22=(s[9]-2.0*mu2*s[3]+mu2*mu2*W0)/Ws + 1e-6;
    double det = C00*(C11*C22-C12*C12) - C01*(C01*C22-C12*C02) + C02*(C01*C12-C11*C02);
    double id = 1.0/det;
    float* P = F + F_DKINV + (b*2+k)*9;
    P[0]=(float)((C11*C22-C12*C12)*id);
    P[1]=(float)((C02*C12-C01*C22)*id);
    P[2]=(float)((C01*C12-C02*C11)*id);
    P[3]=(float)((C00*C22-C02*C02)*id);
    P[4]=(float)((C01*C02-C00*C12)*id);
    P[5]=(float)((C00*C11-C01*C01)*id);
    P[6]=(float)mu0; P[7]=(float)mu1; P[8]=(float)mu2;
  }
}
__global__ void k_dm(const float* Lp,const float* E,const float* S,
                     const float* Ra0,const float* Ra1,const float* F,float* DM){
  int i = blockIdx.x*256 + threadIdx.x; if(i>=BN) return;
  int b=i/NPIX;
  float x0=Lp[i], x1=E[i], x2=S[i];
  float D[2];
#pragma unroll
  for(int k=0;k<2;k++){
    const float* P = F + F_DKINV + (b*2+k)*9;
    float d0=x0-P[6], d1=x1-P[7], d2=x2-P[8];
    float q = d0*d0*P[0] + d1*d1*P[3] + d2*d2*P[5]
            + 2.f*(d0*d1*P[1] + d0*d2*P[2] + d1*d2*P[4]);
    D[k]=sqrtf(q+1e-8f);
  }
  float w0=Ra0[i]+1e-8f, w1=Ra1[i]+1e-8f;
  DM[i] = (w0*D[0]+w1*D[1])/(w0+w1);
}

__global__ void k_minmax(const float* Lp, float* F){
  int i = blockIdx.x*256 + threadIdx.x; if(i>=BN) return;
  int b=i/NPIX;
  unsigned u = f2u(Lp[i]);
  unsigned mn=u, mx=u;
#pragma unroll
  for(int o=32;o;o>>=1){
    unsigned a = __shfl_down(mn,o,64); mn = (a<mn)?a:mn;
    unsigned c = __shfl_down(mx,o,64); mx = (c>mx)?c:mx;
  }
  unsigned* U = (unsigned*)F;
  if((threadIdx.x&63)==0){ atomicMin(&U[F_MM+b], mn); atomicMax(&U[F_MM+2+b], mx); }
}
__global__ void k_idx(const float* Lp, const float* F, int* idxP){
  int i = blockIdx.x*256 + threadIdx.x; if(i>=BN) return;
  int b=i/NPIX;
  const unsigned* U = (const unsigned*)F;
  float mn=u2f(U[F_MM+b]), mx=u2f(U[F_MM+2+b]);
  float ln = (Lp[i]-mn)/(mx-mn+1e-8f);
  ln = fminf(fmaxf(ln,0.f),1.f);
  int id = (int)(ln*32.f);
  idxP[i] = id>31?31:(id<0?0:id);
}

__global__ void k_lla_boxh(const float* rk,const float* Lp,float* tA,float* tB,float* tC){
  int i = blockIdx.x*256 + threadIdx.x; if(i>=BN) return;
  int n=i%NPIX, x=n%WW;
  int x0 = x-7<0?0:x-7, x1 = x+7>WW-1?WW-1:x+7;
  float s0=0,s1=0,s2=0;
  for(int xx=x0;xx<=x1;xx++){
    int j = i - x + xx;
    float r=rk[j], l=Lp[j];
    s0+=r; s1+=r*l; s2+=r*l*l;
  }
  tA[i]=s0; tB[i]=s1; tC[i]=s2;
}
__global__ void k_lla_boxv(const float* tA,const float* tB,const float* tC,const float* Lp,
                           float* tmpL,float* BSrk){
  int i = blockIdx.x*256 + threadIdx.x; if(i>=BN) return;
  int n=i%NPIX, y=n/WW, x=n%WW;
  int y0 = y-7<0?0:y-7, y1 = y+7>HH-1?HH-1:y+7;
  float S0=0,S1=0,S2=0;
  for(int yy=y0;yy<=y1;yy++){
    int j = i + (yy-y)*WW;
    S0+=tA[j]; S1+=tB[j]; S2+=tC[j];
  }
  float cy = (float)((y+8<HH?y+8:HH)-(y-7>0?y-7:0));
  float cx = (float)((x+8<WW?x+8:WW)-(x-7>0?x-7:0));
  float cnt = cy*cx;
  float den = S0/cnt + 1e-8f;
  float mu  = (S1/cnt)/den;
  float var = fmaxf((S2/cnt)/den - mu*mu, 1e-8f);
  tmpL[i] = fabsf(Lp[i]-mu)/(sqrtf(var)+1e-8f);
  BSrk[i] = S0;
}

__global__ void k_ghist(const float* rk,const int* idxP,double* A){
  __shared__ float h[NBINS];
  if(threadIdx.x<NBINS) h[threadIdx.x]=0.f;
  __syncthreads();
  int i = blockIdx.x*256 + threadIdx.x;
  int b = i/NPIX;
  atomicAdd(&h[idxP[i]], rk[i]);
  __syncthreads();
  if(threadIdx.x<NBINS && h[threadIdx.x]!=0.f)
    atomicAdd(&A[A_GHIST+b*NBINS+threadIdx.x], (double)h[threadIdx.x]);
}
__global__ void k_gcdf(double* A, float* F){
  int b = threadIdx.x;
  if(b>=NB || blockIdx.x) return;
  double sum=0;
  for(int j=0;j<NBINS;j++) sum += A[A_GHIST+b*NBINS+j];
  double c=0;
  for(int j=0;j<NBINS;j++){
    double g = A[A_GHIST+b*NBINS+j]/(sum+1e-8);
    c += g;
    F[F_GCDF+b*NBINS+j]=(float)c;
    A[A_GHIST+b*NBINS+j]=0.0;
  }
}
__global__ __launch_bounds__(256) void k_histh(const float* rk_b,const int* idx_b,float* bufA){
  __shared__ float acc[256*33];
  int tid=threadIdx.x;
  float* my = acc + tid*33;
#pragma unroll
  for(int j=0;j<NBINS;j++) my[j]=0.f;
  int n = blockIdx.x*256+tid;
  int y=n/WW, x=n%WW;
  int x0 = x-7<0?0:x-7, x1 = x+7>WW-1?WW-1:x+7;
  for(int xx=x0;xx<=x1;xx++){
    int m = y*WW+xx;
    my[idx_b[m]] += rk_b[m];
  }
#pragma unroll
  for(int bin=0;bin<NBINS;bin++) bufA[bin*NPIX + n] = my[bin];
}
// fused vertical box + GLD accumulation
__global__ __launch_bounds__(256) void k_gldv(const float* bufA,const float* BSrk,const float* F,
                                              int b,float* tmpG){
  __shared__ float gc[NBINS];
  if(threadIdx.x<NBINS) gc[threadIdx.x]=F[F_GCDF+b*NBINS+threadIdx.x];
  __syncthreads();
  int n = blockIdx.x*256 + threadIdx.x;
  int y=n/WW, x=n%WW;
  int y0 = y-7<0?0:y-7, y1 = y+7>HH-1?HH-1:y+7;
  float cy = (float)((y+8<HH?y+8:HH)-(y-7>0?y-7:0));
  float cx = (float)((x+8<WW?x+8:WW)-(x-7>0?x-7:0));
  float cnt = cy*cx;
  float den = BSrk[b*NPIX+n]/cnt + 1e-8f;
  float cs=0, acc=0;
  for(int bin=0;bin<NBINS;bin++){
    float s=0;
    for(int yy=y0;yy<=y1;yy++) s += bufA[bin*NPIX + yy*WW + x];
    cs += s;
    acc += fabsf((cs/cnt)/den - gc[bin]);
  }
  tmpG[b*NPIX+n] = acc*(1.f/32.f);
}
__global__ void k_gamma(const float* tmpL,const float* tmpG,const float* rk,const float* F,
                        float* gamma,int first){
  int i = blockIdx.x*256 + threadIdx.x; if(i>=BN) return;
  int b=i/NPIX;
  float zl=(tmpL[i]-F[F_LLA+b*2])/F[F_LLA+b*2+1];
  float zg=(tmpG[i]-F[F_GLD+b*2])/F[F_GLD+b*2+1];
  float c = rk[i]*(0.5f*sp(zl)+0.5f*sp(zg));
  gamma[i] = first ? 1.0f + c : gamma[i] + c;
}

__global__ void k_es_red(const float* E,const float* S,const float* F,double* A){
  int b = blockIdx.x / RB, blk = blockIdx.x % RB;
  const float* M = F + F_X3 + b*6;   // ch1=E, ch2=S med/mad (identical to ES stage)
  double s[5]={0,0,0,0,0};
  for(int n = blk*256 + threadIdx.x; n < NPIX; n += RB*256){
    float z0=(E[b*NPIX+n]-M[2])/M[3];
    float z1=(S[b*NPIX+n]-M[4])/M[5];
    s[0]+=z0; s[1]+=z1; s[2]+=(double)z0*z0; s[3]+=(double)z0*z1; s[4]+=(double)z1*z1;
  }
#pragma unroll
  for(int q=0;q<5;q++){
    double v = waveSum(s[q]);
    if((threadIdx.x&63)==0) atomicAdd(&A[A_ES+b*5+q], v);
  }
}
__global__ void k_es_inv(const double* A, float* F){
  if(threadIdx.x||blockIdx.x) return;
  for(int b=0;b<NB;b++){
    const double* s = A + A_ES + b*5;
    double inv=1.0/(double)NPIX;
    double m0=s[0]*inv, m1=s[1]*inv;
    double c00=s[2]*inv - m0*m0 + 1e-6;
    double c01=s[3]*inv - m0*m1;
    double c11=s[4]*inv - m1*m1 + 1e-6;
    double det=c00*c11-c01*c01;
    float* P = F + 940 + b*5;
    P[0]=(float)m0; P[1]=(float)m1;
    P[2]=(float)(c11/det); P[3]=(float)(-c01/det); P[4]=(float)(c00/det);
  }
}
__global__ void k_lanom(const float* E,const float* S,const float* DM,const float* gamma,
                        const float* F,float* La){
  int i = blockIdx.x*256 + threadIdx.x; if(i>=BN) return;
  int b=i/NPIX;
  const float* M = F + F_X3 + b*6;
  const float* P = F + 940 + b*5;
  float z0=(E[i]-M[2])/M[3];
  float z1=(S[i]-M[4])/M[5];
  float d0=z0-P[0], d1=z1-P[1];
  float d2 = d0*d0*P[2] + 2.f*d0*d1*P[3] + d1*d1*P[4];
  float Rs = expf(-0.5f*d2);
  La[i] = fmaxf(DM[i]*gamma[i]*(1.f-Rs), 0.f);
}
__global__ void k_la_q(float* F){
  if(threadIdx.x||blockIdx.x) return;
  for(int b=0;b<NB;b++){
    const float* v = F + F_LAQ + b*4;
    double h1 = 0.01*(double)(NPIX-1); double f1 = h1 - floor(h1);
    double h9 = 0.99*(double)(NPIX-1); double f9 = h9 - floor(h9);
    F[F_Q19+b*2]  =(float)((double)v[0] + f1*((double)v[1]-(double)v[0]));
    F[F_Q19+b*2+1]=(float)((double)v[2] + f9*((double)v[3]-(double)v[2]));
  }
}
__global__ void k_out2(const float* La, const float* F, float* out){
  int i = blockIdx.x*256 + threadIdx.x; if(i>=BN) return;
  int b=i/NPIX;
  float q1=F[F_Q19+b*2], q9=F[F_Q19+b*2+1];
  float v = (La[i]-q1)/(q9-q1+1e-8f);
  out[BN + i] = fminf(fmaxf(v,0.f),1.f);
}

// ---------------- host ----------------
static void run_sel(const SelBatch& sb, unsigned* H, float* F, hipStream_t s){
  k_selz<<<64,256,0,s>>>(H);
  for(int p=3;p>=0;--p) k_selp<<<sb.nt*SEL_BLK,256,0,s>>>(sb,H,0,p);
  if(sb.medmad) for(int p=3;p>=0;--p) k_selp<<<sb.nt*SEL_BLK,256,0,s>>>(sb,H,1,p);
  k_self<<<sb.nt,256,0,s>>>(sb,H,F);
}

extern "C" void kernel_launch(void* const* d_in, const int* in_sizes, int n_in,
                              void* d_out, int out_size, void* d_ws, size_t ws_size,
                              hipStream_t stream){
  (void)in_sizes; (void)n_in; (void)out_size; (void)ws_size;
  const float* lab   = (const float*)d_in[0];
  const float* arand = (const float*)d_in[1];
  float* out = (float*)d_out;
  char* wsb = (char*)d_ws;
  double* A = (double*)wsb;                       // 512 doubles
  float*  F = (float*)(wsb + 8192);               // 4096 floats
  unsigned* H = (unsigned*)(wsb + 24576);         // 16384 uints (sel hists)
  float* planes = (float*)(wsb + 98304);
  float* E    = planes;
  float* S    = planes + (size_t)BN;
  float* tA   = planes + (size_t)2*BN;
  float* tB   = planes + (size_t)3*BN;
  float* tC   = planes + (size_t)4*BN;
  float* tmpL = planes + (size_t)5*BN;
  float* tmpG = planes + (size_t)6*BN;
  float* Xw0  = planes + (size_t)7*BN;
  float* Xw1  = planes + (size_t)8*BN;
  float* Xw2  = planes + (size_t)9*BN;
  float* zb   = planes + (size_t)10*BN;
  float* Ra0  = planes + (size_t)11*BN;
  float* Ra1  = planes + (size_t)12*BN;
  float* DM   = planes + (size_t)13*BN;
  float* gamma= planes + (size_t)14*BN;
  float* BSrk = planes + (size_t)15*BN;
  int*   idxP = (int*)(planes + (size_t)16*BN);
  float* bufA = planes + (size_t)17*BN;
  double* kpart = (double*)bufA;  // kurt partials reuse bufA (disjoint in time)

  const int GBN = BN/256;      // 1152
  const int GN  = NPIX/256;    // 576

  k_zero<<<16,256,0,stream>>>(A,F);
  k_prep<<<GBN,256,0,stream>>>(lab,S,tA);
  k_box3h<<<GBN,256,0,stream>>>(tA,tB);
  k_box3v<<<GBN,256,0,stream>>>(tB,E);
  k_beta_red<<<NB*RB,256,0,stream>>>(E,S,lab,A);
  k_beta_solve<<<1,1,0,stream>>>(A,F);
  k_lperp<<<GBN,256,0,stream>>>(lab,E,S,F,out);

  // med+mad for X3 channels (Lp,E,S per batch); E,S results also serve the ES stage
  SelBatch sbX; sbX.nt=6; sbX.medmad=1;
  for(int b=0;b<NB;b++){
    sbX.src[b*3+0]=out+(size_t)b*NPIX; sbX.src[b*3+1]=E+(size_t)b*NPIX; sbX.src[b*3+2]=S+(size_t)b*NPIX;
    for(int ch=0;ch<3;ch++){ sbX.rank[b*3+ch]=MEDRANK; sbX.fslot[b*3+ch]=F_X3+(b*3+ch)*2; }
  }
  run_sel(sbX,H,F,stream);

  k_xz_red<<<NB*RB,256,0,stream>>>(out,E,S,F,A);
  k_eigh<<<1,64,0,stream>>>(A,F);
  k_xw<<<GBN,256,0,stream>>>(out,E,S,F,Xw0,Xw1,Xw2);
  k_an<<<1,256,0,stream>>>(arand,F);
  k_kurt<<<128,256,0,stream>>>(Xw0,Xw1,Xw2,F,kpart);
  k_kurt_pick<<<NB,128,0,stream>>>(kpart,F);
  k_zbest<<<GBN,256,0,stream>>>(Xw0,Xw1,Xw2,F,zb);

  // zb quantile ranks (q25/q75 interpolation endpoints)
  SelBatch sbZ; sbZ.nt=8; sbZ.medmad=0;
  {
    int rr[4]={36863,36864,110591,110592};
    for(int b=0;b<NB;b++) for(int ri=0;ri<4;ri++){
      int t=b*4+ri;
      sbZ.src[t]=zb+(size_t)b*NPIX; sbZ.rank[t]=rr[ri]; sbZ.fslot[t]=F_ZBQ+b*4+ri;
    }
  }
  run_sel(sbZ,H,F,stream);

  k_gmm_init<<<1,1,0,stream>>>(F);
  for(int it=0; it<9; ++it)
    k_gmm_red<<<NB*RB,256,0,stream>>>(zb,F,A,it);
  k_ralpha<<<GBN,256,0,stream>>>(zb,F,A,Ra0,Ra1);
  k_dk_red<<<NB*RB,256,0,stream>>>(out,E,S,Ra0,Ra1,A);
  k_dk_inv<<<1,1,0,stream>>>(A,F);
  k_dm<<<GBN,256,0,stream>>>(out,E,S,Ra0,Ra1,F,DM);
  k_minmax<<<GBN,256,0,stream>>>(out,F);
  k_idx<<<GBN,256,0,stream>>>(out,F,idxP);

  SelBatch sbC; sbC.nt=4; sbC.medmad=1;
  for(int b=0;b<NB;b++){
    sbC.src[b]  =tmpL+(size_t)b*NPIX; sbC.rank[b]  =MEDRANK; sbC.fslot[b]  =F_LLA+b*2;
    sbC.src[2+b]=tmpG+(size_t)b*NPIX; sbC.rank[2+b]=MEDRANK; sbC.fslot[2+b]=F_GLD+b*2;
  }

  for(int k=0;k<2;k++){
    const float* Rk = k ? Ra1 : Ra0;
    k_lla_boxh<<<GBN,256,0,stream>>>(Rk,out,tA,tB,tC);
    k_lla_boxv<<<GBN,256,0,stream>>>(tA,tB,tC,out,tmpL,BSrk);
    k_ghist<<<GBN,256,0,stream>>>(Rk,idxP,A);
    k_gcdf<<<1,64,0,stream>>>(A,F);
    for(int b=0;b<NB;b++){
      k_histh<<<GN,256,0,stream>>>(Rk+(size_t)b*NPIX, idxP+(size_t)b*NPIX, bufA);
      k_gldv<<<GN,256,0,stream>>>(bufA,BSrk,F,b,tmpG);
    }
    run_sel(sbC,H,F,stream);
    k_gamma<<<GBN,256,0,stream>>>(tmpL,tmpG,Rk,F,gamma,k==0?1:0);
  }

  k_es_red<<<NB*RB,256,0,stream>>>(E,S,F,A);
  k_es_inv<<<1,1,0,stream>>>(A,F);
  k_lanom<<<GBN,256,0,stream>>>(E,S,DM,gamma,F,tA);

  SelBatch sbL; sbL.nt=8; sbL.medmad=0;
  {
    int rr[4]={1474,1475,145980,145981};
    for(int b=0;b<NB;b++) for(int ri=0;ri<4;ri++){
      int t=b*4+ri;
      sbL.src[t]=tA+(size_t)b*NPIX; sbL.rank[t]=rr[ri]; sbL.fslot[t]=F_LAQ+b*4+ri;
    }
  }
  run_sel(sbL,H,F,stream);

  k_la_q<<<1,1,0,stream>>>(F);
  k_out2<<<GBN,256,0,stream>>>(tA,F,out);
}

// Round 3
// 1529.592 us; speedup vs baseline: 2.4441x; 1.2007x over previous
//
#include <hip/hip_runtime.h>
#include <math.h>

#define HH 384
#define WW 384
#define NPIX (HH*WW)          // 147456
#define NB 2
#define BN (NB*NPIX)          // 294912
#define NT 128
#define NBINS 32
#define MEDRANK ((NPIX-1)/2)  // 73727
#define RB 72                 // reduction blocks per batch
#define SEL_BLK 64            // blocks per select task per pass

// ---- double arena (ws+0, 512 doubles) ----
#define A_BETA 0    // 10
#define A_XZ   16   // 18
#define A_ES   40   // 10
#define A_DK   56   // 40
#define A_GMM  96   // 9 iters * 12 = 108 -> 96..203
#define A_GHIST 208 // (k*NB+b)*32+bin -> 128 -> 208..335

// ---- float arena (ws+8192, 4096 floats) ----
#define F_BETA 0
#define F_X3   8    // (b*3+ch)*2 {med,mad}; ch1=E ch2=S also serve ES stage
#define F_MEAN 24
#define F_WWH  32
#define F_ASTAR 828
#define F_ZBQ  868
#define F_DKINV 880
#define F_LLA  918
#define F_GLD  924
#define F_MM   928  // uint slots: min 928+b, max 930+b
#define F_LAQ  952
#define F_GCDF 968  // (k*NB+b)*32+bin -> 968..1095
#define F_KABS 1100 // b*128+t -> 1100..1355

// ---- ticket / sel-meta arena T (u32, ws+24576, 256 u32) ----
// T[0..15]  : fused-reduction tickets (0=beta,1=xz,2=ralpha,3=dk,4=es)
// T[16..79] : sel pass counters: task*8 + stage*4 + pass
// T[80..143]: sel meta: task*8 + {pre0,rank0,pre1,rank1,center}

// ---------------- device helpers ----------------
__device__ __forceinline__ double waveSum(double v){
#pragma unroll
  for(int o=32;o;o>>=1) v += __shfl_down(v,o,64);
  return v;
}
__device__ __forceinline__ unsigned f2u(float f){
  unsigned u = __float_as_uint(f);
  return (u & 0x80000000u) ? ~u : (u | 0x80000000u);
}
__device__ __forceinline__ float u2f(unsigned u){
  return __uint_as_float((u & 0x80000000u) ? (u ^ 0x80000000u) : ~u);
}
__device__ __forceinline__ float sp(float x){
  float t = log1pf(expf(-fabsf(x)));
  return x >= 0.f ? x + t : t;
}

struct SelBatch {
  const float* src[8];
  int rank[8];
  int fslot[8];
  int nt;
  int medmad;
};

// block-parallel: find bin containing rank in 256-bin hist (blockDim.x==256)
__device__ void pick256(const unsigned* hp, int rank, unsigned& sel, int& nrank){
  __shared__ unsigned s_cum[256];
  __shared__ unsigned s_res[2];
  int tid = threadIdx.x;
  unsigned x = hp[tid];
  s_cum[tid] = x;
  __syncthreads();
  for(int o=1;o<256;o<<=1){
    unsigned t = (tid>=o)? s_cum[tid-o] : 0u;
    __syncthreads();
    s_cum[tid] += t;
    __syncthreads();
  }
  unsigned cum = s_cum[tid];
  unsigned ex  = cum - x;
  if(x>0u && (unsigned)rank>=ex && (unsigned)rank<cum){
    s_res[0]=(unsigned)tid; s_res[1]=(unsigned)(rank-(int)ex);
  }
  __syncthreads();
  sel = s_res[0]; nrank = (int)s_res[1];
  __syncthreads();
}

// zero arenas
__global__ void k_zero(double* A, float* F, unsigned* T){
  int i = blockIdx.x*blockDim.x + threadIdx.x;
  if(i < 512) A[i] = 0.0;
  if(i < 4096){
    unsigned* U = (unsigned*)F;
    unsigned v = 0u;
    if(i==F_MM || i==F_MM+1) v = 0xFFFFFFFFu;
    U[i] = v;
  }
  if(i < 16) T[i] = 0u;
}

__global__ void k_selz(SelBatch sb, unsigned* Hh, unsigned* T){
  int i = blockIdx.x*256 + threadIdx.x;
  if(i < 16384) Hh[i]=0u;
  if(i < 64) T[16+i]=0u;
  if(i < 8 && i < sb.nt){
    unsigned* m = T + 80 + i*8;
    m[0]=0u; m[1]=(unsigned)sb.rank[i];
    m[2]=0u; m[3]=(unsigned)sb.rank[i];
    m[4]=0u;
  }
}

// one streaming pass; last block locates the selected bin and advances meta
__global__ __launch_bounds__(256) void k_selp(SelBatch sb, unsigned* Hh, unsigned* T,
                                              float* F, int stage, int pass){
  int task = blockIdx.x / SEL_BLK;
  int blk  = blockIdx.x % SEL_BLK;
  unsigned* meta = T + 80 + task*8;
  float center = (stage==1) ? __uint_as_float(meta[4]) : 0.f;
  unsigned prefix = meta[stage*2];
  unsigned himask = (pass==3)?0u:(0xFFFFFFFFu<<((pass+1)*8));
  __shared__ unsigned lh[256];
  lh[threadIdx.x]=0u; __syncthreads();
  const float* src = sb.src[task];
  for(int i=blk*256+threadIdx.x; i<NPIX; i+=SEL_BLK*256){
    float v = src[i];
    if(stage) v = fabsf(v-center);
    unsigned u = f2u(v);
    if((u&himask)==prefix) atomicAdd(&lh[(u>>(pass*8))&255u],1u);
  }
  __syncthreads();
  unsigned c = lh[threadIdx.x];
  unsigned* hp = Hh + task*2048 + stage*1024 + pass*256;
  if(c) atomicAdd(hp+threadIdx.x, c);
  __shared__ int s_last;
  __syncthreads();
  if(threadIdx.x==0){
    __threadfence();
    s_last = (atomicAdd(&T[16+task*8+stage*4+pass],1u) == (unsigned)(SEL_BLK-1));
  }
  __syncthreads();
  if(!s_last) return;
  int r = (int)meta[stage*2+1];
  unsigned sel; int nr;
  pick256(hp, r, sel, nr);
  unsigned npref = prefix | (sel<<(pass*8));
  if(threadIdx.x==0){
    if(pass>0){ meta[stage*2]=npref; meta[stage*2+1]=(unsigned)nr; }
    else {
      float val = u2f(npref);
      if(stage==0){
        if(sb.medmad) meta[4]=__float_as_uint(val);
        else F[sb.fslot[task]] = val;
      } else {
        F[sb.fslot[task]]   = __uint_as_float(meta[4]);
        F[sb.fslot[task]+1] = val*1.4826f + 1e-8f;
      }
    }
  }
}

// GMM params after `it` updates (it==0 -> init from zb quantiles)
__device__ void derive_params(const float* F, const double* A, int it, int b,
                              double& mu0,double& mu1,double& iv0h,double& iv1h,
                              double& c0,double& c1){
  if(it==0){
    const float* z = F + F_ZBQ + b*4;
    double h25 = 0.25*(double)(NPIX-1); double f25 = h25 - floor(h25);
    double h75 = 0.75*(double)(NPIX-1); double f75 = h75 - floor(h75);
    mu0 = (double)z[0] + f25*((double)z[1]-(double)z[0]);
    mu1 = (double)z[2] + f75*((double)z[3]-(double)z[2]);
    double v0=1.0, v1=1.0, p0=0.5, p1=0.5;
    c0=-0.5*log(v0+1e-6)+log(p0+1e-8);
    c1=-0.5*log(v1+1e-6)+log(p1+1e-8);
    iv0h=0.5/(v0+1e-6); iv1h=0.5/(v1+1e-6);
  } else {
    const double* g = A + A_GMM + (it-1)*12 + b*6;
    double N0=g[0],N1=g[1];
    mu0=g[2]/(N0+1e-8); mu1=g[3]/(N1+1e-8);
    double v0=(g[4]-2.0*mu0*g[2]+mu0*mu0*N0)/(N0+1e-8)+1e-6;
    double v1=(g[5]-2.0*mu1*g[3]+mu1*mu1*N1)/(N1+1e-8)+1e-6;
    double p0=N0/(double)NPIX, p1=N1/(double)NPIX;
    c0=-0.5*log(v0+1e-6)+log(p0+1e-8);
    c1=-0.5*log(v1+1e-6)+log(p1+1e-8);
    iv0h=0.5/(v0+1e-6); iv1h=0.5/(v1+1e-6);
  }
}
__device__ __forceinline__ void estep2f(float x,float mu0,float mu1,float iv0h,float iv1h,
                                        float c0,float c1,float& r0,float& r1){
  float d0=x-mu0, d1=x-mu1;
  float l0=-d0*d0*iv0h+c0, l1=-d1*d1*iv1h+c1;
  float m=fmaxf(l0,l1);
  float e0=expf(l0-m), e1=expf(l1-m);
  float s=e0+e1;
  r0=e0/s; r1=e1/s;
}

// ---------------- main pipeline kernels ----------------
__global__ void k_prep(const float* lab, float* S, float* G2){
  int i = blockIdx.x*256 + threadIdx.x; if(i>=BN) return;
  int b=i/NPIX, n=i%NPIX, y=n/WW, x=n%WW;
  const float* Lb = lab + b*3*NPIX;
  float av = Lb[NPIX+n], bv = Lb[2*NPIX+n];
  S[i] = sqrtf(av*av + bv*bv + 1e-8f);
  auto l = [&](int yy,int xx)->float{
    return (yy<0||yy>=HH||xx<0||xx>=WW)?0.f:Lb[yy*WW+xx]; };
  float gx = -l(y-1,x-1)+l(y-1,x+1) -2.f*l(y,x-1)+2.f*l(y,x+1) -l(y+1,x-1)+l(y+1,x+1);
  float gy = -l(y-1,x-1)-2.f*l(y-1,x)-l(y-1,x+1) +l(y+1,x-1)+2.f*l(y+1,x)+l(y+1,x+1);
  G2[i] = gx*gx + gy*gy;
}
__global__ void k_box3h(const float* in, float* out){
  int i = blockIdx.x*256 + threadIdx.x; if(i>=BN) return;
  int x = (i%NPIX)%WW;
  float s = in[i];
  if(x>0) s += in[i-1];
  if(x<WW-1) s += in[i+1];
  out[i]=s;
}
__global__ void k_box3v(const float* in, float* out){
  int i = blockIdx.x*256 + threadIdx.x; if(i>=BN) return;
  int y = (i%NPIX)/WW;
  float s = in[i];
  if(y>0) s += in[i-WW];
  if(y<HH-1) s += in[i+WW];
  out[i]=s*(1.f/9.f);
}

// beta reduction + fused 2x2 solve in last block
__global__ void k_beta_red(const float* E,const float* S,const float* lab,double* A,
                           float* F, unsigned* T){
  int b = blockIdx.x / RB, blk = blockIdx.x % RB;
  double s[5]={0,0,0,0,0};
  for(int n = blk*256 + threadIdx.x; n < NPIX; n += RB*256){
    float e=E[b*NPIX+n], ss=S[b*NPIX+n], l=lab[b*3*NPIX+n];
    s[0]+=(double)e*e; s[1]+=(double)e*ss; s[2]+=(double)ss*ss;
    s[3]+=(double)e*l; s[4]+=(double)ss*l;
  }
#pragma unroll
  for(int q=0;q<5;q++){
    double v = waveSum(s[q]);
    if((threadIdx.x&63)==0) atomicAdd(&A[A_BETA+b*5+q], v);
  }
  __shared__ int s_last;
  __syncthreads();
  if(threadIdx.x==0){
    __threadfence();
    s_last = (atomicAdd(&T[0],1u) == (unsigned)(NB*RB-1));
  }
  __syncthreads();
  if(!s_last || threadIdx.x) return;
  for(int bb=0;bb<NB;bb++){
    double EE=A[A_BETA+bb*5],ES=A[A_BETA+bb*5+1],SS=A[A_BETA+bb*5+2],EL=A[A_BETA+bb*5+3],SL=A[A_BETA+bb*5+4];
    double a00=EE+1e-6, a01=ES, a11=SS+1e-6;
    double det=a00*a11-a01*a01;
    F[F_BETA+bb*2]  =(float)(( a11*EL - a01*SL)/det);
    F[F_BETA+bb*2+1]=(float)((-a01*EL + a00*SL)/det);
  }
}

// L_perp + fused global min/max
__global__ void k_lperp(const float* lab,const float* E,const float* S,const float* F,float* out0){
  int i = blockIdx.x*256 + threadIdx.x; if(i>=BN) return;
  int b=i/NPIX, n=i%NPIX;
  float v = lab[b*3*NPIX+n] - F[F_BETA+b*2]*E[i] - F[F_BETA+b*2+1]*S[i];
  out0[i] = v;
  unsigned u = f2u(v);
  unsigned mn=u, mx=u;
#pragma unroll
  for(int o=32;o;o>>=1){
    unsigned a = __shfl_down(mn,o,64); mn = (a<mn)?a:mn;
    unsigned c = __shfl_down(mx,o,64); mx = (c>mx)?c:mx;
  }
  unsigned* U = (unsigned*)F;
  if((threadIdx.x&63)==0){ atomicMin(&U[F_MM+b], mn); atomicMax(&U[F_MM+2+b], mx); }
}

// z-score cov reduction + fused 3x3 Jacobi eigh in last block
__global__ void k_xz_red(const float* Lp,const float* E,const float* S,float* F,double* A,
                         unsigned* T){
  int b = blockIdx.x / RB, blk = blockIdx.x % RB;
  const float* M = F + F_X3 + b*6;
  double s[9]={0,0,0,0,0,0,0,0,0};
  for(int n = blk*256 + threadIdx.x; n < NPIX; n += RB*256){
    float z0=(Lp[b*NPIX+n]-M[0])/M[1];
    float z1=(E [b*NPIX+n]-M[2])/M[3];
    float z2=(S [b*NPIX+n]-M[4])/M[5];
    s[0]+=z0; s[1]+=z1; s[2]+=z2;
    s[3]+=(double)z0*z0; s[4]+=(double)z0*z1; s[5]+=(double)z0*z2;
    s[6]+=(double)z1*z1; s[7]+=(double)z1*z2; s[8]+=(double)z2*z2;
  }
#pragma unroll
  for(int q=0;q<9;q++){
    double v = waveSum(s[q]);
    if((threadIdx.x&63)==0) atomicAdd(&A[A_XZ+b*9+q], v);
  }
  __shared__ int s_last;
  __syncthreads();
  if(threadIdx.x==0){
    __threadfence();
    s_last = (atomicAdd(&T[1],1u) == (unsigned)(NB*RB-1));
  }
  __syncthreads();
  if(!s_last) return;
  int bb = threadIdx.x;
  if(bb>=NB) return;
  const double* ss = A + A_XZ + bb*9;
  double inv = 1.0/(double)NPIX;
  double m0=ss[0]*inv, m1=ss[1]*inv, m2=ss[2]*inv;
  double a[3][3];
  a[0][0]=fmax(ss[3]*inv-m0*m0,1e-8);
  a[0][1]=a[1][0]=fmax(ss[4]*inv-m0*m1,1e-8);
  a[0][2]=a[2][0]=fmax(ss[5]*inv-m0*m2,1e-8);
  a[1][1]=fmax(ss[6]*inv-m1*m1,1e-8);
  a[1][2]=a[2][1]=fmax(ss[7]*inv-m1*m2,1e-8);
  a[2][2]=fmax(ss[8]*inv-m2*m2,1e-8);
  double V[3][3]={{1,0,0},{0,1,0},{0,0,1}};
  for(int sweep=0;sweep<40;sweep++){
    for(int pp=0;pp<3;pp++){
      int p = (pp==2)?1:0;
      int q = (pp==0)?1:2;
      double apq=a[p][q];
      if(fabs(apq)<1e-30) continue;
      double theta=(a[q][q]-a[p][p])/(2.0*apq);
      double t=((theta>=0)?1.0:-1.0)/(fabs(theta)+sqrt(1.0+theta*theta));
      double c=1.0/sqrt(1.0+t*t), sn=t*c;
      for(int k2=0;k2<3;k2++){ double akp=a[k2][p],akq=a[k2][q];
        a[k2][p]=c*akp-sn*akq; a[k2][q]=sn*akp+c*akq; }
      for(int k2=0;k2<3;k2++){ double apk=a[p][k2],aqk=a[q][k2];
        a[p][k2]=c*apk-sn*aqk; a[q][k2]=sn*apk+c*aqk; }
      for(int k2=0;k2<3;k2++){ double vkp=V[k2][p],vkq=V[k2][q];
        V[k2][p]=c*vkp-sn*vkq; V[k2][q]=sn*vkp+c*vkq; }
    }
  }
  double is0=1.0/sqrt(a[0][0]), is1=1.0/sqrt(a[1][1]), is2=1.0/sqrt(a[2][2]);
  for(int i=0;i<3;i++) for(int j=0;j<3;j++){
    double w = V[i][0]*is0*V[j][0] + V[i][1]*is1*V[j][1] + V[i][2]*is2*V[j][2];
    F[F_WWH + bb*9 + i*3 + j] = (float)w;
  }
  F[F_MEAN+bb*3]=(float)m0; F[F_MEAN+bb*3+1]=(float)m1; F[F_MEAN+bb*3+2]=(float)m2;
}

// whiten + fused bin-index computation
__global__ void k_xw(const float* Lp,const float* E,const float* S,const float* F,
                     float* Xw0,float* Xw1,float* Xw2,int* idxP){
  int i = blockIdx.x*256 + threadIdx.x; if(i>=BN) return;
  int b=i/NPIX;
  const float* M = F + F_X3 + b*6;
  float lp = Lp[i];
  float z0=(lp-M[0])/M[1];
  float z1=(E [i]-M[2])/M[3];
  float z2=(S [i]-M[4])/M[5];
  float d0=z0-F[F_MEAN+b*3], d1=z1-F[F_MEAN+b*3+1], d2=z2-F[F_MEAN+b*3+2];
  const float* Wm = F + F_WWH + b*9;
  Xw0[i]=d0*Wm[0]+d1*Wm[3]+d2*Wm[6];
  Xw1[i]=d0*Wm[1]+d1*Wm[4]+d2*Wm[7];
  Xw2[i]=d0*Wm[2]+d1*Wm[5]+d2*Wm[8];
  const unsigned* U = (const unsigned*)F;
  float mn=u2f(U[F_MM+b]), mx=u2f(U[F_MM+2+b]);
  float ln = (lp-mn)/(mx-mn+1e-8f);
  ln = fminf(fmaxf(ln,0.f),1.f);
  int id = (int)(ln*32.f);
  idxP[i] = id>31?31:(id<0?0:id);
}

// one block per (b,t): full moment sums + kurtosis
__global__ __launch_bounds__(256) void k_kurt(const float* Xw0,const float* Xw1,const float* Xw2,
                                              const float* arand, float* F){
  int b = blockIdx.x >> 7;
  int t = blockIdx.x & 127;
  const float* ar = arand + (b*NT+t)*3;
  float q0=ar[0], q1=ar[1], q2=ar[2];
  float nrm = (float)(sqrt((double)q0*q0+(double)q1*q1+(double)q2*q2)+1e-12);
  float a0=q0/nrm, a1=q1/nrm, a2=q2/nrm;
  const float* X0 = Xw0 + (size_t)b*NPIX;
  const float* X1 = Xw1 + (size_t)b*NPIX;
  const float* X2 = Xw2 + (size_t)b*NPIX;
  double s1=0,s2=0,s3=0,s4=0;
  for(int n=threadIdx.x;n<NPIX;n+=256){
    float z = X0[n]*a0 + X1[n]*a1 + X2[n]*a2;
    float z2f = z*z;
    s1 += z; s2 += z2f; s3 += z2f*z; s4 += (double)z2f*z2f;
  }
  s1=waveSum(s1); s2=waveSum(s2); s3=waveSum(s3); s4=waveSum(s4);
  __shared__ double red[4][4];
  int wave=threadIdx.x>>6, lane=threadIdx.x&63;
  if(lane==0){ red[wave][0]=s1; red[wave][1]=s2; red[wave][2]=s3; red[wave][3]=s4; }
  __syncthreads();
  if(threadIdx.x==0){
    double S1=0,S2=0,S3=0,S4=0;
    for(int w=0;w<4;w++){ S1+=red[w][0]; S2+=red[w][1]; S3+=red[w][2]; S4+=red[w][3]; }
    double inv=1.0/(double)NPIX;
    double mean=S1*inv, M2=S2*inv, M3=S3*inv, M4=S4*inv;
    double m2 = M2 - mean*mean + 1e-12;
    double m4 = M4 - 4.0*mean*M3 + 6.0*mean*mean*M2 - 3.0*mean*mean*mean*mean;
    double kurt = m4/(m2*m2) - 3.0;
    F[F_KABS + b*NT + t] = (float)fabs(kurt);
  }
}
__global__ void k_kurt_pick(const float* arand, float* F){
  int b = blockIdx.x;
  if(threadIdx.x) return;
  int best=0; float bv=F[F_KABS+b*NT];
  for(int j=1;j<NT;j++){ float v=F[F_KABS+b*NT+j]; if(v>bv){bv=v;best=j;} }
  const float* ar = arand + (b*NT+best)*3;
  double nrm = sqrt((double)ar[0]*ar[0]+(double)ar[1]*ar[1]+(double)ar[2]*ar[2])+1e-12;
  F[F_ASTAR+b*3]  =(float)(ar[0]/nrm);
  F[F_ASTAR+b*3+1]=(float)(ar[1]/nrm);
  F[F_ASTAR+b*3+2]=(float)(ar[2]/nrm);
}
__global__ void k_zbest(const float* Xw0,const float* Xw1,const float* Xw2,const float* F,float* zb){
  int i = blockIdx.x*256 + threadIdx.x; if(i>=BN) return;
  int b=i/NPIX;
  zb[i] = Xw0[i]*F[F_ASTAR+b*3] + Xw1[i]*F[F_ASTAR+b*3+1] + Xw2[i]*F[F_ASTAR+b*3+2];
}

__global__ void k_gmm_red(const float* zb, const float* F, double* A, int it){
  int b = blockIdx.x / RB, blk = blockIdx.x % RB;
  double mu0,mu1,iv0h,iv1h,c0,c1;
  derive_params(F,A,it,b,mu0,mu1,iv0h,iv1h,c0,c1);
  float fmu0=(float)mu0, fmu1=(float)mu1, fiv0=(float)iv0h, fiv1=(float)iv1h;
  float fc0=(float)c0, fc1=(float)c1;
  double s[6]={0,0,0,0,0,0};
  for(int n = blk*256 + threadIdx.x; n < NPIX; n += RB*256){
    float x = zb[b*NPIX+n];
    float r0,r1; estep2f(x,fmu0,fmu1,fiv0,fiv1,fc0,fc1,r0,r1);
    s[0]+=r0; s[1]+=r1; s[2]+=r0*x; s[3]+=r1*x; s[4]+=(double)(r0*x)*x; s[5]+=(double)(r1*x)*x;
  }
#pragma unroll
  for(int q=0;q<6;q++){
    double v = waveSum(s[q]);
    if((threadIdx.x&63)==0) atomicAdd(&A[A_GMM+it*12+b*6+q], v);
  }
}

// final E-step -> R^alpha, fused global hist (both k) + fused cdf in last block
__global__ void k_ralpha(const float* zb, float* F, double* A, const int* idxP,
                         float* Ra0, float* Ra1, unsigned* T){
  __shared__ float h0[NBINS], h1[NBINS];
  if(threadIdx.x<NBINS){ h0[threadIdx.x]=0.f; h1[threadIdx.x]=0.f; }
  __syncthreads();
  int i = blockIdx.x*256 + threadIdx.x;
  int b=i/NPIX;
  double mu0,mu1,iv0h,iv1h,c0,c1;
  derive_params(F,A,9,b,mu0,mu1,iv0h,iv1h,c0,c1);
  float r0,r1; estep2f(zb[i],(float)mu0,(float)mu1,(float)iv0h,(float)iv1h,(float)c0,(float)c1,r0,r1);
  float ra0=powf(r0,0.9f), ra1=powf(r1,0.9f);
  float s=ra0+ra1+1e-8f;
  ra0/=s; ra1/=s;
  Ra0[i]=ra0; Ra1[i]=ra1;
  int id = idxP[i];
  atomicAdd(&h0[id], ra0);
  atomicAdd(&h1[id], ra1);
  __syncthreads();
  if(threadIdx.x<NBINS){
    if(h0[threadIdx.x]!=0.f) atomicAdd(&A[A_GHIST+(0*NB+b)*32+threadIdx.x], (double)h0[threadIdx.x]);
    if(h1[threadIdx.x]!=0.f) atomicAdd(&A[A_GHIST+(1*NB+b)*32+threadIdx.x], (double)h1[threadIdx.x]);
  }
  __shared__ int s_last;
  __syncthreads();
  if(threadIdx.x==0){
    __threadfence();
    s_last = (atomicAdd(&T[2],1u) == (unsigned)(BN/256-1));
  }
  __syncthreads();
  if(!s_last) return;
  int t = threadIdx.x;
  if(t>=4) return;
  const double* g = A + A_GHIST + t*32;
  double sum=0;
  for(int j=0;j<NBINS;j++) sum += g[j];
  double c=0;
  for(int j=0;j<NBINS;j++){
    c += g[j]/(sum+1e-8);
    F[F_GCDF+t*32+j]=(float)c;
  }
}

// per-component weighted covariance + fused 3x3 inverse in last block
__global__ void k_dk_red(const float* Lp,const float* E,const float* S,
                         const float* Ra0,const float* Ra1,double* A,float* F,unsigned* T){
  int b = blockIdx.x / RB, blk = blockIdx.x % RB;
  double s[20];
#pragma unroll
  for(int q=0;q<20;q++) s[q]=0;
  for(int n = blk*256 + threadIdx.x; n < NPIX; n += RB*256){
    int i=b*NPIX+n;
    double w0=Ra0[i], w1=Ra1[i];
    double x0=Lp[i], x1=E[i], x2=S[i];
    s[0]+=w0; s[1]+=w0*x0; s[2]+=w0*x1; s[3]+=w0*x2;
    s[4]+=w0*x0*x0; s[5]+=w0*x0*x1; s[6]+=w0*x0*x2; s[7]+=w0*x1*x1; s[8]+=w0*x1*x2; s[9]+=w0*x2*x2;
    s[10]+=w1; s[11]+=w1*x0; s[12]+=w1*x1; s[13]+=w1*x2;
    s[14]+=w1*x0*x0; s[15]+=w1*x0*x1; s[16]+=w1*x0*x2; s[17]+=w1*x1*x1; s[18]+=w1*x1*x2; s[19]+=w1*x2*x2;
  }
#pragma unroll
  for(int q=0;q<20;q++){
    double v = waveSum(s[q]);
    if((threadIdx.x&63)==0) atomicAdd(&A[A_DK+b*20+q], v);
  }
  __shared__ int s_last;
  __syncthreads();
  if(threadIdx.x==0){
    __threadfence();
    s_last = (atomicAdd(&T[3],1u) == (unsigned)(NB*RB-1));
  }
  __syncthreads();
  if(!s_last || threadIdx.x) return;
  for(int bb=0;bb<NB;bb++) for(int k=0;k<2;k++){
    const double* ss = A + A_DK + (bb*2+k)*10;
    double W0=ss[0], Ws=W0+1e-8;
    double mu0=ss[1]/Ws, mu1=ss[2]/Ws, mu2=ss[3]/Ws;
    double C00=(ss[4]-2.0*mu0*ss[1]+mu0*mu0*W0)/Ws + 1e-6;
    double C01=(ss[5]-mu0*ss[2]-mu1*ss[1]+mu0*mu1*W0)/Ws;
    double C02=(ss[6]-mu0*ss[3]-mu2*ss[1]+mu0*mu2*W0)/Ws;
    double C11=(ss[7]-2.0*mu1*ss[2]+mu1*mu1*W0)/Ws + 1e-6;
    double C12=(ss[8]-mu1*ss[3]-mu2*ss[2]+mu1*mu2*W0)/Ws;
    double C22=(ss[9]-2.0*mu2*ss[3]+mu2*mu2*W0)/Ws + 1e-6;
    double det = C00*(C11*C22-C12*C12) - C01*(C01*C22-C12*C02) + C02*(C01*C12-C11*C02);
    double id = 1.0/det;
    float* P = F + F_DKINV + (bb*2+k)*9;
    P[0]=(float)((C11*C22-C12*C12)*id);
    P[1]=(float)((C02*C12-C01*C22)*id);
    P[2]=(float)((C01*C12-C02*C11)*id);
    P[3]=(float)((C00*C22-C02*C02)*id);
    P[4]=(float)((C01*C02-C00*C12)*id);
    P[5]=(float)((C00*C11-C01*C01)*id);
    P[6]=(float)mu0; P[7]=(float)mu1; P[8]=(float)mu2;
  }
}
__global__ void k_dm(const float* Lp,const float* E,const float* S,
                     const float* Ra0,const float* Ra1,const float* F,float* DM){
  int i = blockIdx.x*256 + threadIdx.x; if(i>=BN) return;
  int b=i/NPIX;
  float x0=Lp[i], x1=E[i], x2=S[i];
  float D[2];
#pragma unroll
  for(int k=0;k<2;k++){
    const float* P = F + F_DKINV + (b*2+k)*9;
    float d0=x0-P[6], d1=x1-P[7], d2=x2-P[8];
    float q = d0*d0*P[0] + d1*d1*P[3] + d2*d2*P[5]
            + 2.f*(d0*d1*P[1] + d0*d2*P[2] + d1*d2*P[4]);
    D[k]=sqrtf(q+1e-8f);
  }
  float w0=Ra0[i]+1e-8f, w1=Ra1[i]+1e-8f;
  DM[i] = (w0*D[0]+w1*D[1])/(w0+w1);
}

__global__ void k_lla_boxh(const float* rk,const float* Lp,float* tA,float* tB,float* tC){
  int i = blockIdx.x*256 + threadIdx.x; if(i>=BN) return;
  int n=i%NPIX, x=n%WW;
  int x0 = x-7<0?0:x-7, x1 = x+7>WW-1?WW-1:x+7;
  float s0=0,s1=0,s2=0;
  for(int xx=x0;xx<=x1;xx++){
    int j = i - x + xx;
    float r=rk[j], l=Lp[j];
    s0+=r; s1+=r*l; s2+=r*l*l;
  }
  tA[i]=s0; tB[i]=s1; tC[i]=s2;
}
__global__ void k_lla_boxv(const float* tA,const float* tB,const float* tC,const float* Lp,
                           float* tmpL,float* BSrk){
  int i = blockIdx.x*256 + threadIdx.x; if(i>=BN) return;
  int n=i%NPIX, y=n/WW, x=n%WW;
  int y0 = y-7<0?0:y-7, y1 = y+7>HH-1?HH-1:y+7;
  float S0=0,S1=0,S2=0;
  for(int yy=y0;yy<=y1;yy++){
    int j = i + (yy-y)*WW;
    S0+=tA[j]; S1+=tB[j]; S2+=tC[j];
  }
  float cy = (float)((y+8<HH?y+8:HH)-(y-7>0?y-7:0));
  float cx = (float)((x+8<WW?x+8:WW)-(x-7>0?x-7:0));
  float cnt = cy*cx;
  float den = S0/cnt + 1e-8f;
  float mu  = (S1/cnt)/den;
  float var = fmaxf((S2/cnt)/den - mu*mu, 1e-8f);
  tmpL[i] = fabsf(Lp[i]-mu)/(sqrtf(var)+1e-8f);
  BSrk[i] = S0;
}

__global__ __launch_bounds__(256) void k_histh(const float* rk_b,const int* idx_b,float* bufA){
  __shared__ float acc[256*33];
  int tid=threadIdx.x;
  float* my = acc + tid*33;
#pragma unroll
  for(int j=0;j<NBINS;j++) my[j]=0.f;
  int n = blockIdx.x*256+tid;
  int y=n/WW, x=n%WW;
  int x0 = x-7<0?0:x-7, x1 = x+7>WW-1?WW-1:x+7;
  for(int xx=x0;xx<=x1;xx++){
    int m = y*WW+xx;
    my[idx_b[m]] += rk_b[m];
  }
#pragma unroll
  for(int bin=0;bin<NBINS;bin++) bufA[bin*NPIX + n] = my[bin];
}
// vertical 15-tap box via sliding window: thread per (x,bin,seg)
__global__ void k_slidev(const float* bufA, float* bufB){
  int idx = blockIdx.x*256 + threadIdx.x;
  if(idx >= WW*NBINS*4) return;
  int x   = idx % WW;
  int bin = (idx/WW) % NBINS;
  int seg = idx/(WW*NBINS);
  int y0 = seg*96;
  const float* a = bufA + (size_t)bin*NPIX + x;
  float* o = bufB + (size_t)bin*NPIX + x;
  float s=0;
  int lo = y0-7; if(lo<0) lo=0;
  int hi = y0+7; if(hi>HH-1) hi=HH-1;
  for(int yy=lo; yy<=hi; ++yy) s += a[yy*WW];
  for(int y=y0; y<y0+96; ++y){
    o[y*WW] = s;
    int add=y+8, rem=y-7;
    if(add<HH) s += a[add*WW];
    if(rem>=0) s -= a[rem*WW];
  }
}
__global__ __launch_bounds__(256) void k_gld(const float* bufB,const float* BSrk,const float* F,
                                             int b,int k,float* tmpG){
  __shared__ float gc[NBINS];
  if(threadIdx.x<NBINS) gc[threadIdx.x]=F[F_GCDF+(k*NB+b)*32+threadIdx.x];
  __syncthreads();
  int n = blockIdx.x*256 + threadIdx.x;
  int y=n/WW, x=n%WW;
  float cy = (float)((y+8<HH?y+8:HH)-(y-7>0?y-7:0));
  float cx = (float)((x+8<WW?x+8:WW)-(x-7>0?x-7:0));
  float cnt = cy*cx;
  float den = BSrk[b*NPIX+n]/cnt + 1e-8f;
  float cs=0, acc=0;
  for(int bin=0;bin<NBINS;bin++){
    cs += bufB[(size_t)bin*NPIX+n];
    acc += fabsf((cs/cnt)/den - gc[bin]);
  }
  tmpG[b*NPIX+n] = acc*(1.f/32.f);
}
__global__ void k_gamma(const float* tmpL,const float* tmpG,const float* rk,const float* F,
                        float* gamma,int first){
  int i = blockIdx.x*256 + threadIdx.x; if(i>=BN) return;
  int b=i/NPIX;
  float zl=(tmpL[i]-F[F_LLA+b*2])/F[F_LLA+b*2+1];
  float zg=(tmpG[i]-F[F_GLD+b*2])/F[F_GLD+b*2+1];
  float c = rk[i]*(0.5f*sp(zl)+0.5f*sp(zg));
  gamma[i] = first ? 1.0f + c : gamma[i] + c;
}

// ES z-cov reduction + fused 2x2 inverse in last block
__global__ void k_es_red(const float* E,const float* S,float* F,double* A,unsigned* T){
  int b = blockIdx.x / RB, blk = blockIdx.x % RB;
  const float* M = F + F_X3 + b*6;
  double s[5]={0,0,0,0,0};
  for(int n = blk*256 + threadIdx.x; n < NPIX; n += RB*256){
    float z0=(E[b*NPIX+n]-M[2])/M[3];
    float z1=(S[b*NPIX+n]-M[4])/M[5];
    s[0]+=z0; s[1]+=z1; s[2]+=(double)z0*z0; s[3]+=(double)z0*z1; s[4]+=(double)z1*z1;
  }
#pragma unroll
  for(int q=0;q<5;q++){
    double v = waveSum(s[q]);
    if((threadIdx.x&63)==0) atomicAdd(&A[A_ES+b*5+q], v);
  }
  __shared__ int s_last;
  __syncthreads();
  if(threadIdx.x==0){
    __threadfence();
    s_last = (atomicAdd(&T[4],1u) == (unsigned)(NB*RB-1));
  }
  __syncthreads();
  if(!s_last || threadIdx.x) return;
  for(int bb=0;bb<NB;bb++){
    const double* ss = A + A_ES + bb*5;
    double inv=1.0/(double)NPIX;
    double m0=ss[0]*inv, m1=ss[1]*inv;
    double c00=ss[2]*inv - m0*m0 + 1e-6;
    double c01=ss[3]*inv - m0*m1;
    double c11=ss[4]*inv - m1*m1 + 1e-6;
    double det=c00*c11-c01*c01;
    float* P = F + 940 + bb*5;
    P[0]=(float)m0; P[1]=(float)m1;
    P[2]=(float)(c11/det); P[3]=(float)(-c01/det); P[4]=(float)(c00/det);
  }
}
__global__ void k_lanom(const float* E,const float* S,const float* DM,const float* gamma,
                        const float* F,float* La){
  int i = blockIdx.x*256 + threadIdx.x; if(i>=BN) return;
  int b=i/NPIX;
  const float* M = F + F_X3 + b*6;
  const float* P = F + 940 + b*5;
  float z0=(E[i]-M[2])/M[3];
  float z1=(S[i]-M[4])/M[5];
  float d0=z0-P[0], d1=z1-P[1];
  float d2 = d0*d0*P[2] + 2.f*d0*d1*P[3] + d1*d1*P[4];
  float Rs = expf(-0.5f*d2);
  La[i] = fmaxf(DM[i]*gamma[i]*(1.f-Rs), 0.f);
}
__global__ void k_out2(const float* La, const float* F, float* out){
  int i = blockIdx.x*256 + threadIdx.x; if(i>=BN) return;
  int b=i/NPIX;
  const float* v = F + F_LAQ + b*4;
  double h1 = 0.01*(double)(NPIX-1); double f1 = h1 - floor(h1);
  double h9 = 0.99*(double)(NPIX-1); double f9 = h9 - floor(h9);
  float q1 = (float)((double)v[0] + f1*((double)v[1]-(double)v[0]));
  float q9 = (float)((double)v[2] + f9*((double)v[3]-(double)v[2]));
  float r = (La[i]-q1)/(q9-q1+1e-8f);
  out[BN + i] = fminf(fmaxf(r,0.f),1.f);
}

// ---------------- host ----------------
static void run_sel(const SelBatch& sb, unsigned* H, unsigned* T, float* F, hipStream_t s){
  k_selz<<<64,256,0,s>>>(sb,H,T);
  for(int p=3;p>=0;--p) k_selp<<<sb.nt*SEL_BLK,256,0,s>>>(sb,H,T,F,0,p);
  if(sb.medmad) for(int p=3;p>=0;--p) k_selp<<<sb.nt*SEL_BLK,256,0,s>>>(sb,H,T,F,1,p);
}

extern "C" void kernel_launch(void* const* d_in, const int* in_sizes, int n_in,
                              void* d_out, int out_size, void* d_ws, size_t ws_size,
                              hipStream_t stream){
  (void)in_sizes; (void)n_in; (void)out_size; (void)ws_size;
  const float* lab   = (const float*)d_in[0];
  const float* arand = (const float*)d_in[1];
  float* out = (float*)d_out;
  char* wsb = (char*)d_ws;
  double* A = (double*)wsb;                   // 512 doubles
  float*  F = (float*)(wsb + 8192);           // 4096 floats
  unsigned* T = (unsigned*)(wsb + 24576);     // 256 u32
  unsigned* H = (unsigned*)(wsb + 32768);     // 16384 u32 sel hists
  float* planes = (float*)(wsb + 131072);
  float* E    = planes;
  float* S    = planes + (size_t)BN;
  float* tA   = planes + (size_t)2*BN;
  float* tB   = planes + (size_t)3*BN;
  float* tC   = planes + (size_t)4*BN;
  float* tmpL = planes + (size_t)5*BN;
  float* tmpG = planes + (size_t)6*BN;
  float* Xw0  = planes + (size_t)7*BN;
  float* Xw1  = planes + (size_t)8*BN;
  float* Xw2  = planes + (size_t)9*BN;
  float* zb   = planes + (size_t)10*BN;
  float* Ra0  = planes + (size_t)11*BN;
  float* Ra1  = planes + (size_t)12*BN;
  float* DM   = planes + (size_t)13*BN;
  float* gamma= planes + (size_t)14*BN;
  float* BSrk = planes + (size_t)15*BN;
  int*   idxP = (int*)(planes + (size_t)16*BN);
  float* bufA = planes + (size_t)17*BN;
  float* bufB = bufA + (size_t)NBINS*NPIX;

  const int GBN = BN/256;      // 1152
  const int GN  = NPIX/256;    // 576

  k_zero<<<16,256,0,stream>>>(A,F,T);
  k_prep<<<GBN,256,0,stream>>>(lab,S,tA);
  k_box3h<<<GBN,256,0,stream>>>(tA,tB);
  k_box3v<<<GBN,256,0,stream>>>(tB,E);
  k_beta_red<<<NB*RB,256,0,stream>>>(E,S,lab,A,F,T);
  k_lperp<<<GBN,256,0,stream>>>(lab,E,S,F,out);

  SelBatch sbX; sbX.nt=6; sbX.medmad=1;
  for(int b=0;b<NB;b++){
    sbX.src[b*3+0]=out+(size_t)b*NPIX; sbX.src[b*3+1]=E+(size_t)b*NPIX; sbX.src[b*3+2]=S+(size_t)b*NPIX;
    for(int ch=0;ch<3;ch++){ sbX.rank[b*3+ch]=MEDRANK; sbX.fslot[b*3+ch]=F_X3+(b*3+ch)*2; }
  }
  run_sel(sbX,H,T,F,stream);

  k_xz_red<<<NB*RB,256,0,stream>>>(out,E,S,F,A,T);
  k_xw<<<GBN,256,0,stream>>>(out,E,S,F,Xw0,Xw1,Xw2,idxP);
  k_kurt<<<NB*NT,256,0,stream>>>(Xw0,Xw1,Xw2,arand,F);
  k_kurt_pick<<<NB,64,0,stream>>>(arand,F);
  k_zbest<<<GBN,256,0,stream>>>(Xw0,Xw1,Xw2,F,zb);

  SelBatch sbZ; sbZ.nt=8; sbZ.medmad=0;
  {
    int rr[4]={36863,36864,110591,110592};
    for(int b=0;b<NB;b++) for(int ri=0;ri<4;ri++){
      int t=b*4+ri;
      sbZ.src[t]=zb+(size_t)b*NPIX; sbZ.rank[t]=rr[ri]; sbZ.fslot[t]=F_ZBQ+b*4+ri;
    }
  }
  run_sel(sbZ,H,T,F,stream);

  for(int it=0; it<9; ++it)
    k_gmm_red<<<NB*RB,256,0,stream>>>(zb,F,A,it);
  k_ralpha<<<GBN,256,0,stream>>>(zb,F,A,idxP,Ra0,Ra1,T);
  k_dk_red<<<NB*RB,256,0,stream>>>(out,E,S,Ra0,Ra1,A,F,T);
  k_dm<<<GBN,256,0,stream>>>(out,E,S,Ra0,Ra1,F,DM);

  SelBatch sbC; sbC.nt=4; sbC.medmad=1;
  for(int b=0;b<NB;b++){
    sbC.src[b]  =tmpL+(size_t)b*NPIX; sbC.rank[b]  =MEDRANK; sbC.fslot[b]  =F_LLA+b*2;
    sbC.src[2+b]=tmpG+(size_t)b*NPIX; sbC.rank[2+b]=MEDRANK; sbC.fslot[2+b]=F_GLD+b*2;
  }

  for(int k=0;k<2;k++){
    const float* Rk = k ? Ra1 : Ra0;
    k_lla_boxh<<<GBN,256,0,stream>>>(Rk,out,tA,tB,tC);
    k_lla_boxv<<<GBN,256,0,stream>>>(tA,tB,tC,out,tmpL,BSrk);
    for(int b=0;b<NB;b++){
      k_histh<<<GN,256,0,stream>>>(Rk+(size_t)b*NPIX, idxP+(size_t)b*NPIX, bufA);
      k_slidev<<<(WW*NBINS*4)/256,256,0,stream>>>(bufA,bufB);
      k_gld<<<GN,256,0,stream>>>(bufB,BSrk,F,b,k,tmpG);
    }
    run_sel(sbC,H,T,F,stream);
    k_gamma<<<GBN,256,0,stream>>>(tmpL,tmpG,Rk,F,gamma,k==0?1:0);
  }

  k_es_red<<<NB*RB,256,0,stream>>>(E,S,F,A,T);
  k_lanom<<<GBN,256,0,stream>>>(E,S,DM,gamma,F,tA);

  SelBatch sbL; sbL.nt=8; sbL.medmad=0;
  {
    int rr[4]={1474,1475,145980,145981};
    for(int b=0;b<NB;b++) for(int ri=0;ri<4;ri++){
      int t=b*4+ri;
      sbL.src[t]=tA+(size_t)b*NPIX; sbL.rank[t]=rr[ri]; sbL.fslot[t]=F_LAQ+b*4+ri;
    }
  }
  run_sel(sbL,H,T,F,stream);

  k_out2<<<GBN,256,0,stream>>>(tA,F,out);
}

// Round 4
// 1522.168 us; speedup vs baseline: 2.4560x; 1.0049x over previous
//
#include <hip/hip_runtime.h>
#include <math.h>

#define HH 384
#define WW 384
#define NPIX (HH*WW)          // 147456
#define NB 2
#define BN (NB*NPIX)          // 294912
#define NT 128
#define NBINS 32
#define MEDRANK ((NPIX-1)/2)  // 73727
#define RB 72                 // reduction blocks per batch
#define SEL_BLK 64            // blocks per select task per pass

// ---- double arena (ws+0, 2048 doubles) ----
#define A_BETA 0    // 10
#define A_XZ   16   // 18
#define A_ES   40   // 10
#define A_DK   56   // 40
#define A_GMM  128  // 9 iters * 16 (128B padded) = 128..271
#define A_GHIST 288 // 288..415
#define A_KURT 512  // (b*128+t)*4+m = 512..1535

// ---- float arena (ws+16384, 4096 floats) ----
#define F_BETA 0
#define F_X3   8    // (b*3+ch)*2 {med,mad}; ch1=E ch2=S also serve ES stage
#define F_MEAN 24
#define F_WWH  32
#define F_ASTAR 828
#define F_ZBQ  868
#define F_DKINV 880
#define F_LLA  918
#define F_GLD  924
#define F_MM   928  // uint slots: min 928+b, max 930+b
#define F_LAQ  952
#define F_ESI  940
#define F_GCDF 968  // (k*NB+b)*32+bin

// ---- ticket/meta arena T (u32, ws+32768, 256 u32) ----
// T[0..7]   : fused-reduction tickets
// T[16..47] : sel pass tickets: task*4 + stage*2 + ps
// T[80..143]: sel meta: task*8 + {sel_s0,rank_s0,sel_s1,rank_s1,center}
// T[128+it] : gmm barrier counters (it 0..8) -> 128..136  [NOTE: separate range]
#define T_GMM 144   // use 144..152 to avoid any overlap

// ---------------- device helpers ----------------
__device__ __forceinline__ double waveSum(double v){
#pragma unroll
  for(int o=32;o;o>>=1) v += __shfl_down(v,o,64);
  return v;
}
__device__ __forceinline__ unsigned f2u(float f){
  unsigned u = __float_as_uint(f);
  return (u & 0x80000000u) ? ~u : (u | 0x80000000u);
}
__device__ __forceinline__ float u2f(unsigned u){
  return __uint_as_float((u & 0x80000000u) ? (u ^ 0x80000000u) : ~u);
}
__device__ __forceinline__ float sp(float x){
  float t = log1pf(expf(-fabsf(x)));
  return x >= 0.f ? x + t : t;
}

struct SelBatch {
  const float* src[8];
  int rank[8];
  int fslot[8];
  int nt;
  int medmad;
};

// pick bin containing rank from per-thread value x (blockDim.x==256)
__device__ void pick256v(unsigned x, int rank, unsigned& sel, int& nrank){
  __shared__ unsigned s_cum[256];
  __shared__ unsigned s_res[2];
  int tid = threadIdx.x;
  s_cum[tid] = x;
  __syncthreads();
  for(int o=1;o<256;o<<=1){
    unsigned t = (tid>=o)? s_cum[tid-o] : 0u;
    __syncthreads();
    s_cum[tid] += t;
    __syncthreads();
  }
  unsigned cum = s_cum[tid];
  unsigned ex  = cum - x;
  if(x>0u && (unsigned)rank>=ex && (unsigned)rank<cum){
    s_res[0]=(unsigned)tid; s_res[1]=(unsigned)(rank-(int)ex);
  }
  __syncthreads();
  sel = s_res[0]; nrank = (int)s_res[1];
  __syncthreads();
}
// 65536-bin locate; hist stored transposed: bin at [(bin&255)*256 + (bin>>8)]
__device__ void locate64k(const unsigned* hp, int rank, unsigned& bin, int& rem){
  unsigned s=0;
  for(int r=0;r<256;r++) s += hp[r*256 + threadIdx.x];  // column c = hi8
  unsigned c; int r1;
  pick256v(s, rank, c, r1);
  unsigned x = hp[threadIdx.x*256 + c];                  // row = lo8
  unsigned rsel; int r2;
  pick256v(x, r1, rsel, r2);
  bin = (c<<8)|rsel; rem = r2;
}

__global__ void k_zero(double* A, float* F, unsigned* T){
  int i = blockIdx.x*blockDim.x + threadIdx.x;
  if(i < 2048) A[i] = 0.0;
  if(i < 4096){
    unsigned* U = (unsigned*)F;
    unsigned v = 0u;
    if(i==F_MM || i==F_MM+1) v = 0xFFFFFFFFu;
    U[i] = v;
  }
  if(i < 256) T[i] = 0u;
}

// zero per-run select hists + init tickets/meta. grid = nt*1024 blocks
__global__ void k_selz16(SelBatch sb, unsigned* Hh, unsigned* T){
  int i = blockIdx.x*256 + threadIdx.x;
  Hh[i]=0u;   // grid sized exactly nt*262144
  if(i < 32) T[16+i]=0u;
  if(i < 8 && i < sb.nt){
    unsigned* m = T + 80 + i*8;
    m[0]=0u; m[1]=(unsigned)sb.rank[i];
    m[2]=0u; m[3]=(unsigned)sb.rank[i];
    m[4]=0u;
  }
}

// one 16-bit radix pass (ps=0: hi16, ps=1: lo16 filtered); last block locates
__global__ __launch_bounds__(256) void k_selp16(SelBatch sb, unsigned* Hh, unsigned* T,
                                                float* F, int stage, int ps){
  int task = blockIdx.x / SEL_BLK;
  int blk  = blockIdx.x % SEL_BLK;
  unsigned* meta = T + 80 + task*8;
  float center = (stage==1) ? __uint_as_float(meta[4]) : 0.f;
  unsigned hisel = meta[stage*2];
  unsigned* hp = Hh + task*262144 + (stage*2+ps)*65536;
  const float* src = sb.src[task];
  for(int i=blk*256+threadIdx.x; i<NPIX; i+=SEL_BLK*256){
    float v = src[i];
    if(stage) v = fabsf(v-center);
    unsigned u = f2u(v);
    if(ps==0){
      unsigned bin = u>>16;
      atomicAdd(&hp[((bin&255u)<<8)|(bin>>8)], 1u);
    } else if((u>>16)==hisel){
      unsigned bin = u&0xFFFFu;
      atomicAdd(&hp[((bin&255u)<<8)|(bin>>8)], 1u);
    }
  }
  __shared__ int s_last;
  __syncthreads();
  if(threadIdx.x==0){
    __threadfence();
    s_last = (atomicAdd(&T[16+task*4+stage*2+ps],1u) == (unsigned)(SEL_BLK-1));
  }
  __syncthreads();
  if(!s_last) return;
  int r = (int)meta[stage*2+1];
  unsigned bin; int rem;
  locate64k(hp, r, bin, rem);
  if(threadIdx.x==0){
    if(ps==0){ meta[stage*2]=bin; meta[stage*2+1]=(unsigned)rem; }
    else {
      float val = u2f((hisel<<16)|bin);
      if(stage==0){
        if(sb.medmad) meta[4]=__float_as_uint(val);
        else F[sb.fslot[task]]=val;
      } else {
        F[sb.fslot[task]]   = __uint_as_float(meta[4]);
        F[sb.fslot[task]+1] = val*1.4826f + 1e-8f;
      }
    }
  }
}

// GMM params from sufficient stats
__device__ void params_from_sums(double N0,double N1,double Sx0,double Sx1,double Sxx0,double Sxx1,
                                 double& mu0,double& mu1,double& iv0h,double& iv1h,
                                 double& c0,double& c1){
  mu0=Sx0/(N0+1e-8); mu1=Sx1/(N1+1e-8);
  double v0=(Sxx0-2.0*mu0*Sx0+mu0*mu0*N0)/(N0+1e-8)+1e-6;
  double v1=(Sxx1-2.0*mu1*Sx1+mu1*mu1*N1)/(N1+1e-8)+1e-6;
  double p0=N0/(double)NPIX, p1=N1/(double)NPIX;
  c0=-0.5*log(v0+1e-6)+log(p0+1e-8);
  c1=-0.5*log(v1+1e-6)+log(p1+1e-8);
  iv0h=0.5/(v0+1e-6); iv1h=0.5/(v1+1e-6);
}
__device__ void params_init(const float* F, int b,
                            double& mu0,double& mu1,double& iv0h,double& iv1h,
                            double& c0,double& c1){
  const float* z = F + F_ZBQ + b*4;
  double h25 = 0.25*(double)(NPIX-1); double f25 = h25 - floor(h25);
  double h75 = 0.75*(double)(NPIX-1); double f75 = h75 - floor(h75);
  mu0 = (double)z[0] + f25*((double)z[1]-(double)z[0]);
  mu1 = (double)z[2] + f75*((double)z[3]-(double)z[2]);
  double v0=1.0, v1=1.0, p0=0.5, p1=0.5;
  c0=-0.5*log(v0+1e-6)+log(p0+1e-8);
  c1=-0.5*log(v1+1e-6)+log(p1+1e-8);
  iv0h=0.5/(v0+1e-6); iv1h=0.5/(v1+1e-6);
}
__device__ __forceinline__ void estep2f(float x,float mu0,float mu1,float iv0h,float iv1h,
                                        float c0,float c1,float& r0,float& r1){
  float d0=x-mu0, d1=x-mu1;
  float l0=-d0*d0*iv0h+c0, l1=-d1*d1*iv1h+c1;
  float m=fmaxf(l0,l1);
  float e0=expf(l0-m), e1=expf(l1-m);
  float s=e0+e1;
  r0=e0/s; r1=e1/s;
}

// ---------------- pipeline kernels ----------------
// fused Sobel + avg3 + S (LDS tile)
__global__ __launch_bounds__(256) void k_sobel(const float* lab, float* S, float* E){
  int bx = blockIdx.x % 24, by = (blockIdx.x/24) % 24, b = blockIdx.x/576;
  __shared__ float Lt[20][21];
  __shared__ float G[18][19];
  const float* Lb = lab + b*3*NPIX;
  int ox = bx*16, oy = by*16;
  for(int i=threadIdx.x; i<400; i+=256){
    int lx=i%20, ly=i/20;
    int gx_=ox-2+lx, gy_=oy-2+ly;
    Lt[ly][lx] = (gx_<0||gx_>=WW||gy_<0||gy_>=HH)?0.f:Lb[gy_*WW+gx_];
  }
  __syncthreads();
  for(int i=threadIdx.x; i<324; i+=256){
    int lx=i%18, ly=i/18;
    int px=lx+1, py=ly+1;
    int gxp=ox-2+px, gyp=oy-2+py;
    float g=0.f;
    if(gxp>=0&&gxp<WW&&gyp>=0&&gyp<HH){
      float gx = -Lt[py-1][px-1]+Lt[py-1][px+1] -2.f*Lt[py][px-1]+2.f*Lt[py][px+1] -Lt[py+1][px-1]+Lt[py+1][px+1];
      float gy = -Lt[py-1][px-1]-2.f*Lt[py-1][px]-Lt[py-1][px+1] +Lt[py+1][px-1]+2.f*Lt[py+1][px]+Lt[py+1][px+1];
      g = gx*gx+gy*gy;
    }
    G[ly][lx]=g;
  }
  __syncthreads();
  int tx = threadIdx.x%16, ty = threadIdx.x/16;
  float s=0;
#pragma unroll
  for(int dy=0;dy<3;dy++)
#pragma unroll
    for(int dx=0;dx<3;dx++) s += G[ty+dy][tx+dx];
  int n = (oy+ty)*WW + ox+tx;
  E[b*NPIX+n] = s*(1.f/9.f);
  float av=Lb[NPIX+n], bv=Lb[2*NPIX+n];
  S[b*NPIX+n] = sqrtf(av*av+bv*bv+1e-8f);
}

__global__ void k_beta_red(const float* E,const float* S,const float* lab,double* A,
                           float* F, unsigned* T){
  int b = blockIdx.x / RB, blk = blockIdx.x % RB;
  double s[5]={0,0,0,0,0};
  for(int n = blk*256 + threadIdx.x; n < NPIX; n += RB*256){
    float e=E[b*NPIX+n], ss=S[b*NPIX+n], l=lab[b*3*NPIX+n];
    s[0]+=(double)e*e; s[1]+=(double)e*ss; s[2]+=(double)ss*ss;
    s[3]+=(double)e*l; s[4]+=(double)ss*l;
  }
#pragma unroll
  for(int q=0;q<5;q++){
    double v = waveSum(s[q]);
    if((threadIdx.x&63)==0) atomicAdd(&A[A_BETA+b*5+q], v);
  }
  __shared__ int s_last;
  __syncthreads();
  if(threadIdx.x==0){
    __threadfence();
    s_last = (atomicAdd(&T[0],1u) == (unsigned)(NB*RB-1));
  }
  __syncthreads();
  if(!s_last || threadIdx.x) return;
  for(int bb=0;bb<NB;bb++){
    double EE=A[A_BETA+bb*5],ES=A[A_BETA+bb*5+1],SS=A[A_BETA+bb*5+2],EL=A[A_BETA+bb*5+3],SL=A[A_BETA+bb*5+4];
    double a00=EE+1e-6, a01=ES, a11=SS+1e-6;
    double det=a00*a11-a01*a01;
    F[F_BETA+bb*2]  =(float)(( a11*EL - a01*SL)/det);
    F[F_BETA+bb*2+1]=(float)((-a01*EL + a00*SL)/det);
  }
}

__global__ void k_lperp(const float* lab,const float* E,const float* S,const float* F,float* out0){
  int i = blockIdx.x*256 + threadIdx.x; if(i>=BN) return;
  int b=i/NPIX, n=i%NPIX;
  float v = lab[b*3*NPIX+n] - F[F_BETA+b*2]*E[i] - F[F_BETA+b*2+1]*S[i];
  out0[i] = v;
  unsigned u = f2u(v);
  unsigned mn=u, mx=u;
#pragma unroll
  for(int o=32;o;o>>=1){
    unsigned a = __shfl_down(mn,o,64); mn = (a<mn)?a:mn;
    unsigned c = __shfl_down(mx,o,64); mx = (c>mx)?c:mx;
  }
  unsigned* U = (unsigned*)F;
  if((threadIdx.x&63)==0){ atomicMin(&U[F_MM+b], mn); atomicMax(&U[F_MM+2+b], mx); }
}

__global__ void k_xz_red(const float* Lp,const float* E,const float* S,float* F,double* A,
                         unsigned* T){
  int b = blockIdx.x / RB, blk = blockIdx.x % RB;
  const float* M = F + F_X3 + b*6;
  double s[9]={0,0,0,0,0,0,0,0,0};
  for(int n = blk*256 + threadIdx.x; n < NPIX; n += RB*256){
    float z0=(Lp[b*NPIX+n]-M[0])/M[1];
    float z1=(E [b*NPIX+n]-M[2])/M[3];
    float z2=(S [b*NPIX+n]-M[4])/M[5];
    s[0]+=z0; s[1]+=z1; s[2]+=z2;
    s[3]+=(double)z0*z0; s[4]+=(double)z0*z1; s[5]+=(double)z0*z2;
    s[6]+=(double)z1*z1; s[7]+=(double)z1*z2; s[8]+=(double)z2*z2;
  }
#pragma unroll
  for(int q=0;q<9;q++){
    double v = waveSum(s[q]);
    if((threadIdx.x&63)==0) atomicAdd(&A[A_XZ+b*9+q], v);
  }
  __shared__ int s_last;
  __syncthreads();
  if(threadIdx.x==0){
    __threadfence();
    s_last = (atomicAdd(&T[1],1u) == (unsigned)(NB*RB-1));
  }
  __syncthreads();
  if(!s_last) return;
  int bb = threadIdx.x;
  if(bb>=NB) return;
  const double* ss = A + A_XZ + bb*9;
  double inv = 1.0/(double)NPIX;
  double m0=ss[0]*inv, m1=ss[1]*inv, m2=ss[2]*inv;
  double a[3][3];
  a[0][0]=fmax(ss[3]*inv-m0*m0,1e-8);
  a[0][1]=a[1][0]=fmax(ss[4]*inv-m0*m1,1e-8);
  a[0][2]=a[2][0]=fmax(ss[5]*inv-m0*m2,1e-8);
  a[1][1]=fmax(ss[6]*inv-m1*m1,1e-8);
  a[1][2]=a[2][1]=fmax(ss[7]*inv-m1*m2,1e-8);
  a[2][2]=fmax(ss[8]*inv-m2*m2,1e-8);
  double V[3][3]={{1,0,0},{0,1,0},{0,0,1}};
  for(int sweep=0;sweep<40;sweep++){
    for(int pp=0;pp<3;pp++){
      int p = (pp==2)?1:0;
      int q = (pp==0)?1:2;
      double apq=a[p][q];
      if(fabs(apq)<1e-30) continue;
      double theta=(a[q][q]-a[p][p])/(2.0*apq);
      double t=((theta>=0)?1.0:-1.0)/(fabs(theta)+sqrt(1.0+theta*theta));
      double c=1.0/sqrt(1.0+t*t), sn=t*c;
      for(int k2=0;k2<3;k2++){ double akp=a[k2][p],akq=a[k2][q];
        a[k2][p]=c*akp-sn*akq; a[k2][q]=sn*akp+c*akq; }
      for(int k2=0;k2<3;k2++){ double apk=a[p][k2],aqk=a[q][k2];
        a[p][k2]=c*apk-sn*aqk; a[q][k2]=sn*apk+c*aqk; }
      for(int k2=0;k2<3;k2++){ double vkp=V[k2][p],vkq=V[k2][q];
        V[k2][p]=c*vkp-sn*vkq; V[k2][q]=sn*vkp+c*vkq; }
    }
  }
  double is0=1.0/sqrt(a[0][0]), is1=1.0/sqrt(a[1][1]), is2=1.0/sqrt(a[2][2]);
  for(int i=0;i<3;i++) for(int j=0;j<3;j++){
    double w = V[i][0]*is0*V[j][0] + V[i][1]*is1*V[j][1] + V[i][2]*is2*V[j][2];
    F[F_WWH + bb*9 + i*3 + j] = (float)w;
  }
  F[F_MEAN+bb*3]=(float)m0; F[F_MEAN+bb*3+1]=(float)m1; F[F_MEAN+bb*3+2]=(float)m2;
}

// whiten (interleaved xyz output) + fused bin index
__global__ void k_xw(const float* Lp,const float* E,const float* S,const float* F,
                     float* Xw,int* idxP){
  int i = blockIdx.x*256 + threadIdx.x; if(i>=BN) return;
  int b=i/NPIX;
  const float* M = F + F_X3 + b*6;
  float lp = Lp[i];
  float z0=(lp-M[0])/M[1];
  float z1=(E [i]-M[2])/M[3];
  float z2=(S [i]-M[4])/M[5];
  float d0=z0-F[F_MEAN+b*3], d1=z1-F[F_MEAN+b*3+1], d2=z2-F[F_MEAN+b*3+2];
  const float* Wm = F + F_WWH + b*9;
  Xw[3*(size_t)i  ]=d0*Wm[0]+d1*Wm[3]+d2*Wm[6];
  Xw[3*(size_t)i+1]=d0*Wm[1]+d1*Wm[4]+d2*Wm[7];
  Xw[3*(size_t)i+2]=d0*Wm[2]+d1*Wm[5]+d2*Wm[8];
  const unsigned* U = (const unsigned*)F;
  float mn=u2f(U[F_MM+b]), mx=u2f(U[F_MM+2+b]);
  float ln = (lp-mn)/(mx-mn+1e-8f);
  ln = fminf(fmaxf(ln,0.f),1.f);
  int id = (int)(ln*32.f);
  idxP[i] = id>31?31:(id<0?0:id);
}

// kurtosis phase A: 4 segments per (b,dir), partial moments -> f64 atomics
__global__ __launch_bounds__(256) void k_kurt(const float* Xw, const float* arand, double* A){
  int g = blockIdx.x;           // 1024
  int b = g >> 9;
  int t = (g >> 2) & 127;
  int seg = g & 3;
  const float* ar = arand + (b*NT+t)*3;
  float q0=ar[0], q1=ar[1], q2=ar[2];
  float nrm = (float)(sqrt((double)q0*q0+(double)q1*q1+(double)q2*q2)+1e-12);
  float a0=q0/nrm, a1=q1/nrm, a2=q2/nrm;
  const float* X = Xw + (size_t)b*NPIX*3;
  double s1=0,s2=0,s3=0,s4=0;
  int start = seg*36864;
  for(int n=start+threadIdx.x; n<start+36864; n+=256){
    const float* p = X + 3*(size_t)n;
    float z = p[0]*a0 + p[1]*a1 + p[2]*a2;
    float z2f = z*z;
    s1 += z; s2 += z2f; s3 += z2f*z; s4 += (double)z2f*z2f;
  }
  s1=waveSum(s1); s2=waveSum(s2); s3=waveSum(s3); s4=waveSum(s4);
  if((threadIdx.x&63)==0){
    double* K = A + A_KURT + (size_t)(b*NT+t)*4;
    atomicAdd(&K[0],s1); atomicAdd(&K[1],s2); atomicAdd(&K[2],s3); atomicAdd(&K[3],s4);
  }
}
__global__ void k_kurt_pick(const double* A, const float* arand, float* F){
  int b = blockIdx.x;
  int t = threadIdx.x;   // 128
  __shared__ float ak[NT];
  const double* K = A + A_KURT + (size_t)(b*NT+t)*4;
  double inv=1.0/(double)NPIX;
  double mean=K[0]*inv, M2=K[1]*inv, M3=K[2]*inv, M4=K[3]*inv;
  double m2 = M2 - mean*mean + 1e-12;
  double m4 = M4 - 4.0*mean*M3 + 6.0*mean*mean*M2 - 3.0*mean*mean*mean*mean;
  ak[t] = (float)fabs(m4/(m2*m2) - 3.0);
  __syncthreads();
  if(t==0){
    int best=0; float bv=ak[0];
    for(int j=1;j<NT;j++) if(ak[j]>bv){bv=ak[j];best=j;}
    const float* ar = arand + (b*NT+best)*3;
    double nrm = sqrt((double)ar[0]*ar[0]+(double)ar[1]*ar[1]+(double)ar[2]*ar[2])+1e-12;
    F[F_ASTAR+b*3]  =(float)(ar[0]/nrm);
    F[F_ASTAR+b*3+1]=(float)(ar[1]/nrm);
    F[F_ASTAR+b*3+2]=(float)(ar[2]/nrm);
  }
}
__global__ void k_zbest(const float* Xw,const float* F,float* zb){
  int i = blockIdx.x*256 + threadIdx.x; if(i>=BN) return;
  int b=i/NPIX;
  const float* p = Xw + 3*(size_t)i;
  zb[i] = p[0]*F[F_ASTAR+b*3] + p[1]*F[F_ASTAR+b*3+1] + p[2]*F[F_ASTAR+b*3+2];
}

// persistent 9-iteration EM (144 blocks, grid spin-barrier per iteration)
__global__ __launch_bounds__(256) void k_gmm(const float* zb, const float* F, double* A, unsigned* T){
  int b = blockIdx.x / RB, blk = blockIdx.x % RB;
  const unsigned NBLK = NB*RB;
  for(int it=0; it<9; ++it){
    double mu0,mu1,iv0h,iv1h,c0,c1;
    if(it==0) params_init(F,b,mu0,mu1,iv0h,iv1h,c0,c1);
    else {
      volatile const double* g = A + A_GMM + (it-1)*16 + b*6;
      double N0=g[0],N1=g[1],Sx0=g[2],Sx1=g[3],Sxx0=g[4],Sxx1=g[5];
      params_from_sums(N0,N1,Sx0,Sx1,Sxx0,Sxx1,mu0,mu1,iv0h,iv1h,c0,c1);
    }
    float fmu0=(float)mu0, fmu1=(float)mu1, fiv0=(float)iv0h, fiv1=(float)iv1h;
    float fc0=(float)c0, fc1=(float)c1;
    double s[6]={0,0,0,0,0,0};
    for(int n = blk*256 + threadIdx.x; n < NPIX; n += RB*256){
      float x = zb[b*NPIX+n];
      float r0,r1; estep2f(x,fmu0,fmu1,fiv0,fiv1,fc0,fc1,r0,r1);
      s[0]+=r0; s[1]+=r1; s[2]+=r0*x; s[3]+=r1*x; s[4]+=(double)(r0*x)*x; s[5]+=(double)(r1*x)*x;
    }
#pragma unroll
    for(int q=0;q<6;q++){
      double v = waveSum(s[q]);
      if((threadIdx.x&63)==0) atomicAdd(&A[A_GMM+it*16+b*6+q], v);
    }
    __syncthreads();
    if(threadIdx.x==0){
      __threadfence();
      atomicAdd(&T[T_GMM+it],1u);
      while(atomicAdd(&T[T_GMM+it],0u) < NBLK) __builtin_amdgcn_s_sleep(8);
    }
    __syncthreads();
  }
}

// final E-step -> R^alpha + fused global hist + cdf
__global__ void k_ralpha(const float* zb, float* F, double* A, const int* idxP,
                         float* Ra0, float* Ra1, unsigned* T){
  __shared__ float h0[NBINS], h1[NBINS];
  if(threadIdx.x<NBINS){ h0[threadIdx.x]=0.f; h1[threadIdx.x]=0.f; }
  __syncthreads();
  int i = blockIdx.x*256 + threadIdx.x;
  int b=i/NPIX;
  const double* g = A + A_GMM + 8*16 + b*6;
  double mu0,mu1,iv0h,iv1h,c0,c1;
  params_from_sums(g[0],g[1],g[2],g[3],g[4],g[5],mu0,mu1,iv0h,iv1h,c0,c1);
  float r0,r1; estep2f(zb[i],(float)mu0,(float)mu1,(float)iv0h,(float)iv1h,(float)c0,(float)c1,r0,r1);
  float ra0=powf(r0,0.9f), ra1=powf(r1,0.9f);
  float s=ra0+ra1+1e-8f;
  ra0/=s; ra1/=s;
  Ra0[i]=ra0; Ra1[i]=ra1;
  int id = idxP[i];
  atomicAdd(&h0[id], ra0);
  atomicAdd(&h1[id], ra1);
  __syncthreads();
  if(threadIdx.x<NBINS){
    if(h0[threadIdx.x]!=0.f) atomicAdd(&A[A_GHIST+(0*NB+b)*32+threadIdx.x], (double)h0[threadIdx.x]);
    if(h1[threadIdx.x]!=0.f) atomicAdd(&A[A_GHIST+(1*NB+b)*32+threadIdx.x], (double)h1[threadIdx.x]);
  }
  __shared__ int s_last;
  __syncthreads();
  if(threadIdx.x==0){
    __threadfence();
    s_last = (atomicAdd(&T[2],1u) == (unsigned)(BN/256-1));
  }
  __syncthreads();
  if(!s_last) return;
  int t = threadIdx.x;
  if(t>=4) return;
  const double* gh = A + A_GHIST + t*32;
  double sum=0;
  for(int j=0;j<NBINS;j++) sum += gh[j];
  double c=0;
  for(int j=0;j<NBINS;j++){
    c += gh[j]/(sum+1e-8);
    F[F_GCDF+t*32+j]=(float)c;
  }
}

__global__ void k_dk_red(const float* Lp,const float* E,const float* S,
                         const float* Ra0,const float* Ra1,double* A,float* F,unsigned* T){
  int b = blockIdx.x / RB, blk = blockIdx.x % RB;
  double s[20];
#pragma unroll
  for(int q=0;q<20;q++) s[q]=0;
  for(int n = blk*256 + threadIdx.x; n < NPIX; n += RB*256){
    int i=b*NPIX+n;
    double w0=Ra0[i], w1=Ra1[i];
    double x0=Lp[i], x1=E[i], x2=S[i];
    s[0]+=w0; s[1]+=w0*x0; s[2]+=w0*x1; s[3]+=w0*x2;
    s[4]+=w0*x0*x0; s[5]+=w0*x0*x1; s[6]+=w0*x0*x2; s[7]+=w0*x1*x1; s[8]+=w0*x1*x2; s[9]+=w0*x2*x2;
    s[10]+=w1; s[11]+=w1*x0; s[12]+=w1*x1; s[13]+=w1*x2;
    s[14]+=w1*x0*x0; s[15]+=w1*x0*x1; s[16]+=w1*x0*x2; s[17]+=w1*x1*x1; s[18]+=w1*x1*x2; s[19]+=w1*x2*x2;
  }
#pragma unroll
  for(int q=0;q<20;q++){
    double v = waveSum(s[q]);
    if((threadIdx.x&63)==0) atomicAdd(&A[A_DK+b*20+q], v);
  }
  __shared__ int s_last;
  __syncthreads();
  if(threadIdx.x==0){
    __threadfence();
    s_last = (atomicAdd(&T[3],1u) == (unsigned)(NB*RB-1));
  }
  __syncthreads();
  if(!s_last || threadIdx.x) return;
  for(int bb=0;bb<NB;bb++) for(int k=0;k<2;k++){
    const double* ss = A + A_DK + (bb*2+k)*10;
    double W0=ss[0], Ws=W0+1e-8;
    double mu0=ss[1]/Ws, mu1=ss[2]/Ws, mu2=ss[3]/Ws;
    double C00=(ss[4]-2.0*mu0*ss[1]+mu0*mu0*W0)/Ws + 1e-6;
    double C01=(ss[5]-mu0*ss[2]-mu1*ss[1]+mu0*mu1*W0)/Ws;
    double C02=(ss[6]-mu0*ss[3]-mu2*ss[1]+mu0*mu2*W0)/Ws;
    double C11=(ss[7]-2.0*mu1*ss[2]+mu1*mu1*W0)/Ws + 1e-6;
    double C12=(ss[8]-mu1*ss[3]-mu2*ss[2]+mu1*mu2*W0)/Ws;
    double C22=(ss[9]-2.0*mu2*ss[3]+mu2*mu2*W0)/Ws + 1e-6;
    double det = C00*(C11*C22-C12*C12) - C01*(C01*C22-C12*C02) + C02*(C01*C12-C11*C02);
    double id = 1.0/det;
    float* P = F + F_DKINV + (bb*2+k)*9;
    P[0]=(float)((C11*C22-C12*C12)*id);
    P[1]=(float)((C02*C12-C01*C22)*id);
    P[2]=(float)((C01*C12-C02*C11)*id);
    P[3]=(float)((C00*C22-C02*C02)*id);
    P[4]=(float)((C01*C02-C00*C12)*id);
    P[5]=(float)((C00*C11-C01*C01)*id);
    P[6]=(float)mu0; P[7]=(float)mu1; P[8]=(float)mu2;
  }
}
__global__ void k_dm(const float* Lp,const float* E,const float* S,
                     const float* Ra0,const float* Ra1,const float* F,float* DM){
  int i = blockIdx.x*256 + threadIdx.x; if(i>=BN) return;
  int b=i/NPIX;
  float x0=Lp[i], x1=E[i], x2=S[i];
  float D[2];
#pragma unroll
  for(int k=0;k<2;k++){
    const float* P = F + F_DKINV + (b*2+k)*9;
    float d0=x0-P[6], d1=x1-P[7], d2=x2-P[8];
    float q = d0*d0*P[0] + d1*d1*P[3] + d2*d2*P[5]
            + 2.f*(d0*d1*P[1] + d0*d2*P[2] + d1*d2*P[4]);
    D[k]=sqrtf(q+1e-8f);
  }
  float w0=Ra0[i]+1e-8f, w1=Ra1[i]+1e-8f;
  DM[i] = (w0*D[0]+w1*D[1])/(w0+w1);
}

// fused 15x15 weighted box stats (LDS tile) -> tmpL, BSrk
__global__ __launch_bounds__(256) void k_lla(const float* rk, const float* Lp,
                                             float* tmpL, float* BSrk){
  int bx = blockIdx.x % 24, by = (blockIdx.x/24) % 24, b = blockIdx.x/576;
  __shared__ float Rt[30][31], Lt[30][31];
  __shared__ float h0[30][17], h1[30][17], h2[30][17];
  int ox = bx*16, oy = by*16;
  const float* Rb = rk + (size_t)b*NPIX;
  const float* Lb = Lp + (size_t)b*NPIX;
  for(int i=threadIdx.x; i<900; i+=256){
    int lx=i%30, ly=i/30;
    int gx_=ox-7+lx, gy_=oy-7+ly;
    bool in = (gx_>=0&&gx_<WW&&gy_>=0&&gy_<HH);
    Rt[ly][lx]= in ? Rb[gy_*WW+gx_] : 0.f;
    Lt[ly][lx]= in ? Lb[gy_*WW+gx_] : 0.f;
  }
  __syncthreads();
  for(int i=threadIdx.x; i<480; i+=256){
    int j=i%16, r=i/16;
    float s0=0,s1=0,s2=0;
#pragma unroll
    for(int d=0;d<15;d++){
      float rr=Rt[r][j+d], ll=Lt[r][j+d];
      s0+=rr; float rl=rr*ll; s1+=rl; s2+=rl*ll;
    }
    h0[r][j]=s0; h1[r][j]=s1; h2[r][j]=s2;
  }
  __syncthreads();
  int tx=threadIdx.x%16, ty=threadIdx.x/16;
  float S0=0,S1=0,S2=0;
#pragma unroll
  for(int d=0;d<15;d++){ S0+=h0[ty+d][tx]; S1+=h1[ty+d][tx]; S2+=h2[ty+d][tx]; }
  int x=ox+tx, y=oy+ty;
  float cy = (float)((y+8<HH?y+8:HH)-(y-7>0?y-7:0));
  float cx = (float)((x+8<WW?x+8:WW)-(x-7>0?x-7:0));
  float cnt = cy*cx;
  float den = S0/cnt + 1e-8f;
  float mu  = (S1/cnt)/den;
  float var = fmaxf((S2/cnt)/den - mu*mu, 1e-8f);
  int n = y*WW+x;
  tmpL[b*NPIX+n] = fabsf(Lb[n]-mu)/(sqrtf(var)+1e-8f);
  BSrk[b*NPIX+n] = S0;
}

__global__ __launch_bounds__(256) void k_histh(const float* rk_b,const int* idx_b,float* bufA){
  __shared__ float acc[256*33];
  int tid=threadIdx.x;
  float* my = acc + tid*33;
#pragma unroll
  for(int j=0;j<NBINS;j++) my[j]=0.f;
  int n = blockIdx.x*256+tid;
  int y=n/WW, x=n%WW;
  int x0 = x-7<0?0:x-7, x1 = x+7>WW-1?WW-1:x+7;
  for(int xx=x0;xx<=x1;xx++){
    int m = y*WW+xx;
    my[idx_b[m]] += rk_b[m];
  }
#pragma unroll
  for(int bin=0;bin<NBINS;bin++) bufA[bin*NPIX + n] = my[bin];
}
__global__ void k_slidev(const float* bufA, float* bufB){
  int idx = blockIdx.x*256 + threadIdx.x;
  if(idx >= WW*NBINS*12) return;
  int x   = idx % WW;
  int bin = (idx/WW) % NBINS;
  int seg = idx/(WW*NBINS);
  int y0 = seg*32;
  const float* a = bufA + (size_t)bin*NPIX + x;
  float* o = bufB + (size_t)bin*NPIX + x;
  float s=0;
  int lo = y0-7; if(lo<0) lo=0;
  int hi = y0+7; if(hi>HH-1) hi=HH-1;
  for(int yy=lo; yy<=hi; ++yy) s += a[yy*WW];
  for(int y=y0; y<y0+32; ++y){
    o[y*WW] = s;
    int add=y+8, rem=y-7;
    if(add<HH) s += a[add*WW];
    if(rem>=0) s -= a[rem*WW];
  }
}
__global__ __launch_bounds__(256) void k_gld(const float* bufB,const float* BSrk,const float* F,
                                             int b,int k,float* tmpG){
  __shared__ float gc[NBINS];
  if(threadIdx.x<NBINS) gc[threadIdx.x]=F[F_GCDF+(k*NB+b)*32+threadIdx.x];
  __syncthreads();
  int n = blockIdx.x*256 + threadIdx.x;
  int y=n/WW, x=n%WW;
  float cy = (float)((y+8<HH?y+8:HH)-(y-7>0?y-7:0));
  float cx = (float)((x+8<WW?x+8:WW)-(x-7>0?x-7:0));
  float cnt = cy*cx;
  float den = BSrk[b*NPIX+n]/cnt + 1e-8f;
  float cs=0, acc=0;
  for(int bin=0;bin<NBINS;bin++){
    cs += bufB[(size_t)bin*NPIX+n];
    acc += fabsf((cs/cnt)/den - gc[bin]);
  }
  tmpG[b*NPIX+n] = acc*(1.f/32.f);
}
__global__ void k_gamma(const float* tmpL,const float* tmpG,const float* rk,const float* F,
                        float* gamma,int first){
  int i = blockIdx.x*256 + threadIdx.x; if(i>=BN) return;
  int b=i/NPIX;
  float zl=(tmpL[i]-F[F_LLA+b*2])/F[F_LLA+b*2+1];
  float zg=(tmpG[i]-F[F_GLD+b*2])/F[F_GLD+b*2+1];
  float c = rk[i]*(0.5f*sp(zl)+0.5f*sp(zg));
  gamma[i] = first ? 1.0f + c : gamma[i] + c;
}

__global__ void k_es_red(const float* E,const float* S,float* F,double* A,unsigned* T){
  int b = blockIdx.x / RB, blk = blockIdx.x % RB;
  const float* M = F + F_X3 + b*6;
  double s[5]={0,0,0,0,0};
  for(int n = blk*256 + threadIdx.x; n < NPIX; n += RB*256){
    float z0=(E[b*NPIX+n]-M[2])/M[3];
    float z1=(S[b*NPIX+n]-M[4])/M[5];
    s[0]+=z0; s[1]+=z1; s[2]+=(double)z0*z0; s[3]+=(double)z0*z1; s[4]+=(double)z1*z1;
  }
#pragma unroll
  for(int q=0;q<5;q++){
    double v = waveSum(s[q]);
    if((threadIdx.x&63)==0) atomicAdd(&A[A_ES+b*5+q], v);
  }
  __shared__ int s_last;
  __syncthreads();
  if(threadIdx.x==0){
    __threadfence();
    s_last = (atomicAdd(&T[4],1u) == (unsigned)(NB*RB-1));
  }
  __syncthreads();
  if(!s_last || threadIdx.x) return;
  for(int bb=0;bb<NB;bb++){
    const double* ss = A + A_ES + bb*5;
    double inv=1.0/(double)NPIX;
    double m0=ss[0]*inv, m1=ss[1]*inv;
    double c00=ss[2]*inv - m0*m0 + 1e-6;
    double c01=ss[3]*inv - m0*m1;
    double c11=ss[4]*inv - m1*m1 + 1e-6;
    double det=c00*c11-c01*c01;
    float* P = F + F_ESI + bb*5;
    P[0]=(float)m0; P[1]=(float)m1;
    P[2]=(float)(c11/det); P[3]=(float)(-c01/det); P[4]=(float)(c00/det);
  }
}
__global__ void k_lanom(const float* E,const float* S,const float* DM,const float* gamma,
                        const float* F,float* La){
  int i = blockIdx.x*256 + threadIdx.x; if(i>=BN) return;
  int b=i/NPIX;
  const float* M = F + F_X3 + b*6;
  const float* P = F + F_ESI + b*5;
  float z0=(E[i]-M[2])/M[3];
  float z1=(S[i]-M[4])/M[5];
  float d0=z0-P[0], d1=z1-P[1];
  float d2 = d0*d0*P[2] + 2.f*d0*d1*P[3] + d1*d1*P[4];
  float Rs = expf(-0.5f*d2);
  La[i] = fmaxf(DM[i]*gamma[i]*(1.f-Rs), 0.f);
}
__global__ void k_out2(const float* La, const float* F, float* out){
  int i = blockIdx.x*256 + threadIdx.x; if(i>=BN) return;
  int b=i/NPIX;
  const float* v = F + F_LAQ + b*4;
  double h1 = 0.01*(double)(NPIX-1); double f1 = h1 - floor(h1);
  double h9 = 0.99*(double)(NPIX-1); double f9 = h9 - floor(h9);
  float q1 = (float)((double)v[0] + f1*((double)v[1]-(double)v[0]));
  float q9 = (float)((double)v[2] + f9*((double)v[3]-(double)v[2]));
  float r = (La[i]-q1)/(q9-q1+1e-8f);
  out[BN + i] = fminf(fmaxf(r,0.f),1.f);
}

// ---------------- host ----------------
static void run_sel(const SelBatch& sb, unsigned* H, unsigned* T, float* F, hipStream_t s){
  k_selz16<<<sb.nt*1024,256,0,s>>>(sb,H,T);
  k_selp16<<<sb.nt*SEL_BLK,256,0,s>>>(sb,H,T,F,0,0);
  k_selp16<<<sb.nt*SEL_BLK,256,0,s>>>(sb,H,T,F,0,1);
  if(sb.medmad){
    k_selp16<<<sb.nt*SEL_BLK,256,0,s>>>(sb,H,T,F,1,0);
    k_selp16<<<sb.nt*SEL_BLK,256,0,s>>>(sb,H,T,F,1,1);
  }
}

extern "C" void kernel_launch(void* const* d_in, const int* in_sizes, int n_in,
                              void* d_out, int out_size, void* d_ws, size_t ws_size,
                              hipStream_t stream){
  (void)in_sizes; (void)n_in; (void)out_size; (void)ws_size;
  const float* lab   = (const float*)d_in[0];
  const float* arand = (const float*)d_in[1];
  float* out = (float*)d_out;
  char* wsb = (char*)d_ws;
  double* A = (double*)wsb;                   // 2048 doubles
  float*  F = (float*)(wsb + 16384);          // 4096 floats
  unsigned* T = (unsigned*)(wsb + 32768);     // 256 u32
  float* planes = (float*)(wsb + 65536);
  float* E    = planes;
  float* S    = planes + (size_t)BN;
  float* tA   = planes + (size_t)2*BN;        // La at the end
  float* tmpL = planes + (size_t)5*BN;
  float* tmpG = planes + (size_t)6*BN;
  float* Xw   = planes + (size_t)7*BN;        // interleaved xyz (3*BN)
  float* zb   = planes + (size_t)10*BN;
  float* Ra0  = planes + (size_t)11*BN;
  float* Ra1  = planes + (size_t)12*BN;
  float* DM   = planes + (size_t)13*BN;
  float* gamma= planes + (size_t)14*BN;
  float* BSrk = planes + (size_t)15*BN;
  int*   idxP = (int*)(planes + (size_t)16*BN);
  float* bufA = planes + (size_t)17*BN;
  float* bufB = bufA + (size_t)NBINS*NPIX;
  unsigned* H16 = (unsigned*)bufA;            // select hists alias bufA (disjoint in time)

  const int GBN = BN/256;      // 1152
  const int GN  = NPIX/256;    // 576

  k_zero<<<16,256,0,stream>>>(A,F,T);
  k_sobel<<<NB*576,256,0,stream>>>(lab,S,E);
  k_beta_red<<<NB*RB,256,0,stream>>>(E,S,lab,A,F,T);
  k_lperp<<<GBN,256,0,stream>>>(lab,E,S,F,out);

  SelBatch sbX; sbX.nt=6; sbX.medmad=1;
  for(int b=0;b<NB;b++){
    sbX.src[b*3+0]=out+(size_t)b*NPIX; sbX.src[b*3+1]=E+(size_t)b*NPIX; sbX.src[b*3+2]=S+(size_t)b*NPIX;
    for(int ch=0;ch<3;ch++){ sbX.rank[b*3+ch]=MEDRANK; sbX.fslot[b*3+ch]=F_X3+(b*3+ch)*2; }
  }
  run_sel(sbX,H16,T,F,stream);

  k_xz_red<<<NB*RB,256,0,stream>>>(out,E,S,F,A,T);
  k_xw<<<GBN,256,0,stream>>>(out,E,S,F,Xw,idxP);
  k_kurt<<<1024,256,0,stream>>>(Xw,arand,A);
  k_kurt_pick<<<NB,128,0,stream>>>(A,arand,F);
  k_zbest<<<GBN,256,0,stream>>>(Xw,F,zb);

  SelBatch sbZ; sbZ.nt=8; sbZ.medmad=0;
  {
    int rr[4]={36863,36864,110591,110592};
    for(int b=0;b<NB;b++) for(int ri=0;ri<4;ri++){
      int t=b*4+ri;
      sbZ.src[t]=zb+(size_t)b*NPIX; sbZ.rank[t]=rr[ri]; sbZ.fslot[t]=F_ZBQ+b*4+ri;
    }
  }
  run_sel(sbZ,H16,T,F,stream);

  k_gmm<<<NB*RB,256,0,stream>>>(zb,F,A,T);
  k_ralpha<<<GBN,256,0,stream>>>(zb,F,A,idxP,Ra0,Ra1,T);
  k_dk_red<<<NB*RB,256,0,stream>>>(out,E,S,Ra0,Ra1,A,F,T);
  k_dm<<<GBN,256,0,stream>>>(out,E,S,Ra0,Ra1,F,DM);

  SelBatch sbC; sbC.nt=4; sbC.medmad=1;
  for(int b=0;b<NB;b++){
    sbC.src[b]  =tmpL+(size_t)b*NPIX; sbC.rank[b]  =MEDRANK; sbC.fslot[b]  =F_LLA+b*2;
    sbC.src[2+b]=tmpG+(size_t)b*NPIX; sbC.rank[2+b]=MEDRANK; sbC.fslot[2+b]=F_GLD+b*2;
  }

  for(int k=0;k<2;k++){
    const float* Rk = k ? Ra1 : Ra0;
    k_lla<<<NB*576,256,0,stream>>>(Rk,out,tmpL,BSrk);
    for(int b=0;b<NB;b++){
      k_histh<<<GN,256,0,stream>>>(Rk+(size_t)b*NPIX, idxP+(size_t)b*NPIX, bufA);
      k_slidev<<<(WW*NBINS*12)/256,256,0,stream>>>(bufA,bufB);
      k_gld<<<GN,256,0,stream>>>(bufB,BSrk,F,b,k,tmpG);
    }
    run_sel(sbC,H16,T,F,stream);
    k_gamma<<<GBN,256,0,stream>>>(tmpL,tmpG,Rk,F,gamma,k==0?1:0);
  }

  k_es_red<<<NB*RB,256,0,stream>>>(E,S,F,A,T);
  k_lanom<<<GBN,256,0,stream>>>(E,S,DM,gamma,F,tA);

  SelBatch sbL; sbL.nt=8; sbL.medmad=0;
  {
    int rr[4]={1474,1475,145980,145981};
    for(int b=0;b<NB;b++) for(int ri=0;ri<4;ri++){
      int t=b*4+ri;
      sbL.src[t]=tA+(size_t)b*NPIX; sbL.rank[t]=rr[ri]; sbL.fslot[t]=F_LAQ+b*4+ri;
    }
  }
  run_sel(sbL,H16,T,F,stream);

  k_out2<<<GBN,256,0,stream>>>(tA,F,out);
}

// Round 5
// 1374.951 us; speedup vs baseline: 2.7190x; 1.1071x over previous
//
#include <hip/hip_runtime.h>
#include <math.h>

#define HH 384
#define WW 384
#define NPIX (HH*WW)          // 147456
#define NB 2
#define BN (NB*NPIX)          // 294912
#define NT 128
#define NBINS 32
#define MEDRANK ((NPIX-1)/2)  // 73727
#define RB 72                 // reduction blocks per batch
#define RB2 288               // gmm reduction blocks per batch
#define SEL_BLK 64            // blocks per select task per pass

// ---- double arena (ws+0, 2048 doubles) ----
#define A_BETA 0    // 10
#define A_XZ   16   // 18
#define A_ES   40   // 10
#define A_DK   56   // 40
#define A_GMM  128  // 9 iters * 16 (128B padded)
#define A_GHIST 288 // (k*NB+b)*32+bin
#define A_KURT 512  // (b*128+t)*4+m

// ---- float arena (ws+16384, 4096 floats) ----
#define F_BETA 0
#define F_X3   8    // (b*3+ch)*2 {med,mad}; ch1=E ch2=S also serve ES stage
#define F_MEAN 24
#define F_WWH  32
#define F_ASTAR 828
#define F_ZBQ  868
#define F_DKINV 880
#define F_LLA  918
#define F_GLD  924
#define F_MM   928  // uint slots: min 928+b, max 930+b
#define F_ESI  940
#define F_LAQ  952
#define F_GCDF 968  // (k*NB+b)*32+bin
#define F_KABS 1100 // b*128+t

// ---- ticket/meta arena T (u32, ws+32768, 256 u32) ----
// T[0..7]: reduction tickets; T[16..47]: sel pass tickets; T[80..143]: sel meta

// ---------------- device helpers ----------------
__device__ __forceinline__ double waveSum(double v){
#pragma unroll
  for(int o=32;o;o>>=1) v += __shfl_down(v,o,64);
  return v;
}
__device__ __forceinline__ unsigned f2u(float f){
  unsigned u = __float_as_uint(f);
  return (u & 0x80000000u) ? ~u : (u | 0x80000000u);
}
__device__ __forceinline__ float u2f(unsigned u){
  return __uint_as_float((u & 0x80000000u) ? (u ^ 0x80000000u) : ~u);
}
__device__ __forceinline__ float sp(float x){
  float t = log1pf(expf(-fabsf(x)));
  return x >= 0.f ? x + t : t;
}

struct SelBatch {
  const float* src[8];
  int rank[8];
  int fslot[8];
  int nt;
  int medmad;
};

__device__ void pick256v(unsigned x, int rank, unsigned& sel, int& nrank){
  __shared__ unsigned s_cum[256];
  __shared__ unsigned s_res[2];
  int tid = threadIdx.x;
  s_cum[tid] = x;
  __syncthreads();
  for(int o=1;o<256;o<<=1){
    unsigned t = (tid>=o)? s_cum[tid-o] : 0u;
    __syncthreads();
    s_cum[tid] += t;
    __syncthreads();
  }
  unsigned cum = s_cum[tid];
  unsigned ex  = cum - x;
  if(x>0u && (unsigned)rank>=ex && (unsigned)rank<cum){
    s_res[0]=(unsigned)tid; s_res[1]=(unsigned)(rank-(int)ex);
  }
  __syncthreads();
  sel = s_res[0]; nrank = (int)s_res[1];
  __syncthreads();
}
// 65536-bin locate; hist transposed: bin at [(bin&255)*256 + (bin>>8)]
__device__ void locate64k(const unsigned* hp, int rank, unsigned& bin, int& rem){
  unsigned s=0;
  for(int r=0;r<256;r++) s += hp[r*256 + threadIdx.x];
  unsigned c; int r1;
  pick256v(s, rank, c, r1);
  unsigned x = hp[threadIdx.x*256 + c];
  unsigned rsel; int r2;
  pick256v(x, r1, rsel, r2);
  bin = (c<<8)|rsel; rem = r2;
}

__global__ void k_zero(double* A, float* F, unsigned* T){
  int i = blockIdx.x*blockDim.x + threadIdx.x;
  if(i < 2048) A[i] = 0.0;
  if(i < 4096){
    unsigned* U = (unsigned*)F;
    unsigned v = 0u;
    if(i==F_MM || i==F_MM+1) v = 0xFFFFFFFFu;
    U[i] = v;
  }
  if(i < 256) T[i] = 0u;
}

__global__ void k_selz16(SelBatch sb, unsigned* Hh, unsigned* T){
  int i = blockIdx.x*256 + threadIdx.x;
  Hh[i]=0u;
  if(i < 32) T[16+i]=0u;
  if(i < 8 && i < sb.nt){
    unsigned* m = T + 80 + i*8;
    m[0]=0u; m[1]=(unsigned)sb.rank[i];
    m[2]=0u; m[3]=(unsigned)sb.rank[i];
    m[4]=0u;
  }
}

__global__ __launch_bounds__(256) void k_selp16(SelBatch sb, unsigned* Hh, unsigned* T,
                                                float* F, int stage, int ps){
  int task = blockIdx.x / SEL_BLK;
  int blk  = blockIdx.x % SEL_BLK;
  unsigned* meta = T + 80 + task*8;
  float center = (stage==1) ? __uint_as_float(meta[4]) : 0.f;
  unsigned hisel = meta[stage*2];
  unsigned* hp = Hh + task*262144 + (stage*2+ps)*65536;
  const float* src = sb.src[task];
  for(int i=blk*256+threadIdx.x; i<NPIX; i+=SEL_BLK*256){
    float v = src[i];
    if(stage) v = fabsf(v-center);
    unsigned u = f2u(v);
    if(ps==0){
      unsigned bin = u>>16;
      atomicAdd(&hp[((bin&255u)<<8)|(bin>>8)], 1u);
    } else if((u>>16)==hisel){
      unsigned bin = u&0xFFFFu;
      atomicAdd(&hp[((bin&255u)<<8)|(bin>>8)], 1u);
    }
  }
  __shared__ int s_last;
  __syncthreads();
  if(threadIdx.x==0){
    __threadfence();
    s_last = (atomicAdd(&T[16+task*4+stage*2+ps],1u) == (unsigned)(SEL_BLK-1));
  }
  __syncthreads();
  if(!s_last) return;
  int r = (int)meta[stage*2+1];
  unsigned bin; int rem;
  locate64k(hp, r, bin, rem);
  if(threadIdx.x==0){
    if(ps==0){ meta[stage*2]=bin; meta[stage*2+1]=(unsigned)rem; }
    else {
      float val = u2f((hisel<<16)|bin);
      if(stage==0){
        if(sb.medmad) meta[4]=__float_as_uint(val);
        else F[sb.fslot[task]]=val;
      } else {
        F[sb.fslot[task]]   = __uint_as_float(meta[4]);
        F[sb.fslot[task]+1] = val*1.4826f + 1e-8f;
      }
    }
  }
}

// GMM params from sufficient stats
__device__ void params_from_sums(double N0,double N1,double Sx0,double Sx1,double Sxx0,double Sxx1,
                                 double& mu0,double& mu1,double& iv0h,double& iv1h,
                                 double& c0,double& c1){
  mu0=Sx0/(N0+1e-8); mu1=Sx1/(N1+1e-8);
  double v0=(Sxx0-2.0*mu0*Sx0+mu0*mu0*N0)/(N0+1e-8)+1e-6;
  double v1=(Sxx1-2.0*mu1*Sx1+mu1*mu1*N1)/(N1+1e-8)+1e-6;
  double p0=N0/(double)NPIX, p1=N1/(double)NPIX;
  c0=-0.5*log(v0+1e-6)+log(p0+1e-8);
  c1=-0.5*log(v1+1e-6)+log(p1+1e-8);
  iv0h=0.5/(v0+1e-6); iv1h=0.5/(v1+1e-6);
}
__device__ void params_init(const float* F, int b,
                            double& mu0,double& mu1,double& iv0h,double& iv1h,
                            double& c0,double& c1){
  const float* z = F + F_ZBQ + b*4;
  double h25 = 0.25*(double)(NPIX-1); double f25 = h25 - floor(h25);
  double h75 = 0.75*(double)(NPIX-1); double f75 = h75 - floor(h75);
  mu0 = (double)z[0] + f25*((double)z[1]-(double)z[0]);
  mu1 = (double)z[2] + f75*((double)z[3]-(double)z[2]);
  double v0=1.0, v1=1.0, p0=0.5, p1=0.5;
  c0=-0.5*log(v0+1e-6)+log(p0+1e-8);
  c1=-0.5*log(v1+1e-6)+log(p1+1e-8);
  iv0h=0.5/(v0+1e-6); iv1h=0.5/(v1+1e-6);
}
__device__ __forceinline__ void estep2f(float x,float mu0,float mu1,float iv0h,float iv1h,
                                        float c0,float c1,float& r0,float& r1){
  float d0=x-mu0, d1=x-mu1;
  float l0=-d0*d0*iv0h+c0, l1=-d1*d1*iv1h+c1;
  float m=fmaxf(l0,l1);
  float e0=expf(l0-m), e1=expf(l1-m);
  float s=e0+e1;
  r0=e0/s; r1=e1/s;
}

// ---------------- pipeline kernels ----------------
__global__ __launch_bounds__(256) void k_sobel(const float* lab, float* S, float* E){
  int bx = blockIdx.x % 24, by = (blockIdx.x/24) % 24, b = blockIdx.x/576;
  __shared__ float Lt[20][21];
  __shared__ float G[18][19];
  const float* Lb = lab + b*3*NPIX;
  int ox = bx*16, oy = by*16;
  for(int i=threadIdx.x; i<400; i+=256){
    int lx=i%20, ly=i/20;
    int gx_=ox-2+lx, gy_=oy-2+ly;
    Lt[ly][lx] = (gx_<0||gx_>=WW||gy_<0||gy_>=HH)?0.f:Lb[gy_*WW+gx_];
  }
  __syncthreads();
  for(int i=threadIdx.x; i<324; i+=256){
    int lx=i%18, ly=i/18;
    int px=lx+1, py=ly+1;
    int gxp=ox-2+px, gyp=oy-2+py;
    float g=0.f;
    if(gxp>=0&&gxp<WW&&gyp>=0&&gyp<HH){
      float gx = -Lt[py-1][px-1]+Lt[py-1][px+1] -2.f*Lt[py][px-1]+2.f*Lt[py][px+1] -Lt[py+1][px-1]+Lt[py+1][px+1];
      float gy = -Lt[py-1][px-1]-2.f*Lt[py-1][px]-Lt[py-1][px+1] +Lt[py+1][px-1]+2.f*Lt[py+1][px]+Lt[py+1][px+1];
      g = gx*gx+gy*gy;
    }
    G[ly][lx]=g;
  }
  __syncthreads();
  int tx = threadIdx.x%16, ty = threadIdx.x/16;
  float s=0;
#pragma unroll
  for(int dy=0;dy<3;dy++)
#pragma unroll
    for(int dx=0;dx<3;dx++) s += G[ty+dy][tx+dx];
  int n = (oy+ty)*WW + ox+tx;
  E[b*NPIX+n] = s*(1.f/9.f);
  float av=Lb[NPIX+n], bv=Lb[2*NPIX+n];
  S[b*NPIX+n] = sqrtf(av*av+bv*bv+1e-8f);
}

__global__ void k_beta_red(const float* E,const float* S,const float* lab,double* A,
                           float* F, unsigned* T){
  int b = blockIdx.x / RB, blk = blockIdx.x % RB;
  double s[5]={0,0,0,0,0};
  for(int n = blk*256 + threadIdx.x; n < NPIX; n += RB*256){
    float e=E[b*NPIX+n], ss=S[b*NPIX+n], l=lab[b*3*NPIX+n];
    s[0]+=(double)e*e; s[1]+=(double)e*ss; s[2]+=(double)ss*ss;
    s[3]+=(double)e*l; s[4]+=(double)ss*l;
  }
#pragma unroll
  for(int q=0;q<5;q++){
    double v = waveSum(s[q]);
    if((threadIdx.x&63)==0) atomicAdd(&A[A_BETA+b*5+q], v);
  }
  __shared__ int s_last;
  __syncthreads();
  if(threadIdx.x==0){
    __threadfence();
    s_last = (atomicAdd(&T[0],1u) == (unsigned)(NB*RB-1));
  }
  __syncthreads();
  if(!s_last || threadIdx.x) return;
  for(int bb=0;bb<NB;bb++){
    double EE=A[A_BETA+bb*5],ES=A[A_BETA+bb*5+1],SS=A[A_BETA+bb*5+2],EL=A[A_BETA+bb*5+3],SL=A[A_BETA+bb*5+4];
    double a00=EE+1e-6, a01=ES, a11=SS+1e-6;
    double det=a00*a11-a01*a01;
    F[F_BETA+bb*2]  =(float)(( a11*EL - a01*SL)/det);
    F[F_BETA+bb*2+1]=(float)((-a01*EL + a00*SL)/det);
  }
}

__global__ void k_lperp(const float* lab,const float* E,const float* S,const float* F,float* out0){
  int i = blockIdx.x*256 + threadIdx.x; if(i>=BN) return;
  int b=i/NPIX, n=i%NPIX;
  float v = lab[b*3*NPIX+n] - F[F_BETA+b*2]*E[i] - F[F_BETA+b*2+1]*S[i];
  out0[i] = v;
  unsigned u = f2u(v);
  unsigned mn=u, mx=u;
#pragma unroll
  for(int o=32;o;o>>=1){
    unsigned a = __shfl_down(mn,o,64); mn = (a<mn)?a:mn;
    unsigned c = __shfl_down(mx,o,64); mx = (c>mx)?c:mx;
  }
  unsigned* U = (unsigned*)F;
  if((threadIdx.x&63)==0){ atomicMin(&U[F_MM+b], mn); atomicMax(&U[F_MM+2+b], mx); }
}

__global__ void k_xz_red(const float* Lp,const float* E,const float* S,float* F,double* A,
                         unsigned* T){
  int b = blockIdx.x / RB, blk = blockIdx.x % RB;
  const float* M = F + F_X3 + b*6;
  double s[9]={0,0,0,0,0,0,0,0,0};
  for(int n = blk*256 + threadIdx.x; n < NPIX; n += RB*256){
    float z0=(Lp[b*NPIX+n]-M[0])/M[1];
    float z1=(E [b*NPIX+n]-M[2])/M[3];
    float z2=(S [b*NPIX+n]-M[4])/M[5];
    s[0]+=z0; s[1]+=z1; s[2]+=z2;
    s[3]+=(double)z0*z0; s[4]+=(double)z0*z1; s[5]+=(double)z0*z2;
    s[6]+=(double)z1*z1; s[7]+=(double)z1*z2; s[8]+=(double)z2*z2;
  }
#pragma unroll
  for(int q=0;q<9;q++){
    double v = waveSum(s[q]);
    if((threadIdx.x&63)==0) atomicAdd(&A[A_XZ+b*9+q], v);
  }
  __shared__ int s_last;
  __syncthreads();
  if(threadIdx.x==0){
    __threadfence();
    s_last = (atomicAdd(&T[1],1u) == (unsigned)(NB*RB-1));
  }
  __syncthreads();
  if(!s_last) return;
  int bb = threadIdx.x;
  if(bb>=NB) return;
  const double* ss = A + A_XZ + bb*9;
  double inv = 1.0/(double)NPIX;
  double m0=ss[0]*inv, m1=ss[1]*inv, m2=ss[2]*inv;
  double a[3][3];
  a[0][0]=fmax(ss[3]*inv-m0*m0,1e-8);
  a[0][1]=a[1][0]=fmax(ss[4]*inv-m0*m1,1e-8);
  a[0][2]=a[2][0]=fmax(ss[5]*inv-m0*m2,1e-8);
  a[1][1]=fmax(ss[6]*inv-m1*m1,1e-8);
  a[1][2]=a[2][1]=fmax(ss[7]*inv-m1*m2,1e-8);
  a[2][2]=fmax(ss[8]*inv-m2*m2,1e-8);
  double V[3][3]={{1,0,0},{0,1,0},{0,0,1}};
  for(int sweep=0;sweep<40;sweep++){
    for(int pp=0;pp<3;pp++){
      int p = (pp==2)?1:0;
      int q = (pp==0)?1:2;
      double apq=a[p][q];
      if(fabs(apq)<1e-30) continue;
      double theta=(a[q][q]-a[p][p])/(2.0*apq);
      double t=((theta>=0)?1.0:-1.0)/(fabs(theta)+sqrt(1.0+theta*theta));
      double c=1.0/sqrt(1.0+t*t), sn=t*c;
      for(int k2=0;k2<3;k2++){ double akp=a[k2][p],akq=a[k2][q];
        a[k2][p]=c*akp-sn*akq; a[k2][q]=sn*akp+c*akq; }
      for(int k2=0;k2<3;k2++){ double apk=a[p][k2],aqk=a[q][k2];
        a[p][k2]=c*apk-sn*aqk; a[q][k2]=sn*apk+c*aqk; }
      for(int k2=0;k2<3;k2++){ double vkp=V[k2][p],vkq=V[k2][q];
        V[k2][p]=c*vkp-sn*vkq; V[k2][q]=sn*vkp+c*vkq; }
    }
  }
  double is0=1.0/sqrt(a[0][0]), is1=1.0/sqrt(a[1][1]), is2=1.0/sqrt(a[2][2]);
  for(int i=0;i<3;i++) for(int j=0;j<3;j++){
    double w = V[i][0]*is0*V[j][0] + V[i][1]*is1*V[j][1] + V[i][2]*is2*V[j][2];
    F[F_WWH + bb*9 + i*3 + j] = (float)w;
  }
  F[F_MEAN+bb*3]=(float)m0; F[F_MEAN+bb*3+1]=(float)m1; F[F_MEAN+bb*3+2]=(float)m2;
}

__global__ void k_xw(const float* Lp,const float* E,const float* S,const float* F,
                     float* Xw,int* idxP){
  int i = blockIdx.x*256 + threadIdx.x; if(i>=BN) return;
  int b=i/NPIX;
  const float* M = F + F_X3 + b*6;
  float lp = Lp[i];
  float z0=(lp-M[0])/M[1];
  float z1=(E [i]-M[2])/M[3];
  float z2=(S [i]-M[4])/M[5];
  float d0=z0-F[F_MEAN+b*3], d1=z1-F[F_MEAN+b*3+1], d2=z2-F[F_MEAN+b*3+2];
  const float* Wm = F + F_WWH + b*9;
  Xw[3*(size_t)i  ]=d0*Wm[0]+d1*Wm[3]+d2*Wm[6];
  Xw[3*(size_t)i+1]=d0*Wm[1]+d1*Wm[4]+d2*Wm[7];
  Xw[3*(size_t)i+2]=d0*Wm[2]+d1*Wm[5]+d2*Wm[8];
  const unsigned* U = (const unsigned*)F;
  float mn=u2f(U[F_MM+b]), mx=u2f(U[F_MM+2+b]);
  float ln = (lp-mn)/(mx-mn+1e-8f);
  ln = fminf(fmaxf(ln,0.f),1.f);
  int id = (int)(ln*32.f);
  idxP[i] = id>31?31:(id<0?0:id);
}

__global__ __launch_bounds__(256) void k_kurt(const float* Xw, const float* arand, double* A){
  int g = blockIdx.x;           // 1024
  int b = g >> 9;
  int t = (g >> 2) & 127;
  int seg = g & 3;
  const float* ar = arand + (b*NT+t)*3;
  float q0=ar[0], q1=ar[1], q2=ar[2];
  float nrm = (float)(sqrt((double)q0*q0+(double)q1*q1+(double)q2*q2)+1e-12);
  float a0=q0/nrm, a1=q1/nrm, a2=q2/nrm;
  const float* X = Xw + (size_t)b*NPIX*3;
  double s1=0,s2=0,s3=0,s4=0;
  int start = seg*36864;
  for(int n=start+threadIdx.x; n<start+36864; n+=256){
    const float* p = X + 3*(size_t)n;
    float z = p[0]*a0 + p[1]*a1 + p[2]*a2;
    float z2f = z*z;
    s1 += z; s2 += z2f; s3 += z2f*z; s4 += (double)z2f*z2f;
  }
  s1=waveSum(s1); s2=waveSum(s2); s3=waveSum(s3); s4=waveSum(s4);
  if((threadIdx.x&63)==0){
    double* K = A + A_KURT + (size_t)(b*NT+t)*4;
    atomicAdd(&K[0],s1); atomicAdd(&K[1],s2); atomicAdd(&K[2],s3); atomicAdd(&K[3],s4);
  }
}
__global__ void k_kurt_pick(const double* A, const float* arand, float* F){
  int b = blockIdx.x;
  int t = threadIdx.x;   // 128
  __shared__ float ak[NT];
  const double* K = A + A_KURT + (size_t)(b*NT+t)*4;
  double inv=1.0/(double)NPIX;
  double mean=K[0]*inv, M2=K[1]*inv, M3=K[2]*inv, M4=K[3]*inv;
  double m2 = M2 - mean*mean + 1e-12;
  double m4 = M4 - 4.0*mean*M3 + 6.0*mean*mean*M2 - 3.0*mean*mean*mean*mean;
  ak[t] = (float)fabs(m4/(m2*m2) - 3.0);
  __syncthreads();
  if(t==0){
    int best=0; float bv=ak[0];
    for(int j=1;j<NT;j++) if(ak[j]>bv){bv=ak[j];best=j;}
    const float* ar = arand + (b*NT+best)*3;
    double nrm = sqrt((double)ar[0]*ar[0]+(double)ar[1]*ar[1]+(double)ar[2]*ar[2])+1e-12;
    F[F_ASTAR+b*3]  =(float)(ar[0]/nrm);
    F[F_ASTAR+b*3+1]=(float)(ar[1]/nrm);
    F[F_ASTAR+b*3+2]=(float)(ar[2]/nrm);
  }
}
__global__ void k_zbest(const float* Xw,const float* F,float* zb){
  int i = blockIdx.x*256 + threadIdx.x; if(i>=BN) return;
  int b=i/NPIX;
  const float* p = Xw + 3*(size_t)i;
  zb[i] = p[0]*F[F_ASTAR+b*3] + p[1]*F[F_ASTAR+b*3+1] + p[2]*F[F_ASTAR+b*3+2];
}

// one EM iteration: 576 blocks, LDS param broadcast + block-level reduction
__global__ __launch_bounds__(256) void k_gmm_red(const float* zb, const float* F, double* A, int it){
  __shared__ float P[6];
  __shared__ double red[4][6];
  int b = blockIdx.x / RB2, blk = blockIdx.x % RB2;
  if(threadIdx.x==0){
    double mu0,mu1,iv0h,iv1h,c0,c1;
    if(it==0) params_init(F,b,mu0,mu1,iv0h,iv1h,c0,c1);
    else {
      const double* g = A + A_GMM + (it-1)*16 + b*6;
      params_from_sums(g[0],g[1],g[2],g[3],g[4],g[5],mu0,mu1,iv0h,iv1h,c0,c1);
    }
    P[0]=(float)mu0; P[1]=(float)mu1; P[2]=(float)iv0h; P[3]=(float)iv1h;
    P[4]=(float)c0;  P[5]=(float)c1;
  }
  __syncthreads();
  float fmu0=P[0], fmu1=P[1], fiv0=P[2], fiv1=P[3], fc0=P[4], fc1=P[5];
  double s[6]={0,0,0,0,0,0};
  for(int n = blk*256 + threadIdx.x; n < NPIX; n += RB2*256){
    float x = zb[b*NPIX+n];
    float r0,r1; estep2f(x,fmu0,fmu1,fiv0,fiv1,fc0,fc1,r0,r1);
    s[0]+=r0; s[1]+=r1; s[2]+=r0*x; s[3]+=r1*x; s[4]+=(double)(r0*x)*x; s[5]+=(double)(r1*x)*x;
  }
  int wave=threadIdx.x>>6, lane=threadIdx.x&63;
#pragma unroll
  for(int q=0;q<6;q++){
    s[q]=waveSum(s[q]);
    if(lane==0) red[wave][q]=s[q];
  }
  __syncthreads();
  if(threadIdx.x==0){
#pragma unroll
    for(int q=0;q<6;q++){
      double v = red[0][q]+red[1][q]+red[2][q]+red[3][q];
      atomicAdd(&A[A_GMM+it*16+b*6+q], v);
    }
  }
}

// final E-step -> R^alpha + fused global hist + cdf
__global__ void k_ralpha(const float* zb, float* F, double* A, const int* idxP,
                         float* Ra0, float* Ra1, unsigned* T){
  __shared__ float h0[NBINS], h1[NBINS];
  __shared__ float P[6];
  if(threadIdx.x<NBINS){ h0[threadIdx.x]=0.f; h1[threadIdx.x]=0.f; }
  int i = blockIdx.x*256 + threadIdx.x;
  int b=i/NPIX;
  if(threadIdx.x==0){
    const double* g = A + A_GMM + 8*16 + b*6;
    double mu0,mu1,iv0h,iv1h,c0,c1;
    params_from_sums(g[0],g[1],g[2],g[3],g[4],g[5],mu0,mu1,iv0h,iv1h,c0,c1);
    P[0]=(float)mu0; P[1]=(float)mu1; P[2]=(float)iv0h; P[3]=(float)iv1h;
    P[4]=(float)c0;  P[5]=(float)c1;
  }
  __syncthreads();
  float r0,r1; estep2f(zb[i],P[0],P[1],P[2],P[3],P[4],P[5],r0,r1);
  float ra0=powf(r0,0.9f), ra1=powf(r1,0.9f);
  float s=ra0+ra1+1e-8f;
  ra0/=s; ra1/=s;
  Ra0[i]=ra0; Ra1[i]=ra1;
  int id = idxP[i];
  atomicAdd(&h0[id], ra0);
  atomicAdd(&h1[id], ra1);
  __syncthreads();
  if(threadIdx.x<NBINS){
    if(h0[threadIdx.x]!=0.f) atomicAdd(&A[A_GHIST+(0*NB+b)*32+threadIdx.x], (double)h0[threadIdx.x]);
    if(h1[threadIdx.x]!=0.f) atomicAdd(&A[A_GHIST+(1*NB+b)*32+threadIdx.x], (double)h1[threadIdx.x]);
  }
  __shared__ int s_last;
  __syncthreads();
  if(threadIdx.x==0){
    __threadfence();
    s_last = (atomicAdd(&T[2],1u) == (unsigned)(BN/256-1));
  }
  __syncthreads();
  if(!s_last) return;
  int t = threadIdx.x;
  if(t>=4) return;
  const double* gh = A + A_GHIST + t*32;
  double sum=0;
  for(int j=0;j<NBINS;j++) sum += gh[j];
  double c=0;
  for(int j=0;j<NBINS;j++){
    c += gh[j]/(sum+1e-8);
    F[F_GCDF+t*32+j]=(float)c;
  }
}

__global__ void k_dk_red(const float* Lp,const float* E,const float* S,
                         const float* Ra0,const float* Ra1,double* A,float* F,unsigned* T){
  int b = blockIdx.x / RB, blk = blockIdx.x % RB;
  double s[20];
#pragma unroll
  for(int q=0;q<20;q++) s[q]=0;
  for(int n = blk*256 + threadIdx.x; n < NPIX; n += RB*256){
    int i=b*NPIX+n;
    double w0=Ra0[i], w1=Ra1[i];
    double x0=Lp[i], x1=E[i], x2=S[i];
    s[0]+=w0; s[1]+=w0*x0; s[2]+=w0*x1; s[3]+=w0*x2;
    s[4]+=w0*x0*x0; s[5]+=w0*x0*x1; s[6]+=w0*x0*x2; s[7]+=w0*x1*x1; s[8]+=w0*x1*x2; s[9]+=w0*x2*x2;
    s[10]+=w1; s[11]+=w1*x0; s[12]+=w1*x1; s[13]+=w1*x2;
    s[14]+=w1*x0*x0; s[15]+=w1*x0*x1; s[16]+=w1*x0*x2; s[17]+=w1*x1*x1; s[18]+=w1*x1*x2; s[19]+=w1*x2*x2;
  }
#pragma unroll
  for(int q=0;q<20;q++){
    double v = waveSum(s[q]);
    if((threadIdx.x&63)==0) atomicAdd(&A[A_DK+b*20+q], v);
  }
  __shared__ int s_last;
  __syncthreads();
  if(threadIdx.x==0){
    __threadfence();
    s_last = (atomicAdd(&T[3],1u) == (unsigned)(NB*RB-1));
  }
  __syncthreads();
  if(!s_last || threadIdx.x) return;
  for(int bb=0;bb<NB;bb++) for(int k=0;k<2;k++){
    const double* ss = A + A_DK + (bb*2+k)*10;
    double W0=ss[0], Ws=W0+1e-8;
    double mu0=ss[1]/Ws, mu1=ss[2]/Ws, mu2=ss[3]/Ws;
    double C00=(ss[4]-2.0*mu0*ss[1]+mu0*mu0*W0)/Ws + 1e-6;
    double C01=(ss[5]-mu0*ss[2]-mu1*ss[1]+mu0*mu1*W0)/Ws;
    double C02=(ss[6]-mu0*ss[3]-mu2*ss[1]+mu0*mu2*W0)/Ws;
    double C11=(ss[7]-2.0*mu1*ss[2]+mu1*mu1*W0)/Ws + 1e-6;
    double C12=(ss[8]-mu1*ss[3]-mu2*ss[2]+mu1*mu2*W0)/Ws;
    double C22=(ss[9]-2.0*mu2*ss[3]+mu2*mu2*W0)/Ws + 1e-6;
    double det = C00*(C11*C22-C12*C12) - C01*(C01*C22-C12*C02) + C02*(C01*C12-C11*C02);
    double id = 1.0/det;
    float* P = F + F_DKINV + (bb*2+k)*9;
    P[0]=(float)((C11*C22-C12*C12)*id);
    P[1]=(float)((C02*C12-C01*C22)*id);
    P[2]=(float)((C01*C12-C02*C11)*id);
    P[3]=(float)((C00*C22-C02*C02)*id);
    P[4]=(float)((C01*C02-C00*C12)*id);
    P[5]=(float)((C00*C11-C01*C01)*id);
    P[6]=(float)mu0; P[7]=(float)mu1; P[8]=(float)mu2;
  }
}
__global__ void k_dm(const float* Lp,const float* E,const float* S,
                     const float* Ra0,const float* Ra1,const float* F,float* DM){
  int i = blockIdx.x*256 + threadIdx.x; if(i>=BN) return;
  int b=i/NPIX;
  float x0=Lp[i], x1=E[i], x2=S[i];
  float D[2];
#pragma unroll
  for(int k=0;k<2;k++){
    const float* P = F + F_DKINV + (b*2+k)*9;
    float d0=x0-P[6], d1=x1-P[7], d2=x2-P[8];
    float q = d0*d0*P[0] + d1*d1*P[3] + d2*d2*P[5]
            + 2.f*(d0*d1*P[1] + d0*d2*P[2] + d1*d2*P[4]);
    D[k]=sqrtf(q+1e-8f);
  }
  float w0=Ra0[i]+1e-8f, w1=Ra1[i]+1e-8f;
  DM[i] = (w0*D[0]+w1*D[1])/(w0+w1);
}

// fused 15x15 weighted box stats (LDS tile) -> tmpL
__global__ __launch_bounds__(256) void k_lla(const float* rk, const float* Lp, float* tmpL){
  int bx = blockIdx.x % 24, by = (blockIdx.x/24) % 24, b = blockIdx.x/576;
  __shared__ float Rt[30][31], Lt[30][31];
  __shared__ float h0[30][17], h1[30][17], h2[30][17];
  int ox = bx*16, oy = by*16;
  const float* Rb = rk + (size_t)b*NPIX;
  const float* Lb = Lp + (size_t)b*NPIX;
  for(int i=threadIdx.x; i<900; i+=256){
    int lx=i%30, ly=i/30;
    int gx_=ox-7+lx, gy_=oy-7+ly;
    bool in = (gx_>=0&&gx_<WW&&gy_>=0&&gy_<HH);
    Rt[ly][lx]= in ? Rb[gy_*WW+gx_] : 0.f;
    Lt[ly][lx]= in ? Lb[gy_*WW+gx_] : 0.f;
  }
  __syncthreads();
  for(int i=threadIdx.x; i<480; i+=256){
    int j=i%16, r=i/16;
    float s0=0,s1=0,s2=0;
#pragma unroll
    for(int d=0;d<15;d++){
      float rr=Rt[r][j+d], ll=Lt[r][j+d];
      s0+=rr; float rl=rr*ll; s1+=rl; s2+=rl*ll;
    }
    h0[r][j]=s0; h1[r][j]=s1; h2[r][j]=s2;
  }
  __syncthreads();
  int tx=threadIdx.x%16, ty=threadIdx.x/16;
  float S0=0,S1=0,S2=0;
#pragma unroll
  for(int d=0;d<15;d++){ S0+=h0[ty+d][tx]; S1+=h1[ty+d][tx]; S2+=h2[ty+d][tx]; }
  int x=ox+tx, y=oy+ty;
  float cy = (float)((y+8<HH?y+8:HH)-(y-7>0?y-7:0));
  float cx = (float)((x+8<WW?x+8:WW)-(x-7>0?x-7:0));
  float cnt = cy*cx;
  float den = S0/cnt + 1e-8f;
  float mu  = (S1/cnt)/den;
  float var = fmaxf((S2/cnt)/den - mu*mu, 1e-8f);
  int n = y*WW+x;
  tmpL[b*NPIX+n] = fabsf(Lb[n]-mu)/(sqrtf(var)+1e-8f);
}

// fused windowed 32-bin histogram box + GLD (replaces histh/slidev/gld)
__global__ __launch_bounds__(256) void k_gldf(const float* rk, const int* idxP, const float* F,
                                              int k, float* tmpG){
  int bx = blockIdx.x % 24, by = (blockIdx.x/24) % 24, b = blockIdx.x/576;
  __shared__ float Rt[30][31];
  __shared__ unsigned char It[30][32];
  __shared__ float Hh[480*33];
  __shared__ float gc[NBINS];
  if(threadIdx.x<NBINS) gc[threadIdx.x]=F[F_GCDF+(k*NB+b)*32+threadIdx.x];
  int ox=bx*16, oy=by*16;
  const float* Rb = rk + (size_t)b*NPIX;
  const int* Ib = idxP + (size_t)b*NPIX;
  for(int i=threadIdx.x;i<900;i+=256){
    int lx=i%30, ly=i/30;
    int gx_=ox-7+lx, gy_=oy-7+ly;
    bool in = (gx_>=0&&gx_<WW&&gy_>=0&&gy_<HH);
    Rt[ly][lx] = in? Rb[gy_*WW+gx_] : 0.f;
    It[ly][lx] = in? (unsigned char)Ib[gy_*WW+gx_] : 0;
  }
  for(int i=threadIdx.x;i<480*33;i+=256) Hh[i]=0.f;
  __syncthreads();
  for(int i=threadIdx.x;i<480;i+=256){
    int j=i%16, r=i/16;
    float* my = Hh + i*33;
    for(int d=0;d<15;d++) my[It[r][j+d]] += Rt[r][j+d];
  }
  __syncthreads();
  int tx=threadIdx.x%16, ty=threadIdx.x/16;
  float vs[32];
  float tot=0;
#pragma unroll
  for(int bin=0;bin<NBINS;bin++){
    float s=0;
#pragma unroll
    for(int d=0;d<15;d++) s += Hh[((ty+d)*16+tx)*33+bin];
    vs[bin]=s; tot+=s;
  }
  int x=ox+tx, y=oy+ty;
  float cy = (float)((y+8<HH?y+8:HH)-(y-7>0?y-7:0));
  float cx = (float)((x+8<WW?x+8:WW)-(x-7>0?x-7:0));
  float cnt = cy*cx;
  float den = tot/cnt + 1e-8f;
  float cs=0, acc=0;
#pragma unroll
  for(int bin=0;bin<NBINS;bin++){
    cs += vs[bin];
    acc += fabsf((cs/cnt)/den - gc[bin]);
  }
  tmpG[b*NPIX + y*WW + x] = acc*(1.f/32.f);
}

__global__ void k_gamma(const float* tmpL,const float* tmpG,const float* rk,const float* F,
                        float* gamma,int first){
  int i = blockIdx.x*256 + threadIdx.x; if(i>=BN) return;
  int b=i/NPIX;
  float zl=(tmpL[i]-F[F_LLA+b*2])/F[F_LLA+b*2+1];
  float zg=(tmpG[i]-F[F_GLD+b*2])/F[F_GLD+b*2+1];
  float c = rk[i]*(0.5f*sp(zl)+0.5f*sp(zg));
  gamma[i] = first ? 1.0f + c : gamma[i] + c;
}

__global__ void k_es_red(const float* E,const float* S,float* F,double* A,unsigned* T){
  int b = blockIdx.x / RB, blk = blockIdx.x % RB;
  const float* M = F + F_X3 + b*6;
  double s[5]={0,0,0,0,0};
  for(int n = blk*256 + threadIdx.x; n < NPIX; n += RB*256){
    float z0=(E[b*NPIX+n]-M[2])/M[3];
    float z1=(S[b*NPIX+n]-M[4])/M[5];
    s[0]+=z0; s[1]+=z1; s[2]+=(double)z0*z0; s[3]+=(double)z0*z1; s[4]+=(double)z1*z1;
  }
#pragma unroll
  for(int q=0;q<5;q++){
    double v = waveSum(s[q]);
    if((threadIdx.x&63)==0) atomicAdd(&A[A_ES+b*5+q], v);
  }
  __shared__ int s_last;
  __syncthreads();
  if(threadIdx.x==0){
    __threadfence();
    s_last = (atomicAdd(&T[4],1u) == (unsigned)(NB*RB-1));
  }
  __syncthreads();
  if(!s_last || threadIdx.x) return;
  for(int bb=0;bb<NB;bb++){
    const double* ss = A + A_ES + bb*5;
    double inv=1.0/(double)NPIX;
    double m0=ss[0]*inv, m1=ss[1]*inv;
    double c00=ss[2]*inv - m0*m0 + 1e-6;
    double c01=ss[3]*inv - m0*m1;
    double c11=ss[4]*inv - m1*m1 + 1e-6;
    double det=c00*c11-c01*c01;
    float* P = F + F_ESI + bb*5;
    P[0]=(float)m0; P[1]=(float)m1;
    P[2]=(float)(c11/det); P[3]=(float)(-c01/det); P[4]=(float)(c00/det);
  }
}
__global__ void k_lanom(const float* E,const float* S,const float* DM,const float* gamma,
                        const float* F,float* La){
  int i = blockIdx.x*256 + threadIdx.x; if(i>=BN) return;
  int b=i/NPIX;
  const float* M = F + F_X3 + b*6;
  const float* P = F + F_ESI + b*5;
  float z0=(E[i]-M[2])/M[3];
  float z1=(S[i]-M[4])/M[5];
  float d0=z0-P[0], d1=z1-P[1];
  float d2 = d0*d0*P[2] + 2.f*d0*d1*P[3] + d1*d1*P[4];
  float Rs = expf(-0.5f*d2);
  La[i] = fmaxf(DM[i]*gamma[i]*(1.f-Rs), 0.f);
}
__global__ void k_out2(const float* La, const float* F, float* out){
  int i = blockIdx.x*256 + threadIdx.x; if(i>=BN) return;
  int b=i/NPIX;
  const float* v = F + F_LAQ + b*4;
  double h1 = 0.01*(double)(NPIX-1); double f1 = h1 - floor(h1);
  double h9 = 0.99*(double)(NPIX-1); double f9 = h9 - floor(h9);
  float q1 = (float)((double)v[0] + f1*((double)v[1]-(double)v[0]));
  float q9 = (float)((double)v[2] + f9*((double)v[3]-(double)v[2]));
  float r = (La[i]-q1)/(q9-q1+1e-8f);
  out[BN + i] = fminf(fmaxf(r,0.f),1.f);
}

// ---------------- host ----------------
static void run_sel(const SelBatch& sb, unsigned* H, unsigned* T, float* F, hipStream_t s){
  k_selz16<<<sb.nt*1024,256,0,s>>>(sb,H,T);
  k_selp16<<<sb.nt*SEL_BLK,256,0,s>>>(sb,H,T,F,0,0);
  k_selp16<<<sb.nt*SEL_BLK,256,0,s>>>(sb,H,T,F,0,1);
  if(sb.medmad){
    k_selp16<<<sb.nt*SEL_BLK,256,0,s>>>(sb,H,T,F,1,0);
    k_selp16<<<sb.nt*SEL_BLK,256,0,s>>>(sb,H,T,F,1,1);
  }
}

extern "C" void kernel_launch(void* const* d_in, const int* in_sizes, int n_in,
                              void* d_out, int out_size, void* d_ws, size_t ws_size,
                              hipStream_t stream){
  (void)in_sizes; (void)n_in; (void)out_size; (void)ws_size;
  const float* lab   = (const float*)d_in[0];
  const float* arand = (const float*)d_in[1];
  float* out = (float*)d_out;
  char* wsb = (char*)d_ws;
  double* A = (double*)wsb;                   // 2048 doubles
  float*  F = (float*)(wsb + 16384);          // 4096 floats
  unsigned* T = (unsigned*)(wsb + 32768);     // 256 u32
  float* planes = (float*)(wsb + 65536);
  float* E    = planes;
  float* S    = planes + (size_t)BN;
  float* tA   = planes + (size_t)2*BN;        // La
  float* tmpL = planes + (size_t)5*BN;
  float* tmpG = planes + (size_t)6*BN;
  float* Xw   = planes + (size_t)7*BN;        // interleaved xyz (3*BN)
  float* zb   = planes + (size_t)10*BN;
  float* Ra0  = planes + (size_t)11*BN;
  float* Ra1  = planes + (size_t)12*BN;
  float* DM   = planes + (size_t)13*BN;
  float* gamma= planes + (size_t)14*BN;
  int*   idxP = (int*)(planes + (size_t)16*BN);
  unsigned* H16 = (unsigned*)(planes + (size_t)17*BN);  // select hists (8 MB max)

  const int GBN = BN/256;      // 1152

  k_zero<<<16,256,0,stream>>>(A,F,T);
  k_sobel<<<NB*576,256,0,stream>>>(lab,S,E);
  k_beta_red<<<NB*RB,256,0,stream>>>(E,S,lab,A,F,T);
  k_lperp<<<GBN,256,0,stream>>>(lab,E,S,F,out);

  SelBatch sbX; sbX.nt=6; sbX.medmad=1;
  for(int b=0;b<NB;b++){
    sbX.src[b*3+0]=out+(size_t)b*NPIX; sbX.src[b*3+1]=E+(size_t)b*NPIX; sbX.src[b*3+2]=S+(size_t)b*NPIX;
    for(int ch=0;ch<3;ch++){ sbX.rank[b*3+ch]=MEDRANK; sbX.fslot[b*3+ch]=F_X3+(b*3+ch)*2; }
  }
  run_sel(sbX,H16,T,F,stream);

  k_xz_red<<<NB*RB,256,0,stream>>>(out,E,S,F,A,T);
  k_xw<<<GBN,256,0,stream>>>(out,E,S,F,Xw,idxP);
  k_kurt<<<1024,256,0,stream>>>(Xw,arand,A);
  k_kurt_pick<<<NB,128,0,stream>>>(A,arand,F);
  k_zbest<<<GBN,256,0,stream>>>(Xw,F,zb);

  SelBatch sbZ; sbZ.nt=8; sbZ.medmad=0;
  {
    int rr[4]={36863,36864,110591,110592};
    for(int b=0;b<NB;b++) for(int ri=0;ri<4;ri++){
      int t=b*4+ri;
      sbZ.src[t]=zb+(size_t)b*NPIX; sbZ.rank[t]=rr[ri]; sbZ.fslot[t]=F_ZBQ+b*4+ri;
    }
  }
  run_sel(sbZ,H16,T,F,stream);

  for(int it=0; it<9; ++it)
    k_gmm_red<<<NB*RB2,256,0,stream>>>(zb,F,A,it);
  k_ralpha<<<GBN,256,0,stream>>>(zb,F,A,idxP,Ra0,Ra1,T);
  k_dk_red<<<NB*RB,256,0,stream>>>(out,E,S,Ra0,Ra1,A,F,T);
  k_dm<<<GBN,256,0,stream>>>(out,E,S,Ra0,Ra1,F,DM);

  SelBatch sbC; sbC.nt=4; sbC.medmad=1;
  for(int b=0;b<NB;b++){
    sbC.src[b]  =tmpL+(size_t)b*NPIX; sbC.rank[b]  =MEDRANK; sbC.fslot[b]  =F_LLA+b*2;
    sbC.src[2+b]=tmpG+(size_t)b*NPIX; sbC.rank[2+b]=MEDRANK; sbC.fslot[2+b]=F_GLD+b*2;
  }

  for(int k=0;k<2;k++){
    const float* Rk = k ? Ra1 : Ra0;
    k_lla<<<NB*576,256,0,stream>>>(Rk,out,tmpL);
    k_gldf<<<NB*576,256,0,stream>>>(Rk,idxP,F,k,tmpG);
    run_sel(sbC,H16,T,F,stream);
    k_gamma<<<GBN,256,0,stream>>>(tmpL,tmpG,Rk,F,gamma,k==0?1:0);
  }

  k_es_red<<<NB*RB,256,0,stream>>>(E,S,F,A,T);
  k_lanom<<<GBN,256,0,stream>>>(E,S,DM,gamma,F,tA);

  SelBatch sbL; sbL.nt=8; sbL.medmad=0;
  {
    int rr[4]={1474,1475,145980,145981};
    for(int b=0;b<NB;b++) for(int ri=0;ri<4;ri++){
      int t=b*4+ri;
      sbL.src[t]=tA+(size_t)b*NPIX; sbL.rank[t]=rr[ri]; sbL.fslot[t]=F_LAQ+b*4+ri;
    }
  }
  run_sel(sbL,H16,T,F,stream);

  k_out2<<<GBN,256,0,stream>>>(tA,F,out);
}

// Round 6
// 959.274 us; speedup vs baseline: 3.8972x; 1.4333x over previous
//
#include <hip/hip_runtime.h>
#include <math.h>

#define HH 384
#define WW 384
#define NPIX (HH*WW)          // 147456
#define NB 2
#define BN (NB*NPIX)          // 294912
#define NT 128
#define NBINS 32
#define MEDRANK ((NPIX-1)/2)  // 73727
#define RB 72                 // reduction blocks per batch
#define RB2 288               // gmm reduction blocks per batch
#define SEL_BLK 64            // blocks per select task per pass

// ---- double arena (ws+0, 2048 doubles) ----
#define A_BETA 0
#define A_XZ   16
#define A_ES   40
#define A_DK   56
#define A_GMM  128  // 9 iters * 16
#define A_GHIST 288
#define A_KURT 512

// ---- float arena (ws+16384, 4096 floats) ----
#define F_BETA 0
#define F_X3   8    // (b*3+ch)*2 {med,mad}; ch1=E ch2=S also serve ES stage
#define F_MEAN 24
#define F_WWH  32
#define F_ASTAR 828
#define F_ZBQ  868
#define F_DKINV 880
#define F_LLA  918
#define F_GLD  924
#define F_ESI  940
#define F_LAQ  952
#define F_GCDF 968
#define F_MMS_MIN 1280  // b*32+slot (u32, init 0xFFFFFFFF)
#define F_MMS_MAX 1408  // b*32+slot (u32, init 0)

// ---- ticket/meta arena T (u32, ws+32768, 256 u32) ----

__device__ __forceinline__ double waveSum(double v){
#pragma unroll
  for(int o=32;o;o>>=1) v += __shfl_down(v,o,64);
  return v;
}
__device__ __forceinline__ unsigned f2u(float f){
  unsigned u = __float_as_uint(f);
  return (u & 0x80000000u) ? ~u : (u | 0x80000000u);
}
__device__ __forceinline__ float u2f(unsigned u){
  return __uint_as_float((u & 0x80000000u) ? (u ^ 0x80000000u) : ~u);
}
__device__ __forceinline__ float sp(float x){
  float t = log1pf(expf(-fabsf(x)));
  return x >= 0.f ? x + t : t;
}

struct SelBatch {
  const float* src[8];
  int rank[8];
  int fslot[8];
  int nt;
  int medmad;
};

__device__ void pick256v(unsigned x, int rank, unsigned& sel, int& nrank){
  __shared__ unsigned s_cum[256];
  __shared__ unsigned s_res[2];
  int tid = threadIdx.x;
  s_cum[tid] = x;
  __syncthreads();
  for(int o=1;o<256;o<<=1){
    unsigned t = (tid>=o)? s_cum[tid-o] : 0u;
    __syncthreads();
    s_cum[tid] += t;
    __syncthreads();
  }
  unsigned cum = s_cum[tid];
  unsigned ex  = cum - x;
  if(x>0u && (unsigned)rank>=ex && (unsigned)rank<cum){
    s_res[0]=(unsigned)tid; s_res[1]=(unsigned)(rank-(int)ex);
  }
  __syncthreads();
  sel = s_res[0]; nrank = (int)s_res[1];
  __syncthreads();
}
__device__ void locate64k(const unsigned* hp, int rank, unsigned& bin, int& rem){
  unsigned s=0;
  for(int r=0;r<256;r++) s += hp[r*256 + threadIdx.x];
  unsigned c; int r1;
  pick256v(s, rank, c, r1);
  unsigned x = hp[threadIdx.x*256 + c];
  unsigned rsel; int r2;
  pick256v(x, r1, rsel, r2);
  bin = (c<<8)|rsel; rem = r2;
}

__global__ void k_zero(double* A, float* F, unsigned* T){
  int i = blockIdx.x*blockDim.x + threadIdx.x;
  if(i < 2048) A[i] = 0.0;
  if(i < 4096){
    unsigned* U = (unsigned*)F;
    unsigned v = 0u;
    if(i>=F_MMS_MIN && i<F_MMS_MIN+64) v = 0xFFFFFFFFu;
    U[i] = v;
  }
  if(i < 256) T[i] = 0u;
}

__global__ void k_selz16(SelBatch sb, unsigned* Hh, unsigned* T){
  int i = blockIdx.x*256 + threadIdx.x;
  Hh[i]=0u;
  if(i < 32) T[16+i]=0u;
  if(i < 8 && i < sb.nt){
    unsigned* m = T + 80 + i*8;
    m[0]=0u; m[1]=(unsigned)sb.rank[i];
    m[2]=0u; m[3]=(unsigned)sb.rank[i];
    m[4]=0u;
  }
}

__global__ __launch_bounds__(256) void k_selp16(SelBatch sb, unsigned* Hh, unsigned* T,
                                                float* F, int stage, int ps){
  int task = blockIdx.x / SEL_BLK;
  int blk  = blockIdx.x % SEL_BLK;
  unsigned* meta = T + 80 + task*8;
  float center = (stage==1) ? __uint_as_float(meta[4]) : 0.f;
  unsigned hisel = meta[stage*2];
  unsigned* hp = Hh + task*262144 + (stage*2+ps)*65536;
  const float* src = sb.src[task];
  for(int i=blk*256+threadIdx.x; i<NPIX; i+=SEL_BLK*256){
    float v = src[i];
    if(stage) v = fabsf(v-center);
    unsigned u = f2u(v);
    if(ps==0){
      unsigned bin = u>>16;
      atomicAdd(&hp[((bin&255u)<<8)|(bin>>8)], 1u);
    } else if((u>>16)==hisel){
      unsigned bin = u&0xFFFFu;
      atomicAdd(&hp[((bin&255u)<<8)|(bin>>8)], 1u);
    }
  }
  __shared__ int s_last;
  __syncthreads();
  if(threadIdx.x==0){
    __threadfence();
    s_last = (atomicAdd(&T[16+task*4+stage*2+ps],1u) == (unsigned)(SEL_BLK-1));
  }
  __syncthreads();
  if(!s_last) return;
  int r = (int)meta[stage*2+1];
  unsigned bin; int rem;
  locate64k(hp, r, bin, rem);
  if(threadIdx.x==0){
    if(ps==0){ meta[stage*2]=bin; meta[stage*2+1]=(unsigned)rem; }
    else {
      float val = u2f((hisel<<16)|bin);
      if(stage==0){
        if(sb.medmad) meta[4]=__float_as_uint(val);
        else F[sb.fslot[task]]=val;
      } else {
        F[sb.fslot[task]]   = __uint_as_float(meta[4]);
        F[sb.fslot[task]+1] = val*1.4826f + 1e-8f;
      }
    }
  }
}

__device__ void params_from_sums(double N0,double N1,double Sx0,double Sx1,double Sxx0,double Sxx1,
                                 double& mu0,double& mu1,double& iv0h,double& iv1h,
                                 double& c0,double& c1){
  mu0=Sx0/(N0+1e-8); mu1=Sx1/(N1+1e-8);
  double v0=(Sxx0-2.0*mu0*Sx0+mu0*mu0*N0)/(N0+1e-8)+1e-6;
  double v1=(Sxx1-2.0*mu1*Sx1+mu1*mu1*N1)/(N1+1e-8)+1e-6;
  double p0=N0/(double)NPIX, p1=N1/(double)NPIX;
  c0=-0.5*log(v0+1e-6)+log(p0+1e-8);
  c1=-0.5*log(v1+1e-6)+log(p1+1e-8);
  iv0h=0.5/(v0+1e-6); iv1h=0.5/(v1+1e-6);
}
__device__ void params_init(const float* F, int b,
                            double& mu0,double& mu1,double& iv0h,double& iv1h,
                            double& c0,double& c1){
  const float* z = F + F_ZBQ + b*4;
  double h25 = 0.25*(double)(NPIX-1); double f25 = h25 - floor(h25);
  double h75 = 0.75*(double)(NPIX-1); double f75 = h75 - floor(h75);
  mu0 = (double)z[0] + f25*((double)z[1]-(double)z[0]);
  mu1 = (double)z[2] + f75*((double)z[3]-(double)z[2]);
  double v0=1.0, v1=1.0, p0=0.5, p1=0.5;
  c0=-0.5*log(v0+1e-6)+log(p0+1e-8);
  c1=-0.5*log(v1+1e-6)+log(p1+1e-8);
  iv0h=0.5/(v0+1e-6); iv1h=0.5/(v1+1e-6);
}
__device__ __forceinline__ void estep2f(float x,float mu0,float mu1,float iv0h,float iv1h,
                                        float c0,float c1,float& r0,float& r1){
  float d0=x-mu0, d1=x-mu1;
  float l0=-d0*d0*iv0h+c0, l1=-d1*d1*iv1h+c1;
  float m=fmaxf(l0,l1);
  float e0=expf(l0-m), e1=expf(l1-m);
  float s=e0+e1;
  r0=e0/s; r1=e1/s;
}

// ---------------- pipeline kernels ----------------
__global__ __launch_bounds__(256) void k_sobel(const float* lab, float* S, float* E){
  int bx = blockIdx.x % 24, by = (blockIdx.x/24) % 24, b = blockIdx.x/576;
  __shared__ float Lt[20][21];
  __shared__ float G[18][19];
  const float* Lb = lab + b*3*NPIX;
  int ox = bx*16, oy = by*16;
  for(int i=threadIdx.x; i<400; i+=256){
    int lx=i%20, ly=i/20;
    int gx_=ox-2+lx, gy_=oy-2+ly;
    Lt[ly][lx] = (gx_<0||gx_>=WW||gy_<0||gy_>=HH)?0.f:Lb[gy_*WW+gx_];
  }
  __syncthreads();
  for(int i=threadIdx.x; i<324; i+=256){
    int lx=i%18, ly=i/18;
    int px=lx+1, py=ly+1;
    int gxp=ox-2+px, gyp=oy-2+py;
    float g=0.f;
    if(gxp>=0&&gxp<WW&&gyp>=0&&gyp<HH){
      float gx = -Lt[py-1][px-1]+Lt[py-1][px+1] -2.f*Lt[py][px-1]+2.f*Lt[py][px+1] -Lt[py+1][px-1]+Lt[py+1][px+1];
      float gy = -Lt[py-1][px-1]-2.f*Lt[py-1][px]-Lt[py-1][px+1] +Lt[py+1][px-1]+2.f*Lt[py+1][px]+Lt[py+1][px+1];
      g = gx*gx+gy*gy;
    }
    G[ly][lx]=g;
  }
  __syncthreads();
  int tx = threadIdx.x%16, ty = threadIdx.x/16;
  float s=0;
#pragma unroll
  for(int dy=0;dy<3;dy++)
#pragma unroll
    for(int dx=0;dx<3;dx++) s += G[ty+dy][tx+dx];
  int n = (oy+ty)*WW + ox+tx;
  E[b*NPIX+n] = s*(1.f/9.f);
  float av=Lb[NPIX+n], bv=Lb[2*NPIX+n];
  S[b*NPIX+n] = sqrtf(av*av+bv*bv+1e-8f);
}

__global__ void k_beta_red(const float* E,const float* S,const float* lab,double* A,
                           float* F, unsigned* T){
  int b = blockIdx.x / RB, blk = blockIdx.x % RB;
  double s[5]={0,0,0,0,0};
  for(int n = blk*256 + threadIdx.x; n < NPIX; n += RB*256){
    float e=E[b*NPIX+n], ss=S[b*NPIX+n], l=lab[b*3*NPIX+n];
    s[0]+=(double)e*e; s[1]+=(double)e*ss; s[2]+=(double)ss*ss;
    s[3]+=(double)e*l; s[4]+=(double)ss*l;
  }
  __shared__ double red[4][5];
  int wave=threadIdx.x>>6, lane=threadIdx.x&63;
#pragma unroll
  for(int q=0;q<5;q++){
    s[q]=waveSum(s[q]);
    if(lane==0) red[wave][q]=s[q];
  }
  __syncthreads();
  if(threadIdx.x<5){
    double v = red[0][threadIdx.x]+red[1][threadIdx.x]+red[2][threadIdx.x]+red[3][threadIdx.x];
    atomicAdd(&A[A_BETA+b*5+threadIdx.x], v);
  }
  __shared__ int s_last;
  __syncthreads();
  if(threadIdx.x==0){
    __threadfence();
    s_last = (atomicAdd(&T[0],1u) == (unsigned)(NB*RB-1));
  }
  __syncthreads();
  if(!s_last || threadIdx.x) return;
  for(int bb=0;bb<NB;bb++){
    double EE=A[A_BETA+bb*5],ES=A[A_BETA+bb*5+1],SS=A[A_BETA+bb*5+2],EL=A[A_BETA+bb*5+3],SL=A[A_BETA+bb*5+4];
    double a00=EE+1e-6, a01=ES, a11=SS+1e-6;
    double det=a00*a11-a01*a01;
    F[F_BETA+bb*2]  =(float)(( a11*EL - a01*SL)/det);
    F[F_BETA+bb*2+1]=(float)((-a01*EL + a00*SL)/det);
  }
}

// L_perp + block-level min/max into 32 padded slots per batch
__global__ void k_lperp(const float* lab,const float* E,const float* S,const float* F,float* out0){
  int i = blockIdx.x*256 + threadIdx.x;
  int b=i/NPIX, n=i%NPIX;
  float v = lab[b*3*NPIX+n] - F[F_BETA+b*2]*E[i] - F[F_BETA+b*2+1]*S[i];
  out0[i] = v;
  unsigned u = f2u(v);
  unsigned mn=u, mx=u;
#pragma unroll
  for(int o=32;o;o>>=1){
    unsigned a = __shfl_down(mn,o,64); mn = (a<mn)?a:mn;
    unsigned c = __shfl_down(mx,o,64); mx = (c>mx)?c:mx;
  }
  __shared__ unsigned rmn[4], rmx[4];
  int wave=threadIdx.x>>6, lane=threadIdx.x&63;
  if(lane==0){ rmn[wave]=mn; rmx[wave]=mx; }
  __syncthreads();
  if(threadIdx.x==0){
    unsigned m0 = rmn[0]; unsigned m1 = rmx[0];
    for(int w=1;w<4;w++){ if(rmn[w]<m0)m0=rmn[w]; if(rmx[w]>m1)m1=rmx[w]; }
    unsigned* U = (unsigned*)F;
    int slot = blockIdx.x & 31;
    atomicMin(&U[F_MMS_MIN+b*32+slot], m0);
    atomicMax(&U[F_MMS_MAX+b*32+slot], m1);
  }
}

__global__ void k_xz_red(const float* Lp,const float* E,const float* S,float* F,double* A,
                         unsigned* T){
  int b = blockIdx.x / RB, blk = blockIdx.x % RB;
  const float* M = F + F_X3 + b*6;
  double s[9]={0,0,0,0,0,0,0,0,0};
  for(int n = blk*256 + threadIdx.x; n < NPIX; n += RB*256){
    float z0=(Lp[b*NPIX+n]-M[0])/M[1];
    float z1=(E [b*NPIX+n]-M[2])/M[3];
    float z2=(S [b*NPIX+n]-M[4])/M[5];
    s[0]+=z0; s[1]+=z1; s[2]+=z2;
    s[3]+=(double)z0*z0; s[4]+=(double)z0*z1; s[5]+=(double)z0*z2;
    s[6]+=(double)z1*z1; s[7]+=(double)z1*z2; s[8]+=(double)z2*z2;
  }
  __shared__ double red[4][9];
  int wave=threadIdx.x>>6, lane=threadIdx.x&63;
#pragma unroll
  for(int q=0;q<9;q++){
    s[q]=waveSum(s[q]);
    if(lane==0) red[wave][q]=s[q];
  }
  __syncthreads();
  if(threadIdx.x<9){
    double v = red[0][threadIdx.x]+red[1][threadIdx.x]+red[2][threadIdx.x]+red[3][threadIdx.x];
    atomicAdd(&A[A_XZ+b*9+threadIdx.x], v);
  }
  __shared__ int s_last;
  __syncthreads();
  if(threadIdx.x==0){
    __threadfence();
    s_last = (atomicAdd(&T[1],1u) == (unsigned)(NB*RB-1));
  }
  __syncthreads();
  if(!s_last) return;
  int bb = threadIdx.x;
  if(bb>=NB) return;
  const double* ss = A + A_XZ + bb*9;
  double inv = 1.0/(double)NPIX;
  double m0=ss[0]*inv, m1=ss[1]*inv, m2=ss[2]*inv;
  double a[3][3];
  a[0][0]=fmax(ss[3]*inv-m0*m0,1e-8);
  a[0][1]=a[1][0]=fmax(ss[4]*inv-m0*m1,1e-8);
  a[0][2]=a[2][0]=fmax(ss[5]*inv-m0*m2,1e-8);
  a[1][1]=fmax(ss[6]*inv-m1*m1,1e-8);
  a[1][2]=a[2][1]=fmax(ss[7]*inv-m1*m2,1e-8);
  a[2][2]=fmax(ss[8]*inv-m2*m2,1e-8);
  double V[3][3]={{1,0,0},{0,1,0},{0,0,1}};
  for(int sweep=0;sweep<40;sweep++){
    for(int pp=0;pp<3;pp++){
      int p = (pp==2)?1:0;
      int q = (pp==0)?1:2;
      double apq=a[p][q];
      if(fabs(apq)<1e-30) continue;
      double theta=(a[q][q]-a[p][p])/(2.0*apq);
      double t=((theta>=0)?1.0:-1.0)/(fabs(theta)+sqrt(1.0+theta*theta));
      double c=1.0/sqrt(1.0+t*t), sn=t*c;
      for(int k2=0;k2<3;k2++){ double akp=a[k2][p],akq=a[k2][q];
        a[k2][p]=c*akp-sn*akq; a[k2][q]=sn*akp+c*akq; }
      for(int k2=0;k2<3;k2++){ double apk=a[p][k2],aqk=a[q][k2];
        a[p][k2]=c*apk-sn*aqk; a[q][k2]=sn*apk+c*aqk; }
      for(int k2=0;k2<3;k2++){ double vkp=V[k2][p],vkq=V[k2][q];
        V[k2][p]=c*vkp-sn*vkq; V[k2][q]=sn*vkp+c*vkq; }
    }
  }
  double is0=1.0/sqrt(a[0][0]), is1=1.0/sqrt(a[1][1]), is2=1.0/sqrt(a[2][2]);
  for(int i=0;i<3;i++) for(int j=0;j<3;j++){
    double w = V[i][0]*is0*V[j][0] + V[i][1]*is1*V[j][1] + V[i][2]*is2*V[j][2];
    F[F_WWH + bb*9 + i*3 + j] = (float)w;
  }
  F[F_MEAN+bb*3]=(float)m0; F[F_MEAN+bb*3+1]=(float)m1; F[F_MEAN+bb*3+2]=(float)m2;
}

__global__ void k_xw(const float* Lp,const float* E,const float* S,const float* F,
                     float* Xw,int* idxP){
  __shared__ float s_mn, s_mx;
  int i = blockIdx.x*256 + threadIdx.x;
  int b=i/NPIX;
  if(threadIdx.x==0){
    const unsigned* U = (const unsigned*)F;
    unsigned mn=0xFFFFFFFFu, mx=0u;
    for(int s2=0;s2<32;s2++){
      unsigned a=U[F_MMS_MIN+b*32+s2]; if(a<mn)mn=a;
      unsigned c=U[F_MMS_MAX+b*32+s2]; if(c>mx)mx=c;
    }
    s_mn=u2f(mn); s_mx=u2f(mx);
  }
  __syncthreads();
  const float* M = F + F_X3 + b*6;
  float lp = Lp[i];
  float z0=(lp-M[0])/M[1];
  float z1=(E [i]-M[2])/M[3];
  float z2=(S [i]-M[4])/M[5];
  float d0=z0-F[F_MEAN+b*3], d1=z1-F[F_MEAN+b*3+1], d2=z2-F[F_MEAN+b*3+2];
  const float* Wm = F + F_WWH + b*9;
  Xw[3*(size_t)i  ]=d0*Wm[0]+d1*Wm[3]+d2*Wm[6];
  Xw[3*(size_t)i+1]=d0*Wm[1]+d1*Wm[4]+d2*Wm[7];
  Xw[3*(size_t)i+2]=d0*Wm[2]+d1*Wm[5]+d2*Wm[8];
  float ln = (lp-s_mn)/(s_mx-s_mn+1e-8f);
  ln = fminf(fmaxf(ln,0.f),1.f);
  int id = (int)(ln*32.f);
  idxP[i] = id>31?31:(id<0?0:id);
}

__global__ __launch_bounds__(256) void k_kurt(const float* Xw, const float* arand, double* A){
  int g = blockIdx.x;           // 1024
  int b = g >> 9;
  int t = (g >> 2) & 127;
  int seg = g & 3;
  const float* ar = arand + (b*NT+t)*3;
  float q0=ar[0], q1=ar[1], q2=ar[2];
  float nrm = (float)(sqrt((double)q0*q0+(double)q1*q1+(double)q2*q2)+1e-12);
  float a0=q0/nrm, a1=q1/nrm, a2=q2/nrm;
  const float* X = Xw + (size_t)b*NPIX*3;
  double s1=0,s2=0,s3=0,s4=0;
  int start = seg*36864;
  for(int n=start+threadIdx.x; n<start+36864; n+=256){
    const float* p = X + 3*(size_t)n;
    float z = p[0]*a0 + p[1]*a1 + p[2]*a2;
    float z2f = z*z;
    s1 += z; s2 += z2f; s3 += z2f*z; s4 += (double)z2f*z2f;
  }
  s1=waveSum(s1); s2=waveSum(s2); s3=waveSum(s3); s4=waveSum(s4);
  __shared__ double red[4][4];
  int wave=threadIdx.x>>6, lane=threadIdx.x&63;
  if(lane==0){ red[wave][0]=s1; red[wave][1]=s2; red[wave][2]=s3; red[wave][3]=s4; }
  __syncthreads();
  if(threadIdx.x<4){
    double v = red[0][threadIdx.x]+red[1][threadIdx.x]+red[2][threadIdx.x]+red[3][threadIdx.x];
    atomicAdd(&A[A_KURT + (size_t)(b*NT+t)*4 + threadIdx.x], v);
  }
}
__global__ void k_kurt_pick(const double* A, const float* arand, float* F){
  int b = blockIdx.x;
  int t = threadIdx.x;   // 128
  __shared__ float ak[NT];
  const double* K = A + A_KURT + (size_t)(b*NT+t)*4;
  double inv=1.0/(double)NPIX;
  double mean=K[0]*inv, M2=K[1]*inv, M3=K[2]*inv, M4=K[3]*inv;
  double m2 = M2 - mean*mean + 1e-12;
  double m4 = M4 - 4.0*mean*M3 + 6.0*mean*mean*M2 - 3.0*mean*mean*mean*mean;
  ak[t] = (float)fabs(m4/(m2*m2) - 3.0);
  __syncthreads();
  if(t==0){
    int best=0; float bv=ak[0];
    for(int j=1;j<NT;j++) if(ak[j]>bv){bv=ak[j];best=j;}
    const float* ar = arand + (b*NT+best)*3;
    double nrm = sqrt((double)ar[0]*ar[0]+(double)ar[1]*ar[1]+(double)ar[2]*ar[2])+1e-12;
    F[F_ASTAR+b*3]  =(float)(ar[0]/nrm);
    F[F_ASTAR+b*3+1]=(float)(ar[1]/nrm);
    F[F_ASTAR+b*3+2]=(float)(ar[2]/nrm);
  }
}
__global__ void k_zbest(const float* Xw,const float* F,float* zb){
  int i = blockIdx.x*256 + threadIdx.x; if(i>=BN) return;
  int b=i/NPIX;
  const float* p = Xw + 3*(size_t)i;
  zb[i] = p[0]*F[F_ASTAR+b*3] + p[1]*F[F_ASTAR+b*3+1] + p[2]*F[F_ASTAR+b*3+2];
}

__global__ __launch_bounds__(256) void k_gmm_red(const float* zb, const float* F, double* A, int it){
  __shared__ float P[6];
  __shared__ double red[4][6];
  int b = blockIdx.x / RB2, blk = blockIdx.x % RB2;
  if(threadIdx.x==0){
    double mu0,mu1,iv0h,iv1h,c0,c1;
    if(it==0) params_init(F,b,mu0,mu1,iv0h,iv1h,c0,c1);
    else {
      const double* g = A + A_GMM + (it-1)*16 + b*6;
      params_from_sums(g[0],g[1],g[2],g[3],g[4],g[5],mu0,mu1,iv0h,iv1h,c0,c1);
    }
    P[0]=(float)mu0; P[1]=(float)mu1; P[2]=(float)iv0h; P[3]=(float)iv1h;
    P[4]=(float)c0;  P[5]=(float)c1;
  }
  __syncthreads();
  float fmu0=P[0], fmu1=P[1], fiv0=P[2], fiv1=P[3], fc0=P[4], fc1=P[5];
  double s[6]={0,0,0,0,0,0};
  for(int n = blk*256 + threadIdx.x; n < NPIX; n += RB2*256){
    float x = zb[b*NPIX+n];
    float r0,r1; estep2f(x,fmu0,fmu1,fiv0,fiv1,fc0,fc1,r0,r1);
    s[0]+=r0; s[1]+=r1; s[2]+=r0*x; s[3]+=r1*x; s[4]+=(double)(r0*x)*x; s[5]+=(double)(r1*x)*x;
  }
  int wave=threadIdx.x>>6, lane=threadIdx.x&63;
#pragma unroll
  for(int q=0;q<6;q++){
    s[q]=waveSum(s[q]);
    if(lane==0) red[wave][q]=s[q];
  }
  __syncthreads();
  if(threadIdx.x<6){
    double v = red[0][threadIdx.x]+red[1][threadIdx.x]+red[2][threadIdx.x]+red[3][threadIdx.x];
    atomicAdd(&A[A_GMM+it*16+b*6+threadIdx.x], v);
  }
}

__global__ void k_ralpha(const float* zb, float* F, double* A, const int* idxP,
                         float* Ra0, float* Ra1, unsigned* T){
  __shared__ float h0[NBINS], h1[NBINS];
  __shared__ float P[6];
  if(threadIdx.x<NBINS){ h0[threadIdx.x]=0.f; h1[threadIdx.x]=0.f; }
  int i = blockIdx.x*256 + threadIdx.x;
  int b=i/NPIX;
  if(threadIdx.x==0){
    const double* g = A + A_GMM + 8*16 + b*6;
    double mu0,mu1,iv0h,iv1h,c0,c1;
    params_from_sums(g[0],g[1],g[2],g[3],g[4],g[5],mu0,mu1,iv0h,iv1h,c0,c1);
    P[0]=(float)mu0; P[1]=(float)mu1; P[2]=(float)iv0h; P[3]=(float)iv1h;
    P[4]=(float)c0;  P[5]=(float)c1;
  }
  __syncthreads();
  float r0,r1; estep2f(zb[i],P[0],P[1],P[2],P[3],P[4],P[5],r0,r1);
  float ra0=powf(r0,0.9f), ra1=powf(r1,0.9f);
  float s=ra0+ra1+1e-8f;
  ra0/=s; ra1/=s;
  Ra0[i]=ra0; Ra1[i]=ra1;
  int id = idxP[i];
  atomicAdd(&h0[id], ra0);
  atomicAdd(&h1[id], ra1);
  __syncthreads();
  if(threadIdx.x<NBINS){
    if(h0[threadIdx.x]!=0.f) atomicAdd(&A[A_GHIST+(0*NB+b)*32+threadIdx.x], (double)h0[threadIdx.x]);
    if(h1[threadIdx.x]!=0.f) atomicAdd(&A[A_GHIST+(1*NB+b)*32+threadIdx.x], (double)h1[threadIdx.x]);
  }
  __shared__ int s_last;
  __syncthreads();
  if(threadIdx.x==0){
    __threadfence();
    s_last = (atomicAdd(&T[2],1u) == (unsigned)(BN/256-1));
  }
  __syncthreads();
  if(!s_last) return;
  int t = threadIdx.x;
  if(t>=4) return;
  const double* gh = A + A_GHIST + t*32;
  double sum=0;
  for(int j=0;j<NBINS;j++) sum += gh[j];
  double c=0;
  for(int j=0;j<NBINS;j++){
    c += gh[j]/(sum+1e-8);
    F[F_GCDF+t*32+j]=(float)c;
  }
}

__global__ void k_dk_red(const float* Lp,const float* E,const float* S,
                         const float* Ra0,const float* Ra1,double* A,float* F,unsigned* T){
  int b = blockIdx.x / RB, blk = blockIdx.x % RB;
  double s[20];
#pragma unroll
  for(int q=0;q<20;q++) s[q]=0;
  for(int n = blk*256 + threadIdx.x; n < NPIX; n += RB*256){
    int i=b*NPIX+n;
    double w0=Ra0[i], w1=Ra1[i];
    double x0=Lp[i], x1=E[i], x2=S[i];
    s[0]+=w0; s[1]+=w0*x0; s[2]+=w0*x1; s[3]+=w0*x2;
    s[4]+=w0*x0*x0; s[5]+=w0*x0*x1; s[6]+=w0*x0*x2; s[7]+=w0*x1*x1; s[8]+=w0*x1*x2; s[9]+=w0*x2*x2;
    s[10]+=w1; s[11]+=w1*x0; s[12]+=w1*x1; s[13]+=w1*x2;
    s[14]+=w1*x0*x0; s[15]+=w1*x0*x1; s[16]+=w1*x0*x2; s[17]+=w1*x1*x1; s[18]+=w1*x1*x2; s[19]+=w1*x2*x2;
  }
  __shared__ double red[4][20];
  int wave=threadIdx.x>>6, lane=threadIdx.x&63;
#pragma unroll
  for(int q=0;q<20;q++){
    s[q]=waveSum(s[q]);
    if(lane==0) red[wave][q]=s[q];
  }
  __syncthreads();
  if(threadIdx.x<20){
    double v = red[0][threadIdx.x]+red[1][threadIdx.x]+red[2][threadIdx.x]+red[3][threadIdx.x];
    atomicAdd(&A[A_DK+b*20+threadIdx.x], v);
  }
  __shared__ int s_last;
  __syncthreads();
  if(threadIdx.x==0){
    __threadfence();
    s_last = (atomicAdd(&T[3],1u) == (unsigned)(NB*RB-1));
  }
  __syncthreads();
  if(!s_last || threadIdx.x) return;
  for(int bb=0;bb<NB;bb++) for(int k=0;k<2;k++){
    const double* ss = A + A_DK + (bb*2+k)*10;
    double W0=ss[0], Ws=W0+1e-8;
    double mu0=ss[1]/Ws, mu1=ss[2]/Ws, mu2=ss[3]/Ws;
    double C00=(ss[4]-2.0*mu0*ss[1]+mu0*mu0*W0)/Ws + 1e-6;
    double C01=(ss[5]-mu0*ss[2]-mu1*ss[1]+mu0*mu1*W0)/Ws;
    double C02=(ss[6]-mu0*ss[3]-mu2*ss[1]+mu0*mu2*W0)/Ws;
    double C11=(ss[7]-2.0*mu1*ss[2]+mu1*mu1*W0)/Ws + 1e-6;
    double C12=(ss[8]-mu1*ss[3]-mu2*ss[2]+mu1*mu2*W0)/Ws;
    double C22=(ss[9]-2.0*mu2*ss[3]+mu2*mu2*W0)/Ws + 1e-6;
    double det = C00*(C11*C22-C12*C12) - C01*(C01*C22-C12*C02) + C02*(C01*C12-C11*C02);
    double id = 1.0/det;
    float* P = F + F_DKINV + (bb*2+k)*9;
    P[0]=(float)((C11*C22-C12*C12)*id);
    P[1]=(float)((C02*C12-C01*C22)*id);
    P[2]=(float)((C01*C12-C02*C11)*id);
    P[3]=(float)((C00*C22-C02*C02)*id);
    P[4]=(float)((C01*C02-C00*C12)*id);
    P[5]=(float)((C00*C11-C01*C01)*id);
    P[6]=(float)mu0; P[7]=(float)mu1; P[8]=(float)mu2;
  }
}
__global__ void k_dm(const float* Lp,const float* E,const float* S,
                     const float* Ra0,const float* Ra1,const float* F,float* DM){
  int i = blockIdx.x*256 + threadIdx.x; if(i>=BN) return;
  int b=i/NPIX;
  float x0=Lp[i], x1=E[i], x2=S[i];
  float D[2];
#pragma unroll
  for(int k=0;k<2;k++){
    const float* P = F + F_DKINV + (b*2+k)*9;
    float d0=x0-P[6], d1=x1-P[7], d2=x2-P[8];
    float q = d0*d0*P[0] + d1*d1*P[3] + d2*d2*P[5]
            + 2.f*(d0*d1*P[1] + d0*d2*P[2] + d1*d2*P[4]);
    D[k]=sqrtf(q+1e-8f);
  }
  float w0=Ra0[i]+1e-8f, w1=Ra1[i]+1e-8f;
  DM[i] = (w0*D[0]+w1*D[1])/(w0+w1);
}

__global__ __launch_bounds__(256) void k_lla(const float* rk, const float* Lp, float* tmpL){
  int bx = blockIdx.x % 24, by = (blockIdx.x/24) % 24, b = blockIdx.x/576;
  __shared__ float Rt[30][31], Lt[30][31];
  __shared__ float h0[30][17], h1[30][17], h2[30][17];
  int ox = bx*16, oy = by*16;
  const float* Rb = rk + (size_t)b*NPIX;
  const float* Lb = Lp + (size_t)b*NPIX;
  for(int i=threadIdx.x; i<900; i+=256){
    int lx=i%30, ly=i/30;
    int gx_=ox-7+lx, gy_=oy-7+ly;
    bool in = (gx_>=0&&gx_<WW&&gy_>=0&&gy_<HH);
    Rt[ly][lx]= in ? Rb[gy_*WW+gx_] : 0.f;
    Lt[ly][lx]= in ? Lb[gy_*WW+gx_] : 0.f;
  }
  __syncthreads();
  for(int i=threadIdx.x; i<480; i+=256){
    int j=i%16, r=i/16;
    float s0=0,s1=0,s2=0;
#pragma unroll
    for(int d=0;d<15;d++){
      float rr=Rt[r][j+d], ll=Lt[r][j+d];
      s0+=rr; float rl=rr*ll; s1+=rl; s2+=rl*ll;
    }
    h0[r][j]=s0; h1[r][j]=s1; h2[r][j]=s2;
  }
  __syncthreads();
  int tx=threadIdx.x%16, ty=threadIdx.x/16;
  float S0=0,S1=0,S2=0;
#pragma unroll
  for(int d=0;d<15;d++){ S0+=h0[ty+d][tx]; S1+=h1[ty+d][tx]; S2+=h2[ty+d][tx]; }
  int x=ox+tx, y=oy+ty;
  float cy = (float)((y+8<HH?y+8:HH)-(y-7>0?y-7:0));
  float cx = (float)((x+8<WW?x+8:WW)-(x-7>0?x-7:0));
  float cnt = cy*cx;
  float den = S0/cnt + 1e-8f;
  float mu  = (S1/cnt)/den;
  float var = fmaxf((S2/cnt)/den - mu*mu, 1e-8f);
  int n = y*WW+x;
  tmpL[b*NPIX+n] = fabsf(Lb[n]-mu)/(sqrtf(var)+1e-8f);
}

__global__ __launch_bounds__(256) void k_gldf(const float* rk, const int* idxP, const float* F,
                                              int k, float* tmpG){
  int bx = blockIdx.x % 24, by = (blockIdx.x/24) % 24, b = blockIdx.x/576;
  __shared__ float Rt[30][31];
  __shared__ unsigned char It[30][32];
  __shared__ float Hh[480*33];
  __shared__ float gc[NBINS];
  if(threadIdx.x<NBINS) gc[threadIdx.x]=F[F_GCDF+(k*NB+b)*32+threadIdx.x];
  int ox=bx*16, oy=by*16;
  const float* Rb = rk + (size_t)b*NPIX;
  const int* Ib = idxP + (size_t)b*NPIX;
  for(int i=threadIdx.x;i<900;i+=256){
    int lx=i%30, ly=i/30;
    int gx_=ox-7+lx, gy_=oy-7+ly;
    bool in = (gx_>=0&&gx_<WW&&gy_>=0&&gy_<HH);
    Rt[ly][lx] = in? Rb[gy_*WW+gx_] : 0.f;
    It[ly][lx] = in? (unsigned char)Ib[gy_*WW+gx_] : 0;
  }
  for(int i=threadIdx.x;i<480*33;i+=256) Hh[i]=0.f;
  __syncthreads();
  for(int i=threadIdx.x;i<480;i+=256){
    int j=i%16, r=i/16;
    float* my = Hh + i*33;
    for(int d=0;d<15;d++) my[It[r][j+d]] += Rt[r][j+d];
  }
  __syncthreads();
  int tx=threadIdx.x%16, ty=threadIdx.x/16;
  float vs[32];
  float tot=0;
#pragma unroll
  for(int bin=0;bin<NBINS;bin++){
    float s=0;
#pragma unroll
    for(int d=0;d<15;d++) s += Hh[((ty+d)*16+tx)*33+bin];
    vs[bin]=s; tot+=s;
  }
  int x=ox+tx, y=oy+ty;
  float cy = (float)((y+8<HH?y+8:HH)-(y-7>0?y-7:0));
  float cx = (float)((x+8<WW?x+8:WW)-(x-7>0?x-7:0));
  float cnt = cy*cx;
  float den = tot/cnt + 1e-8f;
  float cs=0, acc=0;
#pragma unroll
  for(int bin=0;bin<NBINS;bin++){
    cs += vs[bin];
    acc += fabsf((cs/cnt)/den - gc[bin]);
  }
  tmpG[b*NPIX + y*WW + x] = acc*(1.f/32.f);
}

__global__ void k_gamma(const float* tmpL,const float* tmpG,const float* rk,const float* F,
                        float* gamma,int first){
  int i = blockIdx.x*256 + threadIdx.x; if(i>=BN) return;
  int b=i/NPIX;
  float zl=(tmpL[i]-F[F_LLA+b*2])/F[F_LLA+b*2+1];
  float zg=(tmpG[i]-F[F_GLD+b*2])/F[F_GLD+b*2+1];
  float c = rk[i]*(0.5f*sp(zl)+0.5f*sp(zg));
  gamma[i] = first ? 1.0f + c : gamma[i] + c;
}

__global__ void k_es_red(const float* E,const float* S,float* F,double* A,unsigned* T){
  int b = blockIdx.x / RB, blk = blockIdx.x % RB;
  const float* M = F + F_X3 + b*6;
  double s[5]={0,0,0,0,0};
  for(int n = blk*256 + threadIdx.x; n < NPIX; n += RB*256){
    float z0=(E[b*NPIX+n]-M[2])/M[3];
    float z1=(S[b*NPIX+n]-M[4])/M[5];
    s[0]+=z0; s[1]+=z1; s[2]+=(double)z0*z0; s[3]+=(double)z0*z1; s[4]+=(double)z1*z1;
  }
  __shared__ double red[4][5];
  int wave=threadIdx.x>>6, lane=threadIdx.x&63;
#pragma unroll
  for(int q=0;q<5;q++){
    s[q]=waveSum(s[q]);
    if(lane==0) red[wave][q]=s[q];
  }
  __syncthreads();
  if(threadIdx.x<5){
    double v = red[0][threadIdx.x]+red[1][threadIdx.x]+red[2][threadIdx.x]+red[3][threadIdx.x];
    atomicAdd(&A[A_ES+b*5+threadIdx.x], v);
  }
  __shared__ int s_last;
  __syncthreads();
  if(threadIdx.x==0){
    __threadfence();
    s_last = (atomicAdd(&T[4],1u) == (unsigned)(NB*RB-1));
  }
  __syncthreads();
  if(!s_last || threadIdx.x) return;
  for(int bb=0;bb<NB;bb++){
    const double* ss = A + A_ES + bb*5;
    double inv=1.0/(double)NPIX;
    double m0=ss[0]*inv, m1=ss[1]*inv;
    double c00=ss[2]*inv - m0*m0 + 1e-6;
    double c01=ss[3]*inv - m0*m1;
    double c11=ss[4]*inv - m1*m1 + 1e-6;
    double det=c00*c11-c01*c01;
    float* P = F + F_ESI + bb*5;
    P[0]=(float)m0; P[1]=(float)m1;
    P[2]=(float)(c11/det); P[3]=(float)(-c01/det); P[4]=(float)(c00/det);
  }
}
__global__ void k_lanom(const float* E,const float* S,const float* DM,const float* gamma,
                        const float* F,float* La){
  int i = blockIdx.x*256 + threadIdx.x; if(i>=BN) return;
  int b=i/NPIX;
  const float* M = F + F_X3 + b*6;
  const float* P = F + F_ESI + b*5;
  float z0=(E[i]-M[2])/M[3];
  float z1=(S[i]-M[4])/M[5];
  float d0=z0-P[0], d1=z1-P[1];
  float d2 = d0*d0*P[2] + 2.f*d0*d1*P[3] + d1*d1*P[4];
  float Rs = expf(-0.5f*d2);
  La[i] = fmaxf(DM[i]*gamma[i]*(1.f-Rs), 0.f);
}
__global__ void k_out2(const float* La, const float* F, float* out){
  int i = blockIdx.x*256 + threadIdx.x; if(i>=BN) return;
  int b=i/NPIX;
  const float* v = F + F_LAQ + b*4;
  double h1 = 0.01*(double)(NPIX-1); double f1 = h1 - floor(h1);
  double h9 = 0.99*(double)(NPIX-1); double f9 = h9 - floor(h9);
  float q1 = (float)((double)v[0] + f1*((double)v[1]-(double)v[0]));
  float q9 = (float)((double)v[2] + f9*((double)v[3]-(double)v[2]));
  float r = (La[i]-q1)/(q9-q1+1e-8f);
  out[BN + i] = fminf(fmaxf(r,0.f),1.f);
}

// ---------------- host ----------------
static void run_sel(const SelBatch& sb, unsigned* H, unsigned* T, float* F, hipStream_t s){
  k_selz16<<<sb.nt*1024,256,0,s>>>(sb,H,T);
  k_selp16<<<sb.nt*SEL_BLK,256,0,s>>>(sb,H,T,F,0,0);
  k_selp16<<<sb.nt*SEL_BLK,256,0,s>>>(sb,H,T,F,0,1);
  if(sb.medmad){
    k_selp16<<<sb.nt*SEL_BLK,256,0,s>>>(sb,H,T,F,1,0);
    k_selp16<<<sb.nt*SEL_BLK,256,0,s>>>(sb,H,T,F,1,1);
  }
}

extern "C" void kernel_launch(void* const* d_in, const int* in_sizes, int n_in,
                              void* d_out, int out_size, void* d_ws, size_t ws_size,
                              hipStream_t stream){
  (void)in_sizes; (void)n_in; (void)out_size; (void)ws_size;
  const float* lab   = (const float*)d_in[0];
  const float* arand = (const float*)d_in[1];
  float* out = (float*)d_out;
  char* wsb = (char*)d_ws;
  double* A = (double*)wsb;                   // 2048 doubles
  float*  F = (float*)(wsb + 16384);          // 4096 floats
  unsigned* T = (unsigned*)(wsb + 32768);     // 256 u32
  float* planes = (float*)(wsb + 65536);
  float* E    = planes;
  float* S    = planes + (size_t)BN;
  float* tA   = planes + (size_t)2*BN;        // La
  float* tmpL = planes + (size_t)5*BN;
  float* tmpG = planes + (size_t)6*BN;
  float* Xw   = planes + (size_t)7*BN;        // interleaved xyz (3*BN)
  float* zb   = planes + (size_t)10*BN;
  float* Ra0  = planes + (size_t)11*BN;
  float* Ra1  = planes + (size_t)12*BN;
  float* DM   = planes + (size_t)13*BN;
  float* gamma= planes + (size_t)14*BN;
  int*   idxP = (int*)(planes + (size_t)16*BN);
  unsigned* H16 = (unsigned*)(planes + (size_t)17*BN);  // select hists

  const int GBN = BN/256;      // 1152

  k_zero<<<16,256,0,stream>>>(A,F,T);
  k_sobel<<<NB*576,256,0,stream>>>(lab,S,E);
  k_beta_red<<<NB*RB,256,0,stream>>>(E,S,lab,A,F,T);
  k_lperp<<<GBN,256,0,stream>>>(lab,E,S,F,out);

  SelBatch sbX; sbX.nt=6; sbX.medmad=1;
  for(int b=0;b<NB;b++){
    sbX.src[b*3+0]=out+(size_t)b*NPIX; sbX.src[b*3+1]=E+(size_t)b*NPIX; sbX.src[b*3+2]=S+(size_t)b*NPIX;
    for(int ch=0;ch<3;ch++){ sbX.rank[b*3+ch]=MEDRANK; sbX.fslot[b*3+ch]=F_X3+(b*3+ch)*2; }
  }
  run_sel(sbX,H16,T,F,stream);

  k_xz_red<<<NB*RB,256,0,stream>>>(out,E,S,F,A,T);
  k_xw<<<GBN,256,0,stream>>>(out,E,S,F,Xw,idxP);
  k_kurt<<<1024,256,0,stream>>>(Xw,arand,A);
  k_kurt_pick<<<NB,128,0,stream>>>(A,arand,F);
  k_zbest<<<GBN,256,0,stream>>>(Xw,F,zb);

  SelBatch sbZ; sbZ.nt=8; sbZ.medmad=0;
  {
    int rr[4]={36863,36864,110591,110592};
    for(int b=0;b<NB;b++) for(int ri=0;ri<4;ri++){
      int t=b*4+ri;
      sbZ.src[t]=zb+(size_t)b*NPIX; sbZ.rank[t]=rr[ri]; sbZ.fslot[t]=F_ZBQ+b*4+ri;
    }
  }
  run_sel(sbZ,H16,T,F,stream);

  for(int it=0; it<9; ++it)
    k_gmm_red<<<NB*RB2,256,0,stream>>>(zb,F,A,it);
  k_ralpha<<<GBN,256,0,stream>>>(zb,F,A,idxP,Ra0,Ra1,T);
  k_dk_red<<<NB*RB,256,0,stream>>>(out,E,S,Ra0,Ra1,A,F,T);
  k_dm<<<GBN,256,0,stream>>>(out,E,S,Ra0,Ra1,F,DM);

  SelBatch sbC; sbC.nt=4; sbC.medmad=1;
  for(int b=0;b<NB;b++){
    sbC.src[b]  =tmpL+(size_t)b*NPIX; sbC.rank[b]  =MEDRANK; sbC.fslot[b]  =F_LLA+b*2;
    sbC.src[2+b]=tmpG+(size_t)b*NPIX; sbC.rank[2+b]=MEDRANK; sbC.fslot[2+b]=F_GLD+b*2;
  }

  for(int k=0;k<2;k++){
    const float* Rk = k ? Ra1 : Ra0;
    k_lla<<<NB*576,256,0,stream>>>(Rk,out,tmpL);
    k_gldf<<<NB*576,256,0,stream>>>(Rk,idxP,F,k,tmpG);
    run_sel(sbC,H16,T,F,stream);
    k_gamma<<<GBN,256,0,stream>>>(tmpL,tmpG,Rk,F,gamma,k==0?1:0);
  }

  k_es_red<<<NB*RB,256,0,stream>>>(E,S,F,A,T);
  k_lanom<<<GBN,256,0,stream>>>(E,S,DM,gamma,F,tA);

  SelBatch sbL; sbL.nt=8; sbL.medmad=0;
  {
    int rr[4]={1474,1475,145980,145981};
    for(int b=0;b<NB;b++) for(int ri=0;ri<4;ri++){
      int t=b*4+ri;
      sbL.src[t]=tA+(size_t)b*NPIX; sbL.rank[t]=rr[ri]; sbL.fslot[t]=F_LAQ+b*4+ri;
    }
  }
  run_sel(sbL,H16,T,F,stream);

  k_out2<<<GBN,256,0,stream>>>(tA,F,out);
}

// Round 8
// 753.453 us; speedup vs baseline: 4.9618x; 1.2732x over previous
//
#include <hip/hip_runtime.h>
#include <math.h>

#define HH 384
#define WW 384
#define NPIX (HH*WW)          // 147456
#define NB 2
#define BN (NB*NPIX)          // 294912
#define NT 128
#define NBINS 32
#define MEDRANK ((NPIX-1)/2)  // 73727
#define RB 72                 // reduction blocks per batch
#define RB2 288               // gmm reduction blocks per batch
#define SEL_BLK 64            // blocks per select task per pass

// ---- double arena (ws+0, 2048 doubles) ----
#define A_BETA 0
#define A_XZ   16
#define A_ES   40
#define A_DK   56
#define A_GMM  128  // 9 iters * 16
#define A_GHIST 288
#define A_KURT 512

// ---- float arena (ws+16384, 4096 floats) ----
#define F_BETA 0
#define F_X3   8    // (b*3+ch)*2 {med,mad}; ch1=E ch2=S also serve ES stage
#define F_MEAN 24
#define F_WWH  32
#define F_ASTAR 828
#define F_ZBQ  868
#define F_DKINV 880
#define F_LLA  918
#define F_GLD  924
#define F_ESI  940
#define F_LAQ  952
#define F_GCDF 968
#define F_MMS_MIN 1280  // b*32+slot (u32, init 0xFFFFFFFF)
#define F_MMS_MAX 1408  // b*32+slot (u32, init 0)

// ---- ticket/meta arena T (u32, ws+32768, 256 u32) ----
// T[0..7]: reduction tickets
// T[16..79]: sel pass tickets: task*8 + stage*4 + pass
// T[80..143]: sel meta: task*8 + {pre0,rank0,pre1,rank1,center}
// ---- select hists H8 (u32, ws+65536, 16384 u32 = 64 KB) ----
// planes at ws+131072

__device__ __forceinline__ double waveSum(double v){
#pragma unroll
  for(int o=32;o;o>>=1) v += __shfl_down(v,o,64);
  return v;
}
__device__ __forceinline__ unsigned f2u(float f){
  unsigned u = __float_as_uint(f);
  return (u & 0x80000000u) ? ~u : (u | 0x80000000u);
}
__device__ __forceinline__ float u2f(unsigned u){
  return __uint_as_float((u & 0x80000000u) ? (u ^ 0x80000000u) : ~u);
}
__device__ __forceinline__ float sp(float x){
  float t = log1pf(expf(-fabsf(x)));
  return x >= 0.f ? x + t : t;
}

struct SelBatch {
  const float* src[8];
  int rank[8];
  int fslot[8];
  int nt;
  int medmad;
};

// pick bin containing rank from per-thread count x (blockDim.x==256)
__device__ void pick256v(unsigned x, int rank, unsigned& sel, int& nrank){
  __shared__ unsigned s_cum[256];
  __shared__ unsigned s_res[2];
  int tid = threadIdx.x;
  s_cum[tid] = x;
  __syncthreads();
  for(int o=1;o<256;o<<=1){
    unsigned t = (tid>=o)? s_cum[tid-o] : 0u;
    __syncthreads();
    s_cum[tid] += t;
    __syncthreads();
  }
  unsigned cum = s_cum[tid];
  unsigned ex  = cum - x;
  if(x>0u && (unsigned)rank>=ex && (unsigned)rank<cum){
    s_res[0]=(unsigned)tid; s_res[1]=(unsigned)(rank-(int)ex);
  }
  __syncthreads();
  sel = s_res[0]; nrank = (int)s_res[1];
  __syncthreads();
}

__global__ void k_zero(double* A, float* F, unsigned* T){
  int i = blockIdx.x*blockDim.x + threadIdx.x;
  if(i < 2048) A[i] = 0.0;
  if(i < 4096){
    unsigned* U = (unsigned*)F;
    unsigned v = 0u;
    if(i>=F_MMS_MIN && i<F_MMS_MIN+64) v = 0xFFFFFFFFu;
    U[i] = v;
  }
  if(i < 256) T[i] = 0u;
}

// zero 64 KB hist + tickets + meta (grid: 64 blocks x 256)
__global__ void k_selz8(SelBatch sb, unsigned* Hh, unsigned* T){
  int i = blockIdx.x*256 + threadIdx.x;
  if(i < 16384) Hh[i]=0u;
  if(i < 64) T[16+i]=0u;
  if(i < 8 && i < sb.nt){
    unsigned* m = T + 80 + i*8;
    m[0]=0u; m[1]=(unsigned)sb.rank[i];
    m[2]=0u; m[3]=(unsigned)sb.rank[i];
    m[4]=0u;
  }
}

// 8-bit radix pass with LDS-privatized hist; last block locates
__global__ __launch_bounds__(256) void k_selp8(SelBatch sb, unsigned* Hh, unsigned* T,
                                               float* F, int stage, int pass){
  int task = blockIdx.x / SEL_BLK;
  int blk  = blockIdx.x % SEL_BLK;
  unsigned* meta = T + 80 + task*8;
  float center = (stage==1) ? __uint_as_float(meta[4]) : 0.f;
  unsigned prefix = meta[stage*2];
  unsigned himask = (pass==3)?0u:(0xFFFFFFFFu<<((pass+1)*8));
  __shared__ unsigned lh[256];
  lh[threadIdx.x]=0u; __syncthreads();
  const float* src = sb.src[task];
  for(int i=blk*256+threadIdx.x; i<NPIX; i+=SEL_BLK*256){
    float v = src[i];
    if(stage) v = fabsf(v-center);
    unsigned u = f2u(v);
    if((u&himask)==prefix) atomicAdd(&lh[(u>>(pass*8))&255u],1u);
  }
  __syncthreads();
  unsigned c = lh[threadIdx.x];
  unsigned* hp = Hh + task*2048 + stage*1024 + pass*256;
  if(c) atomicAdd(hp+threadIdx.x, c);
  __shared__ int s_last;
  __syncthreads();
  if(threadIdx.x==0){
    __threadfence();
    s_last = (atomicAdd(&T[16+task*8+stage*4+pass],1u) == (unsigned)(SEL_BLK-1));
  }
  __syncthreads();
  if(!s_last) return;
  int r = (int)meta[stage*2+1];
  unsigned x = hp[threadIdx.x];
  unsigned sel; int nr;
  pick256v(x, r, sel, nr);
  unsigned npref = prefix | (sel<<(pass*8));
  if(threadIdx.x==0){
    if(pass>0){ meta[stage*2]=npref; meta[stage*2+1]=(unsigned)nr; }
    else {
      float val = u2f(npref);
      if(stage==0){
        if(sb.medmad) meta[4]=__float_as_uint(val);
        else F[sb.fslot[task]]=val;
      } else {
        F[sb.fslot[task]]   = __uint_as_float(meta[4]);
        F[sb.fslot[task]+1] = val*1.4826f + 1e-8f;
      }
    }
  }
}

__device__ void params_from_sums(double N0,double N1,double Sx0,double Sx1,double Sxx0,double Sxx1,
                                 double& mu0,double& mu1,double& iv0h,double& iv1h,
                                 double& c0,double& c1){
  mu0=Sx0/(N0+1e-8); mu1=Sx1/(N1+1e-8);
  double v0=(Sxx0-2.0*mu0*Sx0+mu0*mu0*N0)/(N0+1e-8)+1e-6;
  double v1=(Sxx1-2.0*mu1*Sx1+mu1*mu1*N1)/(N1+1e-8)+1e-6;
  double p0=N0/(double)NPIX, p1=N1/(double)NPIX;
  c0=-0.5*log(v0+1e-6)+log(p0+1e-8);
  c1=-0.5*log(v1+1e-6)+log(p1+1e-8);
  iv0h=0.5/(v0+1e-6); iv1h=0.5/(v1+1e-6);
}
__device__ void params_init(const float* F, int b,
                            double& mu0,double& mu1,double& iv0h,double& iv1h,
                            double& c0,double& c1){
  const float* z = F + F_ZBQ + b*4;
  double h25 = 0.25*(double)(NPIX-1); double f25 = h25 - floor(h25);
  double h75 = 0.75*(double)(NPIX-1); double f75 = h75 - floor(h75);
  mu0 = (double)z[0] + f25*((double)z[1]-(double)z[0]);
  mu1 = (double)z[2] + f75*((double)z[3]-(double)z[2]);
  double v0=1.0, v1=1.0, p0=0.5, p1=0.5;
  c0=-0.5*log(v0+1e-6)+log(p0+1e-8);
  c1=-0.5*log(v1+1e-6)+log(p1+1e-8);
  iv0h=0.5/(v0+1e-6); iv1h=0.5/(v1+1e-6);
}
__device__ __forceinline__ void estep2f(float x,float mu0,float mu1,float iv0h,float iv1h,
                                        float c0,float c1,float& r0,float& r1){
  float d0=x-mu0, d1=x-mu1;
  float l0=-d0*d0*iv0h+c0, l1=-d1*d1*iv1h+c1;
  float m=fmaxf(l0,l1);
  float e0=expf(l0-m), e1=expf(l1-m);
  float s=e0+e1;
  r0=e0/s; r1=e1/s;
}

// ---------------- pipeline kernels ----------------
__global__ __launch_bounds__(256) void k_sobel(const float* lab, float* S, float* E){
  int bx = blockIdx.x % 24, by = (blockIdx.x/24) % 24, b = blockIdx.x/576;
  __shared__ float Lt[20][21];
  __shared__ float G[18][19];
  const float* Lb = lab + b*3*NPIX;
  int ox = bx*16, oy = by*16;
  for(int i=threadIdx.x; i<400; i+=256){
    int lx=i%20, ly=i/20;
    int gx_=ox-2+lx, gy_=oy-2+ly;
    Lt[ly][lx] = (gx_<0||gx_>=WW||gy_<0||gy_>=HH)?0.f:Lb[gy_*WW+gx_];
  }
  __syncthreads();
  for(int i=threadIdx.x; i<324; i+=256){
    int lx=i%18, ly=i/18;
    int px=lx+1, py=ly+1;
    int gxp=ox-2+px, gyp=oy-2+py;
    float g=0.f;
    if(gxp>=0&&gxp<WW&&gyp>=0&&gyp<HH){
      float gx = -Lt[py-1][px-1]+Lt[py-1][px+1] -2.f*Lt[py][px-1]+2.f*Lt[py][px+1] -Lt[py+1][px-1]+Lt[py+1][px+1];
      float gy = -Lt[py-1][px-1]-2.f*Lt[py-1][px]-Lt[py-1][px+1] +Lt[py+1][px-1]+2.f*Lt[py+1][px]+Lt[py+1][px+1];
      g = gx*gx+gy*gy;
    }
    G[ly][lx]=g;
  }
  __syncthreads();
  int tx = threadIdx.x%16, ty = threadIdx.x/16;
  float s=0;
#pragma unroll
  for(int dy=0;dy<3;dy++)
#pragma unroll
    for(int dx=0;dx<3;dx++) s += G[ty+dy][tx+dx];
  int n = (oy+ty)*WW + ox+tx;
  E[b*NPIX+n] = s*(1.f/9.f);
  float av=Lb[NPIX+n], bv=Lb[2*NPIX+n];
  S[b*NPIX+n] = sqrtf(av*av+bv*bv+1e-8f);
}

__global__ void k_beta_red(const float* E,const float* S,const float* lab,double* A,
                           float* F, unsigned* T){
  int b = blockIdx.x / RB, blk = blockIdx.x % RB;
  double s[5]={0,0,0,0,0};
  for(int n = blk*256 + threadIdx.x; n < NPIX; n += RB*256){
    float e=E[b*NPIX+n], ss=S[b*NPIX+n], l=lab[b*3*NPIX+n];
    s[0]+=(double)e*e; s[1]+=(double)e*ss; s[2]+=(double)ss*ss;
    s[3]+=(double)e*l; s[4]+=(double)ss*l;
  }
  __shared__ double red[4][5];
  int wave=threadIdx.x>>6, lane=threadIdx.x&63;
#pragma unroll
  for(int q=0;q<5;q++){
    s[q]=waveSum(s[q]);
    if(lane==0) red[wave][q]=s[q];
  }
  __syncthreads();
  if(threadIdx.x<5){
    double v = red[0][threadIdx.x]+red[1][threadIdx.x]+red[2][threadIdx.x]+red[3][threadIdx.x];
    atomicAdd(&A[A_BETA+b*5+threadIdx.x], v);
  }
  __shared__ int s_last;
  __syncthreads();
  if(threadIdx.x==0){
    __threadfence();
    s_last = (atomicAdd(&T[0],1u) == (unsigned)(NB*RB-1));
  }
  __syncthreads();
  if(!s_last || threadIdx.x) return;
  for(int bb=0;bb<NB;bb++){
    double EE=A[A_BETA+bb*5],ES=A[A_BETA+bb*5+1],SS=A[A_BETA+bb*5+2],EL=A[A_BETA+bb*5+3],SL=A[A_BETA+bb*5+4];
    double a00=EE+1e-6, a01=ES, a11=SS+1e-6;
    double det=a00*a11-a01*a01;
    F[F_BETA+bb*2]  =(float)(( a11*EL - a01*SL)/det);
    F[F_BETA+bb*2+1]=(float)((-a01*EL + a00*SL)/det);
  }
}

__global__ void k_lperp(const float* lab,const float* E,const float* S,const float* F,float* out0){
  int i = blockIdx.x*256 + threadIdx.x;
  int b=i/NPIX, n=i%NPIX;
  float v = lab[b*3*NPIX+n] - F[F_BETA+b*2]*E[i] - F[F_BETA+b*2+1]*S[i];
  out0[i] = v;
  unsigned u = f2u(v);
  unsigned mn=u, mx=u;
#pragma unroll
  for(int o=32;o;o>>=1){
    unsigned a = __shfl_down(mn,o,64); mn = (a<mn)?a:mn;
    unsigned c = __shfl_down(mx,o,64); mx = (c>mx)?c:mx;
  }
  __shared__ unsigned rmn[4], rmx[4];
  int wave=threadIdx.x>>6, lane=threadIdx.x&63;
  if(lane==0){ rmn[wave]=mn; rmx[wave]=mx; }
  __syncthreads();
  if(threadIdx.x==0){
    unsigned m0 = rmn[0]; unsigned m1 = rmx[0];
    for(int w=1;w<4;w++){ if(rmn[w]<m0)m0=rmn[w]; if(rmx[w]>m1)m1=rmx[w]; }
    unsigned* U = (unsigned*)F;
    int slot = blockIdx.x & 31;
    atomicMin(&U[F_MMS_MIN+b*32+slot], m0);
    atomicMax(&U[F_MMS_MAX+b*32+slot], m1);
  }
}

__global__ void k_xz_red(const float* Lp,const float* E,const float* S,float* F,double* A,
                         unsigned* T){
  int b = blockIdx.x / RB, blk = blockIdx.x % RB;
  const float* M = F + F_X3 + b*6;
  double s[9]={0,0,0,0,0,0,0,0,0};
  for(int n = blk*256 + threadIdx.x; n < NPIX; n += RB*256){
    float z0=(Lp[b*NPIX+n]-M[0])/M[1];
    float z1=(E [b*NPIX+n]-M[2])/M[3];
    float z2=(S [b*NPIX+n]-M[4])/M[5];
    s[0]+=z0; s[1]+=z1; s[2]+=z2;
    s[3]+=(double)z0*z0; s[4]+=(double)z0*z1; s[5]+=(double)z0*z2;
    s[6]+=(double)z1*z1; s[7]+=(double)z1*z2; s[8]+=(double)z2*z2;
  }
  __shared__ double red[4][9];
  int wave=threadIdx.x>>6, lane=threadIdx.x&63;
#pragma unroll
  for(int q=0;q<9;q++){
    s[q]=waveSum(s[q]);
    if(lane==0) red[wave][q]=s[q];
  }
  __syncthreads();
  if(threadIdx.x<9){
    double v = red[0][threadIdx.x]+red[1][threadIdx.x]+red[2][threadIdx.x]+red[3][threadIdx.x];
    atomicAdd(&A[A_XZ+b*9+threadIdx.x], v);
  }
  __shared__ int s_last;
  __syncthreads();
  if(threadIdx.x==0){
    __threadfence();
    s_last = (atomicAdd(&T[1],1u) == (unsigned)(NB*RB-1));
  }
  __syncthreads();
  if(!s_last) return;
  int bb = threadIdx.x;
  if(bb>=NB) return;
  const double* ss = A + A_XZ + bb*9;
  double inv = 1.0/(double)NPIX;
  double m0=ss[0]*inv, m1=ss[1]*inv, m2=ss[2]*inv;
  double a[3][3];
  a[0][0]=fmax(ss[3]*inv-m0*m0,1e-8);
  a[0][1]=a[1][0]=fmax(ss[4]*inv-m0*m1,1e-8);
  a[0][2]=a[2][0]=fmax(ss[5]*inv-m0*m2,1e-8);
  a[1][1]=fmax(ss[6]*inv-m1*m1,1e-8);
  a[1][2]=a[2][1]=fmax(ss[7]*inv-m1*m2,1e-8);
  a[2][2]=fmax(ss[8]*inv-m2*m2,1e-8);
  double V[3][3]={{1,0,0},{0,1,0},{0,0,1}};
  for(int sweep=0;sweep<40;sweep++){
    for(int pp=0;pp<3;pp++){
      int p = (pp==2)?1:0;
      int q = (pp==0)?1:2;
      double apq=a[p][q];
      if(fabs(apq)<1e-30) continue;
      double theta=(a[q][q]-a[p][p])/(2.0*apq);
      double t=((theta>=0)?1.0:-1.0)/(fabs(theta)+sqrt(1.0+theta*theta));
      double c=1.0/sqrt(1.0+t*t), sn=t*c;
      for(int k2=0;k2<3;k2++){ double akp=a[k2][p],akq=a[k2][q];
        a[k2][p]=c*akp-sn*akq; a[k2][q]=sn*akp+c*akq; }
      for(int k2=0;k2<3;k2++){ double apk=a[p][k2],aqk=a[q][k2];
        a[p][k2]=c*apk-sn*aqk; a[q][k2]=sn*apk+c*aqk; }
      for(int k2=0;k2<3;k2++){ double vkp=V[k2][p],vkq=V[k2][q];
        V[k2][p]=c*vkp-sn*vkq; V[k2][q]=sn*vkp+c*vkq; }
    }
  }
  double is0=1.0/sqrt(a[0][0]), is1=1.0/sqrt(a[1][1]), is2=1.0/sqrt(a[2][2]);
  for(int i=0;i<3;i++) for(int j=0;j<3;j++){
    double w = V[i][0]*is0*V[j][0] + V[i][1]*is1*V[j][1] + V[i][2]*is2*V[j][2];
    F[F_WWH + bb*9 + i*3 + j] = (float)w;
  }
  F[F_MEAN+bb*3]=(float)m0; F[F_MEAN+bb*3+1]=(float)m1; F[F_MEAN+bb*3+2]=(float)m2;
}

__global__ void k_xw(const float* Lp,const float* E,const float* S,const float* F,
                     float* Xw,int* idxP){
  __shared__ float s_mn, s_mx;
  int i = blockIdx.x*256 + threadIdx.x;
  int b=i/NPIX;
  if(threadIdx.x==0){
    const unsigned* U = (const unsigned*)F;
    unsigned mn=0xFFFFFFFFu, mx=0u;
    for(int s2=0;s2<32;s2++){
      unsigned a=U[F_MMS_MIN+b*32+s2]; if(a<mn)mn=a;
      unsigned c=U[F_MMS_MAX+b*32+s2]; if(c>mx)mx=c;
    }
    s_mn=u2f(mn); s_mx=u2f(mx);
  }
  __syncthreads();
  const float* M = F + F_X3 + b*6;
  float lp = Lp[i];
  float z0=(lp-M[0])/M[1];
  float z1=(E [i]-M[2])/M[3];
  float z2=(S [i]-M[4])/M[5];
  float d0=z0-F[F_MEAN+b*3], d1=z1-F[F_MEAN+b*3+1], d2=z2-F[F_MEAN+b*3+2];
  const float* Wm = F + F_WWH + b*9;
  Xw[3*(size_t)i  ]=d0*Wm[0]+d1*Wm[3]+d2*Wm[6];
  Xw[3*(size_t)i+1]=d0*Wm[1]+d1*Wm[4]+d2*Wm[7];
  Xw[3*(size_t)i+2]=d0*Wm[2]+d1*Wm[5]+d2*Wm[8];
  float ln = (lp-s_mn)/(s_mx-s_mn+1e-8f);
  ln = fminf(fmaxf(ln,0.f),1.f);
  int id = (int)(ln*32.f);
  idxP[i] = id>31?31:(id<0?0:id);
}

__global__ __launch_bounds__(256) void k_kurt(const float* Xw, const float* arand, double* A){
  int g = blockIdx.x;           // 1024
  int b = g >> 9;
  int t = (g >> 2) & 127;
  int seg = g & 3;
  const float* ar = arand + (b*NT+t)*3;
  float q0=ar[0], q1=ar[1], q2=ar[2];
  float nrm = (float)(sqrt((double)q0*q0+(double)q1*q1+(double)q2*q2)+1e-12);
  float a0=q0/nrm, a1=q1/nrm, a2=q2/nrm;
  const float* X = Xw + (size_t)b*NPIX*3;
  double s1=0,s2=0,s3=0,s4=0;
  int start = seg*36864;
  for(int n=start+threadIdx.x; n<start+36864; n+=256){
    const float* p = X + 3*(size_t)n;
    float z = p[0]*a0 + p[1]*a1 + p[2]*a2;
    float z2f = z*z;
    s1 += z; s2 += z2f; s3 += z2f*z; s4 += (double)z2f*z2f;
  }
  s1=waveSum(s1); s2=waveSum(s2); s3=waveSum(s3); s4=waveSum(s4);
  __shared__ double red[4][4];
  int wave=threadIdx.x>>6, lane=threadIdx.x&63;
  if(lane==0){ red[wave][0]=s1; red[wave][1]=s2; red[wave][2]=s3; red[wave][3]=s4; }
  __syncthreads();
  if(threadIdx.x<4){
    double v = red[0][threadIdx.x]+red[1][threadIdx.x]+red[2][threadIdx.x]+red[3][threadIdx.x];
    atomicAdd(&A[A_KURT + (size_t)(b*NT+t)*4 + threadIdx.x], v);
  }
}
__global__ void k_kurt_pick(const double* A, const float* arand, float* F){
  int b = blockIdx.x;
  int t = threadIdx.x;   // 128
  __shared__ float ak[NT];
  const double* K = A + A_KURT + (size_t)(b*NT+t)*4;
  double inv=1.0/(double)NPIX;
  double mean=K[0]*inv, M2=K[1]*inv, M3=K[2]*inv, M4=K[3]*inv;
  double m2 = M2 - mean*mean + 1e-12;
  double m4 = M4 - 4.0*mean*M3 + 6.0*mean*mean*M2 - 3.0*mean*mean*mean*mean;
  ak[t] = (float)fabs(m4/(m2*m2) - 3.0);
  __syncthreads();
  if(t==0){
    int best=0; float bv=ak[0];
    for(int j=1;j<NT;j++) if(ak[j]>bv){bv=ak[j];best=j;}
    const float* ar = arand + (b*NT+best)*3;
    double nrm = sqrt((double)ar[0]*ar[0]+(double)ar[1]*ar[1]+(double)ar[2]*ar[2])+1e-12;
    F[F_ASTAR+b*3]  =(float)(ar[0]/nrm);
    F[F_ASTAR+b*3+1]=(float)(ar[1]/nrm);
    F[F_ASTAR+b*3+2]=(float)(ar[2]/nrm);
  }
}
__global__ void k_zbest(const float* Xw,const float* F,float* zb){
  int i = blockIdx.x*256 + threadIdx.x; if(i>=BN) return;
  int b=i/NPIX;
  const float* p = Xw + 3*(size_t)i;
  zb[i] = p[0]*F[F_ASTAR+b*3] + p[1]*F[F_ASTAR+b*3+1] + p[2]*F[F_ASTAR+b*3+2];
}

__global__ __launch_bounds__(256) void k_gmm_red(const float* zb, const float* F, double* A, int it){
  __shared__ float P[6];
  __shared__ double red[4][6];
  int b = blockIdx.x / RB2, blk = blockIdx.x % RB2;
  if(threadIdx.x==0){
    double mu0,mu1,iv0h,iv1h,c0,c1;
    if(it==0) params_init(F,b,mu0,mu1,iv0h,iv1h,c0,c1);
    else {
      const double* g = A + A_GMM + (it-1)*16 + b*6;
      params_from_sums(g[0],g[1],g[2],g[3],g[4],g[5],mu0,mu1,iv0h,iv1h,c0,c1);
    }
    P[0]=(float)mu0; P[1]=(float)mu1; P[2]=(float)iv0h; P[3]=(float)iv1h;
    P[4]=(float)c0;  P[5]=(float)c1;
  }
  __syncthreads();
  float fmu0=P[0], fmu1=P[1], fiv0=P[2], fiv1=P[3], fc0=P[4], fc1=P[5];
  double s[6]={0,0,0,0,0,0};
  for(int n = blk*256 + threadIdx.x; n < NPIX; n += RB2*256){
    float x = zb[b*NPIX+n];
    float r0,r1; estep2f(x,fmu0,fmu1,fiv0,fiv1,fc0,fc1,r0,r1);
    s[0]+=r0; s[1]+=r1; s[2]+=r0*x; s[3]+=r1*x; s[4]+=(double)(r0*x)*x; s[5]+=(double)(r1*x)*x;
  }
  int wave=threadIdx.x>>6, lane=threadIdx.x&63;
#pragma unroll
  for(int q=0;q<6;q++){
    s[q]=waveSum(s[q]);
    if(lane==0) red[wave][q]=s[q];
  }
  __syncthreads();
  if(threadIdx.x<6){
    double v = red[0][threadIdx.x]+red[1][threadIdx.x]+red[2][threadIdx.x]+red[3][threadIdx.x];
    atomicAdd(&A[A_GMM+it*16+b*6+threadIdx.x], v);
  }
}

__global__ void k_ralpha(const float* zb, float* F, double* A, const int* idxP,
                         float* Ra0, float* Ra1, unsigned* T){
  __shared__ float h0[NBINS], h1[NBINS];
  __shared__ float P[6];
  if(threadIdx.x<NBINS){ h0[threadIdx.x]=0.f; h1[threadIdx.x]=0.f; }
  int i = blockIdx.x*256 + threadIdx.x;
  int b=i/NPIX;
  if(threadIdx.x==0){
    const double* g = A + A_GMM + 8*16 + b*6;
    double mu0,mu1,iv0h,iv1h,c0,c1;
    params_from_sums(g[0],g[1],g[2],g[3],g[4],g[5],mu0,mu1,iv0h,iv1h,c0,c1);
    P[0]=(float)mu0; P[1]=(float)mu1; P[2]=(float)iv0h; P[3]=(float)iv1h;
    P[4]=(float)c0;  P[5]=(float)c1;
  }
  __syncthreads();
  float r0,r1; estep2f(zb[i],P[0],P[1],P[2],P[3],P[4],P[5],r0,r1);
  float ra0=powf(r0,0.9f), ra1=powf(r1,0.9f);
  float s=ra0+ra1+1e-8f;
  ra0/=s; ra1/=s;
  Ra0[i]=ra0; Ra1[i]=ra1;
  int id = idxP[i];
  atomicAdd(&h0[id], ra0);
  atomicAdd(&h1[id], ra1);
  __syncthreads();
  if(threadIdx.x<NBINS){
    if(h0[threadIdx.x]!=0.f) atomicAdd(&A[A_GHIST+(0*NB+b)*32+threadIdx.x], (double)h0[threadIdx.x]);
    if(h1[threadIdx.x]!=0.f) atomicAdd(&A[A_GHIST+(1*NB+b)*32+threadIdx.x], (double)h1[threadIdx.x]);
  }
  __shared__ int s_last;
  __syncthreads();
  if(threadIdx.x==0){
    __threadfence();
    s_last = (atomicAdd(&T[2],1u) == (unsigned)(BN/256-1));
  }
  __syncthreads();
  if(!s_last) return;
  int t = threadIdx.x;
  if(t>=4) return;
  const double* gh = A + A_GHIST + t*32;
  double sum=0;
  for(int j=0;j<NBINS;j++) sum += gh[j];
  double c=0;
  for(int j=0;j<NBINS;j++){
    c += gh[j]/(sum+1e-8);
    F[F_GCDF+t*32+j]=(float)c;
  }
}

__global__ void k_dk_red(const float* Lp,const float* E,const float* S,
                         const float* Ra0,const float* Ra1,double* A,float* F,unsigned* T){
  int b = blockIdx.x / RB, blk = blockIdx.x % RB;
  double s[20];
#pragma unroll
  for(int q=0;q<20;q++) s[q]=0;
  for(int n = blk*256 + threadIdx.x; n < NPIX; n += RB*256){
    int i=b*NPIX+n;
    double w0=Ra0[i], w1=Ra1[i];
    double x0=Lp[i], x1=E[i], x2=S[i];
    s[0]+=w0; s[1]+=w0*x0; s[2]+=w0*x1; s[3]+=w0*x2;
    s[4]+=w0*x0*x0; s[5]+=w0*x0*x1; s[6]+=w0*x0*x2; s[7]+=w0*x1*x1; s[8]+=w0*x1*x2; s[9]+=w0*x2*x2;
    s[10]+=w1; s[11]+=w1*x0; s[12]+=w1*x1; s[13]+=w1*x2;
    s[14]+=w1*x0*x0; s[15]+=w1*x0*x1; s[16]+=w1*x0*x2; s[17]+=w1*x1*x1; s[18]+=w1*x1*x2; s[19]+=w1*x2*x2;
  }
  __shared__ double red[4][20];
  int wave=threadIdx.x>>6, lane=threadIdx.x&63;
#pragma unroll
  for(int q=0;q<20;q++){
    s[q]=waveSum(s[q]);
    if(lane==0) red[wave][q]=s[q];
  }
  __syncthreads();
  if(threadIdx.x<20){
    double v = red[0][threadIdx.x]+red[1][threadIdx.x]+red[2][threadIdx.x]+red[3][threadIdx.x];
    atomicAdd(&A[A_DK+b*20+threadIdx.x], v);
  }
  __shared__ int s_last;
  __syncthreads();
  if(threadIdx.x==0){
    __threadfence();
    s_last = (atomicAdd(&T[3],1u) == (unsigned)(NB*RB-1));
  }
  __syncthreads();
  if(!s_last || threadIdx.x) return;
  for(int bb=0;bb<NB;bb++) for(int k=0;k<2;k++){
    const double* ss = A + A_DK + (bb*2+k)*10;
    double W0=ss[0], Ws=W0+1e-8;
    double mu0=ss[1]/Ws, mu1=ss[2]/Ws, mu2=ss[3]/Ws;
    double C00=(ss[4]-2.0*mu0*ss[1]+mu0*mu0*W0)/Ws + 1e-6;
    double C01=(ss[5]-mu0*ss[2]-mu1*ss[1]+mu0*mu1*W0)/Ws;
    double C02=(ss[6]-mu0*ss[3]-mu2*ss[1]+mu0*mu2*W0)/Ws;
    double C11=(ss[7]-2.0*mu1*ss[2]+mu1*mu1*W0)/Ws + 1e-6;
    double C12=(ss[8]-mu1*ss[3]-mu2*ss[2]+mu1*mu2*W0)/Ws;
    double C22=(ss[9]-2.0*mu2*ss[3]+mu2*mu2*W0)/Ws + 1e-6;
    double det = C00*(C11*C22-C12*C12) - C01*(C01*C22-C12*C02) + C02*(C01*C12-C11*C02);
    double id = 1.0/det;
    float* P = F + F_DKINV + (bb*2+k)*9;
    P[0]=(float)((C11*C22-C12*C12)*id);
    P[1]=(float)((C02*C12-C01*C22)*id);
    P[2]=(float)((C01*C12-C02*C11)*id);
    P[3]=(float)((C00*C22-C02*C02)*id);
    P[4]=(float)((C01*C02-C00*C12)*id);
    P[5]=(float)((C00*C11-C01*C01)*id);
    P[6]=(float)mu0; P[7]=(float)mu1; P[8]=(float)mu2;
  }
}
__global__ void k_dm(const float* Lp,const float* E,const float* S,
                     const float* Ra0,const float* Ra1,const float* F,float* DM){
  int i = blockIdx.x*256 + threadIdx.x; if(i>=BN) return;
  int b=i/NPIX;
  float x0=Lp[i], x1=E[i], x2=S[i];
  float D[2];
#pragma unroll
  for(int k=0;k<2;k++){
    const float* P = F + F_DKINV + (b*2+k)*9;
    float d0=x0-P[6], d1=x1-P[7], d2=x2-P[8];
    float q = d0*d0*P[0] + d1*d1*P[3] + d2*d2*P[5]
            + 2.f*(d0*d1*P[1] + d0*d2*P[2] + d1*d2*P[4]);
    D[k]=sqrtf(q+1e-8f);
  }
  float w0=Ra0[i]+1e-8f, w1=Ra1[i]+1e-8f;
  DM[i] = (w0*D[0]+w1*D[1])/(w0+w1);
}

__global__ __launch_bounds__(256) void k_lla(const float* rk, const float* Lp, float* tmpL){
  int bx = blockIdx.x % 24, by = (blockIdx.x/24) % 24, b = blockIdx.x/576;
  __shared__ float Rt[30][31], Lt[30][31];
  __shared__ float h0[30][17], h1[30][17], h2[30][17];
  int ox = bx*16, oy = by*16;
  const float* Rb = rk + (size_t)b*NPIX;
  const float* Lb = Lp + (size_t)b*NPIX;
  for(int i=threadIdx.x; i<900; i+=256){
    int lx=i%30, ly=i/30;
    int gx_=ox-7+lx, gy_=oy-7+ly;
    bool in = (gx_>=0&&gx_<WW&&gy_>=0&&gy_<HH);
    Rt[ly][lx]= in ? Rb[gy_*WW+gx_] : 0.f;
    Lt[ly][lx]= in ? Lb[gy_*WW+gx_] : 0.f;
  }
  __syncthreads();
  for(int i=threadIdx.x; i<480; i+=256){
    int j=i%16, r=i/16;
    float s0=0,s1=0,s2=0;
#pragma unroll
    for(int d=0;d<15;d++){
      float rr=Rt[r][j+d], ll=Lt[r][j+d];
      s0+=rr; float rl=rr*ll; s1+=rl; s2+=rl*ll;
    }
    h0[r][j]=s0; h1[r][j]=s1; h2[r][j]=s2;
  }
  __syncthreads();
  int tx=threadIdx.x%16, ty=threadIdx.x/16;
  float S0=0,S1=0,S2=0;
#pragma unroll
  for(int d=0;d<15;d++){ S0+=h0[ty+d][tx]; S1+=h1[ty+d][tx]; S2+=h2[ty+d][tx]; }
  int x=ox+tx, y=oy+ty;
  float cy = (float)((y+8<HH?y+8:HH)-(y-7>0?y-7:0));
  float cx = (float)((x+8<WW?x+8:WW)-(x-7>0?x-7:0));
  float cnt = cy*cx;
  float den = S0/cnt + 1e-8f;
  float mu  = (S1/cnt)/den;
  float var = fmaxf((S2/cnt)/den - mu*mu, 1e-8f);
  int n = y*WW+x;
  tmpL[b*NPIX+n] = fabsf(Lb[n]-mu)/(sqrtf(var)+1e-8f);
}

__global__ __launch_bounds__(256) void k_gldf(const float* rk, const int* idxP, const float* F,
                                              int k, float* tmpG){
  int bx = blockIdx.x % 24, by = (blockIdx.x/24) % 24, b = blockIdx.x/576;
  __shared__ float Rt[30][31];
  __shared__ unsigned char It[30][32];
  __shared__ float Hh[480*33];
  __shared__ float gc[NBINS];
  if(threadIdx.x<NBINS) gc[threadIdx.x]=F[F_GCDF+(k*NB+b)*32+threadIdx.x];
  int ox=bx*16, oy=by*16;
  const float* Rb = rk + (size_t)b*NPIX;
  const int* Ib = idxP + (size_t)b*NPIX;
  for(int i=threadIdx.x;i<900;i+=256){
    int lx=i%30, ly=i/30;
    int gx_=ox-7+lx, gy_=oy-7+ly;
    bool in = (gx_>=0&&gx_<WW&&gy_>=0&&gy_<HH);
    Rt[ly][lx] = in? Rb[gy_*WW+gx_] : 0.f;
    It[ly][lx] = in? (unsigned char)Ib[gy_*WW+gx_] : 0;
  }
  for(int i=threadIdx.x;i<480*33;i+=256) Hh[i]=0.f;
  __syncthreads();
  for(int i=threadIdx.x;i<480;i+=256){
    int j=i%16, r=i/16;
    float* my = Hh + i*33;
    for(int d=0;d<15;d++) my[It[r][j+d]] += Rt[r][j+d];
  }
  __syncthreads();
  int tx=threadIdx.x%16, ty=threadIdx.x/16;
  float vs[32];
  float tot=0;
#pragma unroll
  for(int bin=0;bin<NBINS;bin++){
    float s=0;
#pragma unroll
    for(int d=0;d<15;d++) s += Hh[((ty+d)*16+tx)*33+bin];
    vs[bin]=s; tot+=s;
  }
  int x=ox+tx, y=oy+ty;
  float cy = (float)((y+8<HH?y+8:HH)-(y-7>0?y-7:0));
  float cx = (float)((x+8<WW?x+8:WW)-(x-7>0?x-7:0));
  float cnt = cy*cx;
  float den = tot/cnt + 1e-8f;
  float cs=0, acc=0;
#pragma unroll
  for(int bin=0;bin<NBINS;bin++){
    cs += vs[bin];
    acc += fabsf((cs/cnt)/den - gc[bin]);
  }
  tmpG[b*NPIX + y*WW + x] = acc*(1.f/32.f);
}

__global__ void k_gamma(const float* tmpL,const float* tmpG,const float* rk,const float* F,
                        float* gamma,int first){
  int i = blockIdx.x*256 + threadIdx.x; if(i>=BN) return;
  int b=i/NPIX;
  float zl=(tmpL[i]-F[F_LLA+b*2])/F[F_LLA+b*2+1];
  float zg=(tmpG[i]-F[F_GLD+b*2])/F[F_GLD+b*2+1];
  float c = rk[i]*(0.5f*sp(zl)+0.5f*sp(zg));
  gamma[i] = first ? 1.0f + c : gamma[i] + c;
}

__global__ void k_es_red(const float* E,const float* S,float* F,double* A,unsigned* T){
  int b = blockIdx.x / RB, blk = blockIdx.x % RB;
  const float* M = F + F_X3 + b*6;
  double s[5]={0,0,0,0,0};
  for(int n = blk*256 + threadIdx.x; n < NPIX; n += RB*256){
    float z0=(E[b*NPIX+n]-M[2])/M[3];
    float z1=(S[b*NPIX+n]-M[4])/M[5];
    s[0]+=z0; s[1]+=z1; s[2]+=(double)z0*z0; s[3]+=(double)z0*z1; s[4]+=(double)z1*z1;
  }
  __shared__ double red[4][5];
  int wave=threadIdx.x>>6, lane=threadIdx.x&63;
#pragma unroll
  for(int q=0;q<5;q++){
    s[q]=waveSum(s[q]);
    if(lane==0) red[wave][q]=s[q];
  }
  __syncthreads();
  if(threadIdx.x<5){
    double v = red[0][threadIdx.x]+red[1][threadIdx.x]+red[2][threadIdx.x]+red[3][threadIdx.x];
    atomicAdd(&A[A_ES+b*5+threadIdx.x], v);
  }
  __shared__ int s_last;
  __syncthreads();
  if(threadIdx.x==0){
    __threadfence();
    s_last = (atomicAdd(&T[4],1u) == (unsigned)(NB*RB-1));
  }
  __syncthreads();
  if(!s_last || threadIdx.x) return;
  for(int bb=0;bb<NB;bb++){
    const double* ss = A + A_ES + bb*5;
    double inv=1.0/(double)NPIX;
    double m0=ss[0]*inv, m1=ss[1]*inv;
    double c00=ss[2]*inv - m0*m0 + 1e-6;
    double c01=ss[3]*inv - m0*m1;
    double c11=ss[4]*inv - m1*m1 + 1e-6;
    double det=c00*c11-c01*c01;
    float* P = F + F_ESI + bb*5;
    P[0]=(float)m0; P[1]=(float)m1;
    P[2]=(float)(c11/det); P[3]=(float)(-c01/det); P[4]=(float)(c00/det);
  }
}
__global__ void k_lanom(const float* E,const float* S,const float* DM,const float* gamma,
                        const float* F,float* La){
  int i = blockIdx.x*256 + threadIdx.x; if(i>=BN) return;
  int b=i/NPIX;
  const float* M = F + F_X3 + b*6;
  const float* P = F + F_ESI + b*5;
  float z0=(E[i]-M[2])/M[3];
  float z1=(S[i]-M[4])/M[5];
  float d0=z0-P[0], d1=z1-P[1];
  float d2 = d0*d0*P[2] + 2.f*d0*d1*P[3] + d1*d1*P[4];
  float Rs = expf(-0.5f*d2);
  La[i] = fmaxf(DM[i]*gamma[i]*(1.f-Rs), 0.f);
}
__global__ void k_out2(const float* La, const float* F, float* out){
  int i = blockIdx.x*256 + threadIdx.x; if(i>=BN) return;
  int b=i/NPIX;
  const float* v = F + F_LAQ + b*4;
  double h1 = 0.01*(double)(NPIX-1); double f1 = h1 - floor(h1);
  double h9 = 0.99*(double)(NPIX-1); double f9 = h9 - floor(h9);
  float q1 = (float)((double)v[0] + f1*((double)v[1]-(double)v[0]));
  float q9 = (float)((double)v[2] + f9*((double)v[3]-(double)v[2]));
  float r = (La[i]-q1)/(q9-q1+1e-8f);
  out[BN + i] = fminf(fmaxf(r,0.f),1.f);
}

// ---------------- host ----------------
static void run_sel(const SelBatch& sb, unsigned* H, unsigned* T, float* F, hipStream_t s){
  k_selz8<<<64,256,0,s>>>(sb,H,T);
  for(int p=3;p>=0;--p) k_selp8<<<sb.nt*SEL_BLK,256,0,s>>>(sb,H,T,F,0,p);
  if(sb.medmad) for(int p=3;p>=0;--p) k_selp8<<<sb.nt*SEL_BLK,256,0,s>>>(sb,H,T,F,1,p);
}

extern "C" void kernel_launch(void* const* d_in, const int* in_sizes, int n_in,
                              void* d_out, int out_size, void* d_ws, size_t ws_size,
                              hipStream_t stream){
  (void)in_sizes; (void)n_in; (void)out_size; (void)ws_size;
  const float* lab   = (const float*)d_in[0];
  const float* arand = (const float*)d_in[1];
  float* out = (float*)d_out;
  char* wsb = (char*)d_ws;
  double* A = (double*)wsb;                   // 2048 doubles (16 KB)
  float*  F = (float*)(wsb + 16384);          // 4096 floats (16 KB)
  unsigned* T = (unsigned*)(wsb + 32768);     // 256 u32 (1 KB)
  unsigned* H8 = (unsigned*)(wsb + 65536);    // 16384 u32 = 64 KB sel hists
  float* planes = (float*)(wsb + 131072);
  float* E    = planes;
  float* S    = planes + (size_t)BN;
  float* tA   = planes + (size_t)2*BN;        // La
  float* tmpL = planes + (size_t)5*BN;
  float* tmpG = planes + (size_t)6*BN;
  float* Xw   = planes + (size_t)7*BN;        // interleaved xyz (3*BN)
  float* zb   = planes + (size_t)10*BN;
  float* Ra0  = planes + (size_t)11*BN;
  float* Ra1  = planes + (size_t)12*BN;
  float* DM   = planes + (size_t)13*BN;
  float* gamma= planes + (size_t)14*BN;
  int*   idxP = (int*)(planes + (size_t)16*BN);

  const int GBN = BN/256;      // 1152

  k_zero<<<16,256,0,stream>>>(A,F,T);
  k_sobel<<<NB*576,256,0,stream>>>(lab,S,E);
  k_beta_red<<<NB*RB,256,0,stream>>>(E,S,lab,A,F,T);
  k_lperp<<<GBN,256,0,stream>>>(lab,E,S,F,out);

  SelBatch sbX; sbX.nt=6; sbX.medmad=1;
  for(int b=0;b<NB;b++){
    sbX.src[b*3+0]=out+(size_t)b*NPIX; sbX.src[b*3+1]=E+(size_t)b*NPIX; sbX.src[b*3+2]=S+(size_t)b*NPIX;
    for(int ch=0;ch<3;ch++){ sbX.rank[b*3+ch]=MEDRANK; sbX.fslot[b*3+ch]=F_X3+(b*3+ch)*2; }
  }
  run_sel(sbX,H8,T,F,stream);

  k_xz_red<<<NB*RB,256,0,stream>>>(out,E,S,F,A,T);
  k_xw<<<GBN,256,0,stream>>>(out,E,S,F,Xw,idxP);
  k_kurt<<<1024,256,0,stream>>>(Xw,arand,A);
  k_kurt_pick<<<NB,128,0,stream>>>(A,arand,F);
  k_zbest<<<GBN,256,0,stream>>>(Xw,F,zb);

  SelBatch sbZ; sbZ.nt=8; sbZ.medmad=0;
  {
    int rr[4]={36863,36864,110591,110592};
    for(int b=0;b<NB;b++) for(int ri=0;ri<4;ri++){
      int t=b*4+ri;
      sbZ.src[t]=zb+(size_t)b*NPIX; sbZ.rank[t]=rr[ri]; sbZ.fslot[t]=F_ZBQ+b*4+ri;
    }
  }
  run_sel(sbZ,H8,T,F,stream);

  for(int it=0; it<9; ++it)
    k_gmm_red<<<NB*RB2,256,0,stream>>>(zb,F,A,it);
  k_ralpha<<<GBN,256,0,stream>>>(zb,F,A,idxP,Ra0,Ra1,T);
  k_dk_red<<<NB*RB,256,0,stream>>>(out,E,S,Ra0,Ra1,A,F,T);
  k_dm<<<GBN,256,0,stream>>>(out,E,S,Ra0,Ra1,F,DM);

  SelBatch sbC; sbC.nt=4; sbC.medmad=1;
  for(int b=0;b<NB;b++){
    sbC.src[b]  =tmpL+(size_t)b*NPIX; sbC.rank[b]  =MEDRANK; sbC.fslot[b]  =F_LLA+b*2;
    sbC.src[2+b]=tmpG+(size_t)b*NPIX; sbC.rank[2+b]=MEDRANK; sbC.fslot[2+b]=F_GLD+b*2;
  }

  for(int k=0;k<2;k++){
    const float* Rk = k ? Ra1 : Ra0;
    k_lla<<<NB*576,256,0,stream>>>(Rk,out,tmpL);
    k_gldf<<<NB*576,256,0,stream>>>(Rk,idxP,F,k,tmpG);
    run_sel(sbC,H8,T,F,stream);
    k_gamma<<<GBN,256,0,stream>>>(tmpL,tmpG,Rk,F,gamma,k==0?1:0);
  }

  k_es_red<<<NB*RB,256,0,stream>>>(E,S,F,A,T);
  k_lanom<<<GBN,256,0,stream>>>(E,S,DM,gamma,F,tA);

  SelBatch sbL; sbL.nt=8; sbL.medmad=0;
  {
    int rr[4]={1474,1475,145980,145981};
    for(int b=0;b<NB;b++) for(int ri=0;ri<4;ri++){
      int t=b*4+ri;
      sbL.src[t]=tA+(size_t)b*NPIX; sbL.rank[t]=rr[ri]; sbL.fslot[t]=F_LAQ+b*4+ri;
    }
  }
  run_sel(sbL,H8,T,F,stream);

  k_out2<<<GBN,256,0,stream>>>(tA,F,out);
}

// Round 9
// 703.267 us; speedup vs baseline: 5.3158x; 1.0714x over previous
//
#include <hip/hip_runtime.h>
#include <math.h>

#define HH 384
#define WW 384
#define NPIX (HH*WW)          // 147456
#define NB 2
#define BN (NB*NPIX)          // 294912
#define NT 128
#define NBINS 32
#define MEDRANK ((NPIX-1)/2)  // 73727
#define RB 72                 // reduction blocks per batch
#define RB2 288               // gmm reduction blocks per batch
#define SEL_BLK 64            // blocks per select task per pass
#define KDG 8                 // kurt dirs per block
#define KSEG 16               // kurt segments

// ---- double arena (ws+0, 2048 doubles) ----
#define A_BETA 0
#define A_XZ   16
#define A_ES   40
#define A_DK   56
#define A_GMM  128  // it*8 + b*4 + {N0,Sx0,Sxx0}
#define A_ZTOT 272  // b*2 + {Sx,Sxx}
#define A_GHIST 288
#define A_KURT 512

// ---- float arena (ws+16384, 4096 floats) ----
#define F_BETA 0
#define F_X3   8    // (b*3+ch)*2 {med,mad}; ch1=E ch2=S also serve ES stage
#define F_MEAN 24
#define F_WWH  32
#define F_ASTAR 828
#define F_ZBQ  868
#define F_DKINV 880
#define F_LLA  918
#define F_GLD  924
#define F_ESI  940
#define F_LAQ  952
#define F_GCDF 968
#define F_MMS_MIN 1280  // b*32+slot (u32, init 0xFFFFFFFF)
#define F_MMS_MAX 1408

// ---- ticket/meta arena T (u32, ws+32768, 512 u32) ----
// T[0..7]: reduction tickets
// T[16..335]: sel pass tickets: bid*64 + task*8 + stage*4 + (2-p)
// T[384..447]: sel meta: task*8 + {pre0,rank0,pre1,rank1,center} (write-before-read per run)
// ---- select hists H (u32, ws+65536): 240 regions x 2048 = 1.92 MB, pre-zeroed once ----
// planes at ws + 4 MB

__device__ __forceinline__ double waveSum(double v){
#pragma unroll
  for(int o=32;o;o>>=1) v += __shfl_down(v,o,64);
  return v;
}
__device__ __forceinline__ unsigned f2u(float f){
  unsigned u = __float_as_uint(f);
  return (u & 0x80000000u) ? ~u : (u | 0x80000000u);
}
__device__ __forceinline__ float u2f(unsigned u){
  return __uint_as_float((u & 0x80000000u) ? (u ^ 0x80000000u) : ~u);
}
__device__ __forceinline__ float sp(float x){
  float t = log1pf(expf(-fabsf(x)));
  return x >= 0.f ? x + t : t;
}

struct SelBatch {
  const float* src[8];
  int rank[8];
  int fslot[8];
  int nt;
  int medmad;
};

// find bin containing rank among nb (<=2048) bins; blockDim.x==256, 8 bins/thread
__device__ void pickN(const unsigned* hp, int nb, int rank, unsigned& sel, int& nrank){
  __shared__ unsigned s_cum[256];
  __shared__ unsigned s_res[2];
  int tid = threadIdx.x;
  int base = tid*8;
  unsigned loc[8]; unsigned tsum=0;
#pragma unroll
  for(int j=0;j<8;j++){ unsigned v=(base+j<nb)?hp[base+j]:0u; loc[j]=v; tsum+=v; }
  s_cum[tid]=tsum;
  __syncthreads();
  for(int o=1;o<256;o<<=1){
    unsigned t=(tid>=o)?s_cum[tid-o]:0u;
    __syncthreads();
    s_cum[tid]+=t;
    __syncthreads();
  }
  unsigned cum=s_cum[tid], ex=cum-tsum;
  if(tsum>0u && (unsigned)rank>=ex && (unsigned)rank<cum){
    int rr=rank-(int)ex; unsigned bsel=0;
#pragma unroll
    for(int j=0;j<8;j++){ if((unsigned)rr<loc[j]){ bsel=(unsigned)(base+j); break; } rr-=(int)loc[j]; }
    s_res[0]=bsel; s_res[1]=(unsigned)rr;
  }
  __syncthreads();
  sel=s_res[0]; nrank=(int)s_res[1];
  __syncthreads();
}

__global__ void k_zero(double* A, float* F, unsigned* T, unsigned* H){
  int i = blockIdx.x*256 + threadIdx.x;   // grid 256 blocks -> 65536 threads
  if(i < 2048) A[i] = 0.0;
  if(i < 4096){
    unsigned* U = (unsigned*)F;
    unsigned v = 0u;
    if(i>=F_MMS_MIN && i<F_MMS_MIN+64) v = 0xFFFFFFFFu;
    U[i] = v;
  }
  if(i < 512) T[i] = 0u;
  for(int j=i; j<240*2048; j+=65536) H[j]=0u;
}

// 11/11/10-bit radix pass; p in {2,1,0}; per-(bid,task,stage,p) pre-zeroed hist region
__global__ __launch_bounds__(256) void k_selp(SelBatch sb, unsigned* Hh, unsigned* T,
                                              float* F, int bid, int stage, int p){
  int task = blockIdx.x / SEL_BLK;
  int blk  = blockIdx.x % SEL_BLK;
  unsigned* meta = T + 384 + task*8;
  float center = (stage==1) ? __uint_as_float(meta[4]) : 0.f;
  unsigned pre = (p==2) ? 0u : meta[stage*2];
  __shared__ unsigned lh[2048];
  for(int j=threadIdx.x;j<2048;j+=256) lh[j]=0u;
  __syncthreads();
  const float* src = sb.src[task];
  for(int i=blk*256+threadIdx.x; i<NPIX; i+=SEL_BLK*256){
    float v = src[i];
    if(stage) v = fabsf(v-center);
    unsigned u = f2u(v);
    unsigned bin; bool ok;
    if(p==2){ bin = u>>21; ok = true; }
    else if(p==1){ bin = (u>>10)&2047u; ok = ((u>>21)==pre); }
    else { bin = u&1023u; ok = ((u>>10)==pre); }
    if(ok) atomicAdd(&lh[bin],1u);
  }
  __syncthreads();
  unsigned* hp = Hh + (size_t)(((bid*8+task)*2+stage)*3 + (2-p))*2048;
  for(int j=threadIdx.x;j<2048;j+=256){ unsigned c=lh[j]; if(c) atomicAdd(hp+j,c); }
  __shared__ int s_last;
  __syncthreads();
  if(threadIdx.x==0){
    __threadfence();
    s_last = (atomicAdd(&T[16+bid*64+task*8+stage*4+(2-p)],1u) == (unsigned)(SEL_BLK-1));
  }
  __syncthreads();
  if(!s_last) return;
  int r = (p==2) ? sb.rank[task] : (int)meta[stage*2+1];
  int nb = (p==0) ? 1024 : 2048;
  unsigned sel; int nr;
  pickN(hp, nb, r, sel, nr);
  if(threadIdx.x==0){
    if(p==2){ meta[stage*2]=sel; meta[stage*2+1]=(unsigned)nr; }
    else if(p==1){ meta[stage*2]=(pre<<11)|sel; meta[stage*2+1]=(unsigned)nr; }
    else {
      float val = u2f((pre<<10)|sel);
      if(stage==0){
        if(sb.medmad) meta[4]=__float_as_uint(val);
        else F[sb.fslot[task]]=val;
      } else {
        F[sb.fslot[task]]   = __uint_as_float(meta[4]);
        F[sb.fslot[task]+1] = val*1.4826f + 1e-8f;
      }
    }
  }
}

// GMM: r0 = 1/(1+exp(qa*x^2+qb*x+qc))
__device__ void quad_from_stats(double N0,double Sx0,double Sxx0,double Sxt,double Sxxt,
                                float& qa,float& qb,float& qc){
  double Nt=(double)NPIX;
  double N1=Nt-N0, Sx1=Sxt-Sx0, Sxx1=Sxxt-Sxx0;
  double mu0=Sx0/(N0+1e-8), mu1=Sx1/(N1+1e-8);
  double v0=(Sxx0-2.0*mu0*Sx0+mu0*mu0*N0)/(N0+1e-8)+1e-6;
  double v1=(Sxx1-2.0*mu1*Sx1+mu1*mu1*N1)/(N1+1e-8)+1e-6;
  double p0=N0/Nt, p1=N1/Nt;
  double c0=-0.5*log(v0+1e-6)+log(p0+1e-8);
  double c1=-0.5*log(v1+1e-6)+log(p1+1e-8);
  double iv0=0.5/(v0+1e-6), iv1=0.5/(v1+1e-6);
  qa=(float)(iv0-iv1);
  qb=(float)(2.0*(iv1*mu1-iv0*mu0));
  qc=(float)(iv0*mu0*mu0-iv1*mu1*mu1+c1-c0);
}
__device__ void quad_init(const float* F,int b,float& qa,float& qb,float& qc){
  const float* z = F + F_ZBQ + b*4;
  double h25 = 0.25*(double)(NPIX-1); double f25 = h25 - floor(h25);
  double h75 = 0.75*(double)(NPIX-1); double f75 = h75 - floor(h75);
  double mu0 = (double)z[0] + f25*((double)z[1]-(double)z[0]);
  double mu1 = (double)z[2] + f75*((double)z[3]-(double)z[2]);
  double iv = 0.5/(1.0+1e-6);
  qa = 0.f;
  qb = (float)(2.0*iv*(mu1-mu0));
  qc = (float)(iv*(mu0*mu0-mu1*mu1));
}

// ---------------- pipeline kernels ----------------
__global__ __launch_bounds__(256) void k_sobel(const float* lab, float* S, float* E){
  int bx = blockIdx.x % 24, by = (blockIdx.x/24) % 24, b = blockIdx.x/576;
  __shared__ float Lt[20][21];
  __shared__ float G[18][19];
  const float* Lb = lab + b*3*NPIX;
  int ox = bx*16, oy = by*16;
  for(int i=threadIdx.x; i<400; i+=256){
    int lx=i%20, ly=i/20;
    int gx_=ox-2+lx, gy_=oy-2+ly;
    Lt[ly][lx] = (gx_<0||gx_>=WW||gy_<0||gy_>=HH)?0.f:Lb[gy_*WW+gx_];
  }
  __syncthreads();
  for(int i=threadIdx.x; i<324; i+=256){
    int lx=i%18, ly=i/18;
    int px=lx+1, py=ly+1;
    int gxp=ox-2+px, gyp=oy-2+py;
    float g=0.f;
    if(gxp>=0&&gxp<WW&&gyp>=0&&gyp<HH){
      float gx = -Lt[py-1][px-1]+Lt[py-1][px+1] -2.f*Lt[py][px-1]+2.f*Lt[py][px+1] -Lt[py+1][px-1]+Lt[py+1][px+1];
      float gy = -Lt[py-1][px-1]-2.f*Lt[py-1][px]-Lt[py-1][px+1] +Lt[py+1][px-1]+2.f*Lt[py+1][px]+Lt[py+1][px+1];
      g = gx*gx+gy*gy;
    }
    G[ly][lx]=g;
  }
  __syncthreads();
  int tx = threadIdx.x%16, ty = threadIdx.x/16;
  float s=0;
#pragma unroll
  for(int dy=0;dy<3;dy++)
#pragma unroll
    for(int dx=0;dx<3;dx++) s += G[ty+dy][tx+dx];
  int n = (oy+ty)*WW + ox+tx;
  E[b*NPIX+n] = s*(1.f/9.f);
  float av=Lb[NPIX+n], bv=Lb[2*NPIX+n];
  S[b*NPIX+n] = sqrtf(av*av+bv*bv+1e-8f);
}

__global__ void k_beta_red(const float* E,const float* S,const float* lab,double* A,
                           float* F, unsigned* T){
  int b = blockIdx.x / RB, blk = blockIdx.x % RB;
  double s[5]={0,0,0,0,0};
  for(int n = blk*256 + threadIdx.x; n < NPIX; n += RB*256){
    float e=E[b*NPIX+n], ss=S[b*NPIX+n], l=lab[b*3*NPIX+n];
    s[0]+=(double)e*e; s[1]+=(double)e*ss; s[2]+=(double)ss*ss;
    s[3]+=(double)e*l; s[4]+=(double)ss*l;
  }
  __shared__ double red[4][5];
  int wave=threadIdx.x>>6, lane=threadIdx.x&63;
#pragma unroll
  for(int q=0;q<5;q++){
    s[q]=waveSum(s[q]);
    if(lane==0) red[wave][q]=s[q];
  }
  __syncthreads();
  if(threadIdx.x<5){
    double v = red[0][threadIdx.x]+red[1][threadIdx.x]+red[2][threadIdx.x]+red[3][threadIdx.x];
    atomicAdd(&A[A_BETA+b*5+threadIdx.x], v);
  }
  __shared__ int s_last;
  __syncthreads();
  if(threadIdx.x==0){
    __threadfence();
    s_last = (atomicAdd(&T[0],1u) == (unsigned)(NB*RB-1));
  }
  __syncthreads();
  if(!s_last || threadIdx.x) return;
  for(int bb=0;bb<NB;bb++){
    double EE=A[A_BETA+bb*5],ES=A[A_BETA+bb*5+1],SS=A[A_BETA+bb*5+2],EL=A[A_BETA+bb*5+3],SL=A[A_BETA+bb*5+4];
    double a00=EE+1e-6, a01=ES, a11=SS+1e-6;
    double det=a00*a11-a01*a01;
    F[F_BETA+bb*2]  =(float)(( a11*EL - a01*SL)/det);
    F[F_BETA+bb*2+1]=(float)((-a01*EL + a00*SL)/det);
  }
}

__global__ void k_lperp(const float* lab,const float* E,const float* S,const float* F,float* out0){
  int i = blockIdx.x*256 + threadIdx.x;
  int b=i/NPIX, n=i%NPIX;
  float v = lab[b*3*NPIX+n] - F[F_BETA+b*2]*E[i] - F[F_BETA+b*2+1]*S[i];
  out0[i] = v;
  unsigned u = f2u(v);
  unsigned mn=u, mx=u;
#pragma unroll
  for(int o=32;o;o>>=1){
    unsigned a = __shfl_down(mn,o,64); mn = (a<mn)?a:mn;
    unsigned c = __shfl_down(mx,o,64); mx = (c>mx)?c:mx;
  }
  __shared__ unsigned rmn[4], rmx[4];
  int wave=threadIdx.x>>6, lane=threadIdx.x&63;
  if(lane==0){ rmn[wave]=mn; rmx[wave]=mx; }
  __syncthreads();
  if(threadIdx.x==0){
    unsigned m0 = rmn[0]; unsigned m1 = rmx[0];
    for(int w=1;w<4;w++){ if(rmn[w]<m0)m0=rmn[w]; if(rmx[w]>m1)m1=rmx[w]; }
    unsigned* U = (unsigned*)F;
    int slot = blockIdx.x & 31;
    atomicMin(&U[F_MMS_MIN+b*32+slot], m0);
    atomicMax(&U[F_MMS_MAX+b*32+slot], m1);
  }
}

__global__ void k_xz_red(const float* Lp,const float* E,const float* S,float* F,double* A,
                         unsigned* T){
  int b = blockIdx.x / RB, blk = blockIdx.x % RB;
  const float* M = F + F_X3 + b*6;
  double s[9]={0,0,0,0,0,0,0,0,0};
  for(int n = blk*256 + threadIdx.x; n < NPIX; n += RB*256){
    float z0=(Lp[b*NPIX+n]-M[0])/M[1];
    float z1=(E [b*NPIX+n]-M[2])/M[3];
    float z2=(S [b*NPIX+n]-M[4])/M[5];
    s[0]+=z0; s[1]+=z1; s[2]+=z2;
    s[3]+=(double)z0*z0; s[4]+=(double)z0*z1; s[5]+=(double)z0*z2;
    s[6]+=(double)z1*z1; s[7]+=(double)z1*z2; s[8]+=(double)z2*z2;
  }
  __shared__ double red[4][9];
  int wave=threadIdx.x>>6, lane=threadIdx.x&63;
#pragma unroll
  for(int q=0;q<9;q++){
    s[q]=waveSum(s[q]);
    if(lane==0) red[wave][q]=s[q];
  }
  __syncthreads();
  if(threadIdx.x<9){
    double v = red[0][threadIdx.x]+red[1][threadIdx.x]+red[2][threadIdx.x]+red[3][threadIdx.x];
    atomicAdd(&A[A_XZ+b*9+threadIdx.x], v);
  }
  __shared__ int s_last;
  __syncthreads();
  if(threadIdx.x==0){
    __threadfence();
    s_last = (atomicAdd(&T[1],1u) == (unsigned)(NB*RB-1));
  }
  __syncthreads();
  if(!s_last) return;
  int bb = threadIdx.x;
  if(bb>=NB) return;
  const double* ss = A + A_XZ + bb*9;
  double inv = 1.0/(double)NPIX;
  double m0=ss[0]*inv, m1=ss[1]*inv, m2=ss[2]*inv;
  double a[3][3];
  a[0][0]=fmax(ss[3]*inv-m0*m0,1e-8);
  a[0][1]=a[1][0]=fmax(ss[4]*inv-m0*m1,1e-8);
  a[0][2]=a[2][0]=fmax(ss[5]*inv-m0*m2,1e-8);
  a[1][1]=fmax(ss[6]*inv-m1*m1,1e-8);
  a[1][2]=a[2][1]=fmax(ss[7]*inv-m1*m2,1e-8);
  a[2][2]=fmax(ss[8]*inv-m2*m2,1e-8);
  double V[3][3]={{1,0,0},{0,1,0},{0,0,1}};
  for(int sweep=0;sweep<40;sweep++){
    for(int pp=0;pp<3;pp++){
      int p = (pp==2)?1:0;
      int q = (pp==0)?1:2;
      double apq=a[p][q];
      if(fabs(apq)<1e-30) continue;
      double theta=(a[q][q]-a[p][p])/(2.0*apq);
      double t=((theta>=0)?1.0:-1.0)/(fabs(theta)+sqrt(1.0+theta*theta));
      double c=1.0/sqrt(1.0+t*t), sn=t*c;
      for(int k2=0;k2<3;k2++){ double akp=a[k2][p],akq=a[k2][q];
        a[k2][p]=c*akp-sn*akq; a[k2][q]=sn*akp+c*akq; }
      for(int k2=0;k2<3;k2++){ double apk=a[p][k2],aqk=a[q][k2];
        a[p][k2]=c*apk-sn*aqk; a[q][k2]=sn*apk+c*aqk; }
      for(int k2=0;k2<3;k2++){ double vkp=V[k2][p],vkq=V[k2][q];
        V[k2][p]=c*vkp-sn*vkq; V[k2][q]=sn*vkp+c*vkq; }
    }
  }
  double is0=1.0/sqrt(a[0][0]), is1=1.0/sqrt(a[1][1]), is2=1.0/sqrt(a[2][2]);
  for(int i=0;i<3;i++) for(int j=0;j<3;j++){
    double w = V[i][0]*is0*V[j][0] + V[i][1]*is1*V[j][1] + V[i][2]*is2*V[j][2];
    F[F_WWH + bb*9 + i*3 + j] = (float)w;
  }
  F[F_MEAN+bb*3]=(float)m0; F[F_MEAN+bb*3+1]=(float)m1; F[F_MEAN+bb*3+2]=(float)m2;
}

__global__ void k_xw(const float* Lp,const float* E,const float* S,const float* F,
                     float* Xw,int* idxP){
  __shared__ float s_mn, s_mx;
  int i = blockIdx.x*256 + threadIdx.x;
  int b=i/NPIX;
  if(threadIdx.x==0){
    const unsigned* U = (const unsigned*)F;
    unsigned mn=0xFFFFFFFFu, mx=0u;
    for(int s2=0;s2<32;s2++){
      unsigned a=U[F_MMS_MIN+b*32+s2]; if(a<mn)mn=a;
      unsigned c=U[F_MMS_MAX+b*32+s2]; if(c>mx)mx=c;
    }
    s_mn=u2f(mn); s_mx=u2f(mx);
  }
  __syncthreads();
  const float* M = F + F_X3 + b*6;
  float lp = Lp[i];
  float z0=(lp-M[0])/M[1];
  float z1=(E [i]-M[2])/M[3];
  float z2=(S [i]-M[4])/M[5];
  float d0=z0-F[F_MEAN+b*3], d1=z1-F[F_MEAN+b*3+1], d2=z2-F[F_MEAN+b*3+2];
  const float* Wm = F + F_WWH + b*9;
  Xw[3*(size_t)i  ]=d0*Wm[0]+d1*Wm[3]+d2*Wm[6];
  Xw[3*(size_t)i+1]=d0*Wm[1]+d1*Wm[4]+d2*Wm[7];
  Xw[3*(size_t)i+2]=d0*Wm[2]+d1*Wm[5]+d2*Wm[8];
  float ln = (lp-s_mn)/(s_mx-s_mn+1e-8f);
  ln = fminf(fmaxf(ln,0.f),1.f);
  int id = (int)(ln*32.f);
  idxP[i] = id>31?31:(id<0?0:id);
}

// kurt: 8 dirs/block x 16 segments -> each element read once per dir-group
__global__ __launch_bounds__(256) void k_kurt(const float* Xw, const float* arand, double* A){
  int g = blockIdx.x;           // NB*(NT/KDG)*KSEG = 512
  int b   = g / ((NT/KDG)*KSEG);
  int rem = g % ((NT/KDG)*KSEG);
  int dg  = rem / KSEG;
  int seg = rem % KSEG;
  float a0[KDG],a1[KDG],a2[KDG];
#pragma unroll
  for(int j=0;j<KDG;j++){
    const float* ar = arand + (b*NT+dg*KDG+j)*3;
    float q0=ar[0],q1=ar[1],q2=ar[2];
    float nrm=(float)(sqrt((double)q0*q0+(double)q1*q1+(double)q2*q2)+1e-12);
    a0[j]=q0/nrm; a1[j]=q1/nrm; a2[j]=q2/nrm;
  }
  const float* X = Xw + (size_t)b*NPIX*3;
  double s[KDG][4];
#pragma unroll
  for(int j=0;j<KDG;j++){ s[j][0]=0; s[j][1]=0; s[j][2]=0; s[j][3]=0; }
  const int cnt = NPIX/KSEG;    // 9216
  int start = seg*cnt;
  for(int n=start+threadIdx.x; n<start+cnt; n+=256){
    const float* p = X + 3*(size_t)n;
    float x=p[0], y=p[1], z=p[2];
#pragma unroll
    for(int j=0;j<KDG;j++){
      float zz = fmaf(x,a0[j],fmaf(y,a1[j], z*a2[j]));
      float z2f = zz*zz;
      s[j][0]+=zz; s[j][1]+=z2f; s[j][2]+=z2f*zz; s[j][3]+=(double)z2f*z2f;
    }
  }
  __shared__ double red[4][KDG*4];
  int wave=threadIdx.x>>6, lane=threadIdx.x&63;
#pragma unroll
  for(int j=0;j<KDG;j++)
#pragma unroll
    for(int m=0;m<4;m++){
      double v=waveSum(s[j][m]);
      if(lane==0) red[wave][j*4+m]=v;
    }
  __syncthreads();
  if(threadIdx.x<KDG*4){
    double v = red[0][threadIdx.x]+red[1][threadIdx.x]+red[2][threadIdx.x]+red[3][threadIdx.x];
    int j=threadIdx.x>>2, m=threadIdx.x&3;
    atomicAdd(&A[A_KURT + (size_t)(b*NT+dg*KDG+j)*4 + m], v);
  }
}
__global__ void k_kurt_pick(const double* A, const float* arand, float* F){
  int b = blockIdx.x;
  int t = threadIdx.x;   // 128
  __shared__ float ak[NT];
  const double* K = A + A_KURT + (size_t)(b*NT+t)*4;
  double inv=1.0/(double)NPIX;
  double mean=K[0]*inv, M2=K[1]*inv, M3=K[2]*inv, M4=K[3]*inv;
  double m2 = M2 - mean*mean + 1e-12;
  double m4 = M4 - 4.0*mean*M3 + 6.0*mean*mean*M2 - 3.0*mean*mean*mean*mean;
  ak[t] = (float)fabs(m4/(m2*m2) - 3.0);
  __syncthreads();
  if(t==0){
    int best=0; float bv=ak[0];
    for(int j=1;j<NT;j++) if(ak[j]>bv){bv=ak[j];best=j;}
    const float* ar = arand + (b*NT+best)*3;
    double nrm = sqrt((double)ar[0]*ar[0]+(double)ar[1]*ar[1]+(double)ar[2]*ar[2])+1e-12;
    F[F_ASTAR+b*3]  =(float)(ar[0]/nrm);
    F[F_ASTAR+b*3+1]=(float)(ar[1]/nrm);
    F[F_ASTAR+b*3+2]=(float)(ar[2]/nrm);
  }
}
// zbest + fused global totals (Sx, Sxx) for GMM
__global__ void k_zbest(const float* Xw,const float* F,float* zb,double* A){
  int i = blockIdx.x*256 + threadIdx.x;
  int b=i/NPIX;
  const float* p = Xw + 3*(size_t)i;
  float v = p[0]*F[F_ASTAR+b*3] + p[1]*F[F_ASTAR+b*3+1] + p[2]*F[F_ASTAR+b*3+2];
  zb[i]=v;
  double s0=waveSum((double)v), s1=waveSum((double)v*v);
  __shared__ double red[4][2];
  int wave=threadIdx.x>>6, lane=threadIdx.x&63;
  if(lane==0){ red[wave][0]=s0; red[wave][1]=s1; }
  __syncthreads();
  if(threadIdx.x<2){
    double v2 = red[0][threadIdx.x]+red[1][threadIdx.x]+red[2][threadIdx.x]+red[3][threadIdx.x];
    atomicAdd(&A[A_ZTOT+b*2+threadIdx.x], v2);
  }
}

__global__ __launch_bounds__(256) void k_gmm_red(const float* zb, const float* F, double* A, int it){
  __shared__ float Q[3];
  __shared__ double red[4][3];
  int b = blockIdx.x / RB2, blk = blockIdx.x % RB2;
  if(threadIdx.x==0){
    float qa,qb,qc;
    if(it==0) quad_init(F,b,qa,qb,qc);
    else {
      const double* g = A + A_GMM + (it-1)*8 + b*4;
      quad_from_stats(g[0],g[1],g[2],A[A_ZTOT+b*2],A[A_ZTOT+b*2+1],qa,qb,qc);
    }
    Q[0]=qa;Q[1]=qb;Q[2]=qc;
  }
  __syncthreads();
  float qa=Q[0],qb=Q[1],qc=Q[2];
  double s0=0,s1=0,s2=0;
  for(int n = blk*256 + threadIdx.x; n < NPIX; n += RB2*256){
    float x = zb[b*NPIX+n];
    float f = fmaf(fmaf(qa,x,qb),x,qc);
    float r0 = 1.f/(1.f+expf(f));
    float rx = r0*x;
    s0+=r0; s1+=rx; s2+=(double)rx*x;
  }
  int wave=threadIdx.x>>6, lane=threadIdx.x&63;
  s0=waveSum(s0); s1=waveSum(s1); s2=waveSum(s2);
  if(lane==0){ red[wave][0]=s0; red[wave][1]=s1; red[wave][2]=s2; }
  __syncthreads();
  if(threadIdx.x<3){
    double v = red[0][threadIdx.x]+red[1][threadIdx.x]+red[2][threadIdx.x]+red[3][threadIdx.x];
    atomicAdd(&A[A_GMM+it*8+b*4+threadIdx.x], v);
  }
}

__global__ void k_ralpha(const float* zb, float* F, double* A, const int* idxP,
                         float* Ra0, float* Ra1, unsigned* T){
  __shared__ float h0[NBINS], h1[NBINS];
  __shared__ float Q[3];
  if(threadIdx.x<NBINS){ h0[threadIdx.x]=0.f; h1[threadIdx.x]=0.f; }
  int i = blockIdx.x*256 + threadIdx.x;
  int b=i/NPIX;
  if(threadIdx.x==0){
    const double* g = A + A_GMM + 8*8 + b*4;
    float qa,qb,qc;
    quad_from_stats(g[0],g[1],g[2],A[A_ZTOT+b*2],A[A_ZTOT+b*2+1],qa,qb,qc);
    Q[0]=qa;Q[1]=qb;Q[2]=qc;
  }
  __syncthreads();
  float x = zb[i];
  float f = fmaf(fmaf(Q[0],x,Q[1]),x,Q[2]);
  float r0 = 1.f/(1.f+expf(f));
  float r1 = 1.f-r0;
  float ra0=powf(r0,0.9f), ra1=powf(r1,0.9f);
  float s=ra0+ra1+1e-8f;
  ra0/=s; ra1/=s;
  Ra0[i]=ra0; Ra1[i]=ra1;
  int id = idxP[i];
  atomicAdd(&h0[id], ra0);
  atomicAdd(&h1[id], ra1);
  __syncthreads();
  if(threadIdx.x<NBINS){
    if(h0[threadIdx.x]!=0.f) atomicAdd(&A[A_GHIST+(0*NB+b)*32+threadIdx.x], (double)h0[threadIdx.x]);
    if(h1[threadIdx.x]!=0.f) atomicAdd(&A[A_GHIST+(1*NB+b)*32+threadIdx.x], (double)h1[threadIdx.x]);
  }
  __shared__ int s_last;
  __syncthreads();
  if(threadIdx.x==0){
    __threadfence();
    s_last = (atomicAdd(&T[2],1u) == (unsigned)(BN/256-1));
  }
  __syncthreads();
  if(!s_last) return;
  int t = threadIdx.x;
  if(t>=4) return;
  const double* gh = A + A_GHIST + t*32;
  double sum=0;
  for(int j=0;j<NBINS;j++) sum += gh[j];
  double c=0;
  for(int j=0;j<NBINS;j++){
    c += gh[j]/(sum+1e-8);
    F[F_GCDF+t*32+j]=(float)c;
  }
}

__global__ void k_dk_red(const float* Lp,const float* E,const float* S,
                         const float* Ra0,const float* Ra1,double* A,float* F,unsigned* T){
  int b = blockIdx.x / RB, blk = blockIdx.x % RB;
  double s[20];
#pragma unroll
  for(int q=0;q<20;q++) s[q]=0;
  for(int n = blk*256 + threadIdx.x; n < NPIX; n += RB*256){
    int i=b*NPIX+n;
    double w0=Ra0[i], w1=Ra1[i];
    double x0=Lp[i], x1=E[i], x2=S[i];
    s[0]+=w0; s[1]+=w0*x0; s[2]+=w0*x1; s[3]+=w0*x2;
    s[4]+=w0*x0*x0; s[5]+=w0*x0*x1; s[6]+=w0*x0*x2; s[7]+=w0*x1*x1; s[8]+=w0*x1*x2; s[9]+=w0*x2*x2;
    s[10]+=w1; s[11]+=w1*x0; s[12]+=w1*x1; s[13]+=w1*x2;
    s[14]+=w1*x0*x0; s[15]+=w1*x0*x1; s[16]+=w1*x0*x2; s[17]+=w1*x1*x1; s[18]+=w1*x1*x2; s[19]+=w1*x2*x2;
  }
  __shared__ double red[4][20];
  int wave=threadIdx.x>>6, lane=threadIdx.x&63;
#pragma unroll
  for(int q=0;q<20;q++){
    s[q]=waveSum(s[q]);
    if(lane==0) red[wave][q]=s[q];
  }
  __syncthreads();
  if(threadIdx.x<20){
    double v = red[0][threadIdx.x]+red[1][threadIdx.x]+red[2][threadIdx.x]+red[3][threadIdx.x];
    atomicAdd(&A[A_DK+b*20+threadIdx.x], v);
  }
  __shared__ int s_last;
  __syncthreads();
  if(threadIdx.x==0){
    __threadfence();
    s_last = (atomicAdd(&T[3],1u) == (unsigned)(NB*RB-1));
  }
  __syncthreads();
  if(!s_last || threadIdx.x) return;
  for(int bb=0;bb<NB;bb++) for(int k=0;k<2;k++){
    const double* ss = A + A_DK + (bb*2+k)*10;
    double W0=ss[0], Ws=W0+1e-8;
    double mu0=ss[1]/Ws, mu1=ss[2]/Ws, mu2=ss[3]/Ws;
    double C00=(ss[4]-2.0*mu0*ss[1]+mu0*mu0*W0)/Ws + 1e-6;
    double C01=(ss[5]-mu0*ss[2]-mu1*ss[1]+mu0*mu1*W0)/Ws;
    double C02=(ss[6]-mu0*ss[3]-mu2*ss[1]+mu0*mu2*W0)/Ws;
    double C11=(ss[7]-2.0*mu1*ss[2]+mu1*mu1*W0)/Ws + 1e-6;
    double C12=(ss[8]-mu1*ss[3]-mu2*ss[2]+mu1*mu2*W0)/Ws;
    double C22=(ss[9]-2.0*mu2*ss[3]+mu2*mu2*W0)/Ws + 1e-6;
    double det = C00*(C11*C22-C12*C12) - C01*(C01*C22-C12*C02) + C02*(C01*C12-C11*C02);
    double id = 1.0/det;
    float* P = F + F_DKINV + (bb*2+k)*9;
    P[0]=(float)((C11*C22-C12*C12)*id);
    P[1]=(float)((C02*C12-C01*C22)*id);
    P[2]=(float)((C01*C12-C02*C11)*id);
    P[3]=(float)((C00*C22-C02*C02)*id);
    P[4]=(float)((C01*C02-C00*C12)*id);
    P[5]=(float)((C00*C11-C01*C01)*id);
    P[6]=(float)mu0; P[7]=(float)mu1; P[8]=(float)mu2;
  }
}
__global__ void k_dm(const float* Lp,const float* E,const float* S,
                     const float* Ra0,const float* Ra1,const float* F,float* DM){
  int i = blockIdx.x*256 + threadIdx.x; if(i>=BN) return;
  int b=i/NPIX;
  float x0=Lp[i], x1=E[i], x2=S[i];
  float D[2];
#pragma unroll
  for(int k=0;k<2;k++){
    const float* P = F + F_DKINV + (b*2+k)*9;
    float d0=x0-P[6], d1=x1-P[7], d2=x2-P[8];
    float q = d0*d0*P[0] + d1*d1*P[3] + d2*d2*P[5]
            + 2.f*(d0*d1*P[1] + d0*d2*P[2] + d1*d2*P[4]);
    D[k]=sqrtf(q+1e-8f);
  }
  float w0=Ra0[i]+1e-8f, w1=Ra1[i]+1e-8f;
  DM[i] = (w0*D[0]+w1*D[1])/(w0+w1);
}

__global__ __launch_bounds__(256) void k_lla(const float* rk, const float* Lp, float* tmpL){
  int bx = blockIdx.x % 24, by = (blockIdx.x/24) % 24, b = blockIdx.x/576;
  __shared__ float Rt[30][31], Lt[30][31];
  __shared__ float h0[30][17], h1[30][17], h2[30][17];
  int ox = bx*16, oy = by*16;
  const float* Rb = rk + (size_t)b*NPIX;
  const float* Lb = Lp + (size_t)b*NPIX;
  for(int i=threadIdx.x; i<900; i+=256){
    int lx=i%30, ly=i/30;
    int gx_=ox-7+lx, gy_=oy-7+ly;
    bool in = (gx_>=0&&gx_<WW&&gy_>=0&&gy_<HH);
    Rt[ly][lx]= in ? Rb[gy_*WW+gx_] : 0.f;
    Lt[ly][lx]= in ? Lb[gy_*WW+gx_] : 0.f;
  }
  __syncthreads();
  for(int i=threadIdx.x; i<480; i+=256){
    int j=i%16, r=i/16;
    float s0=0,s1=0,s2=0;
#pragma unroll
    for(int d=0;d<15;d++){
      float rr=Rt[r][j+d], ll=Lt[r][j+d];
      s0+=rr; float rl=rr*ll; s1+=rl; s2+=rl*ll;
    }
    h0[r][j]=s0; h1[r][j]=s1; h2[r][j]=s2;
  }
  __syncthreads();
  int tx=threadIdx.x%16, ty=threadIdx.x/16;
  float S0=0,S1=0,S2=0;
#pragma unroll
  for(int d=0;d<15;d++){ S0+=h0[ty+d][tx]; S1+=h1[ty+d][tx]; S2+=h2[ty+d][tx]; }
  int x=ox+tx, y=oy+ty;
  float cy = (float)((y+8<HH?y+8:HH)-(y-7>0?y-7:0));
  float cx = (float)((x+8<WW?x+8:WW)-(x-7>0?x-7:0));
  float cnt = cy*cx;
  float den = S0/cnt + 1e-8f;
  float mu  = (S1/cnt)/den;
  float var = fmaxf((S2/cnt)/den - mu*mu, 1e-8f);
  int n = y*WW+x;
  tmpL[b*NPIX+n] = fabsf(Lb[n]-mu)/(sqrtf(var)+1e-8f);
}

__global__ __launch_bounds__(256) void k_gldf(const float* rk, const int* idxP, const float* F,
                                              int k, float* tmpG){
  int bx = blockIdx.x % 24, by = (blockIdx.x/24) % 24, b = blockIdx.x/576;
  __shared__ float Rt[30][31];
  __shared__ unsigned char It[30][32];
  __shared__ float Hh[480*33];
  __shared__ float gc[NBINS];
  if(threadIdx.x<NBINS) gc[threadIdx.x]=F[F_GCDF+(k*NB+b)*32+threadIdx.x];
  int ox=bx*16, oy=by*16;
  const float* Rb = rk + (size_t)b*NPIX;
  const int* Ib = idxP + (size_t)b*NPIX;
  for(int i=threadIdx.x;i<900;i+=256){
    int lx=i%30, ly=i/30;
    int gx_=ox-7+lx, gy_=oy-7+ly;
    bool in = (gx_>=0&&gx_<WW&&gy_>=0&&gy_<HH);
    Rt[ly][lx] = in? Rb[gy_*WW+gx_] : 0.f;
    It[ly][lx] = in? (unsigned char)Ib[gy_*WW+gx_] : 0;
  }
  for(int i=threadIdx.x;i<480*33;i+=256) Hh[i]=0.f;
  __syncthreads();
  for(int i=threadIdx.x;i<480;i+=256){
    int j=i%16, r=i/16;
    float* my = Hh + i*33;
    for(int d=0;d<15;d++) my[It[r][j+d]] += Rt[r][j+d];
  }
  __syncthreads();
  int tx=threadIdx.x%16, ty=threadIdx.x/16;
  float vs[32];
  float tot=0;
#pragma unroll
  for(int bin=0;bin<NBINS;bin++){
    float s=0;
#pragma unroll
    for(int d=0;d<15;d++) s += Hh[((ty+d)*16+tx)*33+bin];
    vs[bin]=s; tot+=s;
  }
  int x=ox+tx, y=oy+ty;
  float cy = (float)((y+8<HH?y+8:HH)-(y-7>0?y-7:0));
  float cx = (float)((x+8<WW?x+8:WW)-(x-7>0?x-7:0));
  float cnt = cy*cx;
  float den = tot/cnt + 1e-8f;
  float cs=0, acc=0;
#pragma unroll
  for(int bin=0;bin<NBINS;bin++){
    cs += vs[bin];
    acc += fabsf((cs/cnt)/den - gc[bin]);
  }
  tmpG[b*NPIX + y*WW + x] = acc*(1.f/32.f);
}

__global__ void k_gamma(const float* tmpL,const float* tmpG,const float* rk,const float* F,
                        float* gamma,int first){
  int i = blockIdx.x*256 + threadIdx.x; if(i>=BN) return;
  int b=i/NPIX;
  float zl=(tmpL[i]-F[F_LLA+b*2])/F[F_LLA+b*2+1];
  float zg=(tmpG[i]-F[F_GLD+b*2])/F[F_GLD+b*2+1];
  float c = rk[i]*(0.5f*sp(zl)+0.5f*sp(zg));
  gamma[i] = first ? 1.0f + c : gamma[i] + c;
}

__global__ void k_es_red(const float* E,const float* S,float* F,double* A,unsigned* T){
  int b = blockIdx.x / RB, blk = blockIdx.x % RB;
  const float* M = F + F_X3 + b*6;
  double s[5]={0,0,0,0,0};
  for(int n = blk*256 + threadIdx.x; n < NPIX; n += RB*256){
    float z0=(E[b*NPIX+n]-M[2])/M[3];
    float z1=(S[b*NPIX+n]-M[4])/M[5];
    s[0]+=z0; s[1]+=z1; s[2]+=(double)z0*z0; s[3]+=(double)z0*z1; s[4]+=(double)z1*z1;
  }
  __shared__ double red[4][5];
  int wave=threadIdx.x>>6, lane=threadIdx.x&63;
#pragma unroll
  for(int q=0;q<5;q++){
    s[q]=waveSum(s[q]);
    if(lane==0) red[wave][q]=s[q];
  }
  __syncthreads();
  if(threadIdx.x<5){
    double v = red[0][threadIdx.x]+red[1][threadIdx.x]+red[2][threadIdx.x]+red[3][threadIdx.x];
    atomicAdd(&A[A_ES+b*5+threadIdx.x], v);
  }
  __shared__ int s_last;
  __syncthreads();
  if(threadIdx.x==0){
    __threadfence();
    s_last = (atomicAdd(&T[4],1u) == (unsigned)(NB*RB-1));
  }
  __syncthreads();
  if(!s_last || threadIdx.x) return;
  for(int bb=0;bb<NB;bb++){
    const double* ss = A + A_ES + bb*5;
    double inv=1.0/(double)NPIX;
    double m0=ss[0]*inv, m1=ss[1]*inv;
    double c00=ss[2]*inv - m0*m0 + 1e-6;
    double c01=ss[3]*inv - m0*m1;
    double c11=ss[4]*inv - m1*m1 + 1e-6;
    double det=c00*c11-c01*c01;
    float* P = F + F_ESI + bb*5;
    P[0]=(float)m0; P[1]=(float)m1;
    P[2]=(float)(c11/det); P[3]=(float)(-c01/det); P[4]=(float)(c00/det);
  }
}
__global__ void k_lanom(const float* E,const float* S,const float* DM,const float* gamma,
                        const float* F,float* La){
  int i = blockIdx.x*256 + threadIdx.x; if(i>=BN) return;
  int b=i/NPIX;
  const float* M = F + F_X3 + b*6;
  const float* P = F + F_ESI + b*5;
  float z0=(E[i]-M[2])/M[3];
  float z1=(S[i]-M[4])/M[5];
  float d0=z0-P[0], d1=z1-P[1];
  float d2 = d0*d0*P[2] + 2.f*d0*d1*P[3] + d1*d1*P[4];
  float Rs = expf(-0.5f*d2);
  La[i] = fmaxf(DM[i]*gamma[i]*(1.f-Rs), 0.f);
}
__global__ void k_out2(const float* La, const float* F, float* out){
  int i = blockIdx.x*256 + threadIdx.x; if(i>=BN) return;
  int b=i/NPIX;
  const float* v = F + F_LAQ + b*4;
  double h1 = 0.01*(double)(NPIX-1); double f1 = h1 - floor(h1);
  double h9 = 0.99*(double)(NPIX-1); double f9 = h9 - floor(h9);
  float q1 = (float)((double)v[0] + f1*((double)v[1]-(double)v[0]));
  float q9 = (float)((double)v[2] + f9*((double)v[3]-(double)v[2]));
  float r = (La[i]-q1)/(q9-q1+1e-8f);
  out[BN + i] = fminf(fmaxf(r,0.f),1.f);
}

// ---------------- host ----------------
static void run_sel(const SelBatch& sb, unsigned* H, unsigned* T, float* F, int bid, hipStream_t s){
  for(int p=2;p>=0;--p) k_selp<<<sb.nt*SEL_BLK,256,0,s>>>(sb,H,T,F,bid,0,p);
  if(sb.medmad) for(int p=2;p>=0;--p) k_selp<<<sb.nt*SEL_BLK,256,0,s>>>(sb,H,T,F,bid,1,p);
}

extern "C" void kernel_launch(void* const* d_in, const int* in_sizes, int n_in,
                              void* d_out, int out_size, void* d_ws, size_t ws_size,
                              hipStream_t stream){
  (void)in_sizes; (void)n_in; (void)out_size; (void)ws_size;
  const float* lab   = (const float*)d_in[0];
  const float* arand = (const float*)d_in[1];
  float* out = (float*)d_out;
  char* wsb = (char*)d_ws;
  double* A = (double*)wsb;                   // 2048 doubles (16 KB)
  float*  F = (float*)(wsb + 16384);          // 4096 floats (16 KB)
  unsigned* T = (unsigned*)(wsb + 32768);     // 512 u32
  unsigned* H = (unsigned*)(wsb + 65536);     // 240*2048 u32 = 1.92 MB
  float* planes = (float*)(wsb + (size_t)4*1024*1024);
  float* E    = planes;
  float* S    = planes + (size_t)BN;
  float* tA   = planes + (size_t)2*BN;        // La
  float* tmpL = planes + (size_t)5*BN;
  float* tmpG = planes + (size_t)6*BN;
  float* Xw   = planes + (size_t)7*BN;        // interleaved xyz (3*BN)
  float* zb   = planes + (size_t)10*BN;
  float* Ra0  = planes + (size_t)11*BN;
  float* Ra1  = planes + (size_t)12*BN;
  float* DM   = planes + (size_t)13*BN;
  float* gamma= planes + (size_t)14*BN;
  int*   idxP = (int*)(planes + (size_t)16*BN);

  const int GBN = BN/256;      // 1152

  k_zero<<<256,256,0,stream>>>(A,F,T,H);
  k_sobel<<<NB*576,256,0,stream>>>(lab,S,E);
  k_beta_red<<<NB*RB,256,0,stream>>>(E,S,lab,A,F,T);
  k_lperp<<<GBN,256,0,stream>>>(lab,E,S,F,out);

  SelBatch sbX; sbX.nt=6; sbX.medmad=1;
  for(int b=0;b<NB;b++){
    sbX.src[b*3+0]=out+(size_t)b*NPIX; sbX.src[b*3+1]=E+(size_t)b*NPIX; sbX.src[b*3+2]=S+(size_t)b*NPIX;
    for(int ch=0;ch<3;ch++){ sbX.rank[b*3+ch]=MEDRANK; sbX.fslot[b*3+ch]=F_X3+(b*3+ch)*2; }
  }
  run_sel(sbX,H,T,F,0,stream);

  k_xz_red<<<NB*RB,256,0,stream>>>(out,E,S,F,A,T);
  k_xw<<<GBN,256,0,stream>>>(out,E,S,F,Xw,idxP);
  k_kurt<<<NB*(NT/KDG)*KSEG,256,0,stream>>>(Xw,arand,A);
  k_kurt_pick<<<NB,128,0,stream>>>(A,arand,F);
  k_zbest<<<GBN,256,0,stream>>>(Xw,F,zb,A);

  SelBatch sbZ; sbZ.nt=8; sbZ.medmad=0;
  {
    int rr[4]={36863,36864,110591,110592};
    for(int b=0;b<NB;b++) for(int ri=0;ri<4;ri++){
      int t=b*4+ri;
      sbZ.src[t]=zb+(size_t)b*NPIX; sbZ.rank[t]=rr[ri]; sbZ.fslot[t]=F_ZBQ+b*4+ri;
    }
  }
  run_sel(sbZ,H,T,F,1,stream);

  for(int it=0; it<9; ++it)
    k_gmm_red<<<NB*RB2,256,0,stream>>>(zb,F,A,it);
  k_ralpha<<<GBN,256,0,stream>>>(zb,F,A,idxP,Ra0,Ra1,T);
  k_dk_red<<<NB*RB,256,0,stream>>>(out,E,S,Ra0,Ra1,A,F,T);
  k_dm<<<GBN,256,0,stream>>>(out,E,S,Ra0,Ra1,F,DM);

  SelBatch sbC; sbC.nt=4; sbC.medmad=1;
  for(int b=0;b<NB;b++){
    sbC.src[b]  =tmpL+(size_t)b*NPIX; sbC.rank[b]  =MEDRANK; sbC.fslot[b]  =F_LLA+b*2;
    sbC.src[2+b]=tmpG+(size_t)b*NPIX; sbC.rank[2+b]=MEDRANK; sbC.fslot[2+b]=F_GLD+b*2;
  }

  for(int k=0;k<2;k++){
    const float* Rk = k ? Ra1 : Ra0;
    k_lla<<<NB*576,256,0,stream>>>(Rk,out,tmpL);
    k_gldf<<<NB*576,256,0,stream>>>(Rk,idxP,F,k,tmpG);
    run_sel(sbC,H,T,F,2+k,stream);
    k_gamma<<<GBN,256,0,stream>>>(tmpL,tmpG,Rk,F,gamma,k==0?1:0);
  }

  k_es_red<<<NB*RB,256,0,stream>>>(E,S,F,A,T);
  k_lanom<<<GBN,256,0,stream>>>(E,S,DM,gamma,F,tA);

  SelBatch sbL; sbL.nt=8; sbL.medmad=0;
  {
    int rr[4]={1474,1475,145980,145981};
    for(int b=0;b<NB;b++) for(int ri=0;ri<4;ri++){
      int t=b*4+ri;
      sbL.src[t]=tA+(size_t)b*NPIX; sbL.rank[t]=rr[ri]; sbL.fslot[t]=F_LAQ+b*4+ri;
    }
  }
  run_sel(sbL,H,T,F,4,stream);

  k_out2<<<GBN,256,0,stream>>>(tA,F,out);
}

// Round 10
// 642.060 us; speedup vs baseline: 5.8226x; 1.0953x over previous
//
#include <hip/hip_runtime.h>
#include <math.h>

#define HH 384
#define WW 384
#define NPIX (HH*WW)          // 147456
#define NB 2
#define BN (NB*NPIX)          // 294912
#define NT 128
#define NBINS 32
#define MEDRANK ((NPIX-1)/2)  // 73727
#define RB 72
#define RB2 288
#define SEL_BLK 64
#define KDG 8
#define KSEG 16

// ---- double arena (ws+0, 2048 doubles) ----
#define A_BETA 0
#define A_XZ   16
#define A_ES   40
#define A_DK   56
#define A_GMM  128  // it*8 + b*4 + {N0,Sx0,Sxx0}
#define A_ZTOT 272
#define A_GHIST 288
#define A_KURT 512

// ---- float arena (ws+16384, 4096 floats) ----
#define F_BETA 0
#define F_X3   8
#define F_MEAN 24
#define F_WWH  32
#define F_ASTAR 828
#define F_ZBQ  868
#define F_DKINV 880
#define F_CM   918   // 8 med/mad pairs: (kk*4+isG*2+b)*2 -> 918..933
#define F_ESI  940
#define F_LAQ  952
#define F_GCDF 968
#define F_MMS_MIN 1280
#define F_MMS_MAX 1408

// T (u32, ws+32768, 512): T[0..7] tickets (5=kurt); T[16..335] sel tickets; T[384..447] sel meta
// H (u32, ws+65536): 240 regions x 2048, pre-zeroed once; planes at ws+4MB

__device__ __forceinline__ double waveSum(double v){
#pragma unroll
  for(int o=32;o;o>>=1) v += __shfl_down(v,o,64);
  return v;
}
__device__ __forceinline__ unsigned f2u(float f){
  unsigned u = __float_as_uint(f);
  return (u & 0x80000000u) ? ~u : (u | 0x80000000u);
}
__device__ __forceinline__ float u2f(unsigned u){
  return __uint_as_float((u & 0x80000000u) ? (u ^ 0x80000000u) : ~u);
}
__device__ __forceinline__ float sp(float x){
  float t = log1pf(expf(-fabsf(x)));
  return x >= 0.f ? x + t : t;
}

struct SelBatch {
  const float* src[8];
  int rank[8];
  int fslot[8];
  int nt;
  int medmad;
};

__device__ void pickN(const unsigned* hp, int nb, int rank, unsigned& sel, int& nrank){
  __shared__ unsigned s_cum[256];
  __shared__ unsigned s_res[2];
  int tid = threadIdx.x;
  int base = tid*8;
  unsigned loc[8]; unsigned tsum=0;
#pragma unroll
  for(int j=0;j<8;j++){ unsigned v=(base+j<nb)?hp[base+j]:0u; loc[j]=v; tsum+=v; }
  s_cum[tid]=tsum;
  __syncthreads();
  for(int o=1;o<256;o<<=1){
    unsigned t=(tid>=o)?s_cum[tid-o]:0u;
    __syncthreads();
    s_cum[tid]+=t;
    __syncthreads();
  }
  unsigned cum=s_cum[tid], ex=cum-tsum;
  if(tsum>0u && (unsigned)rank>=ex && (unsigned)rank<cum){
    int rr=rank-(int)ex; unsigned bsel=0;
#pragma unroll
    for(int j=0;j<8;j++){ if((unsigned)rr<loc[j]){ bsel=(unsigned)(base+j); break; } rr-=(int)loc[j]; }
    s_res[0]=bsel; s_res[1]=(unsigned)rr;
  }
  __syncthreads();
  sel=s_res[0]; nrank=(int)s_res[1];
  __syncthreads();
}

__global__ void k_zero(double* A, float* F, unsigned* T, unsigned* H){
  int i = blockIdx.x*256 + threadIdx.x;
  if(i < 2048) A[i] = 0.0;
  if(i < 4096){
    unsigned* U = (unsigned*)F;
    unsigned v = 0u;
    if(i>=F_MMS_MIN && i<F_MMS_MIN+64) v = 0xFFFFFFFFu;
    U[i] = v;
  }
  if(i < 512) T[i] = 0u;
  for(int j=i; j<240*2048; j+=65536) H[j]=0u;
}

// 11/11/10-bit radix pass
__global__ __launch_bounds__(256) void k_selp(SelBatch sb, unsigned* Hh, unsigned* T,
                                              float* F, int bid, int stage, int p){
  int task = blockIdx.x / SEL_BLK;
  int blk  = blockIdx.x % SEL_BLK;
  unsigned* meta = T + 384 + task*8;
  float center = (stage==1) ? __uint_as_float(meta[4]) : 0.f;
  unsigned pre = (p==2) ? 0u : meta[stage*2];
  __shared__ unsigned lh[2048];
  for(int j=threadIdx.x;j<2048;j+=256) lh[j]=0u;
  __syncthreads();
  const float* src = sb.src[task];
  for(int i=blk*256+threadIdx.x; i<NPIX; i+=SEL_BLK*256){
    float v = src[i];
    if(stage) v = fabsf(v-center);
    unsigned u = f2u(v);
    unsigned bin; bool ok;
    if(p==2){ bin = u>>21; ok = true; }
    else if(p==1){ bin = (u>>10)&2047u; ok = ((u>>21)==pre); }
    else { bin = u&1023u; ok = ((u>>10)==pre); }
    if(ok) atomicAdd(&lh[bin],1u);
  }
  __syncthreads();
  unsigned* hp = Hh + (size_t)(((bid*8+task)*2+stage)*3 + (2-p))*2048;
  for(int j=threadIdx.x;j<2048;j+=256){ unsigned c=lh[j]; if(c) atomicAdd(hp+j,c); }
  __shared__ int s_last;
  __syncthreads();
  if(threadIdx.x==0){
    __threadfence();
    s_last = (atomicAdd(&T[16+bid*64+task*8+stage*4+(2-p)],1u) == (unsigned)(SEL_BLK-1));
  }
  __syncthreads();
  if(!s_last) return;
  int r = (p==2) ? sb.rank[task] : (int)meta[stage*2+1];
  int nb = (p==0) ? 1024 : 2048;
  unsigned sel; int nr;
  pickN(hp, nb, r, sel, nr);
  if(threadIdx.x==0){
    if(p==2){ meta[stage*2]=sel; meta[stage*2+1]=(unsigned)nr; }
    else if(p==1){ meta[stage*2]=(pre<<11)|sel; meta[stage*2+1]=(unsigned)nr; }
    else {
      float val = u2f((pre<<10)|sel);
      if(stage==0){
        if(sb.medmad) meta[4]=__float_as_uint(val);
        else F[sb.fslot[task]]=val;
      } else {
        F[sb.fslot[task]]   = __uint_as_float(meta[4]);
        F[sb.fslot[task]+1] = val*1.4826f + 1e-8f;
      }
    }
  }
}

__device__ void quad_from_stats(double N0,double Sx0,double Sxx0,double Sxt,double Sxxt,
                                float& qa,float& qb,float& qc){
  double Nt=(double)NPIX;
  double N1=Nt-N0, Sx1=Sxt-Sx0, Sxx1=Sxxt-Sxx0;
  double mu0=Sx0/(N0+1e-8), mu1=Sx1/(N1+1e-8);
  double v0=(Sxx0-2.0*mu0*Sx0+mu0*mu0*N0)/(N0+1e-8)+1e-6;
  double v1=(Sxx1-2.0*mu1*Sx1+mu1*mu1*N1)/(N1+1e-8)+1e-6;
  double p0=N0/Nt, p1=N1/Nt;
  double c0=-0.5*log(v0+1e-6)+log(p0+1e-8);
  double c1=-0.5*log(v1+1e-6)+log(p1+1e-8);
  double iv0=0.5/(v0+1e-6), iv1=0.5/(v1+1e-6);
  qa=(float)(iv0-iv1);
  qb=(float)(2.0*(iv1*mu1-iv0*mu0));
  qc=(float)(iv0*mu0*mu0-iv1*mu1*mu1+c1-c0);
}
__device__ void quad_init(const float* F,int b,float& qa,float& qb,float& qc){
  const float* z = F + F_ZBQ + b*4;
  double h25 = 0.25*(double)(NPIX-1); double f25 = h25 - floor(h25);
  double h75 = 0.75*(double)(NPIX-1); double f75 = h75 - floor(h75);
  double mu0 = (double)z[0] + f25*((double)z[1]-(double)z[0]);
  double mu1 = (double)z[2] + f75*((double)z[3]-(double)z[2]);
  double iv = 0.5/(1.0+1e-6);
  qa = 0.f;
  qb = (float)(2.0*iv*(mu1-mu0));
  qc = (float)(iv*(mu0*mu0-mu1*mu1));
}

// ---------------- pipeline kernels ----------------
__global__ __launch_bounds__(256) void k_sobel(const float* lab, float* S, float* E){
  int bx = blockIdx.x % 24, by = (blockIdx.x/24) % 24, b = blockIdx.x/576;
  __shared__ float Lt[20][21];
  __shared__ float G[18][19];
  const float* Lb = lab + b*3*NPIX;
  int ox = bx*16, oy = by*16;
  for(int i=threadIdx.x; i<400; i+=256){
    int lx=i%20, ly=i/20;
    int gx_=ox-2+lx, gy_=oy-2+ly;
    Lt[ly][lx] = (gx_<0||gx_>=WW||gy_<0||gy_>=HH)?0.f:Lb[gy_*WW+gx_];
  }
  __syncthreads();
  for(int i=threadIdx.x; i<324; i+=256){
    int lx=i%18, ly=i/18;
    int px=lx+1, py=ly+1;
    int gxp=ox-2+px, gyp=oy-2+py;
    float g=0.f;
    if(gxp>=0&&gxp<WW&&gyp>=0&&gyp<HH){
      float gx = -Lt[py-1][px-1]+Lt[py-1][px+1] -2.f*Lt[py][px-1]+2.f*Lt[py][px+1] -Lt[py+1][px-1]+Lt[py+1][px+1];
      float gy = -Lt[py-1][px-1]-2.f*Lt[py-1][px]-Lt[py-1][px+1] +Lt[py+1][px-1]+2.f*Lt[py+1][px]+Lt[py+1][px+1];
      g = gx*gx+gy*gy;
    }
    G[ly][lx]=g;
  }
  __syncthreads();
  int tx = threadIdx.x%16, ty = threadIdx.x/16;
  float s=0;
#pragma unroll
  for(int dy=0;dy<3;dy++)
#pragma unroll
    for(int dx=0;dx<3;dx++) s += G[ty+dy][tx+dx];
  int n = (oy+ty)*WW + ox+tx;
  E[b*NPIX+n] = s*(1.f/9.f);
  float av=Lb[NPIX+n], bv=Lb[2*NPIX+n];
  S[b*NPIX+n] = sqrtf(av*av+bv*bv+1e-8f);
}

__global__ void k_beta_red(const float* E,const float* S,const float* lab,double* A,
                           float* F, unsigned* T){
  int b = blockIdx.x / RB, blk = blockIdx.x % RB;
  double s[5]={0,0,0,0,0};
  for(int n = blk*256 + threadIdx.x; n < NPIX; n += RB*256){
    float e=E[b*NPIX+n], ss=S[b*NPIX+n], l=lab[b*3*NPIX+n];
    s[0]+=(double)e*e; s[1]+=(double)e*ss; s[2]+=(double)ss*ss;
    s[3]+=(double)e*l; s[4]+=(double)ss*l;
  }
  __shared__ double red[4][5];
  int wave=threadIdx.x>>6, lane=threadIdx.x&63;
#pragma unroll
  for(int q=0;q<5;q++){
    s[q]=waveSum(s[q]);
    if(lane==0) red[wave][q]=s[q];
  }
  __syncthreads();
  if(threadIdx.x<5){
    double v = red[0][threadIdx.x]+red[1][threadIdx.x]+red[2][threadIdx.x]+red[3][threadIdx.x];
    atomicAdd(&A[A_BETA+b*5+threadIdx.x], v);
  }
  __shared__ int s_last;
  __syncthreads();
  if(threadIdx.x==0){
    __threadfence();
    s_last = (atomicAdd(&T[0],1u) == (unsigned)(NB*RB-1));
  }
  __syncthreads();
  if(!s_last || threadIdx.x) return;
  for(int bb=0;bb<NB;bb++){
    double EE=A[A_BETA+bb*5],ES=A[A_BETA+bb*5+1],SS=A[A_BETA+bb*5+2],EL=A[A_BETA+bb*5+3],SL=A[A_BETA+bb*5+4];
    double a00=EE+1e-6, a01=ES, a11=SS+1e-6;
    double det=a00*a11-a01*a01;
    F[F_BETA+bb*2]  =(float)(( a11*EL - a01*SL)/det);
    F[F_BETA+bb*2+1]=(float)((-a01*EL + a00*SL)/det);
  }
}

__global__ void k_lperp(const float* lab,const float* E,const float* S,const float* F,float* out0){
  int i = blockIdx.x*256 + threadIdx.x;
  int b=i/NPIX, n=i%NPIX;
  float v = lab[b*3*NPIX+n] - F[F_BETA+b*2]*E[i] - F[F_BETA+b*2+1]*S[i];
  out0[i] = v;
  unsigned u = f2u(v);
  unsigned mn=u, mx=u;
#pragma unroll
  for(int o=32;o;o>>=1){
    unsigned a = __shfl_down(mn,o,64); mn = (a<mn)?a:mn;
    unsigned c = __shfl_down(mx,o,64); mx = (c>mx)?c:mx;
  }
  __shared__ unsigned rmn[4], rmx[4];
  int wave=threadIdx.x>>6, lane=threadIdx.x&63;
  if(lane==0){ rmn[wave]=mn; rmx[wave]=mx; }
  __syncthreads();
  if(threadIdx.x==0){
    unsigned m0 = rmn[0]; unsigned m1 = rmx[0];
    for(int w=1;w<4;w++){ if(rmn[w]<m0)m0=rmn[w]; if(rmx[w]>m1)m1=rmx[w]; }
    unsigned* U = (unsigned*)F;
    int slot = blockIdx.x & 31;
    atomicMin(&U[F_MMS_MIN+b*32+slot], m0);
    atomicMax(&U[F_MMS_MAX+b*32+slot], m1);
  }
}

__global__ void k_xz_red(const float* Lp,const float* E,const float* S,float* F,double* A,
                         unsigned* T){
  int b = blockIdx.x / RB, blk = blockIdx.x % RB;
  const float* M = F + F_X3 + b*6;
  double s[9]={0,0,0,0,0,0,0,0,0};
  for(int n = blk*256 + threadIdx.x; n < NPIX; n += RB*256){
    float z0=(Lp[b*NPIX+n]-M[0])/M[1];
    float z1=(E [b*NPIX+n]-M[2])/M[3];
    float z2=(S [b*NPIX+n]-M[4])/M[5];
    s[0]+=z0; s[1]+=z1; s[2]+=z2;
    s[3]+=(double)z0*z0; s[4]+=(double)z0*z1; s[5]+=(double)z0*z2;
    s[6]+=(double)z1*z1; s[7]+=(double)z1*z2; s[8]+=(double)z2*z2;
  }
  __shared__ double red[4][9];
  int wave=threadIdx.x>>6, lane=threadIdx.x&63;
#pragma unroll
  for(int q=0;q<9;q++){
    s[q]=waveSum(s[q]);
    if(lane==0) red[wave][q]=s[q];
  }
  __syncthreads();
  if(threadIdx.x<9){
    double v = red[0][threadIdx.x]+red[1][threadIdx.x]+red[2][threadIdx.x]+red[3][threadIdx.x];
    atomicAdd(&A[A_XZ+b*9+threadIdx.x], v);
  }
  __shared__ int s_last;
  __syncthreads();
  if(threadIdx.x==0){
    __threadfence();
    s_last = (atomicAdd(&T[1],1u) == (unsigned)(NB*RB-1));
  }
  __syncthreads();
  if(!s_last) return;
  int bb = threadIdx.x;
  if(bb>=NB) return;
  const double* ss = A + A_XZ + bb*9;
  double inv = 1.0/(double)NPIX;
  double m0=ss[0]*inv, m1=ss[1]*inv, m2=ss[2]*inv;
  double a[3][3];
  a[0][0]=fmax(ss[3]*inv-m0*m0,1e-8);
  a[0][1]=a[1][0]=fmax(ss[4]*inv-m0*m1,1e-8);
  a[0][2]=a[2][0]=fmax(ss[5]*inv-m0*m2,1e-8);
  a[1][1]=fmax(ss[6]*inv-m1*m1,1e-8);
  a[1][2]=a[2][1]=fmax(ss[7]*inv-m1*m2,1e-8);
  a[2][2]=fmax(ss[8]*inv-m2*m2,1e-8);
  double V[3][3]={{1,0,0},{0,1,0},{0,0,1}};
  for(int sweep=0;sweep<40;sweep++){
    for(int pp=0;pp<3;pp++){
      int p = (pp==2)?1:0;
      int q = (pp==0)?1:2;
      double apq=a[p][q];
      if(fabs(apq)<1e-30) continue;
      double theta=(a[q][q]-a[p][p])/(2.0*apq);
      double t=((theta>=0)?1.0:-1.0)/(fabs(theta)+sqrt(1.0+theta*theta));
      double c=1.0/sqrt(1.0+t*t), sn=t*c;
      for(int k2=0;k2<3;k2++){ double akp=a[k2][p],akq=a[k2][q];
        a[k2][p]=c*akp-sn*akq; a[k2][q]=sn*akp+c*akq; }
      for(int k2=0;k2<3;k2++){ double apk=a[p][k2],aqk=a[q][k2];
        a[p][k2]=c*apk-sn*aqk; a[q][k2]=sn*apk+c*aqk; }
      for(int k2=0;k2<3;k2++){ double vkp=V[k2][p],vkq=V[k2][q];
        V[k2][p]=c*vkp-sn*vkq; V[k2][q]=sn*vkp+c*vkq; }
    }
  }
  double is0=1.0/sqrt(a[0][0]), is1=1.0/sqrt(a[1][1]), is2=1.0/sqrt(a[2][2]);
  for(int i=0;i<3;i++) for(int j=0;j<3;j++){
    double w = V[i][0]*is0*V[j][0] + V[i][1]*is1*V[j][1] + V[i][2]*is2*V[j][2];
    F[F_WWH + bb*9 + i*3 + j] = (float)w;
  }
  F[F_MEAN+bb*3]=(float)m0; F[F_MEAN+bb*3+1]=(float)m1; F[F_MEAN+bb*3+2]=(float)m2;
}

__global__ void k_xw(const float* Lp,const float* E,const float* S,const float* F,
                     float* Xw,int* idxP){
  __shared__ float s_mn, s_mx;
  int i = blockIdx.x*256 + threadIdx.x;
  int b=i/NPIX;
  if(threadIdx.x==0){
    const unsigned* U = (const unsigned*)F;
    unsigned mn=0xFFFFFFFFu, mx=0u;
    for(int s2=0;s2<32;s2++){
      unsigned a=U[F_MMS_MIN+b*32+s2]; if(a<mn)mn=a;
      unsigned c=U[F_MMS_MAX+b*32+s2]; if(c>mx)mx=c;
    }
    s_mn=u2f(mn); s_mx=u2f(mx);
  }
  __syncthreads();
  const float* M = F + F_X3 + b*6;
  float lp = Lp[i];
  float z0=(lp-M[0])/M[1];
  float z1=(E [i]-M[2])/M[3];
  float z2=(S [i]-M[4])/M[5];
  float d0=z0-F[F_MEAN+b*3], d1=z1-F[F_MEAN+b*3+1], d2=z2-F[F_MEAN+b*3+2];
  const float* Wm = F + F_WWH + b*9;
  Xw[3*(size_t)i  ]=d0*Wm[0]+d1*Wm[3]+d2*Wm[6];
  Xw[3*(size_t)i+1]=d0*Wm[1]+d1*Wm[4]+d2*Wm[7];
  Xw[3*(size_t)i+2]=d0*Wm[2]+d1*Wm[5]+d2*Wm[8];
  float ln = (lp-s_mn)/(s_mx-s_mn+1e-8f);
  ln = fminf(fmaxf(ln,0.f),1.f);
  int id = (int)(ln*32.f);
  idxP[i] = id>31?31:(id<0?0:id);
}

// kurt moments + fused argmax/pick in last block
__global__ __launch_bounds__(256) void k_kurt(const float* Xw, const float* arand,
                                              double* A, float* F, unsigned* T){
  int g = blockIdx.x;           // 512
  int b   = g / ((NT/KDG)*KSEG);
  int rem = g % ((NT/KDG)*KSEG);
  int dg  = rem / KSEG;
  int seg = rem % KSEG;
  float a0[KDG],a1[KDG],a2[KDG];
#pragma unroll
  for(int j=0;j<KDG;j++){
    const float* ar = arand + (b*NT+dg*KDG+j)*3;
    float q0=ar[0],q1=ar[1],q2=ar[2];
    float nrm=(float)(sqrt((double)q0*q0+(double)q1*q1+(double)q2*q2)+1e-12);
    a0[j]=q0/nrm; a1[j]=q1/nrm; a2[j]=q2/nrm;
  }
  const float* X = Xw + (size_t)b*NPIX*3;
  double s[KDG][4];
#pragma unroll
  for(int j=0;j<KDG;j++){ s[j][0]=0; s[j][1]=0; s[j][2]=0; s[j][3]=0; }
  const int cnt = NPIX/KSEG;
  int start = seg*cnt;
  for(int n=start+threadIdx.x; n<start+cnt; n+=256){
    const float* p = X + 3*(size_t)n;
    float x=p[0], y=p[1], z=p[2];
#pragma unroll
    for(int j=0;j<KDG;j++){
      float zz = fmaf(x,a0[j],fmaf(y,a1[j], z*a2[j]));
      float z2f = zz*zz;
      s[j][0]+=zz; s[j][1]+=z2f; s[j][2]+=z2f*zz; s[j][3]+=(double)z2f*z2f;
    }
  }
  __shared__ double red[4][KDG*4];
  int wave=threadIdx.x>>6, lane=threadIdx.x&63;
#pragma unroll
  for(int j=0;j<KDG;j++)
#pragma unroll
    for(int m=0;m<4;m++){
      double v=waveSum(s[j][m]);
      if(lane==0) red[wave][j*4+m]=v;
    }
  __syncthreads();
  if(threadIdx.x<KDG*4){
    double v = red[0][threadIdx.x]+red[1][threadIdx.x]+red[2][threadIdx.x]+red[3][threadIdx.x];
    int j=threadIdx.x>>2, m=threadIdx.x&3;
    atomicAdd(&A[A_KURT + (size_t)(b*NT+dg*KDG+j)*4 + m], v);
  }
  __shared__ int s_last;
  __syncthreads();
  if(threadIdx.x==0){
    __threadfence();
    s_last = (atomicAdd(&T[5],1u) == (unsigned)(NB*(NT/KDG)*KSEG-1));
  }
  __syncthreads();
  if(!s_last) return;
  __shared__ float ak[NB*NT];
  {
    int tid=threadIdx.x;       // 256 = NB*NT
    const double* K = A + A_KURT + (size_t)tid*4;
    double inv=1.0/(double)NPIX;
    double mean=K[0]*inv, M2=K[1]*inv, M3=K[2]*inv, M4=K[3]*inv;
    double m2 = M2 - mean*mean + 1e-12;
    double m4 = M4 - 4.0*mean*M3 + 6.0*mean*mean*M2 - 3.0*mean*mean*mean*mean;
    ak[tid] = (float)fabs(m4/(m2*m2) - 3.0);
  }
  __syncthreads();
  if(threadIdx.x<NB){
    int bb=threadIdx.x;
    int best=0; float bv=ak[bb*NT];
    for(int j=1;j<NT;j++){ float v=ak[bb*NT+j]; if(v>bv){bv=v;best=j;} }
    const float* ar = arand + (bb*NT+best)*3;
    double nrm = sqrt((double)ar[0]*ar[0]+(double)ar[1]*ar[1]+(double)ar[2]*ar[2])+1e-12;
    F[F_ASTAR+bb*3]  =(float)(ar[0]/nrm);
    F[F_ASTAR+bb*3+1]=(float)(ar[1]/nrm);
    F[F_ASTAR+bb*3+2]=(float)(ar[2]/nrm);
  }
}

__global__ void k_zbest(const float* Xw,const float* F,float* zb,double* A){
  int i = blockIdx.x*256 + threadIdx.x;
  int b=i/NPIX;
  const float* p = Xw + 3*(size_t)i;
  float v = p[0]*F[F_ASTAR+b*3] + p[1]*F[F_ASTAR+b*3+1] + p[2]*F[F_ASTAR+b*3+2];
  zb[i]=v;
  double s0=waveSum((double)v), s1=waveSum((double)v*v);
  __shared__ double red[4][2];
  int wave=threadIdx.x>>6, lane=threadIdx.x&63;
  if(lane==0){ red[wave][0]=s0; red[wave][1]=s1; }
  __syncthreads();
  if(threadIdx.x<2){
    double v2 = red[0][threadIdx.x]+red[1][threadIdx.x]+red[2][threadIdx.x]+red[3][threadIdx.x];
    atomicAdd(&A[A_ZTOT+b*2+threadIdx.x], v2);
  }
}

__global__ __launch_bounds__(256) void k_gmm_red(const float* zb, const float* F, double* A, int it){
  __shared__ float Q[3];
  __shared__ double red[4][3];
  int b = blockIdx.x / RB2, blk = blockIdx.x % RB2;
  if(threadIdx.x==0){
    float qa,qb,qc;
    if(it==0) quad_init(F,b,qa,qb,qc);
    else {
      const double* g = A + A_GMM + (it-1)*8 + b*4;
      quad_from_stats(g[0],g[1],g[2],A[A_ZTOT+b*2],A[A_ZTOT+b*2+1],qa,qb,qc);
    }
    Q[0]=qa;Q[1]=qb;Q[2]=qc;
  }
  __syncthreads();
  float qa=Q[0],qb=Q[1],qc=Q[2];
  double s0=0,s1=0,s2=0;
  for(int n = blk*256 + threadIdx.x; n < NPIX; n += RB2*256){
    float x = zb[b*NPIX+n];
    float f = fmaf(fmaf(qa,x,qb),x,qc);
    float r0 = 1.f/(1.f+expf(f));
    float rx = r0*x;
    s0+=r0; s1+=rx; s2+=(double)rx*x;
  }
  int wave=threadIdx.x>>6, lane=threadIdx.x&63;
  s0=waveSum(s0); s1=waveSum(s1); s2=waveSum(s2);
  if(lane==0){ red[wave][0]=s0; red[wave][1]=s1; red[wave][2]=s2; }
  __syncthreads();
  if(threadIdx.x<3){
    double v = red[0][threadIdx.x]+red[1][threadIdx.x]+red[2][threadIdx.x]+red[3][threadIdx.x];
    atomicAdd(&A[A_GMM+it*8+b*4+threadIdx.x], v);
  }
}

__global__ void k_ralpha(const float* zb, float* F, double* A, const int* idxP,
                         float* Ra0, float* Ra1, unsigned* T){
  __shared__ float h0[NBINS], h1[NBINS];
  __shared__ float Q[3];
  if(threadIdx.x<NBINS){ h0[threadIdx.x]=0.f; h1[threadIdx.x]=0.f; }
  int i = blockIdx.x*256 + threadIdx.x;
  int b=i/NPIX;
  if(threadIdx.x==0){
    const double* g = A + A_GMM + 8*8 + b*4;
    float qa,qb,qc;
    quad_from_stats(g[0],g[1],g[2],A[A_ZTOT+b*2],A[A_ZTOT+b*2+1],qa,qb,qc);
    Q[0]=qa;Q[1]=qb;Q[2]=qc;
  }
  __syncthreads();
  float x = zb[i];
  float f = fmaf(fmaf(Q[0],x,Q[1]),x,Q[2]);
  float r0 = 1.f/(1.f+expf(f));
  float r1 = 1.f-r0;
  float ra0=powf(r0,0.9f), ra1=powf(r1,0.9f);
  float s=ra0+ra1+1e-8f;
  ra0/=s; ra1/=s;
  Ra0[i]=ra0; Ra1[i]=ra1;
  int id = idxP[i];
  atomicAdd(&h0[id], ra0);
  atomicAdd(&h1[id], ra1);
  __syncthreads();
  if(threadIdx.x<NBINS){
    if(h0[threadIdx.x]!=0.f) atomicAdd(&A[A_GHIST+(0*NB+b)*32+threadIdx.x], (double)h0[threadIdx.x]);
    if(h1[threadIdx.x]!=0.f) atomicAdd(&A[A_GHIST+(1*NB+b)*32+threadIdx.x], (double)h1[threadIdx.x]);
  }
  __shared__ int s_last;
  __syncthreads();
  if(threadIdx.x==0){
    __threadfence();
    s_last = (atomicAdd(&T[2],1u) == (unsigned)(BN/256-1));
  }
  __syncthreads();
  if(!s_last) return;
  int t = threadIdx.x;
  if(t>=4) return;
  const double* gh = A + A_GHIST + t*32;
  double sum=0;
  for(int j=0;j<NBINS;j++) sum += gh[j];
  double c=0;
  for(int j=0;j<NBINS;j++){
    c += gh[j]/(sum+1e-8);
    F[F_GCDF+t*32+j]=(float)c;
  }
}

__global__ void k_dk_red(const float* Lp,const float* E,const float* S,
                         const float* Ra0,const float* Ra1,double* A,float* F,unsigned* T){
  int b = blockIdx.x / RB, blk = blockIdx.x % RB;
  double s[20];
#pragma unroll
  for(int q=0;q<20;q++) s[q]=0;
  for(int n = blk*256 + threadIdx.x; n < NPIX; n += RB*256){
    int i=b*NPIX+n;
    double w0=Ra0[i], w1=Ra1[i];
    double x0=Lp[i], x1=E[i], x2=S[i];
    s[0]+=w0; s[1]+=w0*x0; s[2]+=w0*x1; s[3]+=w0*x2;
    s[4]+=w0*x0*x0; s[5]+=w0*x0*x1; s[6]+=w0*x0*x2; s[7]+=w0*x1*x1; s[8]+=w0*x1*x2; s[9]+=w0*x2*x2;
    s[10]+=w1; s[11]+=w1*x0; s[12]+=w1*x1; s[13]+=w1*x2;
    s[14]+=w1*x0*x0; s[15]+=w1*x0*x1; s[16]+=w1*x0*x2; s[17]+=w1*x1*x1; s[18]+=w1*x1*x2; s[19]+=w1*x2*x2;
  }
  __shared__ double red[4][20];
  int wave=threadIdx.x>>6, lane=threadIdx.x&63;
#pragma unroll
  for(int q=0;q<20;q++){
    s[q]=waveSum(s[q]);
    if(lane==0) red[wave][q]=s[q];
  }
  __syncthreads();
  if(threadIdx.x<20){
    double v = red[0][threadIdx.x]+red[1][threadIdx.x]+red[2][threadIdx.x]+red[3][threadIdx.x];
    atomicAdd(&A[A_DK+b*20+threadIdx.x], v);
  }
  __shared__ int s_last;
  __syncthreads();
  if(threadIdx.x==0){
    __threadfence();
    s_last = (atomicAdd(&T[3],1u) == (unsigned)(NB*RB-1));
  }
  __syncthreads();
  if(!s_last || threadIdx.x) return;
  for(int bb=0;bb<NB;bb++) for(int k=0;k<2;k++){
    const double* ss = A + A_DK + (bb*2+k)*10;
    double W0=ss[0], Ws=W0+1e-8;
    double mu0=ss[1]/Ws, mu1=ss[2]/Ws, mu2=ss[3]/Ws;
    double C00=(ss[4]-2.0*mu0*ss[1]+mu0*mu0*W0)/Ws + 1e-6;
    double C01=(ss[5]-mu0*ss[2]-mu1*ss[1]+mu0*mu1*W0)/Ws;
    double C02=(ss[6]-mu0*ss[3]-mu2*ss[1]+mu0*mu2*W0)/Ws;
    double C11=(ss[7]-2.0*mu1*ss[2]+mu1*mu1*W0)/Ws + 1e-6;
    double C12=(ss[8]-mu1*ss[3]-mu2*ss[2]+mu1*mu2*W0)/Ws;
    double C22=(ss[9]-2.0*mu2*ss[3]+mu2*mu2*W0)/Ws + 1e-6;
    double det = C00*(C11*C22-C12*C12) - C01*(C01*C22-C12*C02) + C02*(C01*C12-C11*C02);
    double id = 1.0/det;
    float* P = F + F_DKINV + (bb*2+k)*9;
    P[0]=(float)((C11*C22-C12*C12)*id);
    P[1]=(float)((C02*C12-C01*C22)*id);
    P[2]=(float)((C01*C12-C02*C11)*id);
    P[3]=(float)((C00*C22-C02*C02)*id);
    P[4]=(float)((C01*C02-C00*C12)*id);
    P[5]=(float)((C00*C11-C01*C01)*id);
    P[6]=(float)mu0; P[7]=(float)mu1; P[8]=(float)mu2;
  }
}
__global__ void k_dm(const float* Lp,const float* E,const float* S,
                     const float* Ra0,const float* Ra1,const float* F,float* DM){
  int i = blockIdx.x*256 + threadIdx.x; if(i>=BN) return;
  int b=i/NPIX;
  float x0=Lp[i], x1=E[i], x2=S[i];
  float D[2];
#pragma unroll
  for(int k=0;k<2;k++){
    const float* P = F + F_DKINV + (b*2+k)*9;
    float d0=x0-P[6], d1=x1-P[7], d2=x2-P[8];
    float q = d0*d0*P[0] + d1*d1*P[3] + d2*d2*P[5]
            + 2.f*(d0*d1*P[1] + d0*d2*P[2] + d1*d2*P[4]);
    D[k]=sqrtf(q+1e-8f);
  }
  float w0=Ra0[i]+1e-8f, w1=Ra1[i]+1e-8f;
  DM[i] = (w0*D[0]+w1*D[1])/(w0+w1);
}

// LLA for both k in one launch: kk = blockIdx / 1152
__global__ __launch_bounds__(256) void k_lla(const float* Ra0, const float* Ra1,
                                             const float* Lp, float* tmpL){
  int kk = blockIdx.x / (NB*576);
  int inner = blockIdx.x % (NB*576);
  int bx = inner % 24, by = (inner/24) % 24, b = inner/576;
  const float* rk = kk ? Ra1 : Ra0;
  __shared__ float Rt[30][31], Lt[30][31];
  __shared__ float h0[30][17], h1[30][17], h2[30][17];
  int ox = bx*16, oy = by*16;
  const float* Rb = rk + (size_t)b*NPIX;
  const float* Lb = Lp + (size_t)b*NPIX;
  for(int i=threadIdx.x; i<900; i+=256){
    int lx=i%30, ly=i/30;
    int gx_=ox-7+lx, gy_=oy-7+ly;
    bool in = (gx_>=0&&gx_<WW&&gy_>=0&&gy_<HH);
    Rt[ly][lx]= in ? Rb[gy_*WW+gx_] : 0.f;
    Lt[ly][lx]= in ? Lb[gy_*WW+gx_] : 0.f;
  }
  __syncthreads();
  for(int i=threadIdx.x; i<480; i+=256){
    int j=i%16, r=i/16;
    float s0=0,s1=0,s2=0;
#pragma unroll
    for(int d=0;d<15;d++){
      float rr=Rt[r][j+d], ll=Lt[r][j+d];
      s0+=rr; float rl=rr*ll; s1+=rl; s2+=rl*ll;
    }
    h0[r][j]=s0; h1[r][j]=s1; h2[r][j]=s2;
  }
  __syncthreads();
  int tx=threadIdx.x%16, ty=threadIdx.x/16;
  float S0=0,S1=0,S2=0;
#pragma unroll
  for(int d=0;d<15;d++){ S0+=h0[ty+d][tx]; S1+=h1[ty+d][tx]; S2+=h2[ty+d][tx]; }
  int x=ox+tx, y=oy+ty;
  float cy = (float)((y+8<HH?y+8:HH)-(y-7>0?y-7:0));
  float cx = (float)((x+8<WW?x+8:WW)-(x-7>0?x-7:0));
  float cnt = cy*cx;
  float den = S0/cnt + 1e-8f;
  float mu  = (S1/cnt)/den;
  float var = fmaxf((S2/cnt)/den - mu*mu, 1e-8f);
  int n = y*WW+x;
  tmpL[(size_t)kk*BN + b*NPIX+n] = fabsf(Lb[n]-mu)/(sqrtf(var)+1e-8f);
}

// GLD for both k, transposed bin-major LDS hist (480%32==0 -> conflict-free writes)
__global__ __launch_bounds__(256) void k_gldf(const float* Ra0, const float* Ra1,
                                              const int* idxP, const float* F, float* tmpG){
  int kk = blockIdx.x / (NB*576);
  int inner = blockIdx.x % (NB*576);
  int bx = inner % 24, by = (inner/24) % 24, b = inner/576;
  const float* rk = kk ? Ra1 : Ra0;
  __shared__ float Rt[30][31];
  __shared__ unsigned char It[30][32];
  __shared__ float Hh[32*480];
  __shared__ float gc[NBINS];
  if(threadIdx.x<NBINS) gc[threadIdx.x]=F[F_GCDF+(kk*NB+b)*32+threadIdx.x];
  int ox=bx*16, oy=by*16;
  const float* Rb = rk + (size_t)b*NPIX;
  const int* Ib = idxP + (size_t)b*NPIX;
  for(int i=threadIdx.x;i<900;i+=256){
    int lx=i%30, ly=i/30;
    int gx_=ox-7+lx, gy_=oy-7+ly;
    bool in = (gx_>=0&&gx_<WW&&gy_>=0&&gy_<HH);
    Rt[ly][lx] = in? Rb[gy_*WW+gx_] : 0.f;
    It[ly][lx] = in? (unsigned char)Ib[gy_*WW+gx_] : 0;
  }
  for(int i=threadIdx.x;i<32*480;i+=256) Hh[i]=0.f;
  __syncthreads();
  for(int i=threadIdx.x;i<480;i+=256){
    int j=i%16, r=i/16;
    for(int d=0;d<15;d++) Hh[(int)It[r][j+d]*480 + i] += Rt[r][j+d];
  }
  __syncthreads();
  int tx=threadIdx.x%16, ty=threadIdx.x/16;
  float vs[32];
  float tot=0;
#pragma unroll
  for(int bin=0;bin<NBINS;bin++){
    float s=0;
#pragma unroll
    for(int d=0;d<15;d++) s += Hh[bin*480 + (ty+d)*16+tx];
    vs[bin]=s; tot+=s;
  }
  int x=ox+tx, y=oy+ty;
  float cy = (float)((y+8<HH?y+8:HH)-(y-7>0?y-7:0));
  float cx = (float)((x+8<WW?x+8:WW)-(x-7>0?x-7:0));
  float cnt = cy*cx;
  float den = tot/cnt + 1e-8f;
  float cs=0, acc=0;
#pragma unroll
  for(int bin=0;bin<NBINS;bin++){
    cs += vs[bin];
    acc += fabsf((cs/cnt)/den - gc[bin]);
  }
  tmpG[(size_t)kk*BN + b*NPIX + y*WW + x] = acc*(1.f/32.f);
}

// gamma = 1 + sum_k rk * (0.5 sp(zl_k) + 0.5 sp(zg_k))
__global__ void k_gamma(const float* tmpL,const float* tmpG,const float* Ra0,const float* Ra1,
                        const float* F,float* gamma){
  int i = blockIdx.x*256 + threadIdx.x; if(i>=BN) return;
  int b=i/NPIX;
  float g = 1.0f;
#pragma unroll
  for(int kk=0;kk<2;kk++){
    const float* ML = F + F_CM + (kk*4 + 0 + b)*2;
    const float* MG = F + F_CM + (kk*4 + 2 + b)*2;
    float zl=(tmpL[(size_t)kk*BN+i]-ML[0])/ML[1];
    float zg=(tmpG[(size_t)kk*BN+i]-MG[0])/MG[1];
    float rk = kk ? Ra1[i] : Ra0[i];
    g += rk*(0.5f*sp(zl)+0.5f*sp(zg));
  }
  gamma[i] = g;
}

__global__ void k_es_red(const float* E,const float* S,float* F,double* A,unsigned* T){
  int b = blockIdx.x / RB, blk = blockIdx.x % RB;
  const float* M = F + F_X3 + b*6;
  double s[5]={0,0,0,0,0};
  for(int n = blk*256 + threadIdx.x; n < NPIX; n += RB*256){
    float z0=(E[b*NPIX+n]-M[2])/M[3];
    float z1=(S[b*NPIX+n]-M[4])/M[5];
    s[0]+=z0; s[1]+=z1; s[2]+=(double)z0*z0; s[3]+=(double)z0*z1; s[4]+=(double)z1*z1;
  }
  __shared__ double red[4][5];
  int wave=threadIdx.x>>6, lane=threadIdx.x&63;
#pragma unroll
  for(int q=0;q<5;q++){
    s[q]=waveSum(s[q]);
    if(lane==0) red[wave][q]=s[q];
  }
  __syncthreads();
  if(threadIdx.x<5){
    double v = red[0][threadIdx.x]+red[1][threadIdx.x]+red[2][threadIdx.x]+red[3][threadIdx.x];
    atomicAdd(&A[A_ES+b*5+threadIdx.x], v);
  }
  __shared__ int s_last;
  __syncthreads();
  if(threadIdx.x==0){
    __threadfence();
    s_last = (atomicAdd(&T[4],1u) == (unsigned)(NB*RB-1));
  }
  __syncthreads();
  if(!s_last || threadIdx.x) return;
  for(int bb=0;bb<NB;bb++){
    const double* ss = A + A_ES + bb*5;
    double inv=1.0/(double)NPIX;
    double m0=ss[0]*inv, m1=ss[1]*inv;
    double c00=ss[2]*inv - m0*m0 + 1e-6;
    double c01=ss[3]*inv - m0*m1;
    double c11=ss[4]*inv - m1*m1 + 1e-6;
    double det=c00*c11-c01*c01;
    float* P = F + F_ESI + bb*5;
    P[0]=(float)m0; P[1]=(float)m1;
    P[2]=(float)(c11/det); P[3]=(float)(-c01/det); P[4]=(float)(c00/det);
  }
}
__global__ void k_lanom(const float* E,const float* S,const float* DM,const float* gamma,
                        const float* F,float* La){
  int i = blockIdx.x*256 + threadIdx.x; if(i>=BN) return;
  int b=i/NPIX;
  const float* M = F + F_X3 + b*6;
  const float* P = F + F_ESI + b*5;
  float z0=(E[i]-M[2])/M[3];
  float z1=(S[i]-M[4])/M[5];
  float d0=z0-P[0], d1=z1-P[1];
  float d2 = d0*d0*P[2] + 2.f*d0*d1*P[3] + d1*d1*P[4];
  float Rs = expf(-0.5f*d2);
  La[i] = fmaxf(DM[i]*gamma[i]*(1.f-Rs), 0.f);
}
__global__ void k_out2(const float* La, const float* F, float* out){
  int i = blockIdx.x*256 + threadIdx.x; if(i>=BN) return;
  int b=i/NPIX;
  const float* v = F + F_LAQ + b*4;
  double h1 = 0.01*(double)(NPIX-1); double f1 = h1 - floor(h1);
  double h9 = 0.99*(double)(NPIX-1); double f9 = h9 - floor(h9);
  float q1 = (float)((double)v[0] + f1*((double)v[1]-(double)v[0]));
  float q9 = (float)((double)v[2] + f9*((double)v[3]-(double)v[2]));
  float r = (La[i]-q1)/(q9-q1+1e-8f);
  out[BN + i] = fminf(fmaxf(r,0.f),1.f);
}

// ---------------- host ----------------
static void run_sel(const SelBatch& sb, unsigned* H, unsigned* T, float* F, int bid, hipStream_t s){
  for(int p=2;p>=0;--p) k_selp<<<sb.nt*SEL_BLK,256,0,s>>>(sb,H,T,F,bid,0,p);
  if(sb.medmad) for(int p=2;p>=0;--p) k_selp<<<sb.nt*SEL_BLK,256,0,s>>>(sb,H,T,F,bid,1,p);
}

extern "C" void kernel_launch(void* const* d_in, const int* in_sizes, int n_in,
                              void* d_out, int out_size, void* d_ws, size_t ws_size,
                              hipStream_t stream){
  (void)in_sizes; (void)n_in; (void)out_size; (void)ws_size;
  const float* lab   = (const float*)d_in[0];
  const float* arand = (const float*)d_in[1];
  float* out = (float*)d_out;
  char* wsb = (char*)d_ws;
  double* A = (double*)wsb;
  float*  F = (float*)(wsb + 16384);
  unsigned* T = (unsigned*)(wsb + 32768);
  unsigned* H = (unsigned*)(wsb + 65536);
  float* planes = (float*)(wsb + (size_t)4*1024*1024);
  float* E    = planes;
  float* S    = planes + (size_t)BN;
  float* tA   = planes + (size_t)2*BN;        // La
  float* tmpL = planes + (size_t)3*BN;        // 2 planes (3,4)
  float* tmpG = planes + (size_t)5*BN;        // 2 planes (5,6)
  float* Xw   = planes + (size_t)7*BN;        // 3 planes
  float* zb   = planes + (size_t)10*BN;
  float* Ra0  = planes + (size_t)11*BN;
  float* Ra1  = planes + (size_t)12*BN;
  float* DM   = planes + (size_t)13*BN;
  float* gamma= planes + (size_t)14*BN;
  int*   idxP = (int*)(planes + (size_t)16*BN);

  const int GBN = BN/256;      // 1152

  k_zero<<<256,256,0,stream>>>(A,F,T,H);
  k_sobel<<<NB*576,256,0,stream>>>(lab,S,E);
  k_beta_red<<<NB*RB,256,0,stream>>>(E,S,lab,A,F,T);
  k_lperp<<<GBN,256,0,stream>>>(lab,E,S,F,out);

  SelBatch sbX; sbX.nt=6; sbX.medmad=1;
  for(int b=0;b<NB;b++){
    sbX.src[b*3+0]=out+(size_t)b*NPIX; sbX.src[b*3+1]=E+(size_t)b*NPIX; sbX.src[b*3+2]=S+(size_t)b*NPIX;
    for(int ch=0;ch<3;ch++){ sbX.rank[b*3+ch]=MEDRANK; sbX.fslot[b*3+ch]=F_X3+(b*3+ch)*2; }
  }
  run_sel(sbX,H,T,F,0,stream);

  k_xz_red<<<NB*RB,256,0,stream>>>(out,E,S,F,A,T);
  k_xw<<<GBN,256,0,stream>>>(out,E,S,F,Xw,idxP);
  k_kurt<<<NB*(NT/KDG)*KSEG,256,0,stream>>>(Xw,arand,A,F,T);
  k_zbest<<<GBN,256,0,stream>>>(Xw,F,zb,A);

  SelBatch sbZ; sbZ.nt=8; sbZ.medmad=0;
  {
    int rr[4]={36863,36864,110591,110592};
    for(int b=0;b<NB;b++) for(int ri=0;ri<4;ri++){
      int t=b*4+ri;
      sbZ.src[t]=zb+(size_t)b*NPIX; sbZ.rank[t]=rr[ri]; sbZ.fslot[t]=F_ZBQ+b*4+ri;
    }
  }
  run_sel(sbZ,H,T,F,1,stream);

  for(int it=0; it<9; ++it)
    k_gmm_red<<<NB*RB2,256,0,stream>>>(zb,F,A,it);
  k_ralpha<<<GBN,256,0,stream>>>(zb,F,A,idxP,Ra0,Ra1,T);
  k_dk_red<<<NB*RB,256,0,stream>>>(out,E,S,Ra0,Ra1,A,F,T);
  k_dm<<<GBN,256,0,stream>>>(out,E,S,Ra0,Ra1,F,DM);

  k_lla<<<2*NB*576,256,0,stream>>>(Ra0,Ra1,out,tmpL);
  k_gldf<<<2*NB*576,256,0,stream>>>(Ra0,Ra1,idxP,F,tmpG);

  SelBatch sbC; sbC.nt=8; sbC.medmad=1;
  for(int kk=0;kk<2;kk++) for(int isG=0;isG<2;isG++) for(int b=0;b<NB;b++){
    int t = kk*4 + isG*2 + b;
    sbC.src[t] = (isG? tmpG: tmpL) + (size_t)kk*BN + (size_t)b*NPIX;
    sbC.rank[t]=MEDRANK; sbC.fslot[t]=F_CM + t*2;
  }
  run_sel(sbC,H,T,F,2,stream);

  k_gamma<<<GBN,256,0,stream>>>(tmpL,tmpG,Ra0,Ra1,F,gamma);

  k_es_red<<<NB*RB,256,0,stream>>>(E,S,F,A,T);
  k_lanom<<<GBN,256,0,stream>>>(E,S,DM,gamma,F,tA);

  SelBatch sbL; sbL.nt=8; sbL.medmad=0;
  {
    int rr[4]={1474,1475,145980,145981};
    for(int b=0;b<NB;b++) for(int ri=0;ri<4;ri++){
      int t=b*4+ri;
      sbL.src[t]=tA+(size_t)b*NPIX; sbL.rank[t]=rr[ri]; sbL.fslot[t]=F_LAQ+b*4+ri;
    }
  }
  run_sel(sbL,H,T,F,3,stream);

  k_out2<<<GBN,256,0,stream>>>(tA,F,out);
}